// Round 1
// baseline (35747.659 us; speedup 1.0000x reference)
//
#include <hip/hip_runtime.h>
#include <cmath>

#define B 4
#define S 1024
#define H 1024
#define NH 16
#define HD 64
#define FF 4096
#define CV 2048
#define CV1 2049
#define BS (B*S)            // 4096
#define BSH ((size_t)BS*H)  // 4194304
#define BSF ((size_t)BS*FF) // 16777216

#define F_BIAS  1
#define F_RESID 2
#define F_SILU  4
#define F_MULIN 8

// ---------------- GEMM: C[M,N] = A[M,K] @ W[K,N]  (+epilogue) ----------------
__global__ __launch_bounds__(256) void gemm_k(
    const float* __restrict__ A, const float* __restrict__ Wm,
    const float* __restrict__ bias, float* __restrict__ C,
    int M, int N, int K, int lda, int ldb, int ldc, int flags)
{
    __shared__ float As[16][65];   // As[k][row], padded
    __shared__ float Bs[16][65];   // Bs[k][col], padded
    const int tid = threadIdx.x;
    const int tx = tid & 15, ty = tid >> 4;
    const int row0 = blockIdx.y * 64, col0 = blockIdx.x * 64;
    float acc[4][4] = {};
    for (int k0 = 0; k0 < K; k0 += 16) {
        #pragma unroll
        for (int l = 0; l < 4; ++l) {
            int e = tid + l * 256;           // 0..1023
            int r = e >> 4, c = e & 15;      // 64 rows x 16 k
            int gr = row0 + r;
            float vv = 0.f;
            if (gr < M) vv = A[(size_t)gr * lda + (k0 + c)];
            As[c][r] = vv;
        }
        #pragma unroll
        for (int l = 0; l < 4; ++l) {
            int e = tid + l * 256;
            int r = e >> 6, c = e & 63;      // 16 k x 64 cols
            int gc = col0 + c;
            float vv = 0.f;
            if (gc < N) vv = Wm[(size_t)(k0 + r) * ldb + gc];
            Bs[r][c] = vv;
        }
        __syncthreads();
        #pragma unroll
        for (int kk = 0; kk < 16; ++kk) {
            float a[4], bb[4];
            #pragma unroll
            for (int i = 0; i < 4; ++i) a[i] = As[kk][ty * 4 + i];
            #pragma unroll
            for (int j = 0; j < 4; ++j) bb[j] = Bs[kk][tx * 4 + j];
            #pragma unroll
            for (int i = 0; i < 4; ++i)
                #pragma unroll
                for (int j = 0; j < 4; ++j)
                    acc[i][j] += a[i] * bb[j];
        }
        __syncthreads();
    }
    #pragma unroll
    for (int i = 0; i < 4; ++i) {
        int gr = row0 + ty * 4 + i;
        if (gr >= M) continue;
        #pragma unroll
        for (int j = 0; j < 4; ++j) {
            int gc = col0 + tx * 4 + j;
            if (gc >= N) continue;
            float vv = acc[i][j];
            if (flags & F_BIAS)  vv += bias[gc];
            if (flags & F_SILU)  vv = vv / (1.f + expf(-vv));
            size_t cidx = (size_t)gr * ldc + gc;
            if (flags & F_MULIN) vv *= C[cidx];
            if (flags & F_RESID) vv += C[cidx];
            C[cidx] = vv;
        }
    }
}

// ---------------- RMSNorm ----------------
__global__ __launch_bounds__(256) void rmsnorm_k(const float* __restrict__ x,
    const float* __restrict__ w, float* __restrict__ y)
{
    int row = blockIdx.x;
    const float* xr = x + (size_t)row * H;
    float* yr = y + (size_t)row * H;
    __shared__ float red[256];
    float s = 0.f;
    for (int i = threadIdx.x; i < H; i += 256) { float v = xr[i]; s += v * v; }
    red[threadIdx.x] = s; __syncthreads();
    for (int off = 128; off > 0; off >>= 1) {
        if (threadIdx.x < off) red[threadIdx.x] += red[threadIdx.x + off];
        __syncthreads();
    }
    float r = 1.0f / sqrtf(red[0] / (float)H + 1e-6f);
    for (int i = threadIdx.x; i < H; i += 256) yr[i] = xr[i] * r * w[i];
}

// ---------------- Embed gather ----------------
__global__ __launch_bounds__(256) void embed_k(const int* __restrict__ ids,
    const float* __restrict__ emb, float* __restrict__ h)
{
    int bs = blockIdx.x;
    const float* e = emb + (size_t)ids[bs] * H;
    float* hr = h + (size_t)bs * H;
    for (int i = threadIdx.x; i < H; i += 256) hr[i] = e[i];
}

// ---------------- RoPE (in-place) ----------------
__global__ __launch_bounds__(256) void rope_k(float* __restrict__ x, const int* __restrict__ pos)
{
    int idx = blockIdx.x * 256 + threadIdx.x;   // B*S*NH*32 total
    int i = idx & 31;
    int head = (idx >> 5) & 15;
    int bs = idx >> 9;
    int p = pos[bs];
    double inv = exp(-((double)(2 * i) / 64.0) * log(10000.0));
    double ang = (double)p * inv;
    float c = (float)cos(ang), sn = (float)sin(ang);
    float* base = x + (size_t)bs * H + head * 64;
    float x1 = base[i], x2 = base[i + 32];
    base[i]      = x1 * c - x2 * sn;
    base[i + 32] = x2 * c + x1 * sn;
}

// ---------------- Attention: one block per (q-row, head, batch) ----------------
__global__ __launch_bounds__(256) void attn_k(const float* __restrict__ q,
    const float* __restrict__ k, const float* __restrict__ v,
    float* __restrict__ o, const int* __restrict__ valid)
{
    const int qi = blockIdx.x, hh = blockIdx.y, b = blockIdx.z;
    __shared__ float sc[S];
    __shared__ float qrow[HD];
    __shared__ float red[256];
    const int tid = threadIdx.x;
    const size_t bq = (size_t)(b * S + qi);
    if (tid < HD) qrow[tid] = q[bq * H + hh * HD + tid];
    __syncthreads();
    const int qv = valid[b * S + qi];
    float m = -3.4e38f;
    for (int kk = tid; kk < S; kk += 256) {
        const float* kp = k + (size_t)(b * S + kk) * H + hh * HD;
        float dot = 0.f;
        #pragma unroll
        for (int d = 0; d < HD; ++d) dot += qrow[d] * kp[d];
        float sval = dot * 0.125f;
        sval += (kk <= qi && qv && valid[b * S + kk]) ? 0.f : -1e9f;
        sc[kk] = sval;
        m = fmaxf(m, sval);
    }
    red[tid] = m; __syncthreads();
    for (int off = 128; off > 0; off >>= 1) {
        if (tid < off) red[tid] = fmaxf(red[tid], red[tid + off]);
        __syncthreads();
    }
    m = red[0]; __syncthreads();
    float ssum = 0.f;
    for (int kk = tid; kk < S; kk += 256) { float e = expf(sc[kk] - m); sc[kk] = e; ssum += e; }
    red[tid] = ssum; __syncthreads();
    for (int off = 128; off > 0; off >>= 1) {
        if (tid < off) red[tid] += red[tid + off];
        __syncthreads();
    }
    float inv = 1.0f / red[0];
    __syncthreads();
    const int d = tid & 63, j = tid >> 6;
    float acc = 0.f;
    for (int kk = j * 256; kk < (j + 1) * 256; ++kk)
        acc += sc[kk] * v[(size_t)(b * S + kk) * H + hh * HD + d];
    red[tid] = acc; __syncthreads();
    if (tid < 64)
        o[bq * H + hh * HD + tid] = (red[tid] + red[tid + 64] + red[tid + 128] + red[tid + 192]) * inv;
}

// ---------------- Discretize: argmax + softmax z ----------------
__global__ __launch_bounds__(256) void discretize_k(const float* __restrict__ logits,
    const float* __restrict__ gumbel, float* __restrict__ z, int* __restrict__ chosen)
{
    int bs = blockIdx.x;
    const float* lg = logits + (size_t)bs * CV1;
    const float* gm = gumbel + (size_t)bs * CV1;
    __shared__ float redv[256]; __shared__ int redi[256];
    int tid = threadIdx.x;
    float m = -3.4e38f; int mi = CV1;
    for (int j = tid; j < CV1; j += 256) {
        float a = lg[j] + gm[j];
        if (a > m) { m = a; mi = j; }
    }
    redv[tid] = m; redi[tid] = mi; __syncthreads();
    for (int off = 128; off > 0; off >>= 1) {
        if (tid < off) {
            float vo = redv[tid + off]; int io = redi[tid + off];
            if (vo > redv[tid] || (vo == redv[tid] && io < redi[tid])) { redv[tid] = vo; redi[tid] = io; }
        }
        __syncthreads();
    }
    m = redv[0]; int amax = redi[0];
    __syncthreads();
    float ssum = 0.f;
    for (int j = tid; j < CV1; j += 256) ssum += expf(lg[j] + gm[j] - m);
    redv[tid] = ssum; __syncthreads();
    for (int off = 128; off > 0; off >>= 1) {
        if (tid < off) redv[tid] += redv[tid + off];
        __syncthreads();
    }
    float inv = 1.0f / redv[0];
    for (int j = tid; j < CV; j += 256)
        z[(size_t)bs * CV + j] = expf(lg[j] + gm[j] - m) * inv;
    if (tid == 0) chosen[bs] = amax;
}

// ---------------- cea + loss partials ----------------
__global__ __launch_bounds__(256) void cea_k(const float* __restrict__ esoft,
    const float* __restrict__ cemb, const int* __restrict__ chosen,
    const int* __restrict__ amask, float* __restrict__ cea, float* __restrict__ partial)
{
    int bs = blockIdx.x;
    int ch = chosen[bs]; int vm = amask[bs];
    int comp = (ch != CV) && vm;
    const float* ehr = cemb + (size_t)(ch < CV - 1 ? ch : CV - 1) * H;
    __shared__ float red[256];
    float part = 0.f;
    float vmf = vm ? 1.f : 0.f;
    for (int i = threadIdx.x; i < H; i += 256) {
        float es = esoft[(size_t)bs * H + i];
        float eh = comp ? ehr[i] : 0.f;
        cea[(size_t)bs * H + i] = ((eh + es) - es) * vmf;   // STE forward
        float d = es - eh;
        part += d * d;
    }
    red[threadIdx.x] = part; __syncthreads();
    for (int off = 128; off > 0; off >>= 1) {
        if (threadIdx.x < off) red[threadIdx.x] += red[threadIdx.x + off];
        __syncthreads();
    }
    if (threadIdx.x == 0) partial[bs] = red[0];
}

__global__ __launch_bounds__(256) void loss_k(const float* __restrict__ partial, float* __restrict__ out)
{
    __shared__ float red[256];
    float s = 0.f;
    for (int i = threadIdx.x; i < BS; i += 256) s += partial[i];
    red[threadIdx.x] = s; __syncthreads();
    for (int off = 128; off > 0; off >>= 1) {
        if (threadIdx.x < off) red[threadIdx.x] += red[threadIdx.x + off];
        __syncthreads();
    }
    if (threadIdx.x == 0) out[0] = 1.25f * red[0] / (float)BSH;
}

// ---------------- Stable pack (serial per batch) ----------------
__global__ void pack_k(const int* __restrict__ chosen, const int* __restrict__ amask,
    int* __restrict__ order, int* __restrict__ cpos, int* __restrict__ cvalid,
    int* __restrict__ counts)
{
    int b = blockIdx.x;
    if (threadIdx.x != 0) return;
    int cnt = 0;
    for (int s2 = 0; s2 < S; ++s2)
        if (chosen[b * S + s2] != CV && amask[b * S + s2]) order[b * S + cnt++] = s2;
    counts[b] = cnt;
    int j2 = cnt;
    for (int s2 = 0; s2 < S; ++s2)
        if (!(chosen[b * S + s2] != CV && amask[b * S + s2])) order[b * S + j2++] = s2;
    for (int j3 = 0; j3 < S; ++j3) {
        cvalid[b * S + j3] = (j3 < cnt) ? 1 : 0;
        cpos[b * S + j3]   = (j3 < cnt) ? order[b * S + j3] : 0;
    }
}

__global__ __launch_bounds__(256) void gather_k(const float* __restrict__ cea,
    const int* __restrict__ order, const int* __restrict__ cvalid, float* __restrict__ h)
{
    int bs = blockIdx.x;
    int b = bs >> 10;
    int src = order[bs];
    float f = cvalid[bs] ? 1.f : 0.f;
    const float* sp = cea + (size_t)(b * S + src) * H;
    float* dst = h + (size_t)bs * H;
    for (int i = threadIdx.x; i < H; i += 256) dst[i] = sp[i] * f;
}

__global__ __launch_bounds__(256) void outmask_k(const float* __restrict__ h,
    const int* __restrict__ cvalid, float* __restrict__ out)
{
    int bs = blockIdx.x;
    float f = cvalid[bs] ? 1.f : 0.f;
    for (int i = threadIdx.x; i < H; i += 256)
        out[(size_t)bs * H + i] = h[(size_t)bs * H + i] * f;
}

__global__ __launch_bounds__(256) void iota_k(int* __restrict__ pos)
{
    int idx = blockIdx.x * 256 + threadIdx.x;
    if (idx < BS) pos[idx] = idx & (S - 1);
}

// ---------------- Host-side block driver ----------------
static void run_block(int layer,
    const float* ln1, const float* wq, const float* wk, const float* wv,
    const float* wo, const float* ln2, const float* wg, const float* wu, const float* wd,
    float* h, float* hn, float* q, float* k, float* v, float* o, float* f1,
    const int* valid, const int* pos, hipStream_t stream)
{
    size_t LHH = (size_t)layer * H * H;
    size_t LHF = (size_t)layer * H * FF;
    rmsnorm_k<<<BS, 256, 0, stream>>>(h, ln1 + (size_t)layer * H, hn);
    gemm_k<<<dim3(16, 64), 256, 0, stream>>>(hn, wq + LHH, nullptr, q, BS, H, H, H, H, H, 0);
    gemm_k<<<dim3(16, 64), 256, 0, stream>>>(hn, wk + LHH, nullptr, k, BS, H, H, H, H, H, 0);
    gemm_k<<<dim3(16, 64), 256, 0, stream>>>(hn, wv + LHH, nullptr, v, BS, H, H, H, H, H, 0);
    rope_k<<<8192, 256, 0, stream>>>(q, pos);
    rope_k<<<8192, 256, 0, stream>>>(k, pos);
    attn_k<<<dim3(S, NH, B), 256, 0, stream>>>(q, k, v, o, valid);
    gemm_k<<<dim3(16, 64), 256, 0, stream>>>(o, wo + LHH, nullptr, h, BS, H, H, H, H, H, F_RESID);
    rmsnorm_k<<<BS, 256, 0, stream>>>(h, ln2 + (size_t)layer * H, hn);
    gemm_k<<<dim3(64, 64), 256, 0, stream>>>(hn, wg + LHF, nullptr, f1, BS, FF, H, H, FF, FF, F_SILU);
    gemm_k<<<dim3(64, 64), 256, 0, stream>>>(hn, wu + LHF, nullptr, f1, BS, FF, H, H, FF, FF, F_MULIN);
    gemm_k<<<dim3(16, 64), 256, 0, stream>>>(f1, wd + (size_t)layer * FF * H, nullptr, h, BS, H, FF, FF, H, H, F_RESID);
}

extern "C" void kernel_launch(void* const* d_in, const int* in_sizes, int n_in,
                              void* d_out, int out_size, void* d_ws, size_t ws_size,
                              hipStream_t stream)
{
    const int*   ids    = (const int*)d_in[0];
    const int*   amask  = (const int*)d_in[1];
    const float* embed  = (const float*)d_in[2];
    const float* ln1    = (const float*)d_in[3];
    const float* wq     = (const float*)d_in[4];
    const float* wk     = (const float*)d_in[5];
    const float* wv     = (const float*)d_in[6];
    const float* wo     = (const float*)d_in[7];
    const float* ln2    = (const float*)d_in[8];
    const float* wg     = (const float*)d_in[9];
    const float* wu     = (const float*)d_in[10];
    const float* wd     = (const float*)d_in[11];
    const float* head_w = (const float*)d_in[12];
    const float* head_b = (const float*)d_in[13];
    const float* cemb   = (const float*)d_in[14];
    const float* gumbel = (const float*)d_in[15];
    float* out = (float*)d_out;

    float* wsf = (float*)d_ws;
    float* h   = wsf;              // BSH
    float* hn  = wsf + BSH;        // BSH
    float* q   = wsf + 2 * BSH;    // BSH
    float* k   = wsf + 3 * BSH;    // BSH
    float* v   = wsf + 4 * BSH;    // BSH
    float* o   = wsf + 5 * BSH;    // BSH
    float* f1  = wsf + 6 * BSH;    // BSF (FFN intermediate; also logits [BS,2049])
    float* zbuf  = q;              // BS*CV floats — spans q..k (both dead here)
    float* esoft = v;              // BSH
    float* ceab  = o;              // BSH
    int* meta   = (int*)(wsf + 6 * BSH + BSF);
    int* chosen = meta;
    int* order  = meta + BS;
    int* cpos   = meta + 2 * BS;
    int* cvalid = meta + 3 * BS;
    int* counts = meta + 4 * BS;
    int* pos_sh = meta + 5 * BS;
    float* partial = (float*)(meta + 6 * BS);  // BS floats

    // 1. embed + positions
    embed_k<<<BS, 256, 0, stream>>>(ids, embed, h);
    iota_k<<<16, 256, 0, stream>>>(pos_sh);

    // 2. shallow blocks (layers 0,1)
    for (int L = 0; L < 2; ++L)
        run_block(L, ln1, wq, wk, wv, wo, ln2, wg, wu, wd,
                  h, hn, q, k, v, o, f1, amask, pos_sh, stream);

    // 3. head logits -> f1 [BS, 2049]
    gemm_k<<<dim3(33, 64), 256, 0, stream>>>(h, head_w, head_b, f1, BS, CV1, H, H, CV1, CV1, F_BIAS);

    // 4. discretize: z + argmax
    discretize_k<<<BS, 256, 0, stream>>>(f1, gumbel, zbuf, chosen);

    // 5. e_soft = z @ concept_emb
    gemm_k<<<dim3(16, 64), 256, 0, stream>>>(zbuf, cemb, nullptr, esoft, BS, H, CV, CV, H, H, 0);

    // 6. cea + loss
    cea_k<<<BS, 256, 0, stream>>>(esoft, cemb, chosen, amask, ceab, partial);
    loss_k<<<1, 256, 0, stream>>>(partial, out + BSH);

    // 7. stable pack + gather cin into h
    pack_k<<<B, 64, 0, stream>>>(chosen, amask, order, cpos, cvalid, counts);
    gather_k<<<BS, 256, 0, stream>>>(ceab, order, cvalid, h);

    // 8. mid blocks (layers 2,3)
    for (int L = 2; L < 4; ++L)
        run_block(L, ln1, wq, wk, wv, wo, ln2, wg, wu, wd,
                  h, hn, q, k, v, o, f1, cvalid, cpos, stream);

    // 9. masked output
    outmask_k<<<BS, 256, 0, stream>>>(h, cvalid, out);
}

// Round 2
// 17779.469 us; speedup vs baseline: 2.0106x; 2.0106x over previous
//
#include <hip/hip_runtime.h>
#include <cmath>

#define B 4
#define S 1024
#define H 1024
#define NH 16
#define HD 64
#define FF 4096
#define CV 2048
#define CV1 2049
#define BS (B*S)            // 4096
#define BSH ((size_t)BS*H)  // 4194304
#define BSF ((size_t)BS*FF) // 16777216

#define F_BIAS  1
#define F_RESID 2
#define F_SILU  4
#define F_MULIN 8

// ---------------- GEMM: C[M,N] = A[M,K] @ W[K,N]  (+epilogue) ----------------
__global__ __launch_bounds__(256) void gemm_k(
    const float* __restrict__ A, const float* __restrict__ Wm,
    const float* __restrict__ bias, float* __restrict__ C,
    int M, int N, int K, int lda, int ldb, int ldc, int flags)
{
    __shared__ float As[16][65];   // As[k][row], padded
    __shared__ float Bs[16][65];   // Bs[k][col], padded
    const int tid = threadIdx.x;
    const int tx = tid & 15, ty = tid >> 4;
    const int row0 = blockIdx.y * 64, col0 = blockIdx.x * 64;
    float acc[4][4] = {};
    for (int k0 = 0; k0 < K; k0 += 16) {
        #pragma unroll
        for (int l = 0; l < 4; ++l) {
            int e = tid + l * 256;           // 0..1023
            int r = e >> 4, c = e & 15;      // 64 rows x 16 k
            int gr = row0 + r;
            float vv = 0.f;
            if (gr < M) vv = A[(size_t)gr * lda + (k0 + c)];
            As[c][r] = vv;
        }
        #pragma unroll
        for (int l = 0; l < 4; ++l) {
            int e = tid + l * 256;
            int r = e >> 6, c = e & 63;      // 16 k x 64 cols
            int gc = col0 + c;
            float vv = 0.f;
            if (gc < N) vv = Wm[(size_t)(k0 + r) * ldb + gc];
            Bs[r][c] = vv;
        }
        __syncthreads();
        #pragma unroll
        for (int kk = 0; kk < 16; ++kk) {
            float a[4], bb[4];
            #pragma unroll
            for (int i = 0; i < 4; ++i) a[i] = As[kk][ty * 4 + i];
            #pragma unroll
            for (int j = 0; j < 4; ++j) bb[j] = Bs[kk][tx * 4 + j];
            #pragma unroll
            for (int i = 0; i < 4; ++i)
                #pragma unroll
                for (int j = 0; j < 4; ++j)
                    acc[i][j] += a[i] * bb[j];
        }
        __syncthreads();
    }
    #pragma unroll
    for (int i = 0; i < 4; ++i) {
        int gr = row0 + ty * 4 + i;
        if (gr >= M) continue;
        #pragma unroll
        for (int j = 0; j < 4; ++j) {
            int gc = col0 + tx * 4 + j;
            if (gc >= N) continue;
            float vv = acc[i][j];
            if (flags & F_BIAS)  vv += bias[gc];
            if (flags & F_SILU)  vv = vv / (1.f + expf(-vv));
            size_t cidx = (size_t)gr * ldc + gc;
            if (flags & F_MULIN) vv *= C[cidx];
            if (flags & F_RESID) vv += C[cidx];
            C[cidx] = vv;
        }
    }
}

// ---------------- RMSNorm ----------------
__global__ __launch_bounds__(256) void rmsnorm_k(const float* __restrict__ x,
    const float* __restrict__ w, float* __restrict__ y)
{
    int row = blockIdx.x;
    const float* xr = x + (size_t)row * H;
    float* yr = y + (size_t)row * H;
    __shared__ float red[256];
    float s = 0.f;
    for (int i = threadIdx.x; i < H; i += 256) { float v = xr[i]; s += v * v; }
    red[threadIdx.x] = s; __syncthreads();
    for (int off = 128; off > 0; off >>= 1) {
        if (threadIdx.x < off) red[threadIdx.x] += red[threadIdx.x + off];
        __syncthreads();
    }
    float r = 1.0f / sqrtf(red[0] / (float)H + 1e-6f);
    for (int i = threadIdx.x; i < H; i += 256) yr[i] = xr[i] * r * w[i];
}

// ---------------- Embed gather ----------------
__global__ __launch_bounds__(256) void embed_k(const int* __restrict__ ids,
    const float* __restrict__ emb, float* __restrict__ h)
{
    int bs = blockIdx.x;
    const float* e = emb + (size_t)ids[bs] * H;
    float* hr = h + (size_t)bs * H;
    for (int i = threadIdx.x; i < H; i += 256) hr[i] = e[i];
}

// ---------------- RoPE (in-place) ----------------
__global__ __launch_bounds__(256) void rope_k(float* __restrict__ x, const int* __restrict__ pos)
{
    int idx = blockIdx.x * 256 + threadIdx.x;   // B*S*NH*32 total
    int i = idx & 31;
    int head = (idx >> 5) & 15;
    int bs = idx >> 9;
    int p = pos[bs];
    double inv = exp(-((double)(2 * i) / 64.0) * log(10000.0));
    double ang = (double)p * inv;
    float c = (float)cos(ang), sn = (float)sin(ang);
    float* base = x + (size_t)bs * H + head * 64;
    float x1 = base[i], x2 = base[i + 32];
    base[i]      = x1 * c - x2 * sn;
    base[i + 32] = x2 * c + x1 * sn;
}

// ---------------- Flash attention: block = (q-tile 64, head, batch) ----------------
// Visits ALL k-tiles (no causal skip) so fully-masked rows reproduce the
// reference's uniform softmax (those rows feed e_soft -> the VQ loss).
__global__ __launch_bounds__(256) void fattn_k(const float* __restrict__ q,
    const float* __restrict__ k, const float* __restrict__ v,
    float* __restrict__ o, const int* __restrict__ valid)
{
    const int qt = blockIdx.x, hh = blockIdx.y, b = blockIdx.z;
    const int tid = threadIdx.x;
    const int tx = tid & 15, ty = tid >> 4;
    __shared__ float Qs[64][68];   // [qrow][d]  (rows 16B-aligned: 68*4=272)
    __shared__ float Ks[64][68];   // [kcol][d]; reused as Ps[qrow][kcol] after S
    __shared__ float Vs[64][68];   // [d][kcol]
    __shared__ int   kvs[64];
    const size_t hoff = (size_t)hh * HD;

    // ---- load Q tile (coalesced, float4) ----
    {
        int row = tid >> 2, d0 = (tid & 3) * 16;
        const float* qp = q + ((size_t)(b * S + qt * 64 + row)) * H + hoff + d0;
        float4* dst = (float4*)&Qs[row][d0];
        const float4* src = (const float4*)qp;
        #pragma unroll
        for (int e = 0; e < 4; ++e) dst[e] = src[e];
    }
    int qv[4]; int qrow_g[4];
    #pragma unroll
    for (int i = 0; i < 4; ++i) {
        qrow_g[i] = qt * 64 + ty * 4 + i;
        qv[i] = valid[b * S + qrow_g[i]];
    }
    float m[4], l[4], acc[4][4];
    #pragma unroll
    for (int i = 0; i < 4; ++i) {
        m[i] = -3.4e38f; l[i] = 0.f;
        #pragma unroll
        for (int j = 0; j < 4; ++j) acc[i][j] = 0.f;
    }

    for (int kt = 0; kt < S / 64; ++kt) {
        __syncthreads();   // previous iter's Ks(P)/Vs reads done
        // ---- load K tile [kcol][d] (coalesced) ----
        {
            int row = tid >> 2, d0 = (tid & 3) * 16;
            const float* kp = k + ((size_t)(b * S + kt * 64 + row)) * H + hoff + d0;
            float4* dst = (float4*)&Ks[row][d0];
            const float4* src = (const float4*)kp;
            #pragma unroll
            for (int e = 0; e < 4; ++e) dst[e] = src[e];
        }
        // ---- load V tile transposed [d][kcol] ----
        {
            int kk = tid >> 2, d0 = (tid & 3) * 16;
            const float* vp = v + ((size_t)(b * S + kt * 64 + kk)) * H + hoff + d0;
            #pragma unroll
            for (int e = 0; e < 16; e += 4) {
                float4 vv = *(const float4*)(vp + e);
                Vs[d0 + e + 0][kk] = vv.x;
                Vs[d0 + e + 1][kk] = vv.y;
                Vs[d0 + e + 2][kk] = vv.z;
                Vs[d0 + e + 3][kk] = vv.w;
            }
        }
        if (tid < 64) kvs[tid] = valid[b * S + kt * 64 + tid];
        __syncthreads();

        // ---- S = Q @ K^T (4x4 per thread, float4 over d) ----
        float s4[4][4];
        #pragma unroll
        for (int i = 0; i < 4; ++i)
            #pragma unroll
            for (int j = 0; j < 4; ++j) s4[i][j] = 0.f;
        #pragma unroll
        for (int c = 0; c < 16; ++c) {
            float4 a[4], bb[4];
            #pragma unroll
            for (int i = 0; i < 4; ++i) a[i]  = ((const float4*)&Qs[ty * 4 + i][0])[c];
            #pragma unroll
            for (int j = 0; j < 4; ++j) bb[j] = ((const float4*)&Ks[tx * 4 + j][0])[c];
            #pragma unroll
            for (int i = 0; i < 4; ++i)
                #pragma unroll
                for (int j = 0; j < 4; ++j) {
                    s4[i][j] += a[i].x * bb[j].x + a[i].y * bb[j].y
                              + a[i].z * bb[j].z + a[i].w * bb[j].w;
                }
        }
        // ---- mask + online softmax ----
        float p[4][4];
        float corr[4];
        #pragma unroll
        for (int i = 0; i < 4; ++i) {
            float rm = -3.4e38f;
            #pragma unroll
            for (int j = 0; j < 4; ++j) {
                int kc = kt * 64 + tx * 4 + j;
                float sv = s4[i][j] * 0.125f;
                int allowed = (kc <= qrow_g[i]) && qv[i] && kvs[tx * 4 + j];
                if (!allowed) sv = sv + -1e9f;   // matches reference rounding
                s4[i][j] = sv;
                rm = fmaxf(rm, sv);
            }
            rm = fmaxf(rm, __shfl_xor(rm, 1));
            rm = fmaxf(rm, __shfl_xor(rm, 2));
            rm = fmaxf(rm, __shfl_xor(rm, 4));
            rm = fmaxf(rm, __shfl_xor(rm, 8));
            float mn = fmaxf(m[i], rm);
            corr[i] = expf(m[i] - mn);
            float rs = 0.f;
            #pragma unroll
            for (int j = 0; j < 4; ++j) { p[i][j] = expf(s4[i][j] - mn); rs += p[i][j]; }
            rs += __shfl_xor(rs, 1);
            rs += __shfl_xor(rs, 2);
            rs += __shfl_xor(rs, 4);
            rs += __shfl_xor(rs, 8);
            l[i] = l[i] * corr[i] + rs;
            m[i] = mn;
            #pragma unroll
            for (int j = 0; j < 4; ++j) acc[i][j] *= corr[i];
        }
        __syncthreads();   // all Ks reads done; safe to overwrite with P
        #pragma unroll
        for (int i = 0; i < 4; ++i) {
            float4 pv4 = make_float4(p[i][0], p[i][1], p[i][2], p[i][3]);
            *(float4*)&Ks[ty * 4 + i][tx * 4] = pv4;   // Ks reused as P[qrow][kcol]
        }
        __syncthreads();
        // ---- O += P @ V ----
        #pragma unroll
        for (int c = 0; c < 16; ++c) {
            float4 a[4], bb[4];
            #pragma unroll
            for (int i = 0; i < 4; ++i) a[i]  = ((const float4*)&Ks[ty * 4 + i][0])[c];
            #pragma unroll
            for (int j = 0; j < 4; ++j) bb[j] = ((const float4*)&Vs[tx * 4 + j][0])[c];
            #pragma unroll
            for (int i = 0; i < 4; ++i)
                #pragma unroll
                for (int j = 0; j < 4; ++j) {
                    acc[i][j] += a[i].x * bb[j].x + a[i].y * bb[j].y
                               + a[i].z * bb[j].z + a[i].w * bb[j].w;
                }
        }
    }
    // ---- write O = acc / l ----
    #pragma unroll
    for (int i = 0; i < 4; ++i) {
        float inv = 1.0f / l[i];
        float4 ov = make_float4(acc[i][0] * inv, acc[i][1] * inv,
                                acc[i][2] * inv, acc[i][3] * inv);
        *(float4*)(o + ((size_t)(b * S + qrow_g[i])) * H + hoff + tx * 4) = ov;
    }
}

// ---------------- Discretize: argmax + softmax z ----------------
__global__ __launch_bounds__(256) void discretize_k(const float* __restrict__ logits,
    const float* __restrict__ gumbel, float* __restrict__ z, int* __restrict__ chosen)
{
    int bs = blockIdx.x;
    const float* lg = logits + (size_t)bs * CV1;
    const float* gm = gumbel + (size_t)bs * CV1;
    __shared__ float redv[256]; __shared__ int redi[256];
    int tid = threadIdx.x;
    float m = -3.4e38f; int mi = CV1;
    for (int j = tid; j < CV1; j += 256) {
        float a = lg[j] + gm[j];
        if (a > m) { m = a; mi = j; }
    }
    redv[tid] = m; redi[tid] = mi; __syncthreads();
    for (int off = 128; off > 0; off >>= 1) {
        if (tid < off) {
            float vo = redv[tid + off]; int io = redi[tid + off];
            if (vo > redv[tid] || (vo == redv[tid] && io < redi[tid])) { redv[tid] = vo; redi[tid] = io; }
        }
        __syncthreads();
    }
    m = redv[0]; int amax = redi[0];
    __syncthreads();
    float ssum = 0.f;
    for (int j = tid; j < CV1; j += 256) ssum += expf(lg[j] + gm[j] - m);
    redv[tid] = ssum; __syncthreads();
    for (int off = 128; off > 0; off >>= 1) {
        if (tid < off) redv[tid] += redv[tid + off];
        __syncthreads();
    }
    float inv = 1.0f / redv[0];
    for (int j = tid; j < CV; j += 256)
        z[(size_t)bs * CV + j] = expf(lg[j] + gm[j] - m) * inv;
    if (tid == 0) chosen[bs] = amax;
}

// ---------------- cea + loss partials ----------------
__global__ __launch_bounds__(256) void cea_k(const float* __restrict__ esoft,
    const float* __restrict__ cemb, const int* __restrict__ chosen,
    const int* __restrict__ amask, float* __restrict__ cea, float* __restrict__ partial)
{
    int bs = blockIdx.x;
    int ch = chosen[bs]; int vm = amask[bs];
    int comp = (ch != CV) && vm;
    const float* ehr = cemb + (size_t)(ch < CV - 1 ? ch : CV - 1) * H;
    __shared__ float red[256];
    float part = 0.f;
    float vmf = vm ? 1.f : 0.f;
    for (int i = threadIdx.x; i < H; i += 256) {
        float es = esoft[(size_t)bs * H + i];
        float eh = comp ? ehr[i] : 0.f;
        cea[(size_t)bs * H + i] = ((eh + es) - es) * vmf;   // STE forward
        float d = es - eh;
        part += d * d;
    }
    red[threadIdx.x] = part; __syncthreads();
    for (int off = 128; off > 0; off >>= 1) {
        if (threadIdx.x < off) red[threadIdx.x] += red[threadIdx.x + off];
        __syncthreads();
    }
    if (threadIdx.x == 0) partial[bs] = red[0];
}

__global__ __launch_bounds__(256) void loss_k(const float* __restrict__ partial, float* __restrict__ out)
{
    __shared__ float red[256];
    float s = 0.f;
    for (int i = threadIdx.x; i < BS; i += 256) s += partial[i];
    red[threadIdx.x] = s; __syncthreads();
    for (int off = 128; off > 0; off >>= 1) {
        if (threadIdx.x < off) red[threadIdx.x] += red[threadIdx.x + off];
        __syncthreads();
    }
    if (threadIdx.x == 0) out[0] = 1.25f * red[0] / (float)BSH;
}

// ---------------- Stable pack (serial per batch) ----------------
__global__ void pack_k(const int* __restrict__ chosen, const int* __restrict__ amask,
    int* __restrict__ order, int* __restrict__ cpos, int* __restrict__ cvalid,
    int* __restrict__ counts)
{
    int b = blockIdx.x;
    if (threadIdx.x != 0) return;
    int cnt = 0;
    for (int s2 = 0; s2 < S; ++s2)
        if (chosen[b * S + s2] != CV && amask[b * S + s2]) order[b * S + cnt++] = s2;
    counts[b] = cnt;
    int j2 = cnt;
    for (int s2 = 0; s2 < S; ++s2)
        if (!(chosen[b * S + s2] != CV && amask[b * S + s2])) order[b * S + j2++] = s2;
    for (int j3 = 0; j3 < S; ++j3) {
        cvalid[b * S + j3] = (j3 < cnt) ? 1 : 0;
        cpos[b * S + j3]   = (j3 < cnt) ? order[b * S + j3] : 0;
    }
}

__global__ __launch_bounds__(256) void gather_k(const float* __restrict__ cea,
    const int* __restrict__ order, const int* __restrict__ cvalid, float* __restrict__ h)
{
    int bs = blockIdx.x;
    int b = bs >> 10;
    int src = order[bs];
    float f = cvalid[bs] ? 1.f : 0.f;
    const float* sp = cea + (size_t)(b * S + src) * H;
    float* dst = h + (size_t)bs * H;
    for (int i = threadIdx.x; i < H; i += 256) dst[i] = sp[i] * f;
}

__global__ __launch_bounds__(256) void outmask_k(const float* __restrict__ h,
    const int* __restrict__ cvalid, float* __restrict__ out)
{
    int bs = blockIdx.x;
    float f = cvalid[bs] ? 1.f : 0.f;
    for (int i = threadIdx.x; i < H; i += 256)
        out[(size_t)bs * H + i] = h[(size_t)bs * H + i] * f;
}

__global__ __launch_bounds__(256) void iota_k(int* __restrict__ pos)
{
    int idx = blockIdx.x * 256 + threadIdx.x;
    if (idx < BS) pos[idx] = idx & (S - 1);
}

// ---------------- Host-side block driver ----------------
static void run_block(int layer,
    const float* ln1, const float* wq, const float* wk, const float* wv,
    const float* wo, const float* ln2, const float* wg, const float* wu, const float* wd,
    float* h, float* hn, float* q, float* k, float* v, float* o, float* f1,
    const int* valid, const int* pos, hipStream_t stream)
{
    size_t LHH = (size_t)layer * H * H;
    size_t LHF = (size_t)layer * H * FF;
    rmsnorm_k<<<BS, 256, 0, stream>>>(h, ln1 + (size_t)layer * H, hn);
    gemm_k<<<dim3(16, 64), 256, 0, stream>>>(hn, wq + LHH, nullptr, q, BS, H, H, H, H, H, 0);
    gemm_k<<<dim3(16, 64), 256, 0, stream>>>(hn, wk + LHH, nullptr, k, BS, H, H, H, H, H, 0);
    gemm_k<<<dim3(16, 64), 256, 0, stream>>>(hn, wv + LHH, nullptr, v, BS, H, H, H, H, H, 0);
    rope_k<<<8192, 256, 0, stream>>>(q, pos);
    rope_k<<<8192, 256, 0, stream>>>(k, pos);
    fattn_k<<<dim3(S / 64, NH, B), 256, 0, stream>>>(q, k, v, o, valid);
    gemm_k<<<dim3(16, 64), 256, 0, stream>>>(o, wo + LHH, nullptr, h, BS, H, H, H, H, H, F_RESID);
    rmsnorm_k<<<BS, 256, 0, stream>>>(h, ln2 + (size_t)layer * H, hn);
    gemm_k<<<dim3(64, 64), 256, 0, stream>>>(hn, wg + LHF, nullptr, f1, BS, FF, H, H, FF, FF, F_SILU);
    gemm_k<<<dim3(64, 64), 256, 0, stream>>>(hn, wu + LHF, nullptr, f1, BS, FF, H, H, FF, FF, F_MULIN);
    gemm_k<<<dim3(16, 64), 256, 0, stream>>>(f1, wd + (size_t)layer * FF * H, nullptr, h, BS, H, FF, FF, H, H, F_RESID);
}

extern "C" void kernel_launch(void* const* d_in, const int* in_sizes, int n_in,
                              void* d_out, int out_size, void* d_ws, size_t ws_size,
                              hipStream_t stream)
{
    const int*   ids    = (const int*)d_in[0];
    const int*   amask  = (const int*)d_in[1];
    const float* embed  = (const float*)d_in[2];
    const float* ln1    = (const float*)d_in[3];
    const float* wq     = (const float*)d_in[4];
    const float* wk     = (const float*)d_in[5];
    const float* wv     = (const float*)d_in[6];
    const float* wo     = (const float*)d_in[7];
    const float* ln2    = (const float*)d_in[8];
    const float* wg     = (const float*)d_in[9];
    const float* wu     = (const float*)d_in[10];
    const float* wd     = (const float*)d_in[11];
    const float* head_w = (const float*)d_in[12];
    const float* head_b = (const float*)d_in[13];
    const float* cemb   = (const float*)d_in[14];
    const float* gumbel = (const float*)d_in[15];
    float* out = (float*)d_out;

    float* wsf = (float*)d_ws;
    float* h   = wsf;              // BSH
    float* hn  = wsf + BSH;        // BSH
    float* q   = wsf + 2 * BSH;    // BSH
    float* k   = wsf + 3 * BSH;    // BSH
    float* v   = wsf + 4 * BSH;    // BSH
    float* o   = wsf + 5 * BSH;    // BSH
    float* f1  = wsf + 6 * BSH;    // BSF (FFN intermediate; also logits [BS,2049])
    float* zbuf  = q;              // BS*CV floats — spans q..k (both dead here)
    float* esoft = v;              // BSH
    float* ceab  = o;              // BSH
    int* meta   = (int*)(wsf + 6 * BSH + BSF);
    int* chosen = meta;
    int* order  = meta + BS;
    int* cpos   = meta + 2 * BS;
    int* cvalid = meta + 3 * BS;
    int* counts = meta + 4 * BS;
    int* pos_sh = meta + 5 * BS;
    float* partial = (float*)(meta + 6 * BS);  // BS floats

    // 1. embed + positions
    embed_k<<<BS, 256, 0, stream>>>(ids, embed, h);
    iota_k<<<16, 256, 0, stream>>>(pos_sh);

    // 2. shallow blocks (layers 0,1)
    for (int L = 0; L < 2; ++L)
        run_block(L, ln1, wq, wk, wv, wo, ln2, wg, wu, wd,
                  h, hn, q, k, v, o, f1, amask, pos_sh, stream);

    // 3. head logits -> f1 [BS, 2049]
    gemm_k<<<dim3(33, 64), 256, 0, stream>>>(h, head_w, head_b, f1, BS, CV1, H, H, CV1, CV1, F_BIAS);

    // 4. discretize: z + argmax
    discretize_k<<<BS, 256, 0, stream>>>(f1, gumbel, zbuf, chosen);

    // 5. e_soft = z @ concept_emb
    gemm_k<<<dim3(16, 64), 256, 0, stream>>>(zbuf, cemb, nullptr, esoft, BS, H, CV, CV, H, H, 0);

    // 6. cea + loss
    cea_k<<<BS, 256, 0, stream>>>(esoft, cemb, chosen, amask, ceab, partial);
    loss_k<<<1, 256, 0, stream>>>(partial, out + BSH);

    // 7. stable pack + gather cin into h
    pack_k<<<B, 64, 0, stream>>>(chosen, amask, order, cpos, cvalid, counts);
    gather_k<<<BS, 256, 0, stream>>>(ceab, order, cvalid, h);

    // 8. mid blocks (layers 2,3)
    for (int L = 2; L < 4; ++L)
        run_block(L, ln1, wq, wk, wv, wo, ln2, wg, wu, wd,
                  h, hn, q, k, v, o, f1, cvalid, cpos, stream);

    // 9. masked output
    outmask_k<<<BS, 256, 0, stream>>>(h, cvalid, out);
}

// Round 3
// 9456.577 us; speedup vs baseline: 3.7802x; 1.8801x over previous
//
#include <hip/hip_runtime.h>
#include <hip/hip_bf16.h>
#include <cmath>

#define B 4
#define S 1024
#define H 1024
#define NH 16
#define HD 64
#define FF 4096
#define CV 2048
#define CV1 2049
#define BS (B*S)            // 4096
#define BSH ((size_t)BS*H)  // 4194304
#define BSF ((size_t)BS*FF) // 16777216

#define F_BIAS  1
#define F_RESID 2
#define F_SILU  4
#define F_MULIN 8

typedef __attribute__((ext_vector_type(8))) short s16x8;
typedef __attribute__((ext_vector_type(4))) float f32x4;

static __device__ inline short bf_of(float v) {
    __hip_bfloat16 h = __float2bfloat16(v);
    return *reinterpret_cast<short*>(&h);
}
static __device__ inline float f_of(short s) {
    __hip_bfloat16 h = *reinterpret_cast<__hip_bfloat16*>(&s);
    return __bfloat162float(h);
}
static __device__ inline void split_store(float v, short* p, size_t plane, size_t idx, int np) {
    short b0 = bf_of(v); p[idx] = b0;
    if (np == 3) {
        float r1 = v - f_of(b0);
        short b1 = bf_of(r1); p[plane + idx] = b1;
        p[2 * plane + idx] = bf_of(r1 - f_of(b1));
    }
}

// ============ MFMA GEMM: C[M,N] = (resid?) + sum_passes A_p[M,K] @ Wt_p[N,K]^T ============
// 128x128 tile, BK=32, 4 waves (2x2), 4x4 16x16x32 frags per wave.
// A planes row-major [M,K]; Wt planes row-major [N,K] (pre-transposed weights).
__global__ __launch_bounds__(256) void gemm_mf_k(
    const short* __restrict__ A, const short* __restrict__ Wt,
    float* __restrict__ C, const float* __restrict__ resid,
    int M, int N, int K, size_t planeA, size_t planeW, int npass)
{
    __shared__ short As[128 * 32];
    __shared__ short Bs[128 * 32];
    const int tid = threadIdx.x;
    const int w = tid >> 6, l = tid & 63;
    const int wm = w >> 1, wn = w & 1;
    const int row0 = blockIdx.y * 128, col0 = blockIdx.x * 128;
    const int PAt[6] = {0, 0, 1, 0, 1, 2};
    const int PWt[6] = {0, 1, 0, 2, 1, 0};

    f32x4 acc[4][4];
    #pragma unroll
    for (int i = 0; i < 4; ++i)
        #pragma unroll
        for (int j = 0; j < 4; ++j)
            #pragma unroll
            for (int r = 0; r < 4; ++r) acc[i][j][r] = 0.f;

    const int lr = l & 15, q = l >> 4;
    for (int p = 0; p < npass; ++p) {
        const short* Ap = A + (size_t)PAt[p] * planeA;
        const short* Wp = Wt + (size_t)PWt[p] * planeW;
        for (int k0 = 0; k0 < K; k0 += 32) {
            __syncthreads();
            #pragma unroll
            for (int s = 0; s < 2; ++s) {
                int e = s * 256 + tid;
                int r = e >> 2, cq = e & 3;
                int sw = cq ^ ((r >> 1) & 3);
                s16x8 va = *(const s16x8*)(Ap + (size_t)(row0 + r) * K + k0 + cq * 8);
                *(s16x8*)&As[r * 32 + sw * 8] = va;
                s16x8 vb = *(const s16x8*)(Wp + (size_t)(col0 + r) * K + k0 + cq * 8);
                *(s16x8*)&Bs[r * 32 + sw * 8] = vb;
            }
            __syncthreads();
            s16x8 af[4], bfv[4];
            #pragma unroll
            for (int i = 0; i < 4; ++i) {
                int ra = wm * 64 + i * 16 + lr;
                af[i] = *(const s16x8*)&As[ra * 32 + (q ^ ((ra >> 1) & 3)) * 8];
                int rb = wn * 64 + i * 16 + lr;
                bfv[i] = *(const s16x8*)&Bs[rb * 32 + (q ^ ((rb >> 1) & 3)) * 8];
            }
            #pragma unroll
            for (int mi = 0; mi < 4; ++mi)
                #pragma unroll
                for (int ni = 0; ni < 4; ++ni)
                    acc[mi][ni] = __builtin_amdgcn_mfma_f32_16x16x32_bf16(
                        af[mi], bfv[ni], acc[mi][ni], 0, 0, 0);
        }
    }
    const int cw = l & 15, rw = (l >> 4) * 4;
    #pragma unroll
    for (int mi = 0; mi < 4; ++mi)
        #pragma unroll
        for (int ni = 0; ni < 4; ++ni)
            #pragma unroll
            for (int r = 0; r < 4; ++r) {
                int gr = row0 + wm * 64 + mi * 16 + rw + r;
                int gc = col0 + wn * 64 + ni * 16 + cw;
                size_t ci = (size_t)gr * N + gc;
                float val = acc[mi][ni][r];
                if (resid) val += resid[ci];
                C[ci] = val;
            }
}

// ============ Fused gate-up: F = silu(A@Wg) * (A@Wu), written as bf16 split planes ============
__global__ __launch_bounds__(256) void gateup_k(
    const short* __restrict__ A, const short* __restrict__ Wg, const short* __restrict__ Wu,
    short* __restrict__ F, int M, int N, int K,
    size_t planeA, size_t planeW, size_t planeF, int npass, int npOut)
{
    __shared__ short As[128 * 32];
    __shared__ short Bg[128 * 32];
    __shared__ short Bu[128 * 32];
    const int tid = threadIdx.x;
    const int w = tid >> 6, l = tid & 63;
    const int wm = w >> 1, wn = w & 1;
    const int row0 = blockIdx.y * 128, col0 = blockIdx.x * 128;
    const int PAt[6] = {0, 0, 1, 0, 1, 2};
    const int PWt[6] = {0, 1, 0, 2, 1, 0};

    f32x4 accg[4][4], accu[4][4];
    #pragma unroll
    for (int i = 0; i < 4; ++i)
        #pragma unroll
        for (int j = 0; j < 4; ++j)
            #pragma unroll
            for (int r = 0; r < 4; ++r) { accg[i][j][r] = 0.f; accu[i][j][r] = 0.f; }

    const int lr = l & 15, q = l >> 4;
    for (int p = 0; p < npass; ++p) {
        const short* Ap = A + (size_t)PAt[p] * planeA;
        const short* Wgp = Wg + (size_t)PWt[p] * planeW;
        const short* Wup = Wu + (size_t)PWt[p] * planeW;
        for (int k0 = 0; k0 < K; k0 += 32) {
            __syncthreads();
            #pragma unroll
            for (int s = 0; s < 2; ++s) {
                int e = s * 256 + tid;
                int r = e >> 2, cq = e & 3;
                int sw = cq ^ ((r >> 1) & 3);
                s16x8 va = *(const s16x8*)(Ap + (size_t)(row0 + r) * K + k0 + cq * 8);
                *(s16x8*)&As[r * 32 + sw * 8] = va;
                s16x8 vg = *(const s16x8*)(Wgp + (size_t)(col0 + r) * K + k0 + cq * 8);
                *(s16x8*)&Bg[r * 32 + sw * 8] = vg;
                s16x8 vu = *(const s16x8*)(Wup + (size_t)(col0 + r) * K + k0 + cq * 8);
                *(s16x8*)&Bu[r * 32 + sw * 8] = vu;
            }
            __syncthreads();
            s16x8 af[4], bg[4], bu[4];
            #pragma unroll
            for (int i = 0; i < 4; ++i) {
                int ra = wm * 64 + i * 16 + lr;
                af[i] = *(const s16x8*)&As[ra * 32 + (q ^ ((ra >> 1) & 3)) * 8];
                int rb = wn * 64 + i * 16 + lr;
                int sb = (q ^ ((rb >> 1) & 3)) * 8;
                bg[i] = *(const s16x8*)&Bg[rb * 32 + sb];
                bu[i] = *(const s16x8*)&Bu[rb * 32 + sb];
            }
            #pragma unroll
            for (int mi = 0; mi < 4; ++mi)
                #pragma unroll
                for (int ni = 0; ni < 4; ++ni) {
                    accg[mi][ni] = __builtin_amdgcn_mfma_f32_16x16x32_bf16(
                        af[mi], bg[ni], accg[mi][ni], 0, 0, 0);
                    accu[mi][ni] = __builtin_amdgcn_mfma_f32_16x16x32_bf16(
                        af[mi], bu[ni], accu[mi][ni], 0, 0, 0);
                }
        }
    }
    const int cw = l & 15, rw = (l >> 4) * 4;
    #pragma unroll
    for (int mi = 0; mi < 4; ++mi)
        #pragma unroll
        for (int ni = 0; ni < 4; ++ni)
            #pragma unroll
            for (int r = 0; r < 4; ++r) {
                int gr = row0 + wm * 64 + mi * 16 + rw + r;
                int gc = col0 + wn * 64 + ni * 16 + cw;
                float g = accg[mi][ni][r], u = accu[mi][ni][r];
                float val = g / (1.f + expf(-g)) * u;
                split_store(val, F, planeF, (size_t)gr * N + gc, npOut);
            }
}

// ============ Weight transpose + bf16 split: W[K,N] f32 -> Wt planes [N,K] bf16 ============
__global__ __launch_bounds__(256) void splitwt_k(const float* __restrict__ W,
    short* __restrict__ Wt, int K, int N, size_t plane, int np)
{
    __shared__ float t[32][33];
    const int tid = threadIdx.x;
    const int n0 = blockIdx.x * 32, k0 = blockIdx.y * 32;
    #pragma unroll
    for (int i = 0; i < 4; ++i) {
        int e = tid + i * 256;
        int rk = e >> 5, cn = e & 31;
        t[rk][cn] = W[(size_t)(k0 + rk) * N + n0 + cn];
    }
    __syncthreads();
    #pragma unroll
    for (int i = 0; i < 4; ++i) {
        int e = tid + i * 256;
        int rn = e >> 5, ck = e & 31;
        split_store(t[ck][rn], Wt, plane, (size_t)(n0 + rn) * K + k0 + ck, np);
    }
}

// ============ Straight bf16 split for activations ============
__global__ __launch_bounds__(256) void splita_k(const float* __restrict__ x,
    short* __restrict__ y, size_t n, size_t plane, int np)
{
    for (size_t i = blockIdx.x * 256 + threadIdx.x; i < n; i += (size_t)gridDim.x * 256)
        split_store(x[i], y, plane, i, np);
}

// ============ RMSNorm -> bf16 split planes ============
__global__ __launch_bounds__(256) void rmsnorm_split_k(const float* __restrict__ x,
    const float* __restrict__ w, short* __restrict__ y, size_t plane, int np)
{
    int row = blockIdx.x;
    const float* xr = x + (size_t)row * H;
    __shared__ float red[256];
    float s = 0.f;
    for (int i = threadIdx.x; i < H; i += 256) { float v = xr[i]; s += v * v; }
    red[threadIdx.x] = s; __syncthreads();
    for (int off = 128; off > 0; off >>= 1) {
        if (threadIdx.x < off) red[threadIdx.x] += red[threadIdx.x + off];
        __syncthreads();
    }
    float r = 1.0f / sqrtf(red[0] / (float)H + 1e-6f);
    for (int i = threadIdx.x; i < H; i += 256)
        split_store(xr[i] * r * w[i], y, plane, (size_t)row * H + i, np);
}

// ---------------- fp32 GEMM (head logits + fallback path) ----------------
__global__ __launch_bounds__(256) void gemm_k(
    const float* __restrict__ A, const float* __restrict__ Wm,
    const float* __restrict__ bias, float* __restrict__ C,
    int M, int N, int K, int lda, int ldb, int ldc, int flags)
{
    __shared__ float As[16][65];
    __shared__ float Bs[16][65];
    const int tid = threadIdx.x;
    const int tx = tid & 15, ty = tid >> 4;
    const int row0 = blockIdx.y * 64, col0 = blockIdx.x * 64;
    float acc[4][4] = {};
    for (int k0 = 0; k0 < K; k0 += 16) {
        #pragma unroll
        for (int l = 0; l < 4; ++l) {
            int e = tid + l * 256;
            int r = e >> 4, c = e & 15;
            int gr = row0 + r;
            float vv = 0.f;
            if (gr < M) vv = A[(size_t)gr * lda + (k0 + c)];
            As[c][r] = vv;
        }
        #pragma unroll
        for (int l = 0; l < 4; ++l) {
            int e = tid + l * 256;
            int r = e >> 6, c = e & 63;
            int gc = col0 + c;
            float vv = 0.f;
            if (gc < N) vv = Wm[(size_t)(k0 + r) * ldb + gc];
            Bs[r][c] = vv;
        }
        __syncthreads();
        #pragma unroll
        for (int kk = 0; kk < 16; ++kk) {
            float a[4], bb[4];
            #pragma unroll
            for (int i = 0; i < 4; ++i) a[i] = As[kk][ty * 4 + i];
            #pragma unroll
            for (int j = 0; j < 4; ++j) bb[j] = Bs[kk][tx * 4 + j];
            #pragma unroll
            for (int i = 0; i < 4; ++i)
                #pragma unroll
                for (int j = 0; j < 4; ++j)
                    acc[i][j] += a[i] * bb[j];
        }
        __syncthreads();
    }
    #pragma unroll
    for (int i = 0; i < 4; ++i) {
        int gr = row0 + ty * 4 + i;
        if (gr >= M) continue;
        #pragma unroll
        for (int j = 0; j < 4; ++j) {
            int gc = col0 + tx * 4 + j;
            if (gc >= N) continue;
            float vv = acc[i][j];
            if (flags & F_BIAS)  vv += bias[gc];
            if (flags & F_SILU)  vv = vv / (1.f + expf(-vv));
            size_t cidx = (size_t)gr * ldc + gc;
            if (flags & F_MULIN) vv *= C[cidx];
            if (flags & F_RESID) vv += C[cidx];
            C[cidx] = vv;
        }
    }
}

// ---------------- RMSNorm fp32 (fallback) ----------------
__global__ __launch_bounds__(256) void rmsnorm_k(const float* __restrict__ x,
    const float* __restrict__ w, float* __restrict__ y)
{
    int row = blockIdx.x;
    const float* xr = x + (size_t)row * H;
    float* yr = y + (size_t)row * H;
    __shared__ float red[256];
    float s = 0.f;
    for (int i = threadIdx.x; i < H; i += 256) { float v = xr[i]; s += v * v; }
    red[threadIdx.x] = s; __syncthreads();
    for (int off = 128; off > 0; off >>= 1) {
        if (threadIdx.x < off) red[threadIdx.x] += red[threadIdx.x + off];
        __syncthreads();
    }
    float r = 1.0f / sqrtf(red[0] / (float)H + 1e-6f);
    for (int i = threadIdx.x; i < H; i += 256) yr[i] = xr[i] * r * w[i];
}

// ---------------- Embed gather ----------------
__global__ __launch_bounds__(256) void embed_k(const int* __restrict__ ids,
    const float* __restrict__ emb, float* __restrict__ h)
{
    int bs = blockIdx.x;
    const float* e = emb + (size_t)ids[bs] * H;
    float* hr = h + (size_t)bs * H;
    for (int i = threadIdx.x; i < H; i += 256) hr[i] = e[i];
}

// ---------------- RoPE (in-place) ----------------
__global__ __launch_bounds__(256) void rope_k(float* __restrict__ x, const int* __restrict__ pos)
{
    int idx = blockIdx.x * 256 + threadIdx.x;
    int i = idx & 31;
    int head = (idx >> 5) & 15;
    int bs = idx >> 9;
    int p = pos[bs];
    double inv = exp(-((double)(2 * i) / 64.0) * log(10000.0));
    double ang = (double)p * inv;
    float c = (float)cos(ang), sn = (float)sin(ang);
    float* base = x + (size_t)bs * H + head * 64;
    float x1 = base[i], x2 = base[i + 32];
    base[i]      = x1 * c - x2 * sn;
    base[i + 32] = x2 * c + x1 * sn;
}

// ---------------- Flash attention (fp32) ----------------
__global__ __launch_bounds__(256) void fattn_k(const float* __restrict__ q,
    const float* __restrict__ k, const float* __restrict__ v,
    float* __restrict__ o, const int* __restrict__ valid)
{
    const int qt = blockIdx.x, hh = blockIdx.y, b = blockIdx.z;
    const int tid = threadIdx.x;
    const int tx = tid & 15, ty = tid >> 4;
    __shared__ float Qs[64][68];
    __shared__ float Ks[64][68];
    __shared__ float Vs[64][68];
    __shared__ int   kvs[64];
    const size_t hoff = (size_t)hh * HD;

    {
        int row = tid >> 2, d0 = (tid & 3) * 16;
        const float* qp = q + ((size_t)(b * S + qt * 64 + row)) * H + hoff + d0;
        float4* dst = (float4*)&Qs[row][d0];
        const float4* src = (const float4*)qp;
        #pragma unroll
        for (int e = 0; e < 4; ++e) dst[e] = src[e];
    }
    int qv[4]; int qrow_g[4];
    #pragma unroll
    for (int i = 0; i < 4; ++i) {
        qrow_g[i] = qt * 64 + ty * 4 + i;
        qv[i] = valid[b * S + qrow_g[i]];
    }
    float m[4], l[4], acc[4][4];
    #pragma unroll
    for (int i = 0; i < 4; ++i) {
        m[i] = -3.4e38f; l[i] = 0.f;
        #pragma unroll
        for (int j = 0; j < 4; ++j) acc[i][j] = 0.f;
    }

    for (int kt = 0; kt < S / 64; ++kt) {
        __syncthreads();
        {
            int row = tid >> 2, d0 = (tid & 3) * 16;
            const float* kp = k + ((size_t)(b * S + kt * 64 + row)) * H + hoff + d0;
            float4* dst = (float4*)&Ks[row][d0];
            const float4* src = (const float4*)kp;
            #pragma unroll
            for (int e = 0; e < 4; ++e) dst[e] = src[e];
        }
        {
            int kk = tid >> 2, d0 = (tid & 3) * 16;
            const float* vp = v + ((size_t)(b * S + kt * 64 + kk)) * H + hoff + d0;
            #pragma unroll
            for (int e = 0; e < 16; e += 4) {
                float4 vv = *(const float4*)(vp + e);
                Vs[d0 + e + 0][kk] = vv.x;
                Vs[d0 + e + 1][kk] = vv.y;
                Vs[d0 + e + 2][kk] = vv.z;
                Vs[d0 + e + 3][kk] = vv.w;
            }
        }
        if (tid < 64) kvs[tid] = valid[b * S + kt * 64 + tid];
        __syncthreads();

        float s4[4][4];
        #pragma unroll
        for (int i = 0; i < 4; ++i)
            #pragma unroll
            for (int j = 0; j < 4; ++j) s4[i][j] = 0.f;
        #pragma unroll
        for (int c = 0; c < 16; ++c) {
            float4 a[4], bb[4];
            #pragma unroll
            for (int i = 0; i < 4; ++i) a[i]  = ((const float4*)&Qs[ty * 4 + i][0])[c];
            #pragma unroll
            for (int j = 0; j < 4; ++j) bb[j] = ((const float4*)&Ks[tx * 4 + j][0])[c];
            #pragma unroll
            for (int i = 0; i < 4; ++i)
                #pragma unroll
                for (int j = 0; j < 4; ++j) {
                    s4[i][j] += a[i].x * bb[j].x + a[i].y * bb[j].y
                              + a[i].z * bb[j].z + a[i].w * bb[j].w;
                }
        }
        float p[4][4];
        float corr[4];
        #pragma unroll
        for (int i = 0; i < 4; ++i) {
            float rm = -3.4e38f;
            #pragma unroll
            for (int j = 0; j < 4; ++j) {
                int kc = kt * 64 + tx * 4 + j;
                float sv = s4[i][j] * 0.125f;
                int allowed = (kc <= qrow_g[i]) && qv[i] && kvs[tx * 4 + j];
                if (!allowed) sv = sv + -1e9f;
                s4[i][j] = sv;
                rm = fmaxf(rm, sv);
            }
            rm = fmaxf(rm, __shfl_xor(rm, 1));
            rm = fmaxf(rm, __shfl_xor(rm, 2));
            rm = fmaxf(rm, __shfl_xor(rm, 4));
            rm = fmaxf(rm, __shfl_xor(rm, 8));
            float mn = fmaxf(m[i], rm);
            corr[i] = expf(m[i] - mn);
            float rs = 0.f;
            #pragma unroll
            for (int j = 0; j < 4; ++j) { p[i][j] = expf(s4[i][j] - mn); rs += p[i][j]; }
            rs += __shfl_xor(rs, 1);
            rs += __shfl_xor(rs, 2);
            rs += __shfl_xor(rs, 4);
            rs += __shfl_xor(rs, 8);
            l[i] = l[i] * corr[i] + rs;
            m[i] = mn;
            #pragma unroll
            for (int j = 0; j < 4; ++j) acc[i][j] *= corr[i];
        }
        __syncthreads();
        #pragma unroll
        for (int i = 0; i < 4; ++i) {
            float4 pv4 = make_float4(p[i][0], p[i][1], p[i][2], p[i][3]);
            *(float4*)&Ks[ty * 4 + i][tx * 4] = pv4;
        }
        __syncthreads();
        #pragma unroll
        for (int c = 0; c < 16; ++c) {
            float4 a[4], bb[4];
            #pragma unroll
            for (int i = 0; i < 4; ++i) a[i]  = ((const float4*)&Ks[ty * 4 + i][0])[c];
            #pragma unroll
            for (int j = 0; j < 4; ++j) bb[j] = ((const float4*)&Vs[tx * 4 + j][0])[c];
            #pragma unroll
            for (int i = 0; i < 4; ++i)
                #pragma unroll
                for (int j = 0; j < 4; ++j) {
                    acc[i][j] += a[i].x * bb[j].x + a[i].y * bb[j].y
                               + a[i].z * bb[j].z + a[i].w * bb[j].w;
                }
        }
    }
    #pragma unroll
    for (int i = 0; i < 4; ++i) {
        float inv = 1.0f / l[i];
        float4 ov = make_float4(acc[i][0] * inv, acc[i][1] * inv,
                                acc[i][2] * inv, acc[i][3] * inv);
        *(float4*)(o + ((size_t)(b * S + qrow_g[i])) * H + hoff + tx * 4) = ov;
    }
}

// ---------------- Discretize (bf16 z variant + fp32 fallback) ----------------
__global__ __launch_bounds__(256) void discretize_bf_k(const float* __restrict__ logits,
    const float* __restrict__ gumbel, short* __restrict__ z, int* __restrict__ chosen)
{
    int bs = blockIdx.x;
    const float* lg = logits + (size_t)bs * CV1;
    const float* gm = gumbel + (size_t)bs * CV1;
    __shared__ float redv[256]; __shared__ int redi[256];
    int tid = threadIdx.x;
    float m = -3.4e38f; int mi = CV1;
    for (int j = tid; j < CV1; j += 256) {
        float a = lg[j] + gm[j];
        if (a > m) { m = a; mi = j; }
    }
    redv[tid] = m; redi[tid] = mi; __syncthreads();
    for (int off = 128; off > 0; off >>= 1) {
        if (tid < off) {
            float vo = redv[tid + off]; int io = redi[tid + off];
            if (vo > redv[tid] || (vo == redv[tid] && io < redi[tid])) { redv[tid] = vo; redi[tid] = io; }
        }
        __syncthreads();
    }
    m = redv[0]; int amax = redi[0];
    __syncthreads();
    float ssum = 0.f;
    for (int j = tid; j < CV1; j += 256) ssum += expf(lg[j] + gm[j] - m);
    redv[tid] = ssum; __syncthreads();
    for (int off = 128; off > 0; off >>= 1) {
        if (tid < off) redv[tid] += redv[tid + off];
        __syncthreads();
    }
    float inv = 1.0f / redv[0];
    for (int j = tid; j < CV; j += 256)
        z[(size_t)bs * CV + j] = bf_of(expf(lg[j] + gm[j] - m) * inv);
    if (tid == 0) chosen[bs] = amax;
}

__global__ __launch_bounds__(256) void discretize_k(const float* __restrict__ logits,
    const float* __restrict__ gumbel, float* __restrict__ z, int* __restrict__ chosen)
{
    int bs = blockIdx.x;
    const float* lg = logits + (size_t)bs * CV1;
    const float* gm = gumbel + (size_t)bs * CV1;
    __shared__ float redv[256]; __shared__ int redi[256];
    int tid = threadIdx.x;
    float m = -3.4e38f; int mi = CV1;
    for (int j = tid; j < CV1; j += 256) {
        float a = lg[j] + gm[j];
        if (a > m) { m = a; mi = j; }
    }
    redv[tid] = m; redi[tid] = mi; __syncthreads();
    for (int off = 128; off > 0; off >>= 1) {
        if (tid < off) {
            float vo = redv[tid + off]; int io = redi[tid + off];
            if (vo > redv[tid] || (vo == redv[tid] && io < redi[tid])) { redv[tid] = vo; redi[tid] = io; }
        }
        __syncthreads();
    }
    m = redv[0]; int amax = redi[0];
    __syncthreads();
    float ssum = 0.f;
    for (int j = tid; j < CV1; j += 256) ssum += expf(lg[j] + gm[j] - m);
    redv[tid] = ssum; __syncthreads();
    for (int off = 128; off > 0; off >>= 1) {
        if (tid < off) redv[tid] += redv[tid + off];
        __syncthreads();
    }
    float inv = 1.0f / redv[0];
    for (int j = tid; j < CV; j += 256)
        z[(size_t)bs * CV + j] = expf(lg[j] + gm[j] - m) * inv;
    if (tid == 0) chosen[bs] = amax;
}

// ---------------- cea + loss partials ----------------
__global__ __launch_bounds__(256) void cea_k(const float* __restrict__ esoft,
    const float* __restrict__ cemb, const int* __restrict__ chosen,
    const int* __restrict__ amask, float* __restrict__ cea, float* __restrict__ partial)
{
    int bs = blockIdx.x;
    int ch = chosen[bs]; int vm = amask[bs];
    int comp = (ch != CV) && vm;
    const float* ehr = cemb + (size_t)(ch < CV - 1 ? ch : CV - 1) * H;
    __shared__ float red[256];
    float part = 0.f;
    float vmf = vm ? 1.f : 0.f;
    for (int i = threadIdx.x; i < H; i += 256) {
        float es = esoft[(size_t)bs * H + i];
        float eh = comp ? ehr[i] : 0.f;
        cea[(size_t)bs * H + i] = ((eh + es) - es) * vmf;
        float d = es - eh;
        part += d * d;
    }
    red[threadIdx.x] = part; __syncthreads();
    for (int off = 128; off > 0; off >>= 1) {
        if (threadIdx.x < off) red[threadIdx.x] += red[threadIdx.x + off];
        __syncthreads();
    }
    if (threadIdx.x == 0) partial[bs] = red[0];
}

__global__ __launch_bounds__(256) void loss_k(const float* __restrict__ partial, float* __restrict__ out)
{
    __shared__ float red[256];
    float s = 0.f;
    for (int i = threadIdx.x; i < BS; i += 256) s += partial[i];
    red[threadIdx.x] = s; __syncthreads();
    for (int off = 128; off > 0; off >>= 1) {
        if (threadIdx.x < off) red[threadIdx.x] += red[threadIdx.x + off];
        __syncthreads();
    }
    if (threadIdx.x == 0) out[0] = 1.25f * red[0] / (float)BSH;
}

// ---------------- Stable pack ----------------
__global__ void pack_k(const int* __restrict__ chosen, const int* __restrict__ amask,
    int* __restrict__ order, int* __restrict__ cpos, int* __restrict__ cvalid,
    int* __restrict__ counts)
{
    int b = blockIdx.x;
    if (threadIdx.x != 0) return;
    int cnt = 0;
    for (int s2 = 0; s2 < S; ++s2)
        if (chosen[b * S + s2] != CV && amask[b * S + s2]) order[b * S + cnt++] = s2;
    counts[b] = cnt;
    int j2 = cnt;
    for (int s2 = 0; s2 < S; ++s2)
        if (!(chosen[b * S + s2] != CV && amask[b * S + s2])) order[b * S + j2++] = s2;
    for (int j3 = 0; j3 < S; ++j3) {
        cvalid[b * S + j3] = (j3 < cnt) ? 1 : 0;
        cpos[b * S + j3]   = (j3 < cnt) ? order[b * S + j3] : 0;
    }
}

__global__ __launch_bounds__(256) void gather_k(const float* __restrict__ cea,
    const int* __restrict__ order, const int* __restrict__ cvalid, float* __restrict__ h)
{
    int bs = blockIdx.x;
    int b = bs >> 10;
    int src = order[bs];
    float f = cvalid[bs] ? 1.f : 0.f;
    const float* sp = cea + (size_t)(b * S + src) * H;
    float* dst = h + (size_t)bs * H;
    for (int i = threadIdx.x; i < H; i += 256) dst[i] = sp[i] * f;
}

__global__ __launch_bounds__(256) void outmask_k(const float* __restrict__ h,
    const int* __restrict__ cvalid, float* __restrict__ out)
{
    int bs = blockIdx.x;
    float f = cvalid[bs] ? 1.f : 0.f;
    for (int i = threadIdx.x; i < H; i += 256)
        out[(size_t)bs * H + i] = h[(size_t)bs * H + i] * f;
}

__global__ __launch_bounds__(256) void iota_k(int* __restrict__ pos)
{
    int idx = blockIdx.x * 256 + threadIdx.x;
    if (idx < BS) pos[idx] = idx & (S - 1);
}

// ================= Host-side drivers =================
static void run_block_f32(int layer,
    const float* ln1, const float* wq, const float* wk, const float* wv,
    const float* wo, const float* ln2, const float* wg, const float* wu, const float* wd,
    float* h, float* hn, float* q, float* k, float* v, float* o, float* f1,
    const int* valid, const int* pos, hipStream_t stream)
{
    size_t LHH = (size_t)layer * H * H;
    size_t LHF = (size_t)layer * H * FF;
    rmsnorm_k<<<BS, 256, 0, stream>>>(h, ln1 + (size_t)layer * H, hn);
    gemm_k<<<dim3(16, 64), 256, 0, stream>>>(hn, wq + LHH, nullptr, q, BS, H, H, H, H, H, 0);
    gemm_k<<<dim3(16, 64), 256, 0, stream>>>(hn, wk + LHH, nullptr, k, BS, H, H, H, H, H, 0);
    gemm_k<<<dim3(16, 64), 256, 0, stream>>>(hn, wv + LHH, nullptr, v, BS, H, H, H, H, H, 0);
    rope_k<<<8192, 256, 0, stream>>>(q, pos);
    rope_k<<<8192, 256, 0, stream>>>(k, pos);
    fattn_k<<<dim3(S / 64, NH, B), 256, 0, stream>>>(q, k, v, o, valid);
    gemm_k<<<dim3(16, 64), 256, 0, stream>>>(o, wo + LHH, nullptr, h, BS, H, H, H, H, H, F_RESID);
    rmsnorm_k<<<BS, 256, 0, stream>>>(h, ln2 + (size_t)layer * H, hn);
    gemm_k<<<dim3(64, 64), 256, 0, stream>>>(hn, wg + LHF, nullptr, f1, BS, FF, H, H, FF, FF, F_SILU);
    gemm_k<<<dim3(64, 64), 256, 0, stream>>>(hn, wu + LHF, nullptr, f1, BS, FF, H, H, FF, FF, F_MULIN);
    gemm_k<<<dim3(16, 64), 256, 0, stream>>>(f1, wd + (size_t)layer * FF * H, nullptr, h, BS, H, FF, FF, H, H, F_RESID);
}

// MFMA block: np = planes (3 shallow / 1 mid), npass = 6 or 1
static void run_block_mf(int layer, int np, int npass,
    const float* ln1, const float* wq, const float* wk, const float* wv,
    const float* wo, const float* ln2, const float* wg, const float* wu, const float* wd,
    float* h, float* q, float* k, float* v, float* o,
    short* hnsp, short* osp, short* wsp, short* wsp2, short* f1sp,
    const int* valid, const int* pos, hipStream_t stream)
{
    const size_t PH = (size_t)H * H;       // 1M: wq/wk/wv/wo plane (Wt [H][H])
    const size_t PGU = (size_t)H * FF;     // 4M: wg/wu plane (Wt [FF][H])
    const size_t PA = BSH;                 // 4M: activation plane
    const size_t PF = BSF;                 // 16M: f1 plane
    size_t LHH = (size_t)layer * H * H;
    size_t LHF = (size_t)layer * H * FF;
    dim3 gw32(H / 32, H / 32);

    rmsnorm_split_k<<<BS, 256, 0, stream>>>(h, ln1 + (size_t)layer * H, hnsp, PA, np);
    splitwt_k<<<gw32, 256, 0, stream>>>(wq + LHH, wsp, H, H, PH, np);
    gemm_mf_k<<<dim3(H / 128, BS / 128), 256, 0, stream>>>(hnsp, wsp, q, nullptr, BS, H, H, PA, PH, npass);
    splitwt_k<<<gw32, 256, 0, stream>>>(wk + LHH, wsp, H, H, PH, np);
    gemm_mf_k<<<dim3(H / 128, BS / 128), 256, 0, stream>>>(hnsp, wsp, k, nullptr, BS, H, H, PA, PH, npass);
    splitwt_k<<<gw32, 256, 0, stream>>>(wv + LHH, wsp, H, H, PH, np);
    gemm_mf_k<<<dim3(H / 128, BS / 128), 256, 0, stream>>>(hnsp, wsp, v, nullptr, BS, H, H, PA, PH, npass);
    rope_k<<<8192, 256, 0, stream>>>(q, pos);
    rope_k<<<8192, 256, 0, stream>>>(k, pos);
    fattn_k<<<dim3(S / 64, NH, B), 256, 0, stream>>>(q, k, v, o, valid);
    splita_k<<<2048, 256, 0, stream>>>(o, osp, BSH, PA, np);
    splitwt_k<<<gw32, 256, 0, stream>>>(wo + LHH, wsp, H, H, PH, np);
    gemm_mf_k<<<dim3(H / 128, BS / 128), 256, 0, stream>>>(osp, wsp, h, h, BS, H, H, PA, PH, npass);
    rmsnorm_split_k<<<BS, 256, 0, stream>>>(h, ln2 + (size_t)layer * H, hnsp, PA, np);
    splitwt_k<<<dim3(FF / 32, H / 32), 256, 0, stream>>>(wg + LHF, wsp, H, FF, PGU, np);
    splitwt_k<<<dim3(FF / 32, H / 32), 256, 0, stream>>>(wu + LHF, wsp2, H, FF, PGU, np);
    gateup_k<<<dim3(FF / 128, BS / 128), 256, 0, stream>>>(hnsp, wsp, wsp2, f1sp, BS, FF, H, PA, PGU, PF, npass, np);
    splitwt_k<<<dim3(H / 32, FF / 32), 256, 0, stream>>>(wd + (size_t)layer * FF * H, wsp, FF, H, PGU, np);
    gemm_mf_k<<<dim3(H / 128, BS / 128), 256, 0, stream>>>(f1sp, wsp, h, h, BS, H, FF, PF, PGU, npass);
}

extern "C" void kernel_launch(void* const* d_in, const int* in_sizes, int n_in,
                              void* d_out, int out_size, void* d_ws, size_t ws_size,
                              hipStream_t stream)
{
    const int*   ids    = (const int*)d_in[0];
    const int*   amask  = (const int*)d_in[1];
    const float* embed  = (const float*)d_in[2];
    const float* ln1    = (const float*)d_in[3];
    const float* wq     = (const float*)d_in[4];
    const float* wk     = (const float*)d_in[5];
    const float* wv     = (const float*)d_in[6];
    const float* wo     = (const float*)d_in[7];
    const float* ln2    = (const float*)d_in[8];
    const float* wg     = (const float*)d_in[9];
    const float* wu     = (const float*)d_in[10];
    const float* wd     = (const float*)d_in[11];
    const float* head_w = (const float*)d_in[12];
    const float* head_b = (const float*)d_in[13];
    const float* cemb   = (const float*)d_in[14];
    const float* gumbel = (const float*)d_in[15];
    float* out = (float*)d_out;

    const size_t MB = 1ull << 20;
    const size_t NEED = 274 * MB;

    if (ws_size >= NEED) {
        // ===== MFMA path =====
        char* base = (char*)d_ws;
        float* h = (float*)base;                   // 16MB
        float* q = (float*)(base + 16 * MB);
        float* k = (float*)(base + 32 * MB);
        float* v = (float*)(base + 48 * MB);
        float* o = (float*)(base + 64 * MB);
        short* hnsp = (short*)(base + 80 * MB);    // 3 planes x 4M bf16
        short* osp  = (short*)(base + 104 * MB);
        short* wsp  = (short*)(base + 128 * MB);   // 24MB
        short* wsp2 = (short*)(base + 152 * MB);   // 24MB
        short* f1sp = (short*)(base + 176 * MB);   // 96MB
        int* meta   = (int*)(base + 272 * MB);
        int* chosen = meta;
        int* order  = meta + BS;
        int* cpos   = meta + 2 * BS;
        int* cvalid = meta + 3 * BS;
        int* counts = meta + 4 * BS;
        int* pos_sh = meta + 5 * BS;
        float* partial = (float*)(meta + 6 * BS);
        float* logits = q;          // 33.5MB spans q,k,+v-head (all dead there)
        short* zb = (short*)o;      // 16MB (o dead between layer1-wo and mid attn)
        float* esoft = q;
        float* ceab = k;

        embed_k<<<BS, 256, 0, stream>>>(ids, embed, h);
        iota_k<<<16, 256, 0, stream>>>(pos_sh);

        for (int L = 0; L < 2; ++L)
            run_block_mf(L, 3, 6, ln1, wq, wk, wv, wo, ln2, wg, wu, wd,
                         h, q, k, v, o, hnsp, osp, wsp, wsp2, f1sp, amask, pos_sh, stream);

        // head logits (exact fp32; argmax-critical)
        gemm_k<<<dim3(33, 64), 256, 0, stream>>>(h, head_w, head_b, logits, BS, CV1, H, H, CV1, CV1, F_BIAS);
        discretize_bf_k<<<BS, 256, 0, stream>>>(logits, gumbel, zb, chosen);

        // e_soft = z @ cemb (1-pass bf16)
        splitwt_k<<<dim3(H / 32, CV / 32), 256, 0, stream>>>(cemb, wsp, CV, H, (size_t)CV * H, 1);
        gemm_mf_k<<<dim3(H / 128, BS / 128), 256, 0, stream>>>(zb, wsp, esoft, nullptr, BS, H, CV, (size_t)BS * CV, (size_t)CV * H, 1);

        cea_k<<<BS, 256, 0, stream>>>(esoft, cemb, chosen, amask, ceab, partial);
        loss_k<<<1, 256, 0, stream>>>(partial, out + BSH);
        pack_k<<<B, 64, 0, stream>>>(chosen, amask, order, cpos, cvalid, counts);
        gather_k<<<BS, 256, 0, stream>>>(ceab, order, cvalid, h);

        for (int L = 2; L < 4; ++L)
            run_block_mf(L, 1, 1, ln1, wq, wk, wv, wo, ln2, wg, wu, wd,
                         h, q, k, v, o, hnsp, osp, wsp, wsp2, f1sp, cvalid, cpos, stream);

        outmask_k<<<BS, 256, 0, stream>>>(h, cvalid, out);
    } else {
        // ===== fallback: proven fp32 path =====
        float* wsf = (float*)d_ws;
        float* h   = wsf;
        float* hn  = wsf + BSH;
        float* q   = wsf + 2 * BSH;
        float* k   = wsf + 3 * BSH;
        float* v   = wsf + 4 * BSH;
        float* o   = wsf + 5 * BSH;
        float* f1  = wsf + 6 * BSH;
        float* zbuf  = q;
        float* esoft = v;
        float* ceab  = o;
        int* meta   = (int*)(wsf + 6 * BSH + BSF);
        int* chosen = meta;
        int* order  = meta + BS;
        int* cpos   = meta + 2 * BS;
        int* cvalid = meta + 3 * BS;
        int* counts = meta + 4 * BS;
        int* pos_sh = meta + 5 * BS;
        float* partial = (float*)(meta + 6 * BS);

        embed_k<<<BS, 256, 0, stream>>>(ids, embed, h);
        iota_k<<<16, 256, 0, stream>>>(pos_sh);
        for (int L = 0; L < 2; ++L)
            run_block_f32(L, ln1, wq, wk, wv, wo, ln2, wg, wu, wd,
                          h, hn, q, k, v, o, f1, amask, pos_sh, stream);
        gemm_k<<<dim3(33, 64), 256, 0, stream>>>(h, head_w, head_b, f1, BS, CV1, H, H, CV1, CV1, F_BIAS);
        discretize_k<<<BS, 256, 0, stream>>>(f1, gumbel, zbuf, chosen);
        gemm_k<<<dim3(16, 64), 256, 0, stream>>>(zbuf, cemb, nullptr, esoft, BS, H, CV, CV, H, H, 0);
        cea_k<<<BS, 256, 0, stream>>>(esoft, cemb, chosen, amask, ceab, partial);
        loss_k<<<1, 256, 0, stream>>>(partial, out + BSH);
        pack_k<<<B, 64, 0, stream>>>(chosen, amask, order, cpos, cvalid, counts);
        gather_k<<<BS, 256, 0, stream>>>(ceab, order, cvalid, h);
        for (int L = 2; L < 4; ++L)
            run_block_f32(L, ln1, wq, wk, wv, wo, ln2, wg, wu, wd,
                          h, hn, q, k, v, o, f1, cvalid, cpos, stream);
        outmask_k<<<BS, 256, 0, stream>>>(h, cvalid, out);
    }
}

// Round 4
// 5615.690 us; speedup vs baseline: 6.3657x; 1.6840x over previous
//
#include <hip/hip_runtime.h>
#include <hip/hip_bf16.h>
#include <cmath>

#define B 4
#define S 1024
#define H 1024
#define NH 16
#define HD 64
#define FF 4096
#define CV 2048
#define CV1 2049
#define BS (B*S)            // 4096
#define BSH ((size_t)BS*H)  // 4194304
#define BSF ((size_t)BS*FF) // 16777216

#define F_BIAS  1
#define F_RESID 2
#define F_SILU  4
#define F_MULIN 8

typedef __attribute__((ext_vector_type(8))) short s16x8;
typedef __attribute__((ext_vector_type(4))) float f32x4;

static __device__ inline short bf_of(float v) {
    __hip_bfloat16 h = __float2bfloat16(v);
    return *reinterpret_cast<short*>(&h);
}
static __device__ inline float f_of(short s) {
    __hip_bfloat16 h = *reinterpret_cast<__hip_bfloat16*>(&s);
    return __bfloat162float(h);
}
static __device__ inline void split_store(float v, short* p, size_t plane, size_t idx, int np) {
    short b0 = bf_of(v); p[idx] = b0;
    if (np == 3) {
        float r1 = v - f_of(b0);
        short b1 = bf_of(r1); p[plane + idx] = b1;
        p[2 * plane + idx] = bf_of(r1 - f_of(b1));
    }
}

// ============ MFMA GEMM: C[M,N] = (resid?) + sum_passes A_p[M,K] @ Wt_p[N,K]^T ============
__global__ __launch_bounds__(256) void gemm_mf_k(
    const short* __restrict__ A, const short* __restrict__ Wt,
    float* __restrict__ C, const float* __restrict__ resid,
    int M, int N, int K, size_t planeA, size_t planeW, int npass)
{
    __shared__ short As[128 * 32];
    __shared__ short Bs[128 * 32];
    const int tid = threadIdx.x;
    const int w = tid >> 6, l = tid & 63;
    const int wm = w >> 1, wn = w & 1;
    const int row0 = blockIdx.y * 128, col0 = blockIdx.x * 128;
    const int PAt[6] = {0, 0, 1, 0, 1, 2};
    const int PWt[6] = {0, 1, 0, 2, 1, 0};

    f32x4 acc[4][4];
    #pragma unroll
    for (int i = 0; i < 4; ++i)
        #pragma unroll
        for (int j = 0; j < 4; ++j)
            #pragma unroll
            for (int r = 0; r < 4; ++r) acc[i][j][r] = 0.f;

    const int lr = l & 15, q = l >> 4;
    for (int p = 0; p < npass; ++p) {
        const short* Ap = A + (size_t)PAt[p] * planeA;
        const short* Wp = Wt + (size_t)PWt[p] * planeW;
        for (int k0 = 0; k0 < K; k0 += 32) {
            __syncthreads();
            #pragma unroll
            for (int s = 0; s < 2; ++s) {
                int e = s * 256 + tid;
                int r = e >> 2, cq = e & 3;
                int sw = cq ^ ((r >> 1) & 3);
                s16x8 va = *(const s16x8*)(Ap + (size_t)(row0 + r) * K + k0 + cq * 8);
                *(s16x8*)&As[r * 32 + sw * 8] = va;
                s16x8 vb = *(const s16x8*)(Wp + (size_t)(col0 + r) * K + k0 + cq * 8);
                *(s16x8*)&Bs[r * 32 + sw * 8] = vb;
            }
            __syncthreads();
            s16x8 af[4], bfv[4];
            #pragma unroll
            for (int i = 0; i < 4; ++i) {
                int ra = wm * 64 + i * 16 + lr;
                af[i] = *(const s16x8*)&As[ra * 32 + (q ^ ((ra >> 1) & 3)) * 8];
                int rb = wn * 64 + i * 16 + lr;
                bfv[i] = *(const s16x8*)&Bs[rb * 32 + (q ^ ((rb >> 1) & 3)) * 8];
            }
            #pragma unroll
            for (int mi = 0; mi < 4; ++mi)
                #pragma unroll
                for (int ni = 0; ni < 4; ++ni)
                    acc[mi][ni] = __builtin_amdgcn_mfma_f32_16x16x32_bf16(
                        af[mi], bfv[ni], acc[mi][ni], 0, 0, 0);
        }
    }
    const int cw = l & 15, rw = (l >> 4) * 4;
    #pragma unroll
    for (int mi = 0; mi < 4; ++mi)
        #pragma unroll
        for (int ni = 0; ni < 4; ++ni)
            #pragma unroll
            for (int r = 0; r < 4; ++r) {
                int gr = row0 + wm * 64 + mi * 16 + rw + r;
                int gc = col0 + wn * 64 + ni * 16 + cw;
                size_t ci = (size_t)gr * N + gc;
                float val = acc[mi][ni][r];
                if (resid) val += resid[ci];
                C[ci] = val;
            }
}

// ============ Fused gate-up ============
__global__ __launch_bounds__(256) void gateup_k(
    const short* __restrict__ A, const short* __restrict__ Wg, const short* __restrict__ Wu,
    short* __restrict__ F, int M, int N, int K,
    size_t planeA, size_t planeW, size_t planeF, int npass, int npOut)
{
    __shared__ short As[128 * 32];
    __shared__ short Bg[128 * 32];
    __shared__ short Bu[128 * 32];
    const int tid = threadIdx.x;
    const int w = tid >> 6, l = tid & 63;
    const int wm = w >> 1, wn = w & 1;
    const int row0 = blockIdx.y * 128, col0 = blockIdx.x * 128;
    const int PAt[6] = {0, 0, 1, 0, 1, 2};
    const int PWt[6] = {0, 1, 0, 2, 1, 0};

    f32x4 accg[4][4], accu[4][4];
    #pragma unroll
    for (int i = 0; i < 4; ++i)
        #pragma unroll
        for (int j = 0; j < 4; ++j)
            #pragma unroll
            for (int r = 0; r < 4; ++r) { accg[i][j][r] = 0.f; accu[i][j][r] = 0.f; }

    const int lr = l & 15, q = l >> 4;
    for (int p = 0; p < npass; ++p) {
        const short* Ap = A + (size_t)PAt[p] * planeA;
        const short* Wgp = Wg + (size_t)PWt[p] * planeW;
        const short* Wup = Wu + (size_t)PWt[p] * planeW;
        for (int k0 = 0; k0 < K; k0 += 32) {
            __syncthreads();
            #pragma unroll
            for (int s = 0; s < 2; ++s) {
                int e = s * 256 + tid;
                int r = e >> 2, cq = e & 3;
                int sw = cq ^ ((r >> 1) & 3);
                s16x8 va = *(const s16x8*)(Ap + (size_t)(row0 + r) * K + k0 + cq * 8);
                *(s16x8*)&As[r * 32 + sw * 8] = va;
                s16x8 vg = *(const s16x8*)(Wgp + (size_t)(col0 + r) * K + k0 + cq * 8);
                *(s16x8*)&Bg[r * 32 + sw * 8] = vg;
                s16x8 vu = *(const s16x8*)(Wup + (size_t)(col0 + r) * K + k0 + cq * 8);
                *(s16x8*)&Bu[r * 32 + sw * 8] = vu;
            }
            __syncthreads();
            s16x8 af[4], bg[4], bu[4];
            #pragma unroll
            for (int i = 0; i < 4; ++i) {
                int ra = wm * 64 + i * 16 + lr;
                af[i] = *(const s16x8*)&As[ra * 32 + (q ^ ((ra >> 1) & 3)) * 8];
                int rb = wn * 64 + i * 16 + lr;
                int sb = (q ^ ((rb >> 1) & 3)) * 8;
                bg[i] = *(const s16x8*)&Bg[rb * 32 + sb];
                bu[i] = *(const s16x8*)&Bu[rb * 32 + sb];
            }
            #pragma unroll
            for (int mi = 0; mi < 4; ++mi)
                #pragma unroll
                for (int ni = 0; ni < 4; ++ni) {
                    accg[mi][ni] = __builtin_amdgcn_mfma_f32_16x16x32_bf16(
                        af[mi], bg[ni], accg[mi][ni], 0, 0, 0);
                    accu[mi][ni] = __builtin_amdgcn_mfma_f32_16x16x32_bf16(
                        af[mi], bu[ni], accu[mi][ni], 0, 0, 0);
                }
        }
    }
    const int cw = l & 15, rw = (l >> 4) * 4;
    #pragma unroll
    for (int mi = 0; mi < 4; ++mi)
        #pragma unroll
        for (int ni = 0; ni < 4; ++ni)
            #pragma unroll
            for (int r = 0; r < 4; ++r) {
                int gr = row0 + wm * 64 + mi * 16 + rw + r;
                int gc = col0 + wn * 64 + ni * 16 + cw;
                float g = accg[mi][ni][r], u = accu[mi][ni][r];
                float val = g / (1.f + expf(-g)) * u;
                split_store(val, F, planeF, (size_t)gr * N + gc, npOut);
            }
}

// ============ MFMA flash attention ============
// Block = (64-row q-tile, head, batch); 4 waves x 16 q-rows.
// NP bf16 planes, NPROD split-products (3/6 shallow = ~2^-24 error; 1/1 mid).
// Visits ALL k-tiles so fully-masked rows reproduce reference uniform softmax.
template<int NP, int NPROD>
__global__ __launch_bounds__(256) void mfattn_k(
    const short* __restrict__ qsp, const short* __restrict__ ksp,
    const short* __restrict__ vtp, float* __restrict__ o,
    const int* __restrict__ valid)
{
    __shared__ short KP[NP][2][64 * 32];   // K tile [kcol][d] swizzled; reused as P planes
    __shared__ short Vt[NP][2][64 * 32];   // V^T tile [d][kcol] swizzled
    __shared__ int kvs[64];
    const int tid = threadIdx.x;
    const int w = tid >> 6, l = tid & 63;
    const int lr = l & 15, lq = l >> 4;
    const int qt = blockIdx.x, hh = blockIdx.y, b = blockIdx.z;
    const int PAt[6] = {0, 0, 1, 0, 1, 2};
    const int PWt[6] = {0, 1, 0, 2, 1, 0};

    // Q a-fragments in registers (a-frag row = lane&15)
    s16x8 aq[NP][2];
    {
        const int qrowa = qt * 64 + w * 16 + lr;
        #pragma unroll
        for (int p = 0; p < NP; ++p)
            #pragma unroll
            for (int ks = 0; ks < 2; ++ks)
                aq[p][ks] = *(const s16x8*)(qsp + (size_t)p * BSH
                    + (size_t)(b * S + qrowa) * H + hh * 64 + ks * 32 + lq * 8);
    }
    int qvr[4];
    #pragma unroll
    for (int r = 0; r < 4; ++r)
        qvr[r] = valid[b * S + qt * 64 + w * 16 + lq * 4 + r];

    float m[4], lsum[4];
    f32x4 acco[4];
    #pragma unroll
    for (int r = 0; r < 4; ++r) { m[r] = -3.4e38f; lsum[r] = 0.f; }
    #pragma unroll
    for (int n = 0; n < 4; ++n)
        #pragma unroll
        for (int r = 0; r < 4; ++r) acco[n][r] = 0.f;

    for (int kt = 0; kt < S / 64; ++kt) {
        __syncthreads();   // prior-tile KP(P)/Vt reads done
        {
            int r = tid >> 2, cq = tid & 3;
            int sw = cq ^ ((r >> 1) & 3);
            #pragma unroll
            for (int p = 0; p < NP; ++p)
                #pragma unroll
                for (int hf = 0; hf < 2; ++hf) {
                    *(s16x8*)&KP[p][hf][r * 32 + sw * 8] =
                        *(const s16x8*)(ksp + (size_t)p * BSH
                            + (size_t)(b * S + kt * 64 + r) * H + hh * 64 + hf * 32 + cq * 8);
                    *(s16x8*)&Vt[p][hf][r * 32 + sw * 8] =
                        *(const s16x8*)(vtp + (size_t)p * BSH
                            + ((size_t)(hh * 64 + r) * B + b) * S + kt * 64 + hf * 32 + cq * 8);
                }
        }
        if (tid < 64) kvs[tid] = valid[b * S + kt * 64 + tid];
        __syncthreads();

        // ---- S = Q @ K^T (k-dim = d) ----
        f32x4 accs[4];
        #pragma unroll
        for (int n = 0; n < 4; ++n)
            #pragma unroll
            for (int r = 0; r < 4; ++r) accs[n][r] = 0.f;
        #pragma unroll
        for (int pr = 0; pr < NPROD; ++pr) {
            const int pa = PAt[pr], pw = PWt[pr];
            #pragma unroll
            for (int ks = 0; ks < 2; ++ks)
                #pragma unroll
                for (int n = 0; n < 4; ++n) {
                    int rb = n * 16 + lr;
                    s16x8 bk = *(const s16x8*)&KP[pw][ks][rb * 32 + ((lq ^ ((rb >> 1) & 3))) * 8];
                    accs[n] = __builtin_amdgcn_mfma_f32_16x16x32_bf16(
                        aq[pa][ks], bk, accs[n], 0, 0, 0);
                }
        }
        // ---- mask + online softmax (D-frag: row=lq*4+r, col=n*16+lr) ----
        float pf[4][4];
        int kva[4];
        #pragma unroll
        for (int n = 0; n < 4; ++n) kva[n] = kvs[n * 16 + lr];
        #pragma unroll
        for (int r = 0; r < 4; ++r) {
            int qr = qt * 64 + w * 16 + lq * 4 + r;
            float rowm = -3.4e38f;
            #pragma unroll
            for (int n = 0; n < 4; ++n) {
                int kc = kt * 64 + n * 16 + lr;
                float sv = accs[n][r] * 0.125f;
                int allowed = (kc <= qr) && qvr[r] && kva[n];
                if (!allowed) sv = sv + -1e9f;
                pf[n][r] = sv;
                rowm = fmaxf(rowm, sv);
            }
            rowm = fmaxf(rowm, __shfl_xor(rowm, 1));
            rowm = fmaxf(rowm, __shfl_xor(rowm, 2));
            rowm = fmaxf(rowm, __shfl_xor(rowm, 4));
            rowm = fmaxf(rowm, __shfl_xor(rowm, 8));
            float mn = fmaxf(m[r], rowm);
            float co = __expf(m[r] - mn);
            float rs = 0.f;
            #pragma unroll
            for (int n = 0; n < 4; ++n) { pf[n][r] = __expf(pf[n][r] - mn); rs += pf[n][r]; }
            rs += __shfl_xor(rs, 1);
            rs += __shfl_xor(rs, 2);
            rs += __shfl_xor(rs, 4);
            rs += __shfl_xor(rs, 8);
            lsum[r] = lsum[r] * co + rs;
            m[r] = mn;
            #pragma unroll
            for (int n = 0; n < 4; ++n) acco[n][r] *= co;
        }
        __syncthreads();   // all QK^T reads of KP done -> safe to overwrite with P
        // ---- write P (bf16 split) into KP, swizzled for a-frag reads ----
        #pragma unroll
        for (int n = 0; n < 4; ++n) {
            int col = n * 16 + lr;
            int hf = col >> 5, colh = col & 31, cq2 = colh >> 3, pos = colh & 7;
            #pragma unroll
            for (int r = 0; r < 4; ++r) {
                int rowg = w * 16 + lq * 4 + r;
                int off = rowg * 32 + (cq2 ^ ((rowg >> 1) & 3)) * 8 + pos;
                float pv = pf[n][r];
                short b0 = bf_of(pv);
                KP[0][hf][off] = b0;
                if (NP == 3) {
                    float r1 = pv - f_of(b0);
                    short b1 = bf_of(r1);
                    KP[1][hf][off] = b1;
                    KP[2][hf][off] = bf_of(r1 - f_of(b1));
                }
            }
        }
        __syncthreads();
        // ---- O += P @ V (k-dim = kcol) ----
        #pragma unroll
        for (int pr = 0; pr < NPROD; ++pr) {
            const int pa = PAt[pr], pw = PWt[pr];
            #pragma unroll
            for (int ks = 0; ks < 2; ++ks) {
                int ra = w * 16 + lr;
                s16x8 ap = *(const s16x8*)&KP[pa][ks][ra * 32 + ((lq ^ ((ra >> 1) & 3))) * 8];
                #pragma unroll
                for (int n = 0; n < 4; ++n) {
                    int rb = n * 16 + lr;
                    s16x8 bv = *(const s16x8*)&Vt[pw][ks][rb * 32 + ((lq ^ ((rb >> 1) & 3))) * 8];
                    acco[n] = __builtin_amdgcn_mfma_f32_16x16x32_bf16(
                        ap, bv, acco[n], 0, 0, 0);
                }
            }
        }
    }
    #pragma unroll
    for (int r = 0; r < 4; ++r) {
        float inv = 1.0f / lsum[r];
        int qr = qt * 64 + w * 16 + lq * 4 + r;
        #pragma unroll
        for (int n = 0; n < 4; ++n)
            o[(size_t)(b * S + qr) * H + hh * 64 + n * 16 + lr] = acco[n][r] * inv;
    }
}

// ============ RoPE + bf16 split (reads pre-rope fp32, writes split planes) ============
__global__ __launch_bounds__(256) void rope_split_k(const float* __restrict__ x,
    const int* __restrict__ pos, short* __restrict__ y, size_t plane, int np)
{
    int idx = blockIdx.x * 256 + threadIdx.x;
    int i = idx & 31;
    int head = (idx >> 5) & 15;
    int bs = idx >> 9;
    int p = pos[bs];
    double inv = exp(-((double)(2 * i) / 64.0) * log(10000.0));
    double ang = (double)p * inv;
    float c = (float)cos(ang), sn = (float)sin(ang);
    const float* base = x + (size_t)bs * H + head * 64;
    float x1 = base[i], x2 = base[i + 32];
    size_t o1 = (size_t)bs * H + head * 64 + i;
    split_store(x1 * c - x2 * sn, y, plane, o1, np);
    split_store(x2 * c + x1 * sn, y, plane, o1 + 32, np);
}

// ============ V transpose + split: V[B*S][H] f32 -> planes [(h*64+d)*B+b][S] bf16 ============
__global__ __launch_bounds__(256) void splitvt_k(const float* __restrict__ V,
    short* __restrict__ Vt, size_t plane, int np)
{
    __shared__ float t[32][33];
    const int tid = threadIdx.x;
    const int s0 = blockIdx.x * 32;
    const int hd0 = blockIdx.y * 32;
    const int b = blockIdx.z;
    #pragma unroll
    for (int i = 0; i < 4; ++i) {
        int e = tid + i * 256;
        int rr = e >> 5, cc = e & 31;
        t[rr][cc] = V[(size_t)(b * S + s0 + rr) * H + hd0 + cc];
    }
    __syncthreads();
    #pragma unroll
    for (int i = 0; i < 4; ++i) {
        int e = tid + i * 256;
        int rn = e >> 5, ck = e & 31;
        split_store(t[ck][rn], Vt, plane,
                    ((size_t)(hd0 + rn) * B + b) * S + s0 + ck, np);
    }
}

// ============ Weight transpose + bf16 split ============
__global__ __launch_bounds__(256) void splitwt_k(const float* __restrict__ W,
    short* __restrict__ Wt, int K, int N, size_t plane, int np)
{
    __shared__ float t[32][33];
    const int tid = threadIdx.x;
    const int n0 = blockIdx.x * 32, k0 = blockIdx.y * 32;
    #pragma unroll
    for (int i = 0; i < 4; ++i) {
        int e = tid + i * 256;
        int rk = e >> 5, cn = e & 31;
        t[rk][cn] = W[(size_t)(k0 + rk) * N + n0 + cn];
    }
    __syncthreads();
    #pragma unroll
    for (int i = 0; i < 4; ++i) {
        int e = tid + i * 256;
        int rn = e >> 5, ck = e & 31;
        split_store(t[ck][rn], Wt, plane, (size_t)(n0 + rn) * K + k0 + ck, np);
    }
}

// ============ Straight bf16 split ============
__global__ __launch_bounds__(256) void splita_k(const float* __restrict__ x,
    short* __restrict__ y, size_t n, size_t plane, int np)
{
    for (size_t i = blockIdx.x * 256 + threadIdx.x; i < n; i += (size_t)gridDim.x * 256)
        split_store(x[i], y, plane, i, np);
}

// ============ RMSNorm -> bf16 split ============
__global__ __launch_bounds__(256) void rmsnorm_split_k(const float* __restrict__ x,
    const float* __restrict__ w, short* __restrict__ y, size_t plane, int np)
{
    int row = blockIdx.x;
    const float* xr = x + (size_t)row * H;
    __shared__ float red[256];
    float s = 0.f;
    for (int i = threadIdx.x; i < H; i += 256) { float v = xr[i]; s += v * v; }
    red[threadIdx.x] = s; __syncthreads();
    for (int off = 128; off > 0; off >>= 1) {
        if (threadIdx.x < off) red[threadIdx.x] += red[threadIdx.x + off];
        __syncthreads();
    }
    float r = 1.0f / sqrtf(red[0] / (float)H + 1e-6f);
    for (int i = threadIdx.x; i < H; i += 256)
        split_store(xr[i] * r * w[i], y, plane, (size_t)row * H + i, np);
}

// ---------------- fp32 GEMM (head logits + fallback) ----------------
__global__ __launch_bounds__(256) void gemm_k(
    const float* __restrict__ A, const float* __restrict__ Wm,
    const float* __restrict__ bias, float* __restrict__ C,
    int M, int N, int K, int lda, int ldb, int ldc, int flags)
{
    __shared__ float As[16][65];
    __shared__ float Bs[16][65];
    const int tid = threadIdx.x;
    const int tx = tid & 15, ty = tid >> 4;
    const int row0 = blockIdx.y * 64, col0 = blockIdx.x * 64;
    float acc[4][4] = {};
    for (int k0 = 0; k0 < K; k0 += 16) {
        #pragma unroll
        for (int l = 0; l < 4; ++l) {
            int e = tid + l * 256;
            int r = e >> 4, c = e & 15;
            int gr = row0 + r;
            float vv = 0.f;
            if (gr < M) vv = A[(size_t)gr * lda + (k0 + c)];
            As[c][r] = vv;
        }
        #pragma unroll
        for (int l = 0; l < 4; ++l) {
            int e = tid + l * 256;
            int r = e >> 6, c = e & 63;
            int gc = col0 + c;
            float vv = 0.f;
            if (gc < N) vv = Wm[(size_t)(k0 + r) * ldb + gc];
            Bs[r][c] = vv;
        }
        __syncthreads();
        #pragma unroll
        for (int kk = 0; kk < 16; ++kk) {
            float a[4], bb[4];
            #pragma unroll
            for (int i = 0; i < 4; ++i) a[i] = As[kk][ty * 4 + i];
            #pragma unroll
            for (int j = 0; j < 4; ++j) bb[j] = Bs[kk][tx * 4 + j];
            #pragma unroll
            for (int i = 0; i < 4; ++i)
                #pragma unroll
                for (int j = 0; j < 4; ++j)
                    acc[i][j] += a[i] * bb[j];
        }
        __syncthreads();
    }
    #pragma unroll
    for (int i = 0; i < 4; ++i) {
        int gr = row0 + ty * 4 + i;
        if (gr >= M) continue;
        #pragma unroll
        for (int j = 0; j < 4; ++j) {
            int gc = col0 + tx * 4 + j;
            if (gc >= N) continue;
            float vv = acc[i][j];
            if (flags & F_BIAS)  vv += bias[gc];
            if (flags & F_SILU)  vv = vv / (1.f + expf(-vv));
            size_t cidx = (size_t)gr * ldc + gc;
            if (flags & F_MULIN) vv *= C[cidx];
            if (flags & F_RESID) vv += C[cidx];
            C[cidx] = vv;
        }
    }
}

// ---------------- RMSNorm fp32 (fallback) ----------------
__global__ __launch_bounds__(256) void rmsnorm_k(const float* __restrict__ x,
    const float* __restrict__ w, float* __restrict__ y)
{
    int row = blockIdx.x;
    const float* xr = x + (size_t)row * H;
    float* yr = y + (size_t)row * H;
    __shared__ float red[256];
    float s = 0.f;
    for (int i = threadIdx.x; i < H; i += 256) { float v = xr[i]; s += v * v; }
    red[threadIdx.x] = s; __syncthreads();
    for (int off = 128; off > 0; off >>= 1) {
        if (threadIdx.x < off) red[threadIdx.x] += red[threadIdx.x + off];
        __syncthreads();
    }
    float r = 1.0f / sqrtf(red[0] / (float)H + 1e-6f);
    for (int i = threadIdx.x; i < H; i += 256) yr[i] = xr[i] * r * w[i];
}

// ---------------- Embed gather ----------------
__global__ __launch_bounds__(256) void embed_k(const int* __restrict__ ids,
    const float* __restrict__ emb, float* __restrict__ h)
{
    int bs = blockIdx.x;
    const float* e = emb + (size_t)ids[bs] * H;
    float* hr = h + (size_t)bs * H;
    for (int i = threadIdx.x; i < H; i += 256) hr[i] = e[i];
}

// ---------------- RoPE fp32 in-place (fallback) ----------------
__global__ __launch_bounds__(256) void rope_k(float* __restrict__ x, const int* __restrict__ pos)
{
    int idx = blockIdx.x * 256 + threadIdx.x;
    int i = idx & 31;
    int head = (idx >> 5) & 15;
    int bs = idx >> 9;
    int p = pos[bs];
    double inv = exp(-((double)(2 * i) / 64.0) * log(10000.0));
    double ang = (double)p * inv;
    float c = (float)cos(ang), sn = (float)sin(ang);
    float* base = x + (size_t)bs * H + head * 64;
    float x1 = base[i], x2 = base[i + 32];
    base[i]      = x1 * c - x2 * sn;
    base[i + 32] = x2 * c + x1 * sn;
}

// ---------------- Flash attention fp32 (fallback) ----------------
__global__ __launch_bounds__(256) void fattn_k(const float* __restrict__ q,
    const float* __restrict__ k, const float* __restrict__ v,
    float* __restrict__ o, const int* __restrict__ valid)
{
    const int qt = blockIdx.x, hh = blockIdx.y, b = blockIdx.z;
    const int tid = threadIdx.x;
    const int tx = tid & 15, ty = tid >> 4;
    __shared__ float Qs[64][68];
    __shared__ float Ks[64][68];
    __shared__ float Vs[64][68];
    __shared__ int   kvs[64];
    const size_t hoff = (size_t)hh * HD;

    {
        int row = tid >> 2, d0 = (tid & 3) * 16;
        const float* qp = q + ((size_t)(b * S + qt * 64 + row)) * H + hoff + d0;
        float4* dst = (float4*)&Qs[row][d0];
        const float4* src = (const float4*)qp;
        #pragma unroll
        for (int e = 0; e < 4; ++e) dst[e] = src[e];
    }
    int qv[4]; int qrow_g[4];
    #pragma unroll
    for (int i = 0; i < 4; ++i) {
        qrow_g[i] = qt * 64 + ty * 4 + i;
        qv[i] = valid[b * S + qrow_g[i]];
    }
    float m[4], l[4], acc[4][4];
    #pragma unroll
    for (int i = 0; i < 4; ++i) {
        m[i] = -3.4e38f; l[i] = 0.f;
        #pragma unroll
        for (int j = 0; j < 4; ++j) acc[i][j] = 0.f;
    }

    for (int kt = 0; kt < S / 64; ++kt) {
        __syncthreads();
        {
            int row = tid >> 2, d0 = (tid & 3) * 16;
            const float* kp = k + ((size_t)(b * S + kt * 64 + row)) * H + hoff + d0;
            float4* dst = (float4*)&Ks[row][d0];
            const float4* src = (const float4*)kp;
            #pragma unroll
            for (int e = 0; e < 4; ++e) dst[e] = src[e];
        }
        {
            int kk = tid >> 2, d0 = (tid & 3) * 16;
            const float* vp = v + ((size_t)(b * S + kt * 64 + kk)) * H + hoff + d0;
            #pragma unroll
            for (int e = 0; e < 16; e += 4) {
                float4 vv = *(const float4*)(vp + e);
                Vs[d0 + e + 0][kk] = vv.x;
                Vs[d0 + e + 1][kk] = vv.y;
                Vs[d0 + e + 2][kk] = vv.z;
                Vs[d0 + e + 3][kk] = vv.w;
            }
        }
        if (tid < 64) kvs[tid] = valid[b * S + kt * 64 + tid];
        __syncthreads();

        float s4[4][4];
        #pragma unroll
        for (int i = 0; i < 4; ++i)
            #pragma unroll
            for (int j = 0; j < 4; ++j) s4[i][j] = 0.f;
        #pragma unroll
        for (int c = 0; c < 16; ++c) {
            float4 a[4], bb[4];
            #pragma unroll
            for (int i = 0; i < 4; ++i) a[i]  = ((const float4*)&Qs[ty * 4 + i][0])[c];
            #pragma unroll
            for (int j = 0; j < 4; ++j) bb[j] = ((const float4*)&Ks[tx * 4 + j][0])[c];
            #pragma unroll
            for (int i = 0; i < 4; ++i)
                #pragma unroll
                for (int j = 0; j < 4; ++j) {
                    s4[i][j] += a[i].x * bb[j].x + a[i].y * bb[j].y
                              + a[i].z * bb[j].z + a[i].w * bb[j].w;
                }
        }
        float p[4][4];
        float corr[4];
        #pragma unroll
        for (int i = 0; i < 4; ++i) {
            float rm = -3.4e38f;
            #pragma unroll
            for (int j = 0; j < 4; ++j) {
                int kc = kt * 64 + tx * 4 + j;
                float sv = s4[i][j] * 0.125f;
                int allowed = (kc <= qrow_g[i]) && qv[i] && kvs[tx * 4 + j];
                if (!allowed) sv = sv + -1e9f;
                s4[i][j] = sv;
                rm = fmaxf(rm, sv);
            }
            rm = fmaxf(rm, __shfl_xor(rm, 1));
            rm = fmaxf(rm, __shfl_xor(rm, 2));
            rm = fmaxf(rm, __shfl_xor(rm, 4));
            rm = fmaxf(rm, __shfl_xor(rm, 8));
            float mn = fmaxf(m[i], rm);
            corr[i] = expf(m[i] - mn);
            float rs = 0.f;
            #pragma unroll
            for (int j = 0; j < 4; ++j) { p[i][j] = expf(s4[i][j] - mn); rs += p[i][j]; }
            rs += __shfl_xor(rs, 1);
            rs += __shfl_xor(rs, 2);
            rs += __shfl_xor(rs, 4);
            rs += __shfl_xor(rs, 8);
            l[i] = l[i] * corr[i] + rs;
            m[i] = mn;
            #pragma unroll
            for (int j = 0; j < 4; ++j) acc[i][j] *= corr[i];
        }
        __syncthreads();
        #pragma unroll
        for (int i = 0; i < 4; ++i) {
            float4 pv4 = make_float4(p[i][0], p[i][1], p[i][2], p[i][3]);
            *(float4*)&Ks[ty * 4 + i][tx * 4] = pv4;
        }
        __syncthreads();
        #pragma unroll
        for (int c = 0; c < 16; ++c) {
            float4 a[4], bb[4];
            #pragma unroll
            for (int i = 0; i < 4; ++i) a[i]  = ((const float4*)&Ks[ty * 4 + i][0])[c];
            #pragma unroll
            for (int j = 0; j < 4; ++j) bb[j] = ((const float4*)&Vs[tx * 4 + j][0])[c];
            #pragma unroll
            for (int i = 0; i < 4; ++i)
                #pragma unroll
                for (int j = 0; j < 4; ++j) {
                    acc[i][j] += a[i].x * bb[j].x + a[i].y * bb[j].y
                               + a[i].z * bb[j].z + a[i].w * bb[j].w;
                }
        }
    }
    #pragma unroll
    for (int i = 0; i < 4; ++i) {
        float inv = 1.0f / l[i];
        float4 ov = make_float4(acc[i][0] * inv, acc[i][1] * inv,
                                acc[i][2] * inv, acc[i][3] * inv);
        *(float4*)(o + ((size_t)(b * S + qrow_g[i])) * H + hoff + tx * 4) = ov;
    }
}

// ---------------- Discretize ----------------
__global__ __launch_bounds__(256) void discretize_bf_k(const float* __restrict__ logits,
    const float* __restrict__ gumbel, short* __restrict__ z, int* __restrict__ chosen)
{
    int bs = blockIdx.x;
    const float* lg = logits + (size_t)bs * CV1;
    const float* gm = gumbel + (size_t)bs * CV1;
    __shared__ float redv[256]; __shared__ int redi[256];
    int tid = threadIdx.x;
    float m = -3.4e38f; int mi = CV1;
    for (int j = tid; j < CV1; j += 256) {
        float a = lg[j] + gm[j];
        if (a > m) { m = a; mi = j; }
    }
    redv[tid] = m; redi[tid] = mi; __syncthreads();
    for (int off = 128; off > 0; off >>= 1) {
        if (tid < off) {
            float vo = redv[tid + off]; int io = redi[tid + off];
            if (vo > redv[tid] || (vo == redv[tid] && io < redi[tid])) { redv[tid] = vo; redi[tid] = io; }
        }
        __syncthreads();
    }
    m = redv[0]; int amax = redi[0];
    __syncthreads();
    float ssum = 0.f;
    for (int j = tid; j < CV1; j += 256) ssum += expf(lg[j] + gm[j] - m);
    redv[tid] = ssum; __syncthreads();
    for (int off = 128; off > 0; off >>= 1) {
        if (tid < off) redv[tid] += redv[tid + off];
        __syncthreads();
    }
    float inv = 1.0f / redv[0];
    for (int j = tid; j < CV; j += 256)
        z[(size_t)bs * CV + j] = bf_of(expf(lg[j] + gm[j] - m) * inv);
    if (tid == 0) chosen[bs] = amax;
}

__global__ __launch_bounds__(256) void discretize_k(const float* __restrict__ logits,
    const float* __restrict__ gumbel, float* __restrict__ z, int* __restrict__ chosen)
{
    int bs = blockIdx.x;
    const float* lg = logits + (size_t)bs * CV1;
    const float* gm = gumbel + (size_t)bs * CV1;
    __shared__ float redv[256]; __shared__ int redi[256];
    int tid = threadIdx.x;
    float m = -3.4e38f; int mi = CV1;
    for (int j = tid; j < CV1; j += 256) {
        float a = lg[j] + gm[j];
        if (a > m) { m = a; mi = j; }
    }
    redv[tid] = m; redi[tid] = mi; __syncthreads();
    for (int off = 128; off > 0; off >>= 1) {
        if (tid < off) {
            float vo = redv[tid + off]; int io = redi[tid + off];
            if (vo > redv[tid] || (vo == redv[tid] && io < redi[tid])) { redv[tid] = vo; redi[tid] = io; }
        }
        __syncthreads();
    }
    m = redv[0]; int amax = redi[0];
    __syncthreads();
    float ssum = 0.f;
    for (int j = tid; j < CV1; j += 256) ssum += expf(lg[j] + gm[j] - m);
    redv[tid] = ssum; __syncthreads();
    for (int off = 128; off > 0; off >>= 1) {
        if (tid < off) redv[tid] += redv[tid + off];
        __syncthreads();
    }
    float inv = 1.0f / redv[0];
    for (int j = tid; j < CV; j += 256)
        z[(size_t)bs * CV + j] = expf(lg[j] + gm[j] - m) * inv;
    if (tid == 0) chosen[bs] = amax;
}

// ---------------- cea + loss ----------------
__global__ __launch_bounds__(256) void cea_k(const float* __restrict__ esoft,
    const float* __restrict__ cemb, const int* __restrict__ chosen,
    const int* __restrict__ amask, float* __restrict__ cea, float* __restrict__ partial)
{
    int bs = blockIdx.x;
    int ch = chosen[bs]; int vm = amask[bs];
    int comp = (ch != CV) && vm;
    const float* ehr = cemb + (size_t)(ch < CV - 1 ? ch : CV - 1) * H;
    __shared__ float red[256];
    float part = 0.f;
    float vmf = vm ? 1.f : 0.f;
    for (int i = threadIdx.x; i < H; i += 256) {
        float es = esoft[(size_t)bs * H + i];
        float eh = comp ? ehr[i] : 0.f;
        cea[(size_t)bs * H + i] = ((eh + es) - es) * vmf;
        float d = es - eh;
        part += d * d;
    }
    red[threadIdx.x] = part; __syncthreads();
    for (int off = 128; off > 0; off >>= 1) {
        if (threadIdx.x < off) red[threadIdx.x] += red[threadIdx.x + off];
        __syncthreads();
    }
    if (threadIdx.x == 0) partial[bs] = red[0];
}

__global__ __launch_bounds__(256) void loss_k(const float* __restrict__ partial, float* __restrict__ out)
{
    __shared__ float red[256];
    float s = 0.f;
    for (int i = threadIdx.x; i < BS; i += 256) s += partial[i];
    red[threadIdx.x] = s; __syncthreads();
    for (int off = 128; off > 0; off >>= 1) {
        if (threadIdx.x < off) red[threadIdx.x] += red[threadIdx.x + off];
        __syncthreads();
    }
    if (threadIdx.x == 0) out[0] = 1.25f * red[0] / (float)BSH;
}

// ---------------- Stable pack ----------------
__global__ void pack_k(const int* __restrict__ chosen, const int* __restrict__ amask,
    int* __restrict__ order, int* __restrict__ cpos, int* __restrict__ cvalid,
    int* __restrict__ counts)
{
    int b = blockIdx.x;
    if (threadIdx.x != 0) return;
    int cnt = 0;
    for (int s2 = 0; s2 < S; ++s2)
        if (chosen[b * S + s2] != CV && amask[b * S + s2]) order[b * S + cnt++] = s2;
    counts[b] = cnt;
    int j2 = cnt;
    for (int s2 = 0; s2 < S; ++s2)
        if (!(chosen[b * S + s2] != CV && amask[b * S + s2])) order[b * S + j2++] = s2;
    for (int j3 = 0; j3 < S; ++j3) {
        cvalid[b * S + j3] = (j3 < cnt) ? 1 : 0;
        cpos[b * S + j3]   = (j3 < cnt) ? order[b * S + j3] : 0;
    }
}

__global__ __launch_bounds__(256) void gather_k(const float* __restrict__ cea,
    const int* __restrict__ order, const int* __restrict__ cvalid, float* __restrict__ h)
{
    int bs = blockIdx.x;
    int b = bs >> 10;
    int src = order[bs];
    float f = cvalid[bs] ? 1.f : 0.f;
    const float* sp = cea + (size_t)(b * S + src) * H;
    float* dst = h + (size_t)bs * H;
    for (int i = threadIdx.x; i < H; i += 256) dst[i] = sp[i] * f;
}

__global__ __launch_bounds__(256) void outmask_k(const float* __restrict__ h,
    const int* __restrict__ cvalid, float* __restrict__ out)
{
    int bs = blockIdx.x;
    float f = cvalid[bs] ? 1.f : 0.f;
    for (int i = threadIdx.x; i < H; i += 256)
        out[(size_t)bs * H + i] = h[(size_t)bs * H + i] * f;
}

__global__ __launch_bounds__(256) void iota_k(int* __restrict__ pos)
{
    int idx = blockIdx.x * 256 + threadIdx.x;
    if (idx < BS) pos[idx] = idx & (S - 1);
}

// ================= Host-side drivers =================
static void run_block_f32(int layer,
    const float* ln1, const float* wq, const float* wk, const float* wv,
    const float* wo, const float* ln2, const float* wg, const float* wu, const float* wd,
    float* h, float* hn, float* q, float* k, float* v, float* o, float* f1,
    const int* valid, const int* pos, hipStream_t stream)
{
    size_t LHH = (size_t)layer * H * H;
    size_t LHF = (size_t)layer * H * FF;
    rmsnorm_k<<<BS, 256, 0, stream>>>(h, ln1 + (size_t)layer * H, hn);
    gemm_k<<<dim3(16, 64), 256, 0, stream>>>(hn, wq + LHH, nullptr, q, BS, H, H, H, H, H, 0);
    gemm_k<<<dim3(16, 64), 256, 0, stream>>>(hn, wk + LHH, nullptr, k, BS, H, H, H, H, H, 0);
    gemm_k<<<dim3(16, 64), 256, 0, stream>>>(hn, wv + LHH, nullptr, v, BS, H, H, H, H, H, 0);
    rope_k<<<8192, 256, 0, stream>>>(q, pos);
    rope_k<<<8192, 256, 0, stream>>>(k, pos);
    fattn_k<<<dim3(S / 64, NH, B), 256, 0, stream>>>(q, k, v, o, valid);
    gemm_k<<<dim3(16, 64), 256, 0, stream>>>(o, wo + LHH, nullptr, h, BS, H, H, H, H, H, F_RESID);
    rmsnorm_k<<<BS, 256, 0, stream>>>(h, ln2 + (size_t)layer * H, hn);
    gemm_k<<<dim3(64, 64), 256, 0, stream>>>(hn, wg + LHF, nullptr, f1, BS, FF, H, H, FF, FF, F_SILU);
    gemm_k<<<dim3(64, 64), 256, 0, stream>>>(hn, wu + LHF, nullptr, f1, BS, FF, H, H, FF, FF, F_MULIN);
    gemm_k<<<dim3(16, 64), 256, 0, stream>>>(f1, wd + (size_t)layer * FF * H, nullptr, h, BS, H, FF, FF, H, H, F_RESID);
}

static void run_block_mf(int layer, int np, int npass,
    const float* ln1, const float* wq, const float* wk, const float* wv,
    const float* wo, const float* ln2, const float* wg, const float* wu, const float* wd,
    float* h, float* q, float* k, float* v, float* o,
    short* hnsp, short* osp, short* wsp, short* wsp2, short* f1sp,
    short* qsp, short* ksp, short* vtp,
    const int* valid, const int* pos, hipStream_t stream)
{
    const size_t PH = (size_t)H * H;
    const size_t PGU = (size_t)H * FF;
    const size_t PA = BSH;
    const size_t PF = BSF;
    size_t LHH = (size_t)layer * H * H;
    size_t LHF = (size_t)layer * H * FF;
    dim3 gw32(H / 32, H / 32);

    rmsnorm_split_k<<<BS, 256, 0, stream>>>(h, ln1 + (size_t)layer * H, hnsp, PA, np);
    splitwt_k<<<gw32, 256, 0, stream>>>(wq + LHH, wsp, H, H, PH, np);
    gemm_mf_k<<<dim3(H / 128, BS / 128), 256, 0, stream>>>(hnsp, wsp, q, nullptr, BS, H, H, PA, PH, npass);
    splitwt_k<<<gw32, 256, 0, stream>>>(wk + LHH, wsp, H, H, PH, np);
    gemm_mf_k<<<dim3(H / 128, BS / 128), 256, 0, stream>>>(hnsp, wsp, k, nullptr, BS, H, H, PA, PH, npass);
    splitwt_k<<<gw32, 256, 0, stream>>>(wv + LHH, wsp, H, H, PH, np);
    gemm_mf_k<<<dim3(H / 128, BS / 128), 256, 0, stream>>>(hnsp, wsp, v, nullptr, BS, H, H, PA, PH, npass);
    // bf16 attention operands
    rope_split_k<<<8192, 256, 0, stream>>>(q, pos, qsp, PA, np);
    rope_split_k<<<8192, 256, 0, stream>>>(k, pos, ksp, PA, np);
    splitvt_k<<<dim3(S / 32, H / 32, B), 256, 0, stream>>>(v, vtp, PA, np);
    if (np == 3)
        mfattn_k<3, 6><<<dim3(S / 64, NH, B), 256, 0, stream>>>(qsp, ksp, vtp, o, valid);
    else
        mfattn_k<1, 1><<<dim3(S / 64, NH, B), 256, 0, stream>>>(qsp, ksp, vtp, o, valid);
    splita_k<<<2048, 256, 0, stream>>>(o, osp, BSH, PA, np);
    splitwt_k<<<gw32, 256, 0, stream>>>(wo + LHH, wsp, H, H, PH, np);
    gemm_mf_k<<<dim3(H / 128, BS / 128), 256, 0, stream>>>(osp, wsp, h, h, BS, H, H, PA, PH, npass);
    rmsnorm_split_k<<<BS, 256, 0, stream>>>(h, ln2 + (size_t)layer * H, hnsp, PA, np);
    splitwt_k<<<dim3(FF / 32, H / 32), 256, 0, stream>>>(wg + LHF, wsp, H, FF, PGU, np);
    splitwt_k<<<dim3(FF / 32, H / 32), 256, 0, stream>>>(wu + LHF, wsp2, H, FF, PGU, np);
    gateup_k<<<dim3(FF / 128, BS / 128), 256, 0, stream>>>(hnsp, wsp, wsp2, f1sp, BS, FF, H, PA, PGU, PF, npass, np);
    splitwt_k<<<dim3(H / 32, FF / 32), 256, 0, stream>>>(wd + (size_t)layer * FF * H, wsp, FF, H, PGU, np);
    gemm_mf_k<<<dim3(H / 128, BS / 128), 256, 0, stream>>>(f1sp, wsp, h, h, BS, H, FF, PF, PGU, npass);
}

extern "C" void kernel_launch(void* const* d_in, const int* in_sizes, int n_in,
                              void* d_out, int out_size, void* d_ws, size_t ws_size,
                              hipStream_t stream)
{
    const int*   ids    = (const int*)d_in[0];
    const int*   amask  = (const int*)d_in[1];
    const float* embed  = (const float*)d_in[2];
    const float* ln1    = (const float*)d_in[3];
    const float* wq     = (const float*)d_in[4];
    const float* wk     = (const float*)d_in[5];
    const float* wv     = (const float*)d_in[6];
    const float* wo     = (const float*)d_in[7];
    const float* ln2    = (const float*)d_in[8];
    const float* wg     = (const float*)d_in[9];
    const float* wu     = (const float*)d_in[10];
    const float* wd     = (const float*)d_in[11];
    const float* head_w = (const float*)d_in[12];
    const float* head_b = (const float*)d_in[13];
    const float* cemb   = (const float*)d_in[14];
    const float* gumbel = (const float*)d_in[15];
    float* out = (float*)d_out;

    const size_t MB = 1ull << 20;
    const size_t NEED = 274 * MB;

    if (ws_size >= NEED) {
        // ===== MFMA path =====
        char* base = (char*)d_ws;
        float* h = (float*)base;                   // 16MB
        float* q = (float*)(base + 16 * MB);
        float* k = (float*)(base + 32 * MB);
        float* v = (float*)(base + 48 * MB);
        float* o = (float*)(base + 64 * MB);
        short* hnsp = (short*)(base + 80 * MB);    // 3 planes x 8MB
        short* osp  = (short*)(base + 104 * MB);
        short* wsp  = (short*)(base + 128 * MB);   // 24MB
        short* wsp2 = (short*)(base + 152 * MB);   // 24MB
        short* f1sp = (short*)(base + 176 * MB);   // 96MB (FFN intermediate)
        // attention operand planes alias the (then-dead) f1sp region:
        short* qsp  = (short*)(base + 176 * MB);   // 24MB
        short* ksp  = (short*)(base + 200 * MB);   // 24MB
        short* vtp  = (short*)(base + 224 * MB);   // 24MB
        int* meta   = (int*)(base + 272 * MB);
        int* chosen = meta;
        int* order  = meta + BS;
        int* cpos   = meta + 2 * BS;
        int* cvalid = meta + 3 * BS;
        int* counts = meta + 4 * BS;
        int* pos_sh = meta + 5 * BS;
        float* partial = (float*)(meta + 6 * BS);
        float* logits = q;
        short* zb = (short*)o;
        float* esoft = q;
        float* ceab = k;

        embed_k<<<BS, 256, 0, stream>>>(ids, embed, h);
        iota_k<<<16, 256, 0, stream>>>(pos_sh);

        for (int L = 0; L < 2; ++L)
            run_block_mf(L, 3, 6, ln1, wq, wk, wv, wo, ln2, wg, wu, wd,
                         h, q, k, v, o, hnsp, osp, wsp, wsp2, f1sp,
                         qsp, ksp, vtp, amask, pos_sh, stream);

        gemm_k<<<dim3(33, 64), 256, 0, stream>>>(h, head_w, head_b, logits, BS, CV1, H, H, CV1, CV1, F_BIAS);
        discretize_bf_k<<<BS, 256, 0, stream>>>(logits, gumbel, zb, chosen);

        splitwt_k<<<dim3(H / 32, CV / 32), 256, 0, stream>>>(cemb, wsp, CV, H, (size_t)CV * H, 1);
        gemm_mf_k<<<dim3(H / 128, BS / 128), 256, 0, stream>>>(zb, wsp, esoft, nullptr, BS, H, CV, (size_t)BS * CV, (size_t)CV * H, 1);

        cea_k<<<BS, 256, 0, stream>>>(esoft, cemb, chosen, amask, ceab, partial);
        loss_k<<<1, 256, 0, stream>>>(partial, out + BSH);
        pack_k<<<B, 64, 0, stream>>>(chosen, amask, order, cpos, cvalid, counts);
        gather_k<<<BS, 256, 0, stream>>>(ceab, order, cvalid, h);

        for (int L = 2; L < 4; ++L)
            run_block_mf(L, 1, 1, ln1, wq, wk, wv, wo, ln2, wg, wu, wd,
                         h, q, k, v, o, hnsp, osp, wsp, wsp2, f1sp,
                         qsp, ksp, vtp, cvalid, cpos, stream);

        outmask_k<<<BS, 256, 0, stream>>>(h, cvalid, out);
    } else {
        // ===== fallback: fp32 path =====
        float* wsf = (float*)d_ws;
        float* h   = wsf;
        float* hn  = wsf + BSH;
        float* q   = wsf + 2 * BSH;
        float* k   = wsf + 3 * BSH;
        float* v   = wsf + 4 * BSH;
        float* o   = wsf + 5 * BSH;
        float* f1  = wsf + 6 * BSH;
        float* zbuf  = q;
        float* esoft = v;
        float* ceab  = o;
        int* meta   = (int*)(wsf + 6 * BSH + BSF);
        int* chosen = meta;
        int* order  = meta + BS;
        int* cpos   = meta + 2 * BS;
        int* cvalid = meta + 3 * BS;
        int* counts = meta + 4 * BS;
        int* pos_sh = meta + 5 * BS;
        float* partial = (float*)(meta + 6 * BS);

        embed_k<<<BS, 256, 0, stream>>>(ids, embed, h);
        iota_k<<<16, 256, 0, stream>>>(pos_sh);
        for (int L = 0; L < 2; ++L)
            run_block_f32(L, ln1, wq, wk, wv, wo, ln2, wg, wu, wd,
                          h, hn, q, k, v, o, f1, amask, pos_sh, stream);
        gemm_k<<<dim3(33, 64), 256, 0, stream>>>(h, head_w, head_b, f1, BS, CV1, H, H, CV1, CV1, F_BIAS);
        discretize_k<<<BS, 256, 0, stream>>>(f1, gumbel, zbuf, chosen);
        gemm_k<<<dim3(16, 64), 256, 0, stream>>>(zbuf, cemb, nullptr, esoft, BS, H, CV, CV, H, H, 0);
        cea_k<<<BS, 256, 0, stream>>>(esoft, cemb, chosen, amask, ceab, partial);
        loss_k<<<1, 256, 0, stream>>>(partial, out + BSH);
        pack_k<<<B, 64, 0, stream>>>(chosen, amask, order, cpos, cvalid, counts);
        gather_k<<<BS, 256, 0, stream>>>(ceab, order, cvalid, h);
        for (int L = 2; L < 4; ++L)
            run_block_f32(L, ln1, wq, wk, wv, wo, ln2, wg, wu, wd,
                          h, hn, q, k, v, o, f1, cvalid, cpos, stream);
        outmask_k<<<BS, 256, 0, stream>>>(h, cvalid, out);
    }
}

// Round 5
// 5537.230 us; speedup vs baseline: 6.4559x; 1.0142x over previous
//
#include <hip/hip_runtime.h>
#include <hip/hip_bf16.h>
#include <cmath>

#define B 4
#define S 1024
#define H 1024
#define NH 16
#define HD 64
#define FF 4096
#define CV 2048
#define CV1 2049
#define BS (B*S)            // 4096
#define BSH ((size_t)BS*H)  // 4194304
#define BSF ((size_t)BS*FF) // 16777216

#define F_BIAS  1
#define F_RESID 2
#define F_SILU  4
#define F_MULIN 8

typedef __attribute__((ext_vector_type(8))) short s16x8;
typedef __attribute__((ext_vector_type(4))) float f32x4;

static __device__ inline short bf_of(float v) {
    __hip_bfloat16 h = __float2bfloat16(v);
    return *reinterpret_cast<short*>(&h);
}
static __device__ inline float f_of(short s) {
    __hip_bfloat16 h = *reinterpret_cast<__hip_bfloat16*>(&s);
    return __bfloat162float(h);
}

// Pre-swizzled plane write: element (row,col) of a [rows][ld] plane is stored at
// rowbase + (col&~31) + (((col>>3)&3)^phi)<<3 + (col&7). With phi=(row>>1)&3 this
// makes the GEMM's linear global_load_lds DMA reproduce the swizzled LDS image
// that the MFMA fragment ds_reads expect (source-permutation == read-permutation).
static __device__ inline size_t swz_idx(size_t rowbase, int col, int phi) {
    return rowbase + (size_t)(col & ~31) + ((size_t)(((col >> 3) & 3) ^ phi) << 3) + (col & 7);
}
static __device__ inline void split_store_swz(float v, short* p, size_t plane,
                                              size_t rowbase, int col, int phi, int np) {
    size_t idx = swz_idx(rowbase, col, phi);
    short b0 = bf_of(v); p[idx] = b0;
    if (np == 3) {
        float r1 = v - f_of(b0);
        short b1 = bf_of(r1); p[plane + idx] = b1;
        p[2 * plane + idx] = bf_of(r1 - f_of(b1));
    }
}

// global->LDS async DMA, 16B per lane, LDS dest = base + lane*16 (wave-uniform base)
static __device__ inline void gload16(const short* g, short* l) {
    __builtin_amdgcn_global_load_lds(
        (const __attribute__((address_space(1))) void*)g,
        (__attribute__((address_space(3))) void*)l, 16, 0, 0);
}

// ============ MFMA GEMM: C[M,N] = (resid?) + sum_passes A_p[M,K] @ Wt_p[N,K]^T ============
// 128x128 tile, BK=32, 4 waves. A/Wt planes are PRE-SWIZZLED (see swz_idx);
// staging is linear global_load_lds dwordx4.
__global__ __launch_bounds__(256) void gemm_mf_k(
    const short* __restrict__ A, const short* __restrict__ Wt,
    float* __restrict__ C, const float* __restrict__ resid,
    int M, int N, int K, size_t planeA, size_t planeW, int npass)
{
    __shared__ short As[128 * 32];
    __shared__ short Bs[128 * 32];
    const int tid = threadIdx.x;
    const int w = tid >> 6, l = tid & 63;
    const int wm = w >> 1, wn = w & 1;
    const int row0 = blockIdx.y * 128, col0 = blockIdx.x * 128;
    const int PAt[6] = {0, 0, 1, 0, 1, 2};
    const int PWt[6] = {0, 1, 0, 2, 1, 0};
    const int rA = l >> 2;            // 0..15
    const int cq8 = (l & 3) * 8;

    f32x4 acc[4][4];
    #pragma unroll
    for (int i = 0; i < 4; ++i)
        #pragma unroll
        for (int j = 0; j < 4; ++j)
            #pragma unroll
            for (int r = 0; r < 4; ++r) acc[i][j][r] = 0.f;

    const int lr = l & 15, q = l >> 4;
    for (int p = 0; p < npass; ++p) {
        const short* Ap = A + (size_t)PAt[p] * planeA;
        const short* Wp = Wt + (size_t)PWt[p] * planeW;
        for (int k0 = 0; k0 < K; k0 += 32) {
            __syncthreads();
            #pragma unroll
            for (int s = 0; s < 2; ++s) {
                int rr = (w * 2 + s) * 16 + rA;
                gload16(Ap + (size_t)(row0 + rr) * K + k0 + cq8, &As[(w * 2 + s) * 512]);
                gload16(Wp + (size_t)(col0 + rr) * K + k0 + cq8, &Bs[(w * 2 + s) * 512]);
            }
            __syncthreads();
            s16x8 af[4], bfv[4];
            #pragma unroll
            for (int i = 0; i < 4; ++i) {
                int ra = wm * 64 + i * 16 + lr;
                af[i] = *(const s16x8*)&As[ra * 32 + (q ^ ((ra >> 1) & 3)) * 8];
                int rb = wn * 64 + i * 16 + lr;
                bfv[i] = *(const s16x8*)&Bs[rb * 32 + (q ^ ((rb >> 1) & 3)) * 8];
            }
            #pragma unroll
            for (int mi = 0; mi < 4; ++mi)
                #pragma unroll
                for (int ni = 0; ni < 4; ++ni)
                    acc[mi][ni] = __builtin_amdgcn_mfma_f32_16x16x32_bf16(
                        af[mi], bfv[ni], acc[mi][ni], 0, 0, 0);
        }
    }
    const int cw = l & 15, rw = (l >> 4) * 4;
    #pragma unroll
    for (int mi = 0; mi < 4; ++mi)
        #pragma unroll
        for (int ni = 0; ni < 4; ++ni)
            #pragma unroll
            for (int r = 0; r < 4; ++r) {
                int gr = row0 + wm * 64 + mi * 16 + rw + r;
                int gc = col0 + wn * 64 + ni * 16 + cw;
                size_t ci = (size_t)gr * N + gc;
                float val = acc[mi][ni][r];
                if (resid) val += resid[ci];
                C[ci] = val;
            }
}

// ============ Fused gate-up: F = silu(A@Wg)*(A@Wu) -> pre-swizzled split planes ============
__global__ __launch_bounds__(256) void gateup_k(
    const short* __restrict__ A, const short* __restrict__ Wg, const short* __restrict__ Wu,
    short* __restrict__ F, int M, int N, int K,
    size_t planeA, size_t planeW, size_t planeF, int npass, int npOut)
{
    __shared__ short As[128 * 32];
    __shared__ short Bg[128 * 32];
    __shared__ short Bu[128 * 32];
    const int tid = threadIdx.x;
    const int w = tid >> 6, l = tid & 63;
    const int wm = w >> 1, wn = w & 1;
    const int row0 = blockIdx.y * 128, col0 = blockIdx.x * 128;
    const int PAt[6] = {0, 0, 1, 0, 1, 2};
    const int PWt[6] = {0, 1, 0, 2, 1, 0};
    const int rA = l >> 2;
    const int cq8 = (l & 3) * 8;

    f32x4 accg[4][4], accu[4][4];
    #pragma unroll
    for (int i = 0; i < 4; ++i)
        #pragma unroll
        for (int j = 0; j < 4; ++j)
            #pragma unroll
            for (int r = 0; r < 4; ++r) { accg[i][j][r] = 0.f; accu[i][j][r] = 0.f; }

    const int lr = l & 15, q = l >> 4;
    for (int p = 0; p < npass; ++p) {
        const short* Ap = A + (size_t)PAt[p] * planeA;
        const short* Wgp = Wg + (size_t)PWt[p] * planeW;
        const short* Wup = Wu + (size_t)PWt[p] * planeW;
        for (int k0 = 0; k0 < K; k0 += 32) {
            __syncthreads();
            #pragma unroll
            for (int s = 0; s < 2; ++s) {
                int rr = (w * 2 + s) * 16 + rA;
                gload16(Ap  + (size_t)(row0 + rr) * K + k0 + cq8, &As[(w * 2 + s) * 512]);
                gload16(Wgp + (size_t)(col0 + rr) * K + k0 + cq8, &Bg[(w * 2 + s) * 512]);
                gload16(Wup + (size_t)(col0 + rr) * K + k0 + cq8, &Bu[(w * 2 + s) * 512]);
            }
            __syncthreads();
            s16x8 af[4], bg[4], bu[4];
            #pragma unroll
            for (int i = 0; i < 4; ++i) {
                int ra = wm * 64 + i * 16 + lr;
                af[i] = *(const s16x8*)&As[ra * 32 + (q ^ ((ra >> 1) & 3)) * 8];
                int rb = wn * 64 + i * 16 + lr;
                int sb = (q ^ ((rb >> 1) & 3)) * 8;
                bg[i] = *(const s16x8*)&Bg[rb * 32 + sb];
                bu[i] = *(const s16x8*)&Bu[rb * 32 + sb];
            }
            #pragma unroll
            for (int mi = 0; mi < 4; ++mi)
                #pragma unroll
                for (int ni = 0; ni < 4; ++ni) {
                    accg[mi][ni] = __builtin_amdgcn_mfma_f32_16x16x32_bf16(
                        af[mi], bg[ni], accg[mi][ni], 0, 0, 0);
                    accu[mi][ni] = __builtin_amdgcn_mfma_f32_16x16x32_bf16(
                        af[mi], bu[ni], accu[mi][ni], 0, 0, 0);
                }
        }
    }
    const int cw = l & 15, rw = (l >> 4) * 4;
    #pragma unroll
    for (int mi = 0; mi < 4; ++mi)
        #pragma unroll
        for (int ni = 0; ni < 4; ++ni)
            #pragma unroll
            for (int r = 0; r < 4; ++r) {
                int gr = row0 + wm * 64 + mi * 16 + rw + r;
                int gc = col0 + wn * 64 + ni * 16 + cw;
                float g = accg[mi][ni][r], u = accu[mi][ni][r];
                float val = g / (1.f + expf(-g)) * u;
                split_store_swz(val, F, planeF, (size_t)gr * N, gc, (gr >> 1) & 3, npOut);
            }
}

// ============ MFMA flash attention (pre-swizzled operand planes, gload staging) ============
template<int NP, int NPROD>
__global__ __launch_bounds__(256) void mfattn_k(
    const short* __restrict__ qsp, const short* __restrict__ ksp,
    const short* __restrict__ vtp, short* __restrict__ osp,
    const int* __restrict__ valid)
{
    __shared__ short KP[NP][2][64 * 32];   // K tile [kcol][d]; reused as P planes
    __shared__ short Vt[NP][2][64 * 32];   // V^T tile [d][kcol]
    __shared__ int kvs[64];
    const int tid = threadIdx.x;
    const int w = tid >> 6, l = tid & 63;
    const int lr = l & 15, lq = l >> 4;
    const int qt = blockIdx.x, hh = blockIdx.y, b = blockIdx.z;
    const int PAt[6] = {0, 0, 1, 0, 1, 2};
    const int PWt[6] = {0, 1, 0, 2, 1, 0};
    const int rT = l >> 2;            // 0..15
    const int cq8 = (l & 3) * 8;

    // Q a-fragments from pre-swizzled plane: block (lq^phi) within the 32-col window
    s16x8 aq[NP][2];
    {
        const int qrowa = qt * 64 + w * 16 + lr;
        const int phiq = (qrowa >> 1) & 3;
        #pragma unroll
        for (int p = 0; p < NP; ++p)
            #pragma unroll
            for (int ks = 0; ks < 2; ++ks)
                aq[p][ks] = *(const s16x8*)(qsp + (size_t)p * BSH
                    + (size_t)(b * S + qrowa) * H + hh * 64 + ks * 32 + ((lq ^ phiq) << 3));
    }
    int qvr[4];
    #pragma unroll
    for (int r = 0; r < 4; ++r)
        qvr[r] = valid[b * S + qt * 64 + w * 16 + lq * 4 + r];

    float m[4], lsum[4];
    f32x4 acco[4];
    #pragma unroll
    for (int r = 0; r < 4; ++r) { m[r] = -3.4e38f; lsum[r] = 0.f; }
    #pragma unroll
    for (int n = 0; n < 4; ++n)
        #pragma unroll
        for (int r = 0; r < 4; ++r) acco[n][r] = 0.f;

    for (int kt = 0; kt < S / 64; ++kt) {
        __syncthreads();   // prior-tile KP(P)/Vt reads done
        {
            const int r = w * 16 + rT;
            #pragma unroll
            for (int p = 0; p < NP; ++p)
                #pragma unroll
                for (int hf = 0; hf < 2; ++hf) {
                    gload16(ksp + (size_t)p * BSH
                            + (size_t)(b * S + kt * 64 + r) * H + hh * 64 + hf * 32 + cq8,
                            &KP[p][hf][w * 512]);
                    gload16(vtp + (size_t)p * BSH
                            + ((size_t)(hh * 64 + r) * B + b) * S + kt * 64 + hf * 32 + cq8,
                            &Vt[p][hf][w * 512]);
                }
        }
        if (tid < 64) kvs[tid] = valid[b * S + kt * 64 + tid];
        __syncthreads();

        // ---- S = Q @ K^T ----
        f32x4 accs[4];
        #pragma unroll
        for (int n = 0; n < 4; ++n)
            #pragma unroll
            for (int r = 0; r < 4; ++r) accs[n][r] = 0.f;
        #pragma unroll
        for (int pr = 0; pr < NPROD; ++pr) {
            const int pa = PAt[pr], pw = PWt[pr];
            #pragma unroll
            for (int ks = 0; ks < 2; ++ks)
                #pragma unroll
                for (int n = 0; n < 4; ++n) {
                    int rb = n * 16 + lr;
                    s16x8 bk = *(const s16x8*)&KP[pw][ks][rb * 32 + ((lq ^ ((rb >> 1) & 3))) * 8];
                    accs[n] = __builtin_amdgcn_mfma_f32_16x16x32_bf16(
                        aq[pa][ks], bk, accs[n], 0, 0, 0);
                }
        }
        // ---- mask + online softmax ----
        float pf[4][4];
        int kva[4];
        #pragma unroll
        for (int n = 0; n < 4; ++n) kva[n] = kvs[n * 16 + lr];
        #pragma unroll
        for (int r = 0; r < 4; ++r) {
            int qr = qt * 64 + w * 16 + lq * 4 + r;
            float rowm = -3.4e38f;
            #pragma unroll
            for (int n = 0; n < 4; ++n) {
                int kc = kt * 64 + n * 16 + lr;
                float sv = accs[n][r] * 0.125f;
                int allowed = (kc <= qr) && qvr[r] && kva[n];
                if (!allowed) sv = sv + -1e9f;
                pf[n][r] = sv;
                rowm = fmaxf(rowm, sv);
            }
            rowm = fmaxf(rowm, __shfl_xor(rowm, 1));
            rowm = fmaxf(rowm, __shfl_xor(rowm, 2));
            rowm = fmaxf(rowm, __shfl_xor(rowm, 4));
            rowm = fmaxf(rowm, __shfl_xor(rowm, 8));
            float mn = fmaxf(m[r], rowm);
            float co = __expf(m[r] - mn);
            float rs = 0.f;
            #pragma unroll
            for (int n = 0; n < 4; ++n) { pf[n][r] = __expf(pf[n][r] - mn); rs += pf[n][r]; }
            rs += __shfl_xor(rs, 1);
            rs += __shfl_xor(rs, 2);
            rs += __shfl_xor(rs, 4);
            rs += __shfl_xor(rs, 8);
            lsum[r] = lsum[r] * co + rs;
            m[r] = mn;
            #pragma unroll
            for (int n = 0; n < 4; ++n) acco[n][r] *= co;
        }
        __syncthreads();   // all QK^T reads of KP done
        // ---- write P (bf16 split) into KP, swizzled for a-frag reads ----
        #pragma unroll
        for (int n = 0; n < 4; ++n) {
            int col = n * 16 + lr;
            int hf = col >> 5, colh = col & 31, cq2 = colh >> 3, pos = colh & 7;
            #pragma unroll
            for (int r = 0; r < 4; ++r) {
                int rowg = w * 16 + lq * 4 + r;
                int off = rowg * 32 + (cq2 ^ ((rowg >> 1) & 3)) * 8 + pos;
                float pv = pf[n][r];
                short b0 = bf_of(pv);
                KP[0][hf][off] = b0;
                if (NP == 3) {
                    float r1 = pv - f_of(b0);
                    short b1 = bf_of(r1);
                    KP[1][hf][off] = b1;
                    KP[2][hf][off] = bf_of(r1 - f_of(b1));
                }
            }
        }
        __syncthreads();
        // ---- O += P @ V ----
        #pragma unroll
        for (int pr = 0; pr < NPROD; ++pr) {
            const int pa = PAt[pr], pw = PWt[pr];
            #pragma unroll
            for (int ks = 0; ks < 2; ++ks) {
                int ra = w * 16 + lr;
                s16x8 ap = *(const s16x8*)&KP[pa][ks][ra * 32 + ((lq ^ ((ra >> 1) & 3))) * 8];
                #pragma unroll
                for (int n = 0; n < 4; ++n) {
                    int rb = n * 16 + lr;
                    s16x8 bv = *(const s16x8*)&Vt[pw][ks][rb * 32 + ((lq ^ ((rb >> 1) & 3))) * 8];
                    acco[n] = __builtin_amdgcn_mfma_f32_16x16x32_bf16(
                        ap, bv, acco[n], 0, 0, 0);
                }
            }
        }
    }
    // ---- write O directly as pre-swizzled split planes (skip fp32 bounce) ----
    #pragma unroll
    for (int r = 0; r < 4; ++r) {
        float inv = 1.0f / lsum[r];
        int qr = qt * 64 + w * 16 + lq * 4 + r;
        size_t rowbase = (size_t)(b * S + qr) * H;
        int phi = ((b * S + qr) >> 1) & 3;
        #pragma unroll
        for (int n = 0; n < 4; ++n)
            split_store_swz(acco[n][r] * inv, osp, BSH, rowbase, hh * 64 + n * 16 + lr, phi, NP);
    }
}

// ============ RoPE + bf16 split -> pre-swizzled planes ============
__global__ __launch_bounds__(256) void rope_split_k(const float* __restrict__ x,
    const int* __restrict__ pos, short* __restrict__ y, size_t plane, int np)
{
    int idx = blockIdx.x * 256 + threadIdx.x;
    int i = idx & 31;
    int head = (idx >> 5) & 15;
    int bs = idx >> 9;
    int p = pos[bs];
    double inv = exp(-((double)(2 * i) / 64.0) * log(10000.0));
    double ang = (double)p * inv;
    float c = (float)cos(ang), sn = (float)sin(ang);
    const float* base = x + (size_t)bs * H + head * 64;
    float x1 = base[i], x2 = base[i + 32];
    size_t rowbase = (size_t)bs * H;
    int phi = (bs >> 1) & 3;
    split_store_swz(x1 * c - x2 * sn, y, plane, rowbase, head * 64 + i, phi, np);
    split_store_swz(x2 * c + x1 * sn, y, plane, rowbase, head * 64 + i + 32, phi, np);
}

// ============ V transpose + split: V[B*S][H] -> pre-swz planes [(h*64+d)*B+b][S] ============
// phi keyed to d (= local LDS row in mfattn), NOT the global plane row.
__global__ __launch_bounds__(256) void splitvt_k(const float* __restrict__ V,
    short* __restrict__ Vt, size_t plane, int np)
{
    __shared__ float t[32][33];
    const int tid = threadIdx.x;
    const int s0 = blockIdx.x * 32;
    const int hd0 = blockIdx.y * 32;
    const int b = blockIdx.z;
    #pragma unroll
    for (int i = 0; i < 4; ++i) {
        int e = tid + i * 256;
        int rr = e >> 5, cc = e & 31;
        t[rr][cc] = V[(size_t)(b * S + s0 + rr) * H + hd0 + cc];
    }
    __syncthreads();
    #pragma unroll
    for (int i = 0; i < 4; ++i) {
        int e = tid + i * 256;
        int rn = e >> 5, ck = e & 31;
        int hd = hd0 + rn;
        size_t rowbase = ((size_t)hd * B + b) * S;
        split_store_swz(t[ck][rn], Vt, plane, rowbase, s0 + ck, ((hd & 63) >> 1) & 3, np);
    }
}

// ============ Weight transpose + bf16 split -> pre-swz planes [N][K] ============
__global__ __launch_bounds__(256) void splitwt_k(const float* __restrict__ W,
    short* __restrict__ Wt, int K, int N, size_t plane, int np)
{
    __shared__ float t[32][33];
    const int tid = threadIdx.x;
    const int n0 = blockIdx.x * 32, k0 = blockIdx.y * 32;
    #pragma unroll
    for (int i = 0; i < 4; ++i) {
        int e = tid + i * 256;
        int rk = e >> 5, cn = e & 31;
        t[rk][cn] = W[(size_t)(k0 + rk) * N + n0 + cn];
    }
    __syncthreads();
    #pragma unroll
    for (int i = 0; i < 4; ++i) {
        int e = tid + i * 256;
        int rn = e >> 5, ck = e & 31;
        int nn = n0 + rn;
        split_store_swz(t[ck][rn], Wt, plane, (size_t)nn * K, k0 + ck, (nn >> 1) & 3, np);
    }
}

// ============ RMSNorm -> pre-swz bf16 split ============
__global__ __launch_bounds__(256) void rmsnorm_split_k(const float* __restrict__ x,
    const float* __restrict__ w, short* __restrict__ y, size_t plane, int np)
{
    int row = blockIdx.x;
    const float* xr = x + (size_t)row * H;
    __shared__ float red[256];
    float s = 0.f;
    for (int i = threadIdx.x; i < H; i += 256) { float v = xr[i]; s += v * v; }
    red[threadIdx.x] = s; __syncthreads();
    for (int off = 128; off > 0; off >>= 1) {
        if (threadIdx.x < off) red[threadIdx.x] += red[threadIdx.x + off];
        __syncthreads();
    }
    float r = 1.0f / sqrtf(red[0] / (float)H + 1e-6f);
    size_t rowbase = (size_t)row * H;
    int phi = (row >> 1) & 3;
    for (int i = threadIdx.x; i < H; i += 256)
        split_store_swz(xr[i] * r * w[i], y, plane, rowbase, i, phi, np);
}

// ---------------- fp32 GEMM (head logits + fallback) ----------------
__global__ __launch_bounds__(256) void gemm_k(
    const float* __restrict__ A, const float* __restrict__ Wm,
    const float* __restrict__ bias, float* __restrict__ C,
    int M, int N, int K, int lda, int ldb, int ldc, int flags)
{
    __shared__ float As[16][65];
    __shared__ float Bs[16][65];
    const int tid = threadIdx.x;
    const int tx = tid & 15, ty = tid >> 4;
    const int row0 = blockIdx.y * 64, col0 = blockIdx.x * 64;
    float acc[4][4] = {};
    for (int k0 = 0; k0 < K; k0 += 16) {
        #pragma unroll
        for (int l = 0; l < 4; ++l) {
            int e = tid + l * 256;
            int r = e >> 4, c = e & 15;
            int gr = row0 + r;
            float vv = 0.f;
            if (gr < M) vv = A[(size_t)gr * lda + (k0 + c)];
            As[c][r] = vv;
        }
        #pragma unroll
        for (int l = 0; l < 4; ++l) {
            int e = tid + l * 256;
            int r = e >> 6, c = e & 63;
            int gc = col0 + c;
            float vv = 0.f;
            if (gc < N) vv = Wm[(size_t)(k0 + r) * ldb + gc];
            Bs[r][c] = vv;
        }
        __syncthreads();
        #pragma unroll
        for (int kk = 0; kk < 16; ++kk) {
            float a[4], bb[4];
            #pragma unroll
            for (int i = 0; i < 4; ++i) a[i] = As[kk][ty * 4 + i];
            #pragma unroll
            for (int j = 0; j < 4; ++j) bb[j] = Bs[kk][tx * 4 + j];
            #pragma unroll
            for (int i = 0; i < 4; ++i)
                #pragma unroll
                for (int j = 0; j < 4; ++j)
                    acc[i][j] += a[i] * bb[j];
        }
        __syncthreads();
    }
    #pragma unroll
    for (int i = 0; i < 4; ++i) {
        int gr = row0 + ty * 4 + i;
        if (gr >= M) continue;
        #pragma unroll
        for (int j = 0; j < 4; ++j) {
            int gc = col0 + tx * 4 + j;
            if (gc >= N) continue;
            float vv = acc[i][j];
            if (flags & F_BIAS)  vv += bias[gc];
            if (flags & F_SILU)  vv = vv / (1.f + expf(-vv));
            size_t cidx = (size_t)gr * ldc + gc;
            if (flags & F_MULIN) vv *= C[cidx];
            if (flags & F_RESID) vv += C[cidx];
            C[cidx] = vv;
        }
    }
}

// ---------------- RMSNorm fp32 (fallback) ----------------
__global__ __launch_bounds__(256) void rmsnorm_k(const float* __restrict__ x,
    const float* __restrict__ w, float* __restrict__ y)
{
    int row = blockIdx.x;
    const float* xr = x + (size_t)row * H;
    float* yr = y + (size_t)row * H;
    __shared__ float red[256];
    float s = 0.f;
    for (int i = threadIdx.x; i < H; i += 256) { float v = xr[i]; s += v * v; }
    red[threadIdx.x] = s; __syncthreads();
    for (int off = 128; off > 0; off >>= 1) {
        if (threadIdx.x < off) red[threadIdx.x] += red[threadIdx.x + off];
        __syncthreads();
    }
    float r = 1.0f / sqrtf(red[0] / (float)H + 1e-6f);
    for (int i = threadIdx.x; i < H; i += 256) yr[i] = xr[i] * r * w[i];
}

// ---------------- Embed gather ----------------
__global__ __launch_bounds__(256) void embed_k(const int* __restrict__ ids,
    const float* __restrict__ emb, float* __restrict__ h)
{
    int bs = blockIdx.x;
    const float* e = emb + (size_t)ids[bs] * H;
    float* hr = h + (size_t)bs * H;
    for (int i = threadIdx.x; i < H; i += 256) hr[i] = e[i];
}

// ---------------- RoPE fp32 in-place (fallback) ----------------
__global__ __launch_bounds__(256) void rope_k(float* __restrict__ x, const int* __restrict__ pos)
{
    int idx = blockIdx.x * 256 + threadIdx.x;
    int i = idx & 31;
    int head = (idx >> 5) & 15;
    int bs = idx >> 9;
    int p = pos[bs];
    double inv = exp(-((double)(2 * i) / 64.0) * log(10000.0));
    double ang = (double)p * inv;
    float c = (float)cos(ang), sn = (float)sin(ang);
    float* base = x + (size_t)bs * H + head * 64;
    float x1 = base[i], x2 = base[i + 32];
    base[i]      = x1 * c - x2 * sn;
    base[i + 32] = x2 * c + x1 * sn;
}

// ---------------- Flash attention fp32 (fallback) ----------------
__global__ __launch_bounds__(256) void fattn_k(const float* __restrict__ q,
    const float* __restrict__ k, const float* __restrict__ v,
    float* __restrict__ o, const int* __restrict__ valid)
{
    const int qt = blockIdx.x, hh = blockIdx.y, b = blockIdx.z;
    const int tid = threadIdx.x;
    const int tx = tid & 15, ty = tid >> 4;
    __shared__ float Qs[64][68];
    __shared__ float Ks[64][68];
    __shared__ float Vs[64][68];
    __shared__ int   kvs[64];
    const size_t hoff = (size_t)hh * HD;

    {
        int row = tid >> 2, d0 = (tid & 3) * 16;
        const float* qp = q + ((size_t)(b * S + qt * 64 + row)) * H + hoff + d0;
        float4* dst = (float4*)&Qs[row][d0];
        const float4* src = (const float4*)qp;
        #pragma unroll
        for (int e = 0; e < 4; ++e) dst[e] = src[e];
    }
    int qv[4]; int qrow_g[4];
    #pragma unroll
    for (int i = 0; i < 4; ++i) {
        qrow_g[i] = qt * 64 + ty * 4 + i;
        qv[i] = valid[b * S + qrow_g[i]];
    }
    float m[4], l[4], acc[4][4];
    #pragma unroll
    for (int i = 0; i < 4; ++i) {
        m[i] = -3.4e38f; l[i] = 0.f;
        #pragma unroll
        for (int j = 0; j < 4; ++j) acc[i][j] = 0.f;
    }

    for (int kt = 0; kt < S / 64; ++kt) {
        __syncthreads();
        {
            int row = tid >> 2, d0 = (tid & 3) * 16;
            const float* kp = k + ((size_t)(b * S + kt * 64 + row)) * H + hoff + d0;
            float4* dst = (float4*)&Ks[row][d0];
            const float4* src = (const float4*)kp;
            #pragma unroll
            for (int e = 0; e < 4; ++e) dst[e] = src[e];
        }
        {
            int kk = tid >> 2, d0 = (tid & 3) * 16;
            const float* vp = v + ((size_t)(b * S + kt * 64 + kk)) * H + hoff + d0;
            #pragma unroll
            for (int e = 0; e < 16; e += 4) {
                float4 vv = *(const float4*)(vp + e);
                Vs[d0 + e + 0][kk] = vv.x;
                Vs[d0 + e + 1][kk] = vv.y;
                Vs[d0 + e + 2][kk] = vv.z;
                Vs[d0 + e + 3][kk] = vv.w;
            }
        }
        if (tid < 64) kvs[tid] = valid[b * S + kt * 64 + tid];
        __syncthreads();

        float s4[4][4];
        #pragma unroll
        for (int i = 0; i < 4; ++i)
            #pragma unroll
            for (int j = 0; j < 4; ++j) s4[i][j] = 0.f;
        #pragma unroll
        for (int c = 0; c < 16; ++c) {
            float4 a[4], bb[4];
            #pragma unroll
            for (int i = 0; i < 4; ++i) a[i]  = ((const float4*)&Qs[ty * 4 + i][0])[c];
            #pragma unroll
            for (int j = 0; j < 4; ++j) bb[j] = ((const float4*)&Ks[tx * 4 + j][0])[c];
            #pragma unroll
            for (int i = 0; i < 4; ++i)
                #pragma unroll
                for (int j = 0; j < 4; ++j) {
                    s4[i][j] += a[i].x * bb[j].x + a[i].y * bb[j].y
                              + a[i].z * bb[j].z + a[i].w * bb[j].w;
                }
        }
        float p[4][4];
        float corr[4];
        #pragma unroll
        for (int i = 0; i < 4; ++i) {
            float rm = -3.4e38f;
            #pragma unroll
            for (int j = 0; j < 4; ++j) {
                int kc = kt * 64 + tx * 4 + j;
                float sv = s4[i][j] * 0.125f;
                int allowed = (kc <= qrow_g[i]) && qv[i] && kvs[tx * 4 + j];
                if (!allowed) sv = sv + -1e9f;
                s4[i][j] = sv;
                rm = fmaxf(rm, sv);
            }
            rm = fmaxf(rm, __shfl_xor(rm, 1));
            rm = fmaxf(rm, __shfl_xor(rm, 2));
            rm = fmaxf(rm, __shfl_xor(rm, 4));
            rm = fmaxf(rm, __shfl_xor(rm, 8));
            float mn = fmaxf(m[i], rm);
            corr[i] = expf(m[i] - mn);
            float rs = 0.f;
            #pragma unroll
            for (int j = 0; j < 4; ++j) { p[i][j] = expf(s4[i][j] - mn); rs += p[i][j]; }
            rs += __shfl_xor(rs, 1);
            rs += __shfl_xor(rs, 2);
            rs += __shfl_xor(rs, 4);
            rs += __shfl_xor(rs, 8);
            l[i] = l[i] * corr[i] + rs;
            m[i] = mn;
            #pragma unroll
            for (int j = 0; j < 4; ++j) acc[i][j] *= corr[i];
        }
        __syncthreads();
        #pragma unroll
        for (int i = 0; i < 4; ++i) {
            float4 pv4 = make_float4(p[i][0], p[i][1], p[i][2], p[i][3]);
            *(float4*)&Ks[ty * 4 + i][tx * 4] = pv4;
        }
        __syncthreads();
        #pragma unroll
        for (int c = 0; c < 16; ++c) {
            float4 a[4], bb[4];
            #pragma unroll
            for (int i = 0; i < 4; ++i) a[i]  = ((const float4*)&Ks[ty * 4 + i][0])[c];
            #pragma unroll
            for (int j = 0; j < 4; ++j) bb[j] = ((const float4*)&Vs[tx * 4 + j][0])[c];
            #pragma unroll
            for (int i = 0; i < 4; ++i)
                #pragma unroll
                for (int j = 0; j < 4; ++j) {
                    acc[i][j] += a[i].x * bb[j].x + a[i].y * bb[j].y
                               + a[i].z * bb[j].z + a[i].w * bb[j].w;
                }
        }
    }
    #pragma unroll
    for (int i = 0; i < 4; ++i) {
        float inv = 1.0f / l[i];
        float4 ov = make_float4(acc[i][0] * inv, acc[i][1] * inv,
                                acc[i][2] * inv, acc[i][3] * inv);
        *(float4*)(o + ((size_t)(b * S + qrow_g[i])) * H + hoff + tx * 4) = ov;
    }
}

// ---------------- Discretize (bf16 pre-swz z + fp32 fallback) ----------------
__global__ __launch_bounds__(256) void discretize_bf_k(const float* __restrict__ logits,
    const float* __restrict__ gumbel, short* __restrict__ z, int* __restrict__ chosen)
{
    int bs = blockIdx.x;
    const float* lg = logits + (size_t)bs * CV1;
    const float* gm = gumbel + (size_t)bs * CV1;
    __shared__ float redv[256]; __shared__ int redi[256];
    int tid = threadIdx.x;
    float m = -3.4e38f; int mi = CV1;
    for (int j = tid; j < CV1; j += 256) {
        float a = lg[j] + gm[j];
        if (a > m) { m = a; mi = j; }
    }
    redv[tid] = m; redi[tid] = mi; __syncthreads();
    for (int off = 128; off > 0; off >>= 1) {
        if (tid < off) {
            float vo = redv[tid + off]; int io = redi[tid + off];
            if (vo > redv[tid] || (vo == redv[tid] && io < redi[tid])) { redv[tid] = vo; redi[tid] = io; }
        }
        __syncthreads();
    }
    m = redv[0]; int amax = redi[0];
    __syncthreads();
    float ssum = 0.f;
    for (int j = tid; j < CV1; j += 256) ssum += expf(lg[j] + gm[j] - m);
    redv[tid] = ssum; __syncthreads();
    for (int off = 128; off > 0; off >>= 1) {
        if (tid < off) redv[tid] += redv[tid + off];
        __syncthreads();
    }
    float inv = 1.0f / redv[0];
    size_t rowbase = (size_t)bs * CV;
    int phi = (bs >> 1) & 3;
    for (int j = tid; j < CV; j += 256) {
        float zv = expf(lg[j] + gm[j] - m) * inv;
        z[swz_idx(rowbase, j, phi)] = bf_of(zv);
    }
    if (tid == 0) chosen[bs] = amax;
}

__global__ __launch_bounds__(256) void discretize_k(const float* __restrict__ logits,
    const float* __restrict__ gumbel, float* __restrict__ z, int* __restrict__ chosen)
{
    int bs = blockIdx.x;
    const float* lg = logits + (size_t)bs * CV1;
    const float* gm = gumbel + (size_t)bs * CV1;
    __shared__ float redv[256]; __shared__ int redi[256];
    int tid = threadIdx.x;
    float m = -3.4e38f; int mi = CV1;
    for (int j = tid; j < CV1; j += 256) {
        float a = lg[j] + gm[j];
        if (a > m) { m = a; mi = j; }
    }
    redv[tid] = m; redi[tid] = mi; __syncthreads();
    for (int off = 128; off > 0; off >>= 1) {
        if (tid < off) {
            float vo = redv[tid + off]; int io = redi[tid + off];
            if (vo > redv[tid] || (vo == redv[tid] && io < redi[tid])) { redv[tid] = vo; redi[tid] = io; }
        }
        __syncthreads();
    }
    m = redv[0]; int amax = redi[0];
    __syncthreads();
    float ssum = 0.f;
    for (int j = tid; j < CV1; j += 256) ssum += expf(lg[j] + gm[j] - m);
    redv[tid] = ssum; __syncthreads();
    for (int off = 128; off > 0; off >>= 1) {
        if (tid < off) redv[tid] += redv[tid + off];
        __syncthreads();
    }
    float inv = 1.0f / redv[0];
    for (int j = tid; j < CV; j += 256)
        z[(size_t)bs * CV + j] = expf(lg[j] + gm[j] - m) * inv;
    if (tid == 0) chosen[bs] = amax;
}

// ---------------- cea + loss ----------------
__global__ __launch_bounds__(256) void cea_k(const float* __restrict__ esoft,
    const float* __restrict__ cemb, const int* __restrict__ chosen,
    const int* __restrict__ amask, float* __restrict__ cea, float* __restrict__ partial)
{
    int bs = blockIdx.x;
    int ch = chosen[bs]; int vm = amask[bs];
    int comp = (ch != CV) && vm;
    const float* ehr = cemb + (size_t)(ch < CV - 1 ? ch : CV - 1) * H;
    __shared__ float red[256];
    float part = 0.f;
    float vmf = vm ? 1.f : 0.f;
    for (int i = threadIdx.x; i < H; i += 256) {
        float es = esoft[(size_t)bs * H + i];
        float eh = comp ? ehr[i] : 0.f;
        cea[(size_t)bs * H + i] = ((eh + es) - es) * vmf;
        float d = es - eh;
        part += d * d;
    }
    red[threadIdx.x] = part; __syncthreads();
    for (int off = 128; off > 0; off >>= 1) {
        if (threadIdx.x < off) red[threadIdx.x] += red[threadIdx.x + off];
        __syncthreads();
    }
    if (threadIdx.x == 0) partial[bs] = red[0];
}

__global__ __launch_bounds__(256) void loss_k(const float* __restrict__ partial, float* __restrict__ out)
{
    __shared__ float red[256];
    float s = 0.f;
    for (int i = threadIdx.x; i < BS; i += 256) s += partial[i];
    red[threadIdx.x] = s; __syncthreads();
    for (int off = 128; off > 0; off >>= 1) {
        if (threadIdx.x < off) red[threadIdx.x] += red[threadIdx.x + off];
        __syncthreads();
    }
    if (threadIdx.x == 0) out[0] = 1.25f * red[0] / (float)BSH;
}

// ---------------- Stable pack ----------------
__global__ void pack_k(const int* __restrict__ chosen, const int* __restrict__ amask,
    int* __restrict__ order, int* __restrict__ cpos, int* __restrict__ cvalid,
    int* __restrict__ counts)
{
    int b = blockIdx.x;
    if (threadIdx.x != 0) return;
    int cnt = 0;
    for (int s2 = 0; s2 < S; ++s2)
        if (chosen[b * S + s2] != CV && amask[b * S + s2]) order[b * S + cnt++] = s2;
    counts[b] = cnt;
    int j2 = cnt;
    for (int s2 = 0; s2 < S; ++s2)
        if (!(chosen[b * S + s2] != CV && amask[b * S + s2])) order[b * S + j2++] = s2;
    for (int j3 = 0; j3 < S; ++j3) {
        cvalid[b * S + j3] = (j3 < cnt) ? 1 : 0;
        cpos[b * S + j3]   = (j3 < cnt) ? order[b * S + j3] : 0;
    }
}

__global__ __launch_bounds__(256) void gather_k(const float* __restrict__ cea,
    const int* __restrict__ order, const int* __restrict__ cvalid, float* __restrict__ h)
{
    int bs = blockIdx.x;
    int b = bs >> 10;
    int src = order[bs];
    float f = cvalid[bs] ? 1.f : 0.f;
    const float* sp = cea + (size_t)(b * S + src) * H;
    float* dst = h + (size_t)bs * H;
    for (int i = threadIdx.x; i < H; i += 256) dst[i] = sp[i] * f;
}

__global__ __launch_bounds__(256) void outmask_k(const float* __restrict__ h,
    const int* __restrict__ cvalid, float* __restrict__ out)
{
    int bs = blockIdx.x;
    float f = cvalid[bs] ? 1.f : 0.f;
    for (int i = threadIdx.x; i < H; i += 256)
        out[(size_t)bs * H + i] = h[(size_t)bs * H + i] * f;
}

__global__ __launch_bounds__(256) void iota_k(int* __restrict__ pos)
{
    int idx = blockIdx.x * 256 + threadIdx.x;
    if (idx < BS) pos[idx] = idx & (S - 1);
}

// ================= Host-side drivers =================
static void run_block_f32(int layer,
    const float* ln1, const float* wq, const float* wk, const float* wv,
    const float* wo, const float* ln2, const float* wg, const float* wu, const float* wd,
    float* h, float* hn, float* q, float* k, float* v, float* o, float* f1,
    const int* valid, const int* pos, hipStream_t stream)
{
    size_t LHH = (size_t)layer * H * H;
    size_t LHF = (size_t)layer * H * FF;
    rmsnorm_k<<<BS, 256, 0, stream>>>(h, ln1 + (size_t)layer * H, hn);
    gemm_k<<<dim3(16, 64), 256, 0, stream>>>(hn, wq + LHH, nullptr, q, BS, H, H, H, H, H, 0);
    gemm_k<<<dim3(16, 64), 256, 0, stream>>>(hn, wk + LHH, nullptr, k, BS, H, H, H, H, H, 0);
    gemm_k<<<dim3(16, 64), 256, 0, stream>>>(hn, wv + LHH, nullptr, v, BS, H, H, H, H, H, 0);
    rope_k<<<8192, 256, 0, stream>>>(q, pos);
    rope_k<<<8192, 256, 0, stream>>>(k, pos);
    fattn_k<<<dim3(S / 64, NH, B), 256, 0, stream>>>(q, k, v, o, valid);
    gemm_k<<<dim3(16, 64), 256, 0, stream>>>(o, wo + LHH, nullptr, h, BS, H, H, H, H, H, F_RESID);
    rmsnorm_k<<<BS, 256, 0, stream>>>(h, ln2 + (size_t)layer * H, hn);
    gemm_k<<<dim3(64, 64), 256, 0, stream>>>(hn, wg + LHF, nullptr, f1, BS, FF, H, H, FF, FF, F_SILU);
    gemm_k<<<dim3(64, 64), 256, 0, stream>>>(hn, wu + LHF, nullptr, f1, BS, FF, H, H, FF, FF, F_MULIN);
    gemm_k<<<dim3(16, 64), 256, 0, stream>>>(f1, wd + (size_t)layer * FF * H, nullptr, h, BS, H, FF, FF, H, H, F_RESID);
}

static void run_block_mf(int layer, int np, int npass,
    const float* ln1, const float* wq, const float* wk, const float* wv,
    const float* wo, const float* ln2, const float* wg, const float* wu, const float* wd,
    float* h, float* q, float* k, float* v,
    short* hnsp, short* osp, short* wsp, short* wsp2, short* f1sp,
    short* qsp, short* ksp, short* vtp,
    const int* valid, const int* pos, hipStream_t stream)
{
    const size_t PH = (size_t)H * H;
    const size_t PGU = (size_t)H * FF;
    const size_t PA = BSH;
    const size_t PF = BSF;
    size_t LHH = (size_t)layer * H * H;
    size_t LHF = (size_t)layer * H * FF;
    dim3 gw32(H / 32, H / 32);

    rmsnorm_split_k<<<BS, 256, 0, stream>>>(h, ln1 + (size_t)layer * H, hnsp, PA, np);
    splitwt_k<<<gw32, 256, 0, stream>>>(wq + LHH, wsp, H, H, PH, np);
    gemm_mf_k<<<dim3(H / 128, BS / 128), 256, 0, stream>>>(hnsp, wsp, q, nullptr, BS, H, H, PA, PH, npass);
    splitwt_k<<<gw32, 256, 0, stream>>>(wk + LHH, wsp, H, H, PH, np);
    gemm_mf_k<<<dim3(H / 128, BS / 128), 256, 0, stream>>>(hnsp, wsp, k, nullptr, BS, H, H, PA, PH, npass);
    splitwt_k<<<gw32, 256, 0, stream>>>(wv + LHH, wsp, H, H, PH, np);
    gemm_mf_k<<<dim3(H / 128, BS / 128), 256, 0, stream>>>(hnsp, wsp, v, nullptr, BS, H, H, PA, PH, npass);
    // bf16 attention operands (pre-swizzled planes)
    rope_split_k<<<8192, 256, 0, stream>>>(q, pos, qsp, PA, np);
    rope_split_k<<<8192, 256, 0, stream>>>(k, pos, ksp, PA, np);
    splitvt_k<<<dim3(S / 32, H / 32, B), 256, 0, stream>>>(v, vtp, PA, np);
    if (np == 3)
        mfattn_k<3, 6><<<dim3(S / 64, NH, B), 256, 0, stream>>>(qsp, ksp, vtp, osp, valid);
    else
        mfattn_k<1, 1><<<dim3(S / 64, NH, B), 256, 0, stream>>>(qsp, ksp, vtp, osp, valid);
    splitwt_k<<<gw32, 256, 0, stream>>>(wo + LHH, wsp, H, H, PH, np);
    gemm_mf_k<<<dim3(H / 128, BS / 128), 256, 0, stream>>>(osp, wsp, h, h, BS, H, H, PA, PH, npass);
    rmsnorm_split_k<<<BS, 256, 0, stream>>>(h, ln2 + (size_t)layer * H, hnsp, PA, np);
    splitwt_k<<<dim3(FF / 32, H / 32), 256, 0, stream>>>(wg + LHF, wsp, H, FF, PGU, np);
    splitwt_k<<<dim3(FF / 32, H / 32), 256, 0, stream>>>(wu + LHF, wsp2, H, FF, PGU, np);
    gateup_k<<<dim3(FF / 128, BS / 128), 256, 0, stream>>>(hnsp, wsp, wsp2, f1sp, BS, FF, H, PA, PGU, PF, npass, np);
    splitwt_k<<<dim3(H / 32, FF / 32), 256, 0, stream>>>(wd + (size_t)layer * FF * H, wsp, FF, H, PGU, np);
    gemm_mf_k<<<dim3(H / 128, BS / 128), 256, 0, stream>>>(f1sp, wsp, h, h, BS, H, FF, PF, PGU, npass);
}

extern "C" void kernel_launch(void* const* d_in, const int* in_sizes, int n_in,
                              void* d_out, int out_size, void* d_ws, size_t ws_size,
                              hipStream_t stream)
{
    const int*   ids    = (const int*)d_in[0];
    const int*   amask  = (const int*)d_in[1];
    const float* embed  = (const float*)d_in[2];
    const float* ln1    = (const float*)d_in[3];
    const float* wq     = (const float*)d_in[4];
    const float* wk     = (const float*)d_in[5];
    const float* wv     = (const float*)d_in[6];
    const float* wo     = (const float*)d_in[7];
    const float* ln2    = (const float*)d_in[8];
    const float* wg     = (const float*)d_in[9];
    const float* wu     = (const float*)d_in[10];
    const float* wd     = (const float*)d_in[11];
    const float* head_w = (const float*)d_in[12];
    const float* head_b = (const float*)d_in[13];
    const float* cemb   = (const float*)d_in[14];
    const float* gumbel = (const float*)d_in[15];
    float* out = (float*)d_out;

    const size_t MB = 1ull << 20;
    const size_t NEED = 274 * MB;

    if (ws_size >= NEED) {
        // ===== MFMA path =====
        char* base = (char*)d_ws;
        float* h = (float*)base;                   // 16MB
        float* q = (float*)(base + 16 * MB);
        float* k = (float*)(base + 32 * MB);
        float* v = (float*)(base + 48 * MB);
        float* o = (float*)(base + 64 * MB);       // fp32 scratch (logits tail etc.)
        short* hnsp = (short*)(base + 80 * MB);    // 3 planes x 8MB
        short* osp  = (short*)(base + 104 * MB);
        short* wsp  = (short*)(base + 128 * MB);   // 24MB
        short* wsp2 = (short*)(base + 152 * MB);   // 24MB
        short* f1sp = (short*)(base + 176 * MB);   // 96MB (FFN intermediate)
        short* qsp  = (short*)(base + 176 * MB);   // alias f1sp (disjoint lifetime)
        short* ksp  = (short*)(base + 200 * MB);
        short* vtp  = (short*)(base + 224 * MB);
        int* meta   = (int*)(base + 272 * MB);
        int* chosen = meta;
        int* order  = meta + BS;
        int* cpos   = meta + 2 * BS;
        int* cvalid = meta + 3 * BS;
        int* counts = meta + 4 * BS;
        int* pos_sh = meta + 5 * BS;
        float* partial = (float*)(meta + 6 * BS);
        float* logits = q;          // 33.5MB spans q,k,+v head (dead there)
        short* zb = (short*)o;      // 16MB (o fp32 dead in MFMA path)
        float* esoft = q;
        float* ceab = k;

        embed_k<<<BS, 256, 0, stream>>>(ids, embed, h);
        iota_k<<<16, 256, 0, stream>>>(pos_sh);

        for (int L = 0; L < 2; ++L)
            run_block_mf(L, 3, 6, ln1, wq, wk, wv, wo, ln2, wg, wu, wd,
                         h, q, k, v, hnsp, osp, wsp, wsp2, f1sp,
                         qsp, ksp, vtp, amask, pos_sh, stream);

        gemm_k<<<dim3(33, 64), 256, 0, stream>>>(h, head_w, head_b, logits, BS, CV1, H, H, CV1, CV1, F_BIAS);
        discretize_bf_k<<<BS, 256, 0, stream>>>(logits, gumbel, zb, chosen);

        splitwt_k<<<dim3(H / 32, CV / 32), 256, 0, stream>>>(cemb, wsp, CV, H, (size_t)CV * H, 1);
        gemm_mf_k<<<dim3(H / 128, BS / 128), 256, 0, stream>>>(zb, wsp, esoft, nullptr, BS, H, CV, (size_t)BS * CV, (size_t)CV * H, 1);

        cea_k<<<BS, 256, 0, stream>>>(esoft, cemb, chosen, amask, ceab, partial);
        loss_k<<<1, 256, 0, stream>>>(partial, out + BSH);
        pack_k<<<B, 64, 0, stream>>>(chosen, amask, order, cpos, cvalid, counts);
        gather_k<<<BS, 256, 0, stream>>>(ceab, order, cvalid, h);

        for (int L = 2; L < 4; ++L)
            run_block_mf(L, 1, 1, ln1, wq, wk, wv, wo, ln2, wg, wu, wd,
                         h, q, k, v, hnsp, osp, wsp, wsp2, f1sp,
                         qsp, ksp, vtp, cvalid, cpos, stream);

        outmask_k<<<BS, 256, 0, stream>>>(h, cvalid, out);
    } else {
        // ===== fallback: fp32 path =====
        float* wsf = (float*)d_ws;
        float* h   = wsf;
        float* hn  = wsf + BSH;
        float* q   = wsf + 2 * BSH;
        float* k   = wsf + 3 * BSH;
        float* v   = wsf + 4 * BSH;
        float* o   = wsf + 5 * BSH;
        float* f1  = wsf + 6 * BSH;
        float* zbuf  = q;
        float* esoft = v;
        float* ceab  = o;
        int* meta   = (int*)(wsf + 6 * BSH + BSF);
        int* chosen = meta;
        int* order  = meta + BS;
        int* cpos   = meta + 2 * BS;
        int* cvalid = meta + 3 * BS;
        int* counts = meta + 4 * BS;
        int* pos_sh = meta + 5 * BS;
        float* partial = (float*)(meta + 6 * BS);

        embed_k<<<BS, 256, 0, stream>>>(ids, embed, h);
        iota_k<<<16, 256, 0, stream>>>(pos_sh);
        for (int L = 0; L < 2; ++L)
            run_block_f32(L, ln1, wq, wk, wv, wo, ln2, wg, wu, wd,
                          h, hn, q, k, v, o, f1, amask, pos_sh, stream);
        gemm_k<<<dim3(33, 64), 256, 0, stream>>>(h, head_w, head_b, f1, BS, CV1, H, H, CV1, CV1, F_BIAS);
        discretize_k<<<BS, 256, 0, stream>>>(f1, gumbel, zbuf, chosen);
        gemm_k<<<dim3(16, 64), 256, 0, stream>>>(zbuf, cemb, nullptr, esoft, BS, H, CV, CV, H, H, 0);
        cea_k<<<BS, 256, 0, stream>>>(esoft, cemb, chosen, amask, ceab, partial);
        loss_k<<<1, 256, 0, stream>>>(partial, out + BSH);
        pack_k<<<B, 64, 0, stream>>>(chosen, amask, order, cpos, cvalid, counts);
        gather_k<<<BS, 256, 0, stream>>>(ceab, order, cvalid, h);
        for (int L = 2; L < 4; ++L)
            run_block_f32(L, ln1, wq, wk, wv, wo, ln2, wg, wu, wd,
                          h, hn, q, k, v, o, f1, cvalid, cpos, stream);
        outmask_k<<<BS, 256, 0, stream>>>(h, cvalid, out);
    }
}

// Round 6
// 3387.190 us; speedup vs baseline: 10.5538x; 1.6348x over previous
//
#include <hip/hip_runtime.h>
#include <hip/hip_bf16.h>
#include <cmath>

#define B 4
#define S 1024
#define H 1024
#define NH 16
#define HD 64
#define FF 4096
#define CV 2048
#define CV1 2049
#define BS (B*S)            // 4096
#define BSH ((size_t)BS*H)  // 4194304
#define BSF ((size_t)BS*FF) // 16777216

#define F_BIAS  1
#define F_RESID 2
#define F_SILU  4
#define F_MULIN 8

typedef __attribute__((ext_vector_type(8))) _Float16 f16x8;
typedef __attribute__((ext_vector_type(4))) float f32x4;

// Pre-swizzled plane write: element (row,col) stored at
// rowbase + (col&~31) + ((((col>>3)&3)^phi)<<3) + (col&7), phi=(row>>1)&3.
// Linear global_load_lds DMA then reproduces the LDS image the MFMA ds_reads expect.
static __device__ inline size_t swz_idx(size_t rowbase, int col, int phi) {
    return rowbase + (size_t)(col & ~31) + ((size_t)(((col >> 3) & 3) ^ phi) << 3) + (col & 7);
}
// fp16 2-plane split store (np=1: single plane)
static __device__ inline void split_store_swz(float v, _Float16* p, size_t plane,
                                              size_t rowbase, int col, int phi, int np) {
    size_t idx = swz_idx(rowbase, col, phi);
    _Float16 h0 = (_Float16)v; p[idx] = h0;
    if (np == 2) p[plane + idx] = (_Float16)(v - (float)h0);
}

// global->LDS async DMA, 16B per lane, LDS dest = base + lane*16
static __device__ inline void gload16(const void* g, void* l) {
    __builtin_amdgcn_global_load_lds(
        (const __attribute__((address_space(1))) void*)g,
        (__attribute__((address_space(3))) void*)l, 16, 0, 0);
}

// Split-product pass tables: (A-plane, W-plane) per pass.
// npass=1:(0,0)  npass=3:+(0,1),(1,0)  npass=4:+(1,1)
__device__ __constant__ int PAt4[4] = {0, 0, 1, 1};
__device__ __constant__ int PWt4[4] = {0, 1, 0, 1};

// XCD-chunk block swizzle. swz=0 none; 1=M-contig chunks; 2=N-contig chunks.
// Requires gridDim.x*gridDim.y % 8 == 0 (all our grids satisfy this).
static __device__ inline void tile_coords(int swz, int& bx, int& by) {
    if (swz == 0) { bx = blockIdx.x; by = blockIdx.y; return; }
    int nbx = gridDim.x, nby = gridDim.y;
    int L = blockIdx.y * nbx + blockIdx.x;
    int cpx = (nbx * nby) >> 3;
    int cid = (L & 7) * cpx + (L >> 3);
    if (swz == 1) { by = cid / nbx; bx = cid % nbx; }
    else          { bx = cid / nby; by = cid % nby; }
}

// ============ MFMA GEMM: C[M,N](ldc) = resid? + bias? + sum_p A_p[M,K] @ Wt_p[N,K]^T ============
__global__ __launch_bounds__(256) void gemm_mf_k(
    const _Float16* __restrict__ A, const _Float16* __restrict__ Wt,
    const float* __restrict__ bias, float* __restrict__ C, const float* __restrict__ resid,
    int M, int N, int K, int ldc, size_t planeA, size_t planeW, int npass, int swz)
{
    __shared__ _Float16 As[128 * 32];
    __shared__ _Float16 Bs[128 * 32];
    const int tid = threadIdx.x;
    const int w = tid >> 6, l = tid & 63;
    const int wm = w >> 1, wn = w & 1;
    int bx, by; tile_coords(swz, bx, by);
    const int row0 = by * 128, col0 = bx * 128;
    const int rA = l >> 2;
    const int cq8 = (l & 3) * 8;

    f32x4 acc[4][4];
    #pragma unroll
    for (int i = 0; i < 4; ++i)
        #pragma unroll
        for (int j = 0; j < 4; ++j)
            #pragma unroll
            for (int r = 0; r < 4; ++r) acc[i][j][r] = 0.f;

    const int lr = l & 15, q = l >> 4;
    for (int p = 0; p < npass; ++p) {
        const _Float16* Ap = A + (size_t)PAt4[p] * planeA;
        const _Float16* Wp = Wt + (size_t)PWt4[p] * planeW;
        for (int k0 = 0; k0 < K; k0 += 32) {
            __syncthreads();
            #pragma unroll
            for (int s = 0; s < 2; ++s) {
                int rr = (w * 2 + s) * 16 + rA;
                gload16(Ap + (size_t)(row0 + rr) * K + k0 + cq8, &As[(w * 2 + s) * 512]);
                gload16(Wp + (size_t)(col0 + rr) * K + k0 + cq8, &Bs[(w * 2 + s) * 512]);
            }
            __syncthreads();
            f16x8 af[4], bfv[4];
            #pragma unroll
            for (int i = 0; i < 4; ++i) {
                int ra = wm * 64 + i * 16 + lr;
                af[i] = *(const f16x8*)&As[ra * 32 + (q ^ ((ra >> 1) & 3)) * 8];
                int rb = wn * 64 + i * 16 + lr;
                bfv[i] = *(const f16x8*)&Bs[rb * 32 + (q ^ ((rb >> 1) & 3)) * 8];
            }
            #pragma unroll
            for (int mi = 0; mi < 4; ++mi)
                #pragma unroll
                for (int ni = 0; ni < 4; ++ni)
                    acc[mi][ni] = __builtin_amdgcn_mfma_f32_16x16x32_f16(
                        af[mi], bfv[ni], acc[mi][ni], 0, 0, 0);
        }
    }
    const int cw = l & 15, rw = (l >> 4) * 4;
    #pragma unroll
    for (int mi = 0; mi < 4; ++mi)
        #pragma unroll
        for (int ni = 0; ni < 4; ++ni)
            #pragma unroll
            for (int r = 0; r < 4; ++r) {
                int gr = row0 + wm * 64 + mi * 16 + rw + r;
                int gc = col0 + wn * 64 + ni * 16 + cw;
                size_t ci = (size_t)gr * ldc + gc;
                float val = acc[mi][ni][r];
                if (bias)  val += bias[gc];
                if (resid) val += resid[ci];
                C[ci] = val;
            }
}

// ============ Fused gate-up: F = silu(A@Wg)*(A@Wu) -> pre-swizzled split planes ============
__global__ __launch_bounds__(256) void gateup_k(
    const _Float16* __restrict__ A, const _Float16* __restrict__ Wg, const _Float16* __restrict__ Wu,
    _Float16* __restrict__ F, int M, int N, int K,
    size_t planeA, size_t planeW, size_t planeF, int npass, int npOut, int swz)
{
    __shared__ _Float16 As[128 * 32];
    __shared__ _Float16 Bg[128 * 32];
    __shared__ _Float16 Bu[128 * 32];
    const int tid = threadIdx.x;
    const int w = tid >> 6, l = tid & 63;
    const int wm = w >> 1, wn = w & 1;
    int bx, by; tile_coords(swz, bx, by);
    const int row0 = by * 128, col0 = bx * 128;
    const int rA = l >> 2;
    const int cq8 = (l & 3) * 8;

    f32x4 accg[4][4], accu[4][4];
    #pragma unroll
    for (int i = 0; i < 4; ++i)
        #pragma unroll
        for (int j = 0; j < 4; ++j)
            #pragma unroll
            for (int r = 0; r < 4; ++r) { accg[i][j][r] = 0.f; accu[i][j][r] = 0.f; }

    const int lr = l & 15, q = l >> 4;
    for (int p = 0; p < npass; ++p) {
        const _Float16* Ap = A + (size_t)PAt4[p] * planeA;
        const _Float16* Wgp = Wg + (size_t)PWt4[p] * planeW;
        const _Float16* Wup = Wu + (size_t)PWt4[p] * planeW;
        for (int k0 = 0; k0 < K; k0 += 32) {
            __syncthreads();
            #pragma unroll
            for (int s = 0; s < 2; ++s) {
                int rr = (w * 2 + s) * 16 + rA;
                gload16(Ap  + (size_t)(row0 + rr) * K + k0 + cq8, &As[(w * 2 + s) * 512]);
                gload16(Wgp + (size_t)(col0 + rr) * K + k0 + cq8, &Bg[(w * 2 + s) * 512]);
                gload16(Wup + (size_t)(col0 + rr) * K + k0 + cq8, &Bu[(w * 2 + s) * 512]);
            }
            __syncthreads();
            f16x8 af[4], bg[4], bu[4];
            #pragma unroll
            for (int i = 0; i < 4; ++i) {
                int ra = wm * 64 + i * 16 + lr;
                af[i] = *(const f16x8*)&As[ra * 32 + (q ^ ((ra >> 1) & 3)) * 8];
                int rb = wn * 64 + i * 16 + lr;
                int sb = (q ^ ((rb >> 1) & 3)) * 8;
                bg[i] = *(const f16x8*)&Bg[rb * 32 + sb];
                bu[i] = *(const f16x8*)&Bu[rb * 32 + sb];
            }
            #pragma unroll
            for (int mi = 0; mi < 4; ++mi)
                #pragma unroll
                for (int ni = 0; ni < 4; ++ni) {
                    accg[mi][ni] = __builtin_amdgcn_mfma_f32_16x16x32_f16(
                        af[mi], bg[ni], accg[mi][ni], 0, 0, 0);
                    accu[mi][ni] = __builtin_amdgcn_mfma_f32_16x16x32_f16(
                        af[mi], bu[ni], accu[mi][ni], 0, 0, 0);
                }
        }
    }
    const int cw = l & 15, rw = (l >> 4) * 4;
    #pragma unroll
    for (int mi = 0; mi < 4; ++mi)
        #pragma unroll
        for (int ni = 0; ni < 4; ++ni)
            #pragma unroll
            for (int r = 0; r < 4; ++r) {
                int gr = row0 + wm * 64 + mi * 16 + rw + r;
                int gc = col0 + wn * 64 + ni * 16 + cw;
                float g = accg[mi][ni][r], u = accu[mi][ni][r];
                float val = g / (1.f + expf(-g)) * u;
                split_store_swz(val, F, planeF, (size_t)gr * N, gc, (gr >> 1) & 3, npOut);
            }
}

// ============ MFMA flash attention (fp16, pre-swizzled planes, gload staging) ============
template<int NP, int NPROD>
__global__ __launch_bounds__(256) void mfattn_k(
    const _Float16* __restrict__ qsp, const _Float16* __restrict__ ksp,
    const _Float16* __restrict__ vtp, _Float16* __restrict__ osp,
    const int* __restrict__ valid)
{
    __shared__ _Float16 KP[NP][2][64 * 32];   // K tile; reused as P planes
    __shared__ _Float16 Vt[NP][2][64 * 32];   // V^T tile
    __shared__ int kvs[64];
    const int tid = threadIdx.x;
    const int w = tid >> 6, l = tid & 63;
    const int lr = l & 15, lq = l >> 4;
    const int qt = blockIdx.x, hh = blockIdx.y, b = blockIdx.z;
    const int rT = l >> 2;
    const int cq8 = (l & 3) * 8;

    f16x8 aq[NP][2];
    {
        const int qrowa = qt * 64 + w * 16 + lr;
        const int phiq = (qrowa >> 1) & 3;
        #pragma unroll
        for (int p = 0; p < NP; ++p)
            #pragma unroll
            for (int ks = 0; ks < 2; ++ks)
                aq[p][ks] = *(const f16x8*)(qsp + (size_t)p * BSH
                    + (size_t)(b * S + qrowa) * H + hh * 64 + ks * 32 + ((lq ^ phiq) << 3));
    }
    int qvr[4];
    #pragma unroll
    for (int r = 0; r < 4; ++r)
        qvr[r] = valid[b * S + qt * 64 + w * 16 + lq * 4 + r];

    float m[4], lsum[4];
    f32x4 acco[4];
    #pragma unroll
    for (int r = 0; r < 4; ++r) { m[r] = -3.4e38f; lsum[r] = 0.f; }
    #pragma unroll
    for (int n = 0; n < 4; ++n)
        #pragma unroll
        for (int r = 0; r < 4; ++r) acco[n][r] = 0.f;

    for (int kt = 0; kt < S / 64; ++kt) {
        __syncthreads();
        {
            const int r = w * 16 + rT;
            #pragma unroll
            for (int p = 0; p < NP; ++p)
                #pragma unroll
                for (int hf = 0; hf < 2; ++hf) {
                    gload16(ksp + (size_t)p * BSH
                            + (size_t)(b * S + kt * 64 + r) * H + hh * 64 + hf * 32 + cq8,
                            &KP[p][hf][w * 512]);
                    gload16(vtp + (size_t)p * BSH
                            + ((size_t)(hh * 64 + r) * B + b) * S + kt * 64 + hf * 32 + cq8,
                            &Vt[p][hf][w * 512]);
                }
        }
        if (tid < 64) kvs[tid] = valid[b * S + kt * 64 + tid];
        __syncthreads();

        // ---- S = Q @ K^T ----
        f32x4 accs[4];
        #pragma unroll
        for (int n = 0; n < 4; ++n)
            #pragma unroll
            for (int r = 0; r < 4; ++r) accs[n][r] = 0.f;
        #pragma unroll
        for (int pr = 0; pr < NPROD; ++pr) {
            const int pa = PAt4[pr], pw = PWt4[pr];
            #pragma unroll
            for (int ks = 0; ks < 2; ++ks)
                #pragma unroll
                for (int n = 0; n < 4; ++n) {
                    int rb = n * 16 + lr;
                    f16x8 bk = *(const f16x8*)&KP[pw][ks][rb * 32 + ((lq ^ ((rb >> 1) & 3))) * 8];
                    accs[n] = __builtin_amdgcn_mfma_f32_16x16x32_f16(
                        aq[pa][ks], bk, accs[n], 0, 0, 0);
                }
        }
        // ---- mask + online softmax ----
        float pf[4][4];
        int kva[4];
        #pragma unroll
        for (int n = 0; n < 4; ++n) kva[n] = kvs[n * 16 + lr];
        #pragma unroll
        for (int r = 0; r < 4; ++r) {
            int qr = qt * 64 + w * 16 + lq * 4 + r;
            float rowm = -3.4e38f;
            #pragma unroll
            for (int n = 0; n < 4; ++n) {
                int kc = kt * 64 + n * 16 + lr;
                float sv = accs[n][r] * 0.125f;
                int allowed = (kc <= qr) && qvr[r] && kva[n];
                if (!allowed) sv = sv + -1e9f;
                pf[n][r] = sv;
                rowm = fmaxf(rowm, sv);
            }
            rowm = fmaxf(rowm, __shfl_xor(rowm, 1));
            rowm = fmaxf(rowm, __shfl_xor(rowm, 2));
            rowm = fmaxf(rowm, __shfl_xor(rowm, 4));
            rowm = fmaxf(rowm, __shfl_xor(rowm, 8));
            float mn = fmaxf(m[r], rowm);
            float co = __expf(m[r] - mn);
            float rs = 0.f;
            #pragma unroll
            for (int n = 0; n < 4; ++n) { pf[n][r] = __expf(pf[n][r] - mn); rs += pf[n][r]; }
            rs += __shfl_xor(rs, 1);
            rs += __shfl_xor(rs, 2);
            rs += __shfl_xor(rs, 4);
            rs += __shfl_xor(rs, 8);
            lsum[r] = lsum[r] * co + rs;
            m[r] = mn;
            #pragma unroll
            for (int n = 0; n < 4; ++n) acco[n][r] *= co;
        }
        __syncthreads();
        // ---- write P (fp16 split) into KP, swizzled for a-frag reads ----
        #pragma unroll
        for (int n = 0; n < 4; ++n) {
            int col = n * 16 + lr;
            int hf = col >> 5, colh = col & 31, cq2 = colh >> 3, pos = colh & 7;
            #pragma unroll
            for (int r = 0; r < 4; ++r) {
                int rowg = w * 16 + lq * 4 + r;
                int off = rowg * 32 + (cq2 ^ ((rowg >> 1) & 3)) * 8 + pos;
                float pv = pf[n][r];
                _Float16 h0 = (_Float16)pv;
                KP[0][hf][off] = h0;
                if (NP == 2) KP[1][hf][off] = (_Float16)(pv - (float)h0);
            }
        }
        __syncthreads();
        // ---- O += P @ V ----
        #pragma unroll
        for (int pr = 0; pr < NPROD; ++pr) {
            const int pa = PAt4[pr], pw = PWt4[pr];
            #pragma unroll
            for (int ks = 0; ks < 2; ++ks) {
                int ra = w * 16 + lr;
                f16x8 ap = *(const f16x8*)&KP[pa][ks][ra * 32 + ((lq ^ ((ra >> 1) & 3))) * 8];
                #pragma unroll
                for (int n = 0; n < 4; ++n) {
                    int rb = n * 16 + lr;
                    f16x8 bv = *(const f16x8*)&Vt[pw][ks][rb * 32 + ((lq ^ ((rb >> 1) & 3))) * 8];
                    acco[n] = __builtin_amdgcn_mfma_f32_16x16x32_f16(
                        ap, bv, acco[n], 0, 0, 0);
                }
            }
        }
    }
    // ---- write O as pre-swizzled split planes ----
    #pragma unroll
    for (int r = 0; r < 4; ++r) {
        float inv = 1.0f / lsum[r];
        int qr = qt * 64 + w * 16 + lq * 4 + r;
        size_t rowbase = (size_t)(b * S + qr) * H;
        int phi = ((b * S + qr) >> 1) & 3;
        #pragma unroll
        for (int n = 0; n < 4; ++n)
            split_store_swz(acco[n][r] * inv, osp, BSH, rowbase, hh * 64 + n * 16 + lr, phi, NP);
    }
}

// ============ RoPE + fp16 split -> pre-swizzled planes (reads strided qkv buffer) ============
__global__ __launch_bounds__(256) void rope_split_k(const float* __restrict__ x,
    int xld, int xoff, const int* __restrict__ pos, _Float16* __restrict__ y,
    size_t plane, int np)
{
    int idx = blockIdx.x * 256 + threadIdx.x;
    int i = idx & 31;
    int head = (idx >> 5) & 15;
    int bs = idx >> 9;
    int p = pos[bs];
    double inv = exp(-((double)(2 * i) / 64.0) * log(10000.0));
    double ang = (double)p * inv;
    float c = (float)cos(ang), sn = (float)sin(ang);
    const float* base = x + (size_t)bs * xld + xoff + head * 64;
    float x1 = base[i], x2 = base[i + 32];
    size_t rowbase = (size_t)bs * H;
    int phi = (bs >> 1) & 3;
    split_store_swz(x1 * c - x2 * sn, y, plane, rowbase, head * 64 + i, phi, np);
    split_store_swz(x2 * c + x1 * sn, y, plane, rowbase, head * 64 + i + 32, phi, np);
}

// ============ V transpose + split (reads strided qkv) -> planes [(h*64+d)*B+b][S] ============
__global__ __launch_bounds__(256) void splitvt_k(const float* __restrict__ V,
    int vld, int voff, _Float16* __restrict__ Vt, size_t plane, int np)
{
    __shared__ float t[32][33];
    const int tid = threadIdx.x;
    const int s0 = blockIdx.x * 32;
    const int hd0 = blockIdx.y * 32;
    const int b = blockIdx.z;
    #pragma unroll
    for (int i = 0; i < 4; ++i) {
        int e = tid + i * 256;
        int rr = e >> 5, cc = e & 31;
        t[rr][cc] = V[(size_t)(b * S + s0 + rr) * vld + voff + hd0 + cc];
    }
    __syncthreads();
    #pragma unroll
    for (int i = 0; i < 4; ++i) {
        int e = tid + i * 256;
        int rn = e >> 5, ck = e & 31;
        int hd = hd0 + rn;
        size_t rowbase = ((size_t)hd * B + b) * S;
        split_store_swz(t[ck][rn], Vt, plane, rowbase, s0 + ck, ((hd & 63) >> 1) & 3, np);
    }
}

// ============ Weight transpose + fp16 split: W[K,N](srcld) -> Wt planes [N][K] ============
__global__ __launch_bounds__(256) void splitwt_k(const float* __restrict__ W,
    _Float16* __restrict__ Wt, int K, int N, int srcld, size_t plane, int np)
{
    __shared__ float t[32][33];
    const int tid = threadIdx.x;
    const int n0 = blockIdx.x * 32, k0 = blockIdx.y * 32;
    #pragma unroll
    for (int i = 0; i < 4; ++i) {
        int e = tid + i * 256;
        int rk = e >> 5, cn = e & 31;
        t[rk][cn] = W[(size_t)(k0 + rk) * srcld + n0 + cn];
    }
    __syncthreads();
    #pragma unroll
    for (int i = 0; i < 4; ++i) {
        int e = tid + i * 256;
        int rn = e >> 5, ck = e & 31;
        int nn = n0 + rn;
        split_store_swz(t[ck][rn], Wt, plane, (size_t)nn * K, k0 + ck, (nn >> 1) & 3, np);
    }
}

// ============ Plain fp32 -> fp16 split planes (rows of length H) ============
__global__ __launch_bounds__(256) void splita_swz_k(const float* __restrict__ x,
    _Float16* __restrict__ y, size_t plane, int np)
{
    int row = blockIdx.x;
    size_t rowbase = (size_t)row * H;
    int phi = (row >> 1) & 3;
    for (int i = threadIdx.x; i < H; i += 256)
        split_store_swz(x[rowbase + i], y, plane, rowbase, i, phi, np);
}

// ============ RMSNorm -> pre-swz fp16 split ============
__global__ __launch_bounds__(256) void rmsnorm_split_k(const float* __restrict__ x,
    const float* __restrict__ w, _Float16* __restrict__ y, size_t plane, int np)
{
    int row = blockIdx.x;
    const float* xr = x + (size_t)row * H;
    __shared__ float red[256];
    float s = 0.f;
    for (int i = threadIdx.x; i < H; i += 256) { float v = xr[i]; s += v * v; }
    red[threadIdx.x] = s; __syncthreads();
    for (int off = 128; off > 0; off >>= 1) {
        if (threadIdx.x < off) red[threadIdx.x] += red[threadIdx.x + off];
        __syncthreads();
    }
    float r = 1.0f / sqrtf(red[0] / (float)H + 1e-6f);
    size_t rowbase = (size_t)row * H;
    int phi = (row >> 1) & 3;
    for (int i = threadIdx.x; i < H; i += 256)
        split_store_swz(xr[i] * r * w[i], y, plane, rowbase, i, phi, np);
}

// ============ Head column 2048 (null logit), exact fp32 ============
__global__ __launch_bounds__(64) void headcol_k(const float* __restrict__ h,
    const float* __restrict__ head_w, const float* __restrict__ head_b,
    float* __restrict__ logits)
{
    int row = blockIdx.x;
    int l = threadIdx.x;
    float s = 0.f;
    for (int j = l; j < H; j += 64) s += h[(size_t)row * H + j] * head_w[(size_t)j * CV1 + CV];
    s += __shfl_xor(s, 1);
    s += __shfl_xor(s, 2);
    s += __shfl_xor(s, 4);
    s += __shfl_xor(s, 8);
    s += __shfl_xor(s, 16);
    s += __shfl_xor(s, 32);
    if (l == 0) logits[(size_t)row * CV1 + CV] = s + head_b[CV];
}

// ---------------- fp32 GEMM (fallback path) ----------------
__global__ __launch_bounds__(256) void gemm_k(
    const float* __restrict__ A, const float* __restrict__ Wm,
    const float* __restrict__ bias, float* __restrict__ C,
    int M, int N, int K, int lda, int ldb, int ldc, int flags)
{
    __shared__ float As[16][65];
    __shared__ float Bs[16][65];
    const int tid = threadIdx.x;
    const int tx = tid & 15, ty = tid >> 4;
    const int row0 = blockIdx.y * 64, col0 = blockIdx.x * 64;
    float acc[4][4] = {};
    for (int k0 = 0; k0 < K; k0 += 16) {
        #pragma unroll
        for (int l = 0; l < 4; ++l) {
            int e = tid + l * 256;
            int r = e >> 4, c = e & 15;
            int gr = row0 + r;
            float vv = 0.f;
            if (gr < M) vv = A[(size_t)gr * lda + (k0 + c)];
            As[c][r] = vv;
        }
        #pragma unroll
        for (int l = 0; l < 4; ++l) {
            int e = tid + l * 256;
            int r = e >> 6, c = e & 63;
            int gc = col0 + c;
            float vv = 0.f;
            if (gc < N) vv = Wm[(size_t)(k0 + r) * ldb + gc];
            Bs[r][c] = vv;
        }
        __syncthreads();
        #pragma unroll
        for (int kk = 0; kk < 16; ++kk) {
            float a[4], bb[4];
            #pragma unroll
            for (int i = 0; i < 4; ++i) a[i] = As[kk][ty * 4 + i];
            #pragma unroll
            for (int j = 0; j < 4; ++j) bb[j] = Bs[kk][tx * 4 + j];
            #pragma unroll
            for (int i = 0; i < 4; ++i)
                #pragma unroll
                for (int j = 0; j < 4; ++j)
                    acc[i][j] += a[i] * bb[j];
        }
        __syncthreads();
    }
    #pragma unroll
    for (int i = 0; i < 4; ++i) {
        int gr = row0 + ty * 4 + i;
        if (gr >= M) continue;
        #pragma unroll
        for (int j = 0; j < 4; ++j) {
            int gc = col0 + tx * 4 + j;
            if (gc >= N) continue;
            float vv = acc[i][j];
            if (flags & F_BIAS)  vv += bias[gc];
            if (flags & F_SILU)  vv = vv / (1.f + expf(-vv));
            size_t cidx = (size_t)gr * ldc + gc;
            if (flags & F_MULIN) vv *= C[cidx];
            if (flags & F_RESID) vv += C[cidx];
            C[cidx] = vv;
        }
    }
}

// ---------------- RMSNorm fp32 (fallback) ----------------
__global__ __launch_bounds__(256) void rmsnorm_k(const float* __restrict__ x,
    const float* __restrict__ w, float* __restrict__ y)
{
    int row = blockIdx.x;
    const float* xr = x + (size_t)row * H;
    float* yr = y + (size_t)row * H;
    __shared__ float red[256];
    float s = 0.f;
    for (int i = threadIdx.x; i < H; i += 256) { float v = xr[i]; s += v * v; }
    red[threadIdx.x] = s; __syncthreads();
    for (int off = 128; off > 0; off >>= 1) {
        if (threadIdx.x < off) red[threadIdx.x] += red[threadIdx.x + off];
        __syncthreads();
    }
    float r = 1.0f / sqrtf(red[0] / (float)H + 1e-6f);
    for (int i = threadIdx.x; i < H; i += 256) yr[i] = xr[i] * r * w[i];
}

// ---------------- Embed gather ----------------
__global__ __launch_bounds__(256) void embed_k(const int* __restrict__ ids,
    const float* __restrict__ emb, float* __restrict__ h)
{
    int bs = blockIdx.x;
    const float* e = emb + (size_t)ids[bs] * H;
    float* hr = h + (size_t)bs * H;
    for (int i = threadIdx.x; i < H; i += 256) hr[i] = e[i];
}

// ---------------- RoPE fp32 in-place (fallback) ----------------
__global__ __launch_bounds__(256) void rope_k(float* __restrict__ x, const int* __restrict__ pos)
{
    int idx = blockIdx.x * 256 + threadIdx.x;
    int i = idx & 31;
    int head = (idx >> 5) & 15;
    int bs = idx >> 9;
    int p = pos[bs];
    double inv = exp(-((double)(2 * i) / 64.0) * log(10000.0));
    double ang = (double)p * inv;
    float c = (float)cos(ang), sn = (float)sin(ang);
    float* base = x + (size_t)bs * H + head * 64;
    float x1 = base[i], x2 = base[i + 32];
    base[i]      = x1 * c - x2 * sn;
    base[i + 32] = x2 * c + x1 * sn;
}

// ---------------- Flash attention fp32 (fallback) ----------------
__global__ __launch_bounds__(256) void fattn_k(const float* __restrict__ q,
    const float* __restrict__ k, const float* __restrict__ v,
    float* __restrict__ o, const int* __restrict__ valid)
{
    const int qt = blockIdx.x, hh = blockIdx.y, b = blockIdx.z;
    const int tid = threadIdx.x;
    const int tx = tid & 15, ty = tid >> 4;
    __shared__ float Qs[64][68];
    __shared__ float Ks[64][68];
    __shared__ float Vs[64][68];
    __shared__ int   kvs[64];
    const size_t hoff = (size_t)hh * HD;

    {
        int row = tid >> 2, d0 = (tid & 3) * 16;
        const float* qp = q + ((size_t)(b * S + qt * 64 + row)) * H + hoff + d0;
        float4* dst = (float4*)&Qs[row][d0];
        const float4* src = (const float4*)qp;
        #pragma unroll
        for (int e = 0; e < 4; ++e) dst[e] = src[e];
    }
    int qv[4]; int qrow_g[4];
    #pragma unroll
    for (int i = 0; i < 4; ++i) {
        qrow_g[i] = qt * 64 + ty * 4 + i;
        qv[i] = valid[b * S + qrow_g[i]];
    }
    float m[4], l[4], acc[4][4];
    #pragma unroll
    for (int i = 0; i < 4; ++i) {
        m[i] = -3.4e38f; l[i] = 0.f;
        #pragma unroll
        for (int j = 0; j < 4; ++j) acc[i][j] = 0.f;
    }

    for (int kt = 0; kt < S / 64; ++kt) {
        __syncthreads();
        {
            int row = tid >> 2, d0 = (tid & 3) * 16;
            const float* kp = k + ((size_t)(b * S + kt * 64 + row)) * H + hoff + d0;
            float4* dst = (float4*)&Ks[row][d0];
            const float4* src = (const float4*)kp;
            #pragma unroll
            for (int e = 0; e < 4; ++e) dst[e] = src[e];
        }
        {
            int kk = tid >> 2, d0 = (tid & 3) * 16;
            const float* vp = v + ((size_t)(b * S + kt * 64 + kk)) * H + hoff + d0;
            #pragma unroll
            for (int e = 0; e < 16; e += 4) {
                float4 vv = *(const float4*)(vp + e);
                Vs[d0 + e + 0][kk] = vv.x;
                Vs[d0 + e + 1][kk] = vv.y;
                Vs[d0 + e + 2][kk] = vv.z;
                Vs[d0 + e + 3][kk] = vv.w;
            }
        }
        if (tid < 64) kvs[tid] = valid[b * S + kt * 64 + tid];
        __syncthreads();

        float s4[4][4];
        #pragma unroll
        for (int i = 0; i < 4; ++i)
            #pragma unroll
            for (int j = 0; j < 4; ++j) s4[i][j] = 0.f;
        #pragma unroll
        for (int c = 0; c < 16; ++c) {
            float4 a[4], bb[4];
            #pragma unroll
            for (int i = 0; i < 4; ++i) a[i]  = ((const float4*)&Qs[ty * 4 + i][0])[c];
            #pragma unroll
            for (int j = 0; j < 4; ++j) bb[j] = ((const float4*)&Ks[tx * 4 + j][0])[c];
            #pragma unroll
            for (int i = 0; i < 4; ++i)
                #pragma unroll
                for (int j = 0; j < 4; ++j) {
                    s4[i][j] += a[i].x * bb[j].x + a[i].y * bb[j].y
                              + a[i].z * bb[j].z + a[i].w * bb[j].w;
                }
        }
        float p[4][4];
        float corr[4];
        #pragma unroll
        for (int i = 0; i < 4; ++i) {
            float rm = -3.4e38f;
            #pragma unroll
            for (int j = 0; j < 4; ++j) {
                int kc = kt * 64 + tx * 4 + j;
                float sv = s4[i][j] * 0.125f;
                int allowed = (kc <= qrow_g[i]) && qv[i] && kvs[tx * 4 + j];
                if (!allowed) sv = sv + -1e9f;
                s4[i][j] = sv;
                rm = fmaxf(rm, sv);
            }
            rm = fmaxf(rm, __shfl_xor(rm, 1));
            rm = fmaxf(rm, __shfl_xor(rm, 2));
            rm = fmaxf(rm, __shfl_xor(rm, 4));
            rm = fmaxf(rm, __shfl_xor(rm, 8));
            float mn = fmaxf(m[i], rm);
            corr[i] = expf(m[i] - mn);
            float rs = 0.f;
            #pragma unroll
            for (int j = 0; j < 4; ++j) { p[i][j] = expf(s4[i][j] - mn); rs += p[i][j]; }
            rs += __shfl_xor(rs, 1);
            rs += __shfl_xor(rs, 2);
            rs += __shfl_xor(rs, 4);
            rs += __shfl_xor(rs, 8);
            l[i] = l[i] * corr[i] + rs;
            m[i] = mn;
            #pragma unroll
            for (int j = 0; j < 4; ++j) acc[i][j] *= corr[i];
        }
        __syncthreads();
        #pragma unroll
        for (int i = 0; i < 4; ++i) {
            float4 pv4 = make_float4(p[i][0], p[i][1], p[i][2], p[i][3]);
            *(float4*)&Ks[ty * 4 + i][tx * 4] = pv4;
        }
        __syncthreads();
        #pragma unroll
        for (int c = 0; c < 16; ++c) {
            float4 a[4], bb[4];
            #pragma unroll
            for (int i = 0; i < 4; ++i) a[i]  = ((const float4*)&Ks[ty * 4 + i][0])[c];
            #pragma unroll
            for (int j = 0; j < 4; ++j) bb[j] = ((const float4*)&Vs[tx * 4 + j][0])[c];
            #pragma unroll
            for (int i = 0; i < 4; ++i)
                #pragma unroll
                for (int j = 0; j < 4; ++j) {
                    acc[i][j] += a[i].x * bb[j].x + a[i].y * bb[j].y
                               + a[i].z * bb[j].z + a[i].w * bb[j].w;
                }
        }
    }
    #pragma unroll
    for (int i = 0; i < 4; ++i) {
        float inv = 1.0f / l[i];
        float4 ov = make_float4(acc[i][0] * inv, acc[i][1] * inv,
                                acc[i][2] * inv, acc[i][3] * inv);
        *(float4*)(o + ((size_t)(b * S + qrow_g[i])) * H + hoff + tx * 4) = ov;
    }
}

// ---------------- Discretize: fp16 swizzled z + fp32 fallback ----------------
__global__ __launch_bounds__(256) void discretize_h_k(const float* __restrict__ logits,
    const float* __restrict__ gumbel, _Float16* __restrict__ z, int* __restrict__ chosen)
{
    int bs = blockIdx.x;
    const float* lg = logits + (size_t)bs * CV1;
    const float* gm = gumbel + (size_t)bs * CV1;
    __shared__ float redv[256]; __shared__ int redi[256];
    int tid = threadIdx.x;
    float m = -3.4e38f; int mi = CV1;
    for (int j = tid; j < CV1; j += 256) {
        float a = lg[j] + gm[j];
        if (a > m) { m = a; mi = j; }
    }
    redv[tid] = m; redi[tid] = mi; __syncthreads();
    for (int off = 128; off > 0; off >>= 1) {
        if (tid < off) {
            float vo = redv[tid + off]; int io = redi[tid + off];
            if (vo > redv[tid] || (vo == redv[tid] && io < redi[tid])) { redv[tid] = vo; redi[tid] = io; }
        }
        __syncthreads();
    }
    m = redv[0]; int amax = redi[0];
    __syncthreads();
    float ssum = 0.f;
    for (int j = tid; j < CV1; j += 256) ssum += expf(lg[j] + gm[j] - m);
    redv[tid] = ssum; __syncthreads();
    for (int off = 128; off > 0; off >>= 1) {
        if (tid < off) redv[tid] += redv[tid + off];
        __syncthreads();
    }
    float inv = 1.0f / redv[0];
    size_t rowbase = (size_t)bs * CV;
    int phi = (bs >> 1) & 3;
    for (int j = tid; j < CV; j += 256) {
        float zv = expf(lg[j] + gm[j] - m) * inv;
        z[swz_idx(rowbase, j, phi)] = (_Float16)zv;
    }
    if (tid == 0) chosen[bs] = amax;
}

__global__ __launch_bounds__(256) void discretize_k(const float* __restrict__ logits,
    const float* __restrict__ gumbel, float* __restrict__ z, int* __restrict__ chosen)
{
    int bs = blockIdx.x;
    const float* lg = logits + (size_t)bs * CV1;
    const float* gm = gumbel + (size_t)bs * CV1;
    __shared__ float redv[256]; __shared__ int redi[256];
    int tid = threadIdx.x;
    float m = -3.4e38f; int mi = CV1;
    for (int j = tid; j < CV1; j += 256) {
        float a = lg[j] + gm[j];
        if (a > m) { m = a; mi = j; }
    }
    redv[tid] = m; redi[tid] = mi; __syncthreads();
    for (int off = 128; off > 0; off >>= 1) {
        if (tid < off) {
            float vo = redv[tid + off]; int io = redi[tid + off];
            if (vo > redv[tid] || (vo == redv[tid] && io < redi[tid])) { redv[tid] = vo; redi[tid] = io; }
        }
        __syncthreads();
    }
    m = redv[0]; int amax = redi[0];
    __syncthreads();
    float ssum = 0.f;
    for (int j = tid; j < CV1; j += 256) ssum += expf(lg[j] + gm[j] - m);
    redv[tid] = ssum; __syncthreads();
    for (int off = 128; off > 0; off >>= 1) {
        if (tid < off) redv[tid] += redv[tid + off];
        __syncthreads();
    }
    float inv = 1.0f / redv[0];
    for (int j = tid; j < CV; j += 256)
        z[(size_t)bs * CV + j] = expf(lg[j] + gm[j] - m) * inv;
    if (tid == 0) chosen[bs] = amax;
}

// ---------------- cea + loss ----------------
__global__ __launch_bounds__(256) void cea_k(const float* __restrict__ esoft,
    const float* __restrict__ cemb, const int* __restrict__ chosen,
    const int* __restrict__ amask, float* __restrict__ cea, float* __restrict__ partial)
{
    int bs = blockIdx.x;
    int ch = chosen[bs]; int vm = amask[bs];
    int comp = (ch != CV) && vm;
    const float* ehr = cemb + (size_t)(ch < CV - 1 ? ch : CV - 1) * H;
    __shared__ float red[256];
    float part = 0.f;
    float vmf = vm ? 1.f : 0.f;
    for (int i = threadIdx.x; i < H; i += 256) {
        float es = esoft[(size_t)bs * H + i];
        float eh = comp ? ehr[i] : 0.f;
        cea[(size_t)bs * H + i] = ((eh + es) - es) * vmf;
        float d = es - eh;
        part += d * d;
    }
    red[threadIdx.x] = part; __syncthreads();
    for (int off = 128; off > 0; off >>= 1) {
        if (threadIdx.x < off) red[threadIdx.x] += red[threadIdx.x + off];
        __syncthreads();
    }
    if (threadIdx.x == 0) partial[bs] = red[0];
}

__global__ __launch_bounds__(256) void loss_k(const float* __restrict__ partial, float* __restrict__ out)
{
    __shared__ float red[256];
    float s = 0.f;
    for (int i = threadIdx.x; i < BS; i += 256) s += partial[i];
    red[threadIdx.x] = s; __syncthreads();
    for (int off = 128; off > 0; off >>= 1) {
        if (threadIdx.x < off) red[threadIdx.x] += red[threadIdx.x + off];
        __syncthreads();
    }
    if (threadIdx.x == 0) out[0] = 1.25f * red[0] / (float)BSH;
}

// ---------------- Stable pack ----------------
__global__ void pack_k(const int* __restrict__ chosen, const int* __restrict__ amask,
    int* __restrict__ order, int* __restrict__ cpos, int* __restrict__ cvalid,
    int* __restrict__ counts)
{
    int b = blockIdx.x;
    if (threadIdx.x != 0) return;
    int cnt = 0;
    for (int s2 = 0; s2 < S; ++s2)
        if (chosen[b * S + s2] != CV && amask[b * S + s2]) order[b * S + cnt++] = s2;
    counts[b] = cnt;
    int j2 = cnt;
    for (int s2 = 0; s2 < S; ++s2)
        if (!(chosen[b * S + s2] != CV && amask[b * S + s2])) order[b * S + j2++] = s2;
    for (int j3 = 0; j3 < S; ++j3) {
        cvalid[b * S + j3] = (j3 < cnt) ? 1 : 0;
        cpos[b * S + j3]   = (j3 < cnt) ? order[b * S + j3] : 0;
    }
}

__global__ __launch_bounds__(256) void gather_k(const float* __restrict__ cea,
    const int* __restrict__ order, const int* __restrict__ cvalid, float* __restrict__ h)
{
    int bs = blockIdx.x;
    int b = bs >> 10;
    int src = order[bs];
    float f = cvalid[bs] ? 1.f : 0.f;
    const float* sp = cea + (size_t)(b * S + src) * H;
    float* dst = h + (size_t)bs * H;
    for (int i = threadIdx.x; i < H; i += 256) dst[i] = sp[i] * f;
}

__global__ __launch_bounds__(256) void outmask_k(const float* __restrict__ h,
    const int* __restrict__ cvalid, float* __restrict__ out)
{
    int bs = blockIdx.x;
    float f = cvalid[bs] ? 1.f : 0.f;
    for (int i = threadIdx.x; i < H; i += 256)
        out[(size_t)bs * H + i] = h[(size_t)bs * H + i] * f;
}

__global__ __launch_bounds__(256) void iota_k(int* __restrict__ pos)
{
    int idx = blockIdx.x * 256 + threadIdx.x;
    if (idx < BS) pos[idx] = idx & (S - 1);
}

// ================= Host-side drivers =================
static void run_block_f32(int layer,
    const float* ln1, const float* wq, const float* wk, const float* wv,
    const float* wo, const float* ln2, const float* wg, const float* wu, const float* wd,
    float* h, float* hn, float* q, float* k, float* v, float* o, float* f1,
    const int* valid, const int* pos, hipStream_t stream)
{
    size_t LHH = (size_t)layer * H * H;
    size_t LHF = (size_t)layer * H * FF;
    rmsnorm_k<<<BS, 256, 0, stream>>>(h, ln1 + (size_t)layer * H, hn);
    gemm_k<<<dim3(16, 64), 256, 0, stream>>>(hn, wq + LHH, nullptr, q, BS, H, H, H, H, H, 0);
    gemm_k<<<dim3(16, 64), 256, 0, stream>>>(hn, wk + LHH, nullptr, k, BS, H, H, H, H, H, 0);
    gemm_k<<<dim3(16, 64), 256, 0, stream>>>(hn, wv + LHH, nullptr, v, BS, H, H, H, H, H, 0);
    rope_k<<<8192, 256, 0, stream>>>(q, pos);
    rope_k<<<8192, 256, 0, stream>>>(k, pos);
    fattn_k<<<dim3(S / 64, NH, B), 256, 0, stream>>>(q, k, v, o, valid);
    gemm_k<<<dim3(16, 64), 256, 0, stream>>>(o, wo + LHH, nullptr, h, BS, H, H, H, H, H, F_RESID);
    rmsnorm_k<<<BS, 256, 0, stream>>>(h, ln2 + (size_t)layer * H, hn);
    gemm_k<<<dim3(64, 64), 256, 0, stream>>>(hn, wg + LHF, nullptr, f1, BS, FF, H, H, FF, FF, F_SILU);
    gemm_k<<<dim3(64, 64), 256, 0, stream>>>(hn, wu + LHF, nullptr, f1, BS, FF, H, H, FF, FF, F_MULIN);
    gemm_k<<<dim3(16, 64), 256, 0, stream>>>(f1, wd + (size_t)layer * FF * H, nullptr, h, BS, H, FF, FF, H, H, F_RESID);
}

// MFMA block: np = split planes (2 shallow / 1 mid), npass = 3 or 1
static void run_block_mf(int layer, int np, int npass,
    const float* ln1, const float* wq, const float* wk, const float* wv,
    const float* wo, const float* ln2, const float* wg, const float* wu, const float* wd,
    float* h, float* qkv,
    _Float16* hnsp, _Float16* osp, _Float16* wsp, _Float16* wsp2, _Float16* f1sp,
    _Float16* qsp, _Float16* ksp, _Float16* vtp,
    const int* valid, const int* pos, hipStream_t stream)
{
    const size_t PH = (size_t)H * H;        // wo plane
    const size_t P3H = 3 * PH;              // fused qkv plane
    const size_t PGU = (size_t)H * FF;      // wg/wu/wd plane
    const size_t PA = BSH;                  // activation plane
    const size_t PF = BSF;                  // f1 plane
    size_t LHH = (size_t)layer * H * H;
    size_t LHF = (size_t)layer * H * FF;
    dim3 gw32(H / 32, H / 32);

    rmsnorm_split_k<<<BS, 256, 0, stream>>>(h, ln1 + (size_t)layer * H, hnsp, PA, np);
    // fused QKV weight planes: rows 0..1023=Q, 1024..2047=K, 2048..3071=V
    splitwt_k<<<gw32, 256, 0, stream>>>(wq + LHH, wsp,               H, H, H, P3H, np);
    splitwt_k<<<gw32, 256, 0, stream>>>(wk + LHH, wsp + (size_t)H * H,     H, H, H, P3H, np);
    splitwt_k<<<gw32, 256, 0, stream>>>(wv + LHH, wsp + (size_t)2 * H * H, H, H, H, P3H, np);
    gemm_mf_k<<<dim3(3 * H / 128, BS / 128), 256, 0, stream>>>(
        hnsp, wsp, nullptr, qkv, nullptr, BS, 3 * H, H, 3 * H, PA, P3H, npass, 0);
    rope_split_k<<<8192, 256, 0, stream>>>(qkv, 3 * H, 0, pos, qsp, PA, np);
    rope_split_k<<<8192, 256, 0, stream>>>(qkv, 3 * H, H, pos, ksp, PA, np);
    splitvt_k<<<dim3(S / 32, H / 32, B), 256, 0, stream>>>(qkv, 3 * H, 2 * H, vtp, PA, np);
    if (np == 2)
        mfattn_k<2, 3><<<dim3(S / 64, NH, B), 256, 0, stream>>>(qsp, ksp, vtp, osp, valid);
    else
        mfattn_k<1, 1><<<dim3(S / 64, NH, B), 256, 0, stream>>>(qsp, ksp, vtp, osp, valid);
    splitwt_k<<<gw32, 256, 0, stream>>>(wo + LHH, wsp, H, H, H, PH, np);
    gemm_mf_k<<<dim3(H / 128, BS / 128), 256, 0, stream>>>(
        osp, wsp, nullptr, h, h, BS, H, H, H, PA, PH, npass, 1);
    rmsnorm_split_k<<<BS, 256, 0, stream>>>(h, ln2 + (size_t)layer * H, hnsp, PA, np);
    splitwt_k<<<dim3(FF / 32, H / 32), 256, 0, stream>>>(wg + LHF, wsp,  H, FF, FF, PGU, np);
    splitwt_k<<<dim3(FF / 32, H / 32), 256, 0, stream>>>(wu + LHF, wsp2, H, FF, FF, PGU, np);
    gateup_k<<<dim3(FF / 128, BS / 128), 256, 0, stream>>>(
        hnsp, wsp, wsp2, f1sp, BS, FF, H, PA, PGU, PF, npass, np, 2);
    splitwt_k<<<dim3(H / 32, FF / 32), 256, 0, stream>>>(wd + (size_t)layer * FF * H, wsp, FF, H, H, PGU, np);
    gemm_mf_k<<<dim3(H / 128, BS / 128), 256, 0, stream>>>(
        f1sp, wsp, nullptr, h, h, BS, H, FF, H, PF, PGU, npass, 1);
}

extern "C" void kernel_launch(void* const* d_in, const int* in_sizes, int n_in,
                              void* d_out, int out_size, void* d_ws, size_t ws_size,
                              hipStream_t stream)
{
    const int*   ids    = (const int*)d_in[0];
    const int*   amask  = (const int*)d_in[1];
    const float* embed  = (const float*)d_in[2];
    const float* ln1    = (const float*)d_in[3];
    const float* wq     = (const float*)d_in[4];
    const float* wk     = (const float*)d_in[5];
    const float* wv     = (const float*)d_in[6];
    const float* wo     = (const float*)d_in[7];
    const float* ln2    = (const float*)d_in[8];
    const float* wg     = (const float*)d_in[9];
    const float* wu     = (const float*)d_in[10];
    const float* wd     = (const float*)d_in[11];
    const float* head_w = (const float*)d_in[12];
    const float* head_b = (const float*)d_in[13];
    const float* cemb   = (const float*)d_in[14];
    const float* gumbel = (const float*)d_in[15];
    float* out = (float*)d_out;

    const size_t MB = 1ull << 20;
    const size_t NEED = 274 * MB;

    if (ws_size >= NEED) {
        // ===== MFMA path =====
        char* base = (char*)d_ws;
        float* h   = (float*)base;                  // 16MB
        float* qkv = (float*)(base + 16 * MB);      // 48MB [BS][3072] (spans 16..64)
        _Float16* zb   = (_Float16*)(base + 64 * MB);   // 16MB [BS][CV]
        _Float16* hnsp = (_Float16*)(base + 80 * MB);   // 2 planes x 8MB (also hsp for head)
        _Float16* osp  = (_Float16*)(base + 104 * MB);
        _Float16* wsp  = (_Float16*)(base + 128 * MB);  // <=24MB weight planes
        _Float16* wsp2 = (_Float16*)(base + 152 * MB);
        _Float16* f1sp = (_Float16*)(base + 176 * MB);  // 2 planes x 32MB (176..240)
        _Float16* qsp  = (_Float16*)(base + 176 * MB);  // alias f1sp (disjoint lifetime)
        _Float16* ksp  = (_Float16*)(base + 200 * MB);
        _Float16* vtp  = (_Float16*)(base + 224 * MB);
        int* meta   = (int*)(base + 272 * MB);
        int* chosen = meta;
        int* order  = meta + BS;
        int* cpos   = meta + 2 * BS;
        int* cvalid = meta + 3 * BS;
        int* counts = meta + 4 * BS;
        int* pos_sh = meta + 5 * BS;
        float* partial = (float*)(meta + 6 * BS);
        float* logits = qkv;          // 33.5MB (qkv dead after shallow blocks)
        float* esoft  = qkv;          // 16MB (logits dead after discretize)
        float* ceab   = qkv + BSH;    // next 16MB

        embed_k<<<BS, 256, 0, stream>>>(ids, embed, h);
        iota_k<<<16, 256, 0, stream>>>(pos_sh);

        for (int L = 0; L < 2; ++L)
            run_block_mf(L, 2, 3, ln1, wq, wk, wv, wo, ln2, wg, wu, wd,
                         h, qkv, hnsp, osp, wsp, wsp2, f1sp,
                         qsp, ksp, vtp, amask, pos_sh, stream);

        // ---- head logits: fp16 2-plane, ALL 4 products (argmax-critical) ----
        splita_swz_k<<<BS, 256, 0, stream>>>(h, hnsp, BSH, 2);
        splitwt_k<<<dim3(CV / 32, H / 32), 256, 0, stream>>>(head_w, wsp, H, CV, CV1, (size_t)CV * H, 2);
        gemm_mf_k<<<dim3(CV / 128, BS / 128), 256, 0, stream>>>(
            hnsp, wsp, head_b, logits, nullptr, BS, CV, H, CV1, BSH, (size_t)CV * H, 4, 1);
        headcol_k<<<BS, 64, 0, stream>>>(h, head_w, head_b, logits);
        discretize_h_k<<<BS, 256, 0, stream>>>(logits, gumbel, zb, chosen);

        // ---- e_soft = z @ cemb (fp16 1-plane) ----
        splitwt_k<<<dim3(H / 32, CV / 32), 256, 0, stream>>>(cemb, wsp, CV, H, H, (size_t)H * CV, 1);
        gemm_mf_k<<<dim3(H / 128, BS / 128), 256, 0, stream>>>(
            zb, wsp, nullptr, esoft, nullptr, BS, H, CV, H, (size_t)BS * CV, (size_t)H * CV, 1, 0);

        cea_k<<<BS, 256, 0, stream>>>(esoft, cemb, chosen, amask, ceab, partial);
        loss_k<<<1, 256, 0, stream>>>(partial, out + BSH);
        pack_k<<<B, 64, 0, stream>>>(chosen, amask, order, cpos, cvalid, counts);
        gather_k<<<BS, 256, 0, stream>>>(ceab, order, cvalid, h);

        for (int L = 2; L < 4; ++L)
            run_block_mf(L, 1, 1, ln1, wq, wk, wv, wo, ln2, wg, wu, wd,
                         h, qkv, hnsp, osp, wsp, wsp2, f1sp,
                         qsp, ksp, vtp, cvalid, cpos, stream);

        outmask_k<<<BS, 256, 0, stream>>>(h, cvalid, out);
    } else {
        // ===== fallback: fp32 path =====
        float* wsf = (float*)d_ws;
        float* h   = wsf;
        float* hn  = wsf + BSH;
        float* q   = wsf + 2 * BSH;
        float* k   = wsf + 3 * BSH;
        float* v   = wsf + 4 * BSH;
        float* o   = wsf + 5 * BSH;
        float* f1  = wsf + 6 * BSH;
        float* zbuf  = q;
        float* esoft = v;
        float* ceab  = o;
        int* meta   = (int*)(wsf + 6 * BSH + BSF);
        int* chosen = meta;
        int* order  = meta + BS;
        int* cpos   = meta + 2 * BS;
        int* cvalid = meta + 3 * BS;
        int* counts = meta + 4 * BS;
        int* pos_sh = meta + 5 * BS;
        float* partial = (float*)(meta + 6 * BS);

        embed_k<<<BS, 256, 0, stream>>>(ids, embed, h);
        iota_k<<<16, 256, 0, stream>>>(pos_sh);
        for (int L = 0; L < 2; ++L)
            run_block_f32(L, ln1, wq, wk, wv, wo, ln2, wg, wu, wd,
                          h, hn, q, k, v, o, f1, amask, pos_sh, stream);
        gemm_k<<<dim3(33, 64), 256, 0, stream>>>(h, head_w, head_b, f1, BS, CV1, H, H, CV1, CV1, F_BIAS);
        discretize_k<<<BS, 256, 0, stream>>>(f1, gumbel, zbuf, chosen);
        gemm_k<<<dim3(16, 64), 256, 0, stream>>>(zbuf, cemb, nullptr, esoft, BS, H, CV, CV, H, H, 0);
        cea_k<<<BS, 256, 0, stream>>>(esoft, cemb, chosen, amask, ceab, partial);
        loss_k<<<1, 256, 0, stream>>>(partial, out + BSH);
        pack_k<<<B, 64, 0, stream>>>(chosen, amask, order, cpos, cvalid, counts);
        gather_k<<<BS, 256, 0, stream>>>(ceab, order, cvalid, h);
        for (int L = 2; L < 4; ++L)
            run_block_f32(L, ln1, wq, wk, wv, wo, ln2, wg, wu, wd,
                          h, hn, q, k, v, o, f1, cvalid, cpos, stream);
        outmask_k<<<BS, 256, 0, stream>>>(h, cvalid, out);
    }
}

// Round 7
// 3065.050 us; speedup vs baseline: 11.6630x; 1.1051x over previous
//
#include <hip/hip_runtime.h>
#include <hip/hip_bf16.h>
#include <cmath>

#define B 4
#define S 1024
#define H 1024
#define NH 16
#define HD 64
#define FF 4096
#define CV 2048
#define CV1 2049
#define BS (B*S)            // 4096
#define BSH ((size_t)BS*H)  // 4194304
#define BSF ((size_t)BS*FF) // 16777216

#define F_BIAS  1
#define F_RESID 2
#define F_SILU  4
#define F_MULIN 8

typedef __attribute__((ext_vector_type(8))) _Float16 f16x8;
typedef __attribute__((ext_vector_type(4))) float f32x4;

// Pre-swizzled plane write: element (row,col) stored at
// rowbase + (col&~31) + ((((col>>3)&3)^phi)<<3) + (col&7), phi=(row>>1)&3.
// Linear global_load_lds DMA then reproduces the LDS image the MFMA ds_reads expect.
static __device__ inline size_t swz_idx(size_t rowbase, int col, int phi) {
    return rowbase + (size_t)(col & ~31) + ((size_t)(((col >> 3) & 3) ^ phi) << 3) + (col & 7);
}
// fp16 2-plane split store (np=1: single plane)
static __device__ inline void split_store_swz(float v, _Float16* p, size_t plane,
                                              size_t rowbase, int col, int phi, int np) {
    size_t idx = swz_idx(rowbase, col, phi);
    _Float16 h0 = (_Float16)v; p[idx] = h0;
    if (np == 2) p[plane + idx] = (_Float16)(v - (float)h0);
}

// global->LDS async DMA, 16B per lane, LDS dest = base + lane*16
static __device__ inline void gload16(const void* g, void* l) {
    __builtin_amdgcn_global_load_lds(
        (const __attribute__((address_space(1))) void*)g,
        (__attribute__((address_space(3))) void*)l, 16, 0, 0);
}

// XCD-chunk block swizzle. swz=0 none; 1=M-contig chunks; 2=N-contig chunks.
// Requires gridDim.x*gridDim.y % 8 == 0.
static __device__ inline void tile_coords(int swz, int& bx, int& by) {
    if (swz == 0) { bx = blockIdx.x; by = blockIdx.y; return; }
    int nbx = gridDim.x, nby = gridDim.y;
    int L = blockIdx.y * nbx + blockIdx.x;
    int cpx = (nbx * nby) >> 3;
    int cid = (L & 7) * cpx + (L >> 3);
    if (swz == 1) { by = cid / nbx; bx = cid % nbx; }
    else          { bx = cid / nby; by = cid % nby; }
}

// ============ MFMA GEMM (pass-fused): C = resid? + bias? + sum_{pr<NPROD} A_pa @ Wt_pw^T ============
// NP fp16 planes of A and Wt staged per K-step; NPROD product-combos per staged tile.
// Products: (0,0),(0,1),(1,0),(1,1) — NPROD=3 drops the 2^-22 (1,1) term.
template<int NP, int NPROD>
__global__ __launch_bounds__(256) void gemm_mf_k(
    const _Float16* __restrict__ A, const _Float16* __restrict__ Wt,
    const float* __restrict__ bias, float* __restrict__ C, const float* __restrict__ resid,
    int M, int N, int K, int ldc, size_t planeA, size_t planeW, int swz)
{
    __shared__ _Float16 As[NP][128 * 32];
    __shared__ _Float16 Bs[NP][128 * 32];
    const int tid = threadIdx.x;
    const int w = tid >> 6, l = tid & 63;
    const int wm = w >> 1, wn = w & 1;
    int bx, by; tile_coords(swz, bx, by);
    const int row0 = by * 128, col0 = bx * 128;
    const int rA = l >> 2;
    const int cq8 = (l & 3) * 8;
    const int PA[4] = {0, 0, 1, 1};
    const int PW[4] = {0, 1, 0, 1};

    f32x4 acc[4][4];
    #pragma unroll
    for (int i = 0; i < 4; ++i)
        #pragma unroll
        for (int j = 0; j < 4; ++j)
            #pragma unroll
            for (int r = 0; r < 4; ++r) acc[i][j][r] = 0.f;

    const int lr = l & 15, q = l >> 4;
    for (int k0 = 0; k0 < K; k0 += 32) {
        __syncthreads();
        #pragma unroll
        for (int p = 0; p < NP; ++p)
            #pragma unroll
            for (int s = 0; s < 2; ++s) {
                int rr = (w * 2 + s) * 16 + rA;
                gload16(A + (size_t)p * planeA + (size_t)(row0 + rr) * K + k0 + cq8,
                        &As[p][(w * 2 + s) * 512]);
                gload16(Wt + (size_t)p * planeW + (size_t)(col0 + rr) * K + k0 + cq8,
                        &Bs[p][(w * 2 + s) * 512]);
            }
        __syncthreads();
        f16x8 af[NP][4], bfv[NP][4];
        #pragma unroll
        for (int p = 0; p < NP; ++p)
            #pragma unroll
            for (int i = 0; i < 4; ++i) {
                int ra = wm * 64 + i * 16 + lr;
                af[p][i] = *(const f16x8*)&As[p][ra * 32 + (q ^ ((ra >> 1) & 3)) * 8];
                int rb = wn * 64 + i * 16 + lr;
                bfv[p][i] = *(const f16x8*)&Bs[p][rb * 32 + (q ^ ((rb >> 1) & 3)) * 8];
            }
        #pragma unroll
        for (int pr = 0; pr < NPROD; ++pr) {
            const int pa = PA[pr], pw = PW[pr];
            #pragma unroll
            for (int mi = 0; mi < 4; ++mi)
                #pragma unroll
                for (int ni = 0; ni < 4; ++ni)
                    acc[mi][ni] = __builtin_amdgcn_mfma_f32_16x16x32_f16(
                        af[pa][mi], bfv[pw][ni], acc[mi][ni], 0, 0, 0);
        }
    }
    const int cw = l & 15, rw = (l >> 4) * 4;
    #pragma unroll
    for (int mi = 0; mi < 4; ++mi)
        #pragma unroll
        for (int ni = 0; ni < 4; ++ni)
            #pragma unroll
            for (int r = 0; r < 4; ++r) {
                int gr = row0 + wm * 64 + mi * 16 + rw + r;
                int gc = col0 + wn * 64 + ni * 16 + cw;
                size_t ci = (size_t)gr * ldc + gc;
                float val = acc[mi][ni][r];
                if (bias)  val += bias[gc];
                if (resid) val += resid[ci];
                C[ci] = val;
            }
}

// ============ Fused gate-up (pass-fused): F = silu(A@Wg)*(A@Wu) -> pre-swz split planes ============
template<int NP, int NPROD>
__global__ __launch_bounds__(256) void gateup_k(
    const _Float16* __restrict__ A, const _Float16* __restrict__ Wg, const _Float16* __restrict__ Wu,
    _Float16* __restrict__ F, int M, int N, int K,
    size_t planeA, size_t planeW, size_t planeF, int npOut, int swz)
{
    __shared__ _Float16 As[NP][128 * 32];
    __shared__ _Float16 Bg[NP][128 * 32];
    __shared__ _Float16 Bu[NP][128 * 32];
    const int tid = threadIdx.x;
    const int w = tid >> 6, l = tid & 63;
    const int wm = w >> 1, wn = w & 1;
    int bx, by; tile_coords(swz, bx, by);
    const int row0 = by * 128, col0 = bx * 128;
    const int rA = l >> 2;
    const int cq8 = (l & 3) * 8;
    const int PA[4] = {0, 0, 1, 1};
    const int PW[4] = {0, 1, 0, 1};

    f32x4 accg[4][4], accu[4][4];
    #pragma unroll
    for (int i = 0; i < 4; ++i)
        #pragma unroll
        for (int j = 0; j < 4; ++j)
            #pragma unroll
            for (int r = 0; r < 4; ++r) { accg[i][j][r] = 0.f; accu[i][j][r] = 0.f; }

    const int lr = l & 15, q = l >> 4;
    for (int k0 = 0; k0 < K; k0 += 32) {
        __syncthreads();
        #pragma unroll
        for (int p = 0; p < NP; ++p)
            #pragma unroll
            for (int s = 0; s < 2; ++s) {
                int rr = (w * 2 + s) * 16 + rA;
                gload16(A  + (size_t)p * planeA + (size_t)(row0 + rr) * K + k0 + cq8,
                        &As[p][(w * 2 + s) * 512]);
                gload16(Wg + (size_t)p * planeW + (size_t)(col0 + rr) * K + k0 + cq8,
                        &Bg[p][(w * 2 + s) * 512]);
                gload16(Wu + (size_t)p * planeW + (size_t)(col0 + rr) * K + k0 + cq8,
                        &Bu[p][(w * 2 + s) * 512]);
            }
        __syncthreads();
        // cache A-fragments for both planes; reload Bg/Bu per product (VGPR budget)
        f16x8 af[NP][4];
        #pragma unroll
        for (int p = 0; p < NP; ++p)
            #pragma unroll
            for (int i = 0; i < 4; ++i) {
                int ra = wm * 64 + i * 16 + lr;
                af[p][i] = *(const f16x8*)&As[p][ra * 32 + (q ^ ((ra >> 1) & 3)) * 8];
            }
        #pragma unroll
        for (int pr = 0; pr < NPROD; ++pr) {
            const int pa = PA[pr], pw = PW[pr];
            f16x8 bg[4], bu[4];
            #pragma unroll
            for (int i = 0; i < 4; ++i) {
                int rb = wn * 64 + i * 16 + lr;
                int sb = (q ^ ((rb >> 1) & 3)) * 8;
                bg[i] = *(const f16x8*)&Bg[pw][rb * 32 + sb];
                bu[i] = *(const f16x8*)&Bu[pw][rb * 32 + sb];
            }
            #pragma unroll
            for (int mi = 0; mi < 4; ++mi)
                #pragma unroll
                for (int ni = 0; ni < 4; ++ni) {
                    accg[mi][ni] = __builtin_amdgcn_mfma_f32_16x16x32_f16(
                        af[pa][mi], bg[ni], accg[mi][ni], 0, 0, 0);
                    accu[mi][ni] = __builtin_amdgcn_mfma_f32_16x16x32_f16(
                        af[pa][mi], bu[ni], accu[mi][ni], 0, 0, 0);
                }
        }
    }
    const int cw = l & 15, rw = (l >> 4) * 4;
    #pragma unroll
    for (int mi = 0; mi < 4; ++mi)
        #pragma unroll
        for (int ni = 0; ni < 4; ++ni)
            #pragma unroll
            for (int r = 0; r < 4; ++r) {
                int gr = row0 + wm * 64 + mi * 16 + rw + r;
                int gc = col0 + wn * 64 + ni * 16 + cw;
                float g = accg[mi][ni][r], u = accu[mi][ni][r];
                float val = g / (1.f + expf(-g)) * u;
                split_store_swz(val, F, planeF, (size_t)gr * N, gc, (gr >> 1) & 3, npOut);
            }
}

// ============ MFMA flash attention (fp16, pre-swizzled planes, gload staging) ============
template<int NP, int NPROD>
__global__ __launch_bounds__(256) void mfattn_k(
    const _Float16* __restrict__ qsp, const _Float16* __restrict__ ksp,
    const _Float16* __restrict__ vtp, _Float16* __restrict__ osp,
    const int* __restrict__ valid)
{
    __shared__ _Float16 KP[NP][2][64 * 32];   // K tile; reused as P planes
    __shared__ _Float16 Vt[NP][2][64 * 32];   // V^T tile
    __shared__ int kvs[64];
    const int tid = threadIdx.x;
    const int w = tid >> 6, l = tid & 63;
    const int lr = l & 15, lq = l >> 4;
    const int qt = blockIdx.x, hh = blockIdx.y, b = blockIdx.z;
    const int rT = l >> 2;
    const int cq8 = (l & 3) * 8;
    const int PA[4] = {0, 0, 1, 1};
    const int PW[4] = {0, 1, 0, 1};

    f16x8 aq[NP][2];
    {
        const int qrowa = qt * 64 + w * 16 + lr;
        const int phiq = (qrowa >> 1) & 3;
        #pragma unroll
        for (int p = 0; p < NP; ++p)
            #pragma unroll
            for (int ks = 0; ks < 2; ++ks)
                aq[p][ks] = *(const f16x8*)(qsp + (size_t)p * BSH
                    + (size_t)(b * S + qrowa) * H + hh * 64 + ks * 32 + ((lq ^ phiq) << 3));
    }
    int qvr[4];
    #pragma unroll
    for (int r = 0; r < 4; ++r)
        qvr[r] = valid[b * S + qt * 64 + w * 16 + lq * 4 + r];

    float m[4], lsum[4];
    f32x4 acco[4];
    #pragma unroll
    for (int r = 0; r < 4; ++r) { m[r] = -3.4e38f; lsum[r] = 0.f; }
    #pragma unroll
    for (int n = 0; n < 4; ++n)
        #pragma unroll
        for (int r = 0; r < 4; ++r) acco[n][r] = 0.f;

    for (int kt = 0; kt < S / 64; ++kt) {
        __syncthreads();
        {
            const int r = w * 16 + rT;
            #pragma unroll
            for (int p = 0; p < NP; ++p)
                #pragma unroll
                for (int hf = 0; hf < 2; ++hf) {
                    gload16(ksp + (size_t)p * BSH
                            + (size_t)(b * S + kt * 64 + r) * H + hh * 64 + hf * 32 + cq8,
                            &KP[p][hf][w * 512]);
                    gload16(vtp + (size_t)p * BSH
                            + ((size_t)(hh * 64 + r) * B + b) * S + kt * 64 + hf * 32 + cq8,
                            &Vt[p][hf][w * 512]);
                }
        }
        if (tid < 64) kvs[tid] = valid[b * S + kt * 64 + tid];
        __syncthreads();

        // ---- S = Q @ K^T ----
        f32x4 accs[4];
        #pragma unroll
        for (int n = 0; n < 4; ++n)
            #pragma unroll
            for (int r = 0; r < 4; ++r) accs[n][r] = 0.f;
        #pragma unroll
        for (int pr = 0; pr < NPROD; ++pr) {
            const int pa = PA[pr], pw = PW[pr];
            #pragma unroll
            for (int ks = 0; ks < 2; ++ks)
                #pragma unroll
                for (int n = 0; n < 4; ++n) {
                    int rb = n * 16 + lr;
                    f16x8 bk = *(const f16x8*)&KP[pw][ks][rb * 32 + ((lq ^ ((rb >> 1) & 3))) * 8];
                    accs[n] = __builtin_amdgcn_mfma_f32_16x16x32_f16(
                        aq[pa][ks], bk, accs[n], 0, 0, 0);
                }
        }
        // ---- mask + online softmax ----
        float pf[4][4];
        int kva[4];
        #pragma unroll
        for (int n = 0; n < 4; ++n) kva[n] = kvs[n * 16 + lr];
        #pragma unroll
        for (int r = 0; r < 4; ++r) {
            int qr = qt * 64 + w * 16 + lq * 4 + r;
            float rowm = -3.4e38f;
            #pragma unroll
            for (int n = 0; n < 4; ++n) {
                int kc = kt * 64 + n * 16 + lr;
                float sv = accs[n][r] * 0.125f;
                int allowed = (kc <= qr) && qvr[r] && kva[n];
                if (!allowed) sv = sv + -1e9f;
                pf[n][r] = sv;
                rowm = fmaxf(rowm, sv);
            }
            rowm = fmaxf(rowm, __shfl_xor(rowm, 1));
            rowm = fmaxf(rowm, __shfl_xor(rowm, 2));
            rowm = fmaxf(rowm, __shfl_xor(rowm, 4));
            rowm = fmaxf(rowm, __shfl_xor(rowm, 8));
            float mn = fmaxf(m[r], rowm);
            float co = __expf(m[r] - mn);
            float rs = 0.f;
            #pragma unroll
            for (int n = 0; n < 4; ++n) { pf[n][r] = __expf(pf[n][r] - mn); rs += pf[n][r]; }
            rs += __shfl_xor(rs, 1);
            rs += __shfl_xor(rs, 2);
            rs += __shfl_xor(rs, 4);
            rs += __shfl_xor(rs, 8);
            lsum[r] = lsum[r] * co + rs;
            m[r] = mn;
            #pragma unroll
            for (int n = 0; n < 4; ++n) acco[n][r] *= co;
        }
        __syncthreads();
        // ---- write P (fp16 split) into KP, swizzled for a-frag reads ----
        #pragma unroll
        for (int n = 0; n < 4; ++n) {
            int col = n * 16 + lr;
            int hf = col >> 5, colh = col & 31, cq2 = colh >> 3, pos = colh & 7;
            #pragma unroll
            for (int r = 0; r < 4; ++r) {
                int rowg = w * 16 + lq * 4 + r;
                int off = rowg * 32 + (cq2 ^ ((rowg >> 1) & 3)) * 8 + pos;
                float pv = pf[n][r];
                _Float16 h0 = (_Float16)pv;
                KP[0][hf][off] = h0;
                if (NP == 2) KP[1][hf][off] = (_Float16)(pv - (float)h0);
            }
        }
        __syncthreads();
        // ---- O += P @ V ----
        #pragma unroll
        for (int pr = 0; pr < NPROD; ++pr) {
            const int pa = PA[pr], pw = PW[pr];
            #pragma unroll
            for (int ks = 0; ks < 2; ++ks) {
                int ra = w * 16 + lr;
                f16x8 ap = *(const f16x8*)&KP[pa][ks][ra * 32 + ((lq ^ ((ra >> 1) & 3))) * 8];
                #pragma unroll
                for (int n = 0; n < 4; ++n) {
                    int rb = n * 16 + lr;
                    f16x8 bv = *(const f16x8*)&Vt[pw][ks][rb * 32 + ((lq ^ ((rb >> 1) & 3))) * 8];
                    acco[n] = __builtin_amdgcn_mfma_f32_16x16x32_f16(
                        ap, bv, acco[n], 0, 0, 0);
                }
            }
        }
    }
    // ---- write O as pre-swizzled split planes ----
    #pragma unroll
    for (int r = 0; r < 4; ++r) {
        float inv = 1.0f / lsum[r];
        int qr = qt * 64 + w * 16 + lq * 4 + r;
        size_t rowbase = (size_t)(b * S + qr) * H;
        int phi = ((b * S + qr) >> 1) & 3;
        #pragma unroll
        for (int n = 0; n < 4; ++n)
            split_store_swz(acco[n][r] * inv, osp, BSH, rowbase, hh * 64 + n * 16 + lr, phi, NP);
    }
}

// ============ RoPE + fp16 split -> pre-swizzled planes (reads strided qkv buffer) ============
__global__ __launch_bounds__(256) void rope_split_k(const float* __restrict__ x,
    int xld, int xoff, const int* __restrict__ pos, _Float16* __restrict__ y,
    size_t plane, int np)
{
    int idx = blockIdx.x * 256 + threadIdx.x;
    int i = idx & 31;
    int head = (idx >> 5) & 15;
    int bs = idx >> 9;
    int p = pos[bs];
    double inv = exp(-((double)(2 * i) / 64.0) * log(10000.0));
    double ang = (double)p * inv;
    float c = (float)cos(ang), sn = (float)sin(ang);
    const float* base = x + (size_t)bs * xld + xoff + head * 64;
    float x1 = base[i], x2 = base[i + 32];
    size_t rowbase = (size_t)bs * H;
    int phi = (bs >> 1) & 3;
    split_store_swz(x1 * c - x2 * sn, y, plane, rowbase, head * 64 + i, phi, np);
    split_store_swz(x2 * c + x1 * sn, y, plane, rowbase, head * 64 + i + 32, phi, np);
}

// ============ V transpose + split (reads strided qkv) -> planes [(h*64+d)*B+b][S] ============
__global__ __launch_bounds__(256) void splitvt_k(const float* __restrict__ V,
    int vld, int voff, _Float16* __restrict__ Vt, size_t plane, int np)
{
    __shared__ float t[32][33];
    const int tid = threadIdx.x;
    const int s0 = blockIdx.x * 32;
    const int hd0 = blockIdx.y * 32;
    const int b = blockIdx.z;
    #pragma unroll
    for (int i = 0; i < 4; ++i) {
        int e = tid + i * 256;
        int rr = e >> 5, cc = e & 31;
        t[rr][cc] = V[(size_t)(b * S + s0 + rr) * vld + voff + hd0 + cc];
    }
    __syncthreads();
    #pragma unroll
    for (int i = 0; i < 4; ++i) {
        int e = tid + i * 256;
        int rn = e >> 5, ck = e & 31;
        int hd = hd0 + rn;
        size_t rowbase = ((size_t)hd * B + b) * S;
        split_store_swz(t[ck][rn], Vt, plane, rowbase, s0 + ck, ((hd & 63) >> 1) & 3, np);
    }
}

// ============ Weight transpose + fp16 split: W[K,N](srcld) -> Wt planes [N][K] ============
__global__ __launch_bounds__(256) void splitwt_k(const float* __restrict__ W,
    _Float16* __restrict__ Wt, int K, int N, int srcld, size_t plane, int np)
{
    __shared__ float t[32][33];
    const int tid = threadIdx.x;
    const int n0 = blockIdx.x * 32, k0 = blockIdx.y * 32;
    #pragma unroll
    for (int i = 0; i < 4; ++i) {
        int e = tid + i * 256;
        int rk = e >> 5, cn = e & 31;
        t[rk][cn] = W[(size_t)(k0 + rk) * srcld + n0 + cn];
    }
    __syncthreads();
    #pragma unroll
    for (int i = 0; i < 4; ++i) {
        int e = tid + i * 256;
        int rn = e >> 5, ck = e & 31;
        int nn = n0 + rn;
        split_store_swz(t[ck][rn], Wt, plane, (size_t)nn * K, k0 + ck, (nn >> 1) & 3, np);
    }
}

// ============ Plain fp32 -> fp16 split planes (rows of length H) ============
__global__ __launch_bounds__(256) void splita_swz_k(const float* __restrict__ x,
    _Float16* __restrict__ y, size_t plane, int np)
{
    int row = blockIdx.x;
    size_t rowbase = (size_t)row * H;
    int phi = (row >> 1) & 3;
    for (int i = threadIdx.x; i < H; i += 256)
        split_store_swz(x[rowbase + i], y, plane, rowbase, i, phi, np);
}

// ============ RMSNorm -> pre-swz fp16 split ============
__global__ __launch_bounds__(256) void rmsnorm_split_k(const float* __restrict__ x,
    const float* __restrict__ w, _Float16* __restrict__ y, size_t plane, int np)
{
    int row = blockIdx.x;
    const float* xr = x + (size_t)row * H;
    __shared__ float red[256];
    float s = 0.f;
    for (int i = threadIdx.x; i < H; i += 256) { float v = xr[i]; s += v * v; }
    red[threadIdx.x] = s; __syncthreads();
    for (int off = 128; off > 0; off >>= 1) {
        if (threadIdx.x < off) red[threadIdx.x] += red[threadIdx.x + off];
        __syncthreads();
    }
    float r = 1.0f / sqrtf(red[0] / (float)H + 1e-6f);
    size_t rowbase = (size_t)row * H;
    int phi = (row >> 1) & 3;
    for (int i = threadIdx.x; i < H; i += 256)
        split_store_swz(xr[i] * r * w[i], y, plane, rowbase, i, phi, np);
}

// ============ Head column 2048 (null logit), exact fp32 ============
__global__ __launch_bounds__(64) void headcol_k(const float* __restrict__ h,
    const float* __restrict__ head_w, const float* __restrict__ head_b,
    float* __restrict__ logits)
{
    int row = blockIdx.x;
    int l = threadIdx.x;
    float s = 0.f;
    for (int j = l; j < H; j += 64) s += h[(size_t)row * H + j] * head_w[(size_t)j * CV1 + CV];
    s += __shfl_xor(s, 1);
    s += __shfl_xor(s, 2);
    s += __shfl_xor(s, 4);
    s += __shfl_xor(s, 8);
    s += __shfl_xor(s, 16);
    s += __shfl_xor(s, 32);
    if (l == 0) logits[(size_t)row * CV1 + CV] = s + head_b[CV];
}

// ---------------- fp32 GEMM (fallback path) ----------------
__global__ __launch_bounds__(256) void gemm_k(
    const float* __restrict__ A, const float* __restrict__ Wm,
    const float* __restrict__ bias, float* __restrict__ C,
    int M, int N, int K, int lda, int ldb, int ldc, int flags)
{
    __shared__ float As[16][65];
    __shared__ float Bs[16][65];
    const int tid = threadIdx.x;
    const int tx = tid & 15, ty = tid >> 4;
    const int row0 = blockIdx.y * 64, col0 = blockIdx.x * 64;
    float acc[4][4] = {};
    for (int k0 = 0; k0 < K; k0 += 16) {
        #pragma unroll
        for (int l = 0; l < 4; ++l) {
            int e = tid + l * 256;
            int r = e >> 4, c = e & 15;
            int gr = row0 + r;
            float vv = 0.f;
            if (gr < M) vv = A[(size_t)gr * lda + (k0 + c)];
            As[c][r] = vv;
        }
        #pragma unroll
        for (int l = 0; l < 4; ++l) {
            int e = tid + l * 256;
            int r = e >> 6, c = e & 63;
            int gc = col0 + c;
            float vv = 0.f;
            if (gc < N) vv = Wm[(size_t)(k0 + r) * ldb + gc];
            Bs[r][c] = vv;
        }
        __syncthreads();
        #pragma unroll
        for (int kk = 0; kk < 16; ++kk) {
            float a[4], bb[4];
            #pragma unroll
            for (int i = 0; i < 4; ++i) a[i] = As[kk][ty * 4 + i];
            #pragma unroll
            for (int j = 0; j < 4; ++j) bb[j] = Bs[kk][tx * 4 + j];
            #pragma unroll
            for (int i = 0; i < 4; ++i)
                #pragma unroll
                for (int j = 0; j < 4; ++j)
                    acc[i][j] += a[i] * bb[j];
        }
        __syncthreads();
    }
    #pragma unroll
    for (int i = 0; i < 4; ++i) {
        int gr = row0 + ty * 4 + i;
        if (gr >= M) continue;
        #pragma unroll
        for (int j = 0; j < 4; ++j) {
            int gc = col0 + tx * 4 + j;
            if (gc >= N) continue;
            float vv = acc[i][j];
            if (flags & F_BIAS)  vv += bias[gc];
            if (flags & F_SILU)  vv = vv / (1.f + expf(-vv));
            size_t cidx = (size_t)gr * ldc + gc;
            if (flags & F_MULIN) vv *= C[cidx];
            if (flags & F_RESID) vv += C[cidx];
            C[cidx] = vv;
        }
    }
}

// ---------------- RMSNorm fp32 (fallback) ----------------
__global__ __launch_bounds__(256) void rmsnorm_k(const float* __restrict__ x,
    const float* __restrict__ w, float* __restrict__ y)
{
    int row = blockIdx.x;
    const float* xr = x + (size_t)row * H;
    float* yr = y + (size_t)row * H;
    __shared__ float red[256];
    float s = 0.f;
    for (int i = threadIdx.x; i < H; i += 256) { float v = xr[i]; s += v * v; }
    red[threadIdx.x] = s; __syncthreads();
    for (int off = 128; off > 0; off >>= 1) {
        if (threadIdx.x < off) red[threadIdx.x] += red[threadIdx.x + off];
        __syncthreads();
    }
    float r = 1.0f / sqrtf(red[0] / (float)H + 1e-6f);
    for (int i = threadIdx.x; i < H; i += 256) yr[i] = xr[i] * r * w[i];
}

// ---------------- Embed gather ----------------
__global__ __launch_bounds__(256) void embed_k(const int* __restrict__ ids,
    const float* __restrict__ emb, float* __restrict__ h)
{
    int bs = blockIdx.x;
    const float* e = emb + (size_t)ids[bs] * H;
    float* hr = h + (size_t)bs * H;
    for (int i = threadIdx.x; i < H; i += 256) hr[i] = e[i];
}

// ---------------- RoPE fp32 in-place (fallback) ----------------
__global__ __launch_bounds__(256) void rope_k(float* __restrict__ x, const int* __restrict__ pos)
{
    int idx = blockIdx.x * 256 + threadIdx.x;
    int i = idx & 31;
    int head = (idx >> 5) & 15;
    int bs = idx >> 9;
    int p = pos[bs];
    double inv = exp(-((double)(2 * i) / 64.0) * log(10000.0));
    double ang = (double)p * inv;
    float c = (float)cos(ang), sn = (float)sin(ang);
    float* base = x + (size_t)bs * H + head * 64;
    float x1 = base[i], x2 = base[i + 32];
    base[i]      = x1 * c - x2 * sn;
    base[i + 32] = x2 * c + x1 * sn;
}

// ---------------- Flash attention fp32 (fallback) ----------------
__global__ __launch_bounds__(256) void fattn_k(const float* __restrict__ q,
    const float* __restrict__ k, const float* __restrict__ v,
    float* __restrict__ o, const int* __restrict__ valid)
{
    const int qt = blockIdx.x, hh = blockIdx.y, b = blockIdx.z;
    const int tid = threadIdx.x;
    const int tx = tid & 15, ty = tid >> 4;
    __shared__ float Qs[64][68];
    __shared__ float Ks[64][68];
    __shared__ float Vs[64][68];
    __shared__ int   kvs[64];
    const size_t hoff = (size_t)hh * HD;

    {
        int row = tid >> 2, d0 = (tid & 3) * 16;
        const float* qp = q + ((size_t)(b * S + qt * 64 + row)) * H + hoff + d0;
        float4* dst = (float4*)&Qs[row][d0];
        const float4* src = (const float4*)qp;
        #pragma unroll
        for (int e = 0; e < 4; ++e) dst[e] = src[e];
    }
    int qv[4]; int qrow_g[4];
    #pragma unroll
    for (int i = 0; i < 4; ++i) {
        qrow_g[i] = qt * 64 + ty * 4 + i;
        qv[i] = valid[b * S + qrow_g[i]];
    }
    float m[4], l[4], acc[4][4];
    #pragma unroll
    for (int i = 0; i < 4; ++i) {
        m[i] = -3.4e38f; l[i] = 0.f;
        #pragma unroll
        for (int j = 0; j < 4; ++j) acc[i][j] = 0.f;
    }

    for (int kt = 0; kt < S / 64; ++kt) {
        __syncthreads();
        {
            int row = tid >> 2, d0 = (tid & 3) * 16;
            const float* kp = k + ((size_t)(b * S + kt * 64 + row)) * H + hoff + d0;
            float4* dst = (float4*)&Ks[row][d0];
            const float4* src = (const float4*)kp;
            #pragma unroll
            for (int e = 0; e < 4; ++e) dst[e] = src[e];
        }
        {
            int kk = tid >> 2, d0 = (tid & 3) * 16;
            const float* vp = v + ((size_t)(b * S + kt * 64 + kk)) * H + hoff + d0;
            #pragma unroll
            for (int e = 0; e < 16; e += 4) {
                float4 vv = *(const float4*)(vp + e);
                Vs[d0 + e + 0][kk] = vv.x;
                Vs[d0 + e + 1][kk] = vv.y;
                Vs[d0 + e + 2][kk] = vv.z;
                Vs[d0 + e + 3][kk] = vv.w;
            }
        }
        if (tid < 64) kvs[tid] = valid[b * S + kt * 64 + tid];
        __syncthreads();

        float s4[4][4];
        #pragma unroll
        for (int i = 0; i < 4; ++i)
            #pragma unroll
            for (int j = 0; j < 4; ++j) s4[i][j] = 0.f;
        #pragma unroll
        for (int c = 0; c < 16; ++c) {
            float4 a[4], bb[4];
            #pragma unroll
            for (int i = 0; i < 4; ++i) a[i]  = ((const float4*)&Qs[ty * 4 + i][0])[c];
            #pragma unroll
            for (int j = 0; j < 4; ++j) bb[j] = ((const float4*)&Ks[tx * 4 + j][0])[c];
            #pragma unroll
            for (int i = 0; i < 4; ++i)
                #pragma unroll
                for (int j = 0; j < 4; ++j) {
                    s4[i][j] += a[i].x * bb[j].x + a[i].y * bb[j].y
                              + a[i].z * bb[j].z + a[i].w * bb[j].w;
                }
        }
        float p[4][4];
        float corr[4];
        #pragma unroll
        for (int i = 0; i < 4; ++i) {
            float rm = -3.4e38f;
            #pragma unroll
            for (int j = 0; j < 4; ++j) {
                int kc = kt * 64 + tx * 4 + j;
                float sv = s4[i][j] * 0.125f;
                int allowed = (kc <= qrow_g[i]) && qv[i] && kvs[tx * 4 + j];
                if (!allowed) sv = sv + -1e9f;
                s4[i][j] = sv;
                rm = fmaxf(rm, sv);
            }
            rm = fmaxf(rm, __shfl_xor(rm, 1));
            rm = fmaxf(rm, __shfl_xor(rm, 2));
            rm = fmaxf(rm, __shfl_xor(rm, 4));
            rm = fmaxf(rm, __shfl_xor(rm, 8));
            float mn = fmaxf(m[i], rm);
            corr[i] = expf(m[i] - mn);
            float rs = 0.f;
            #pragma unroll
            for (int j = 0; j < 4; ++j) { p[i][j] = expf(s4[i][j] - mn); rs += p[i][j]; }
            rs += __shfl_xor(rs, 1);
            rs += __shfl_xor(rs, 2);
            rs += __shfl_xor(rs, 4);
            rs += __shfl_xor(rs, 8);
            l[i] = l[i] * corr[i] + rs;
            m[i] = mn;
            #pragma unroll
            for (int j = 0; j < 4; ++j) acc[i][j] *= corr[i];
        }
        __syncthreads();
        #pragma unroll
        for (int i = 0; i < 4; ++i) {
            float4 pv4 = make_float4(p[i][0], p[i][1], p[i][2], p[i][3]);
            *(float4*)&Ks[ty * 4 + i][tx * 4] = pv4;
        }
        __syncthreads();
        #pragma unroll
        for (int c = 0; c < 16; ++c) {
            float4 a[4], bb[4];
            #pragma unroll
            for (int i = 0; i < 4; ++i) a[i]  = ((const float4*)&Ks[ty * 4 + i][0])[c];
            #pragma unroll
            for (int j = 0; j < 4; ++j) bb[j] = ((const float4*)&Vs[tx * 4 + j][0])[c];
            #pragma unroll
            for (int i = 0; i < 4; ++i)
                #pragma unroll
                for (int j = 0; j < 4; ++j) {
                    acc[i][j] += a[i].x * bb[j].x + a[i].y * bb[j].y
                               + a[i].z * bb[j].z + a[i].w * bb[j].w;
                }
        }
    }
    #pragma unroll
    for (int i = 0; i < 4; ++i) {
        float inv = 1.0f / l[i];
        float4 ov = make_float4(acc[i][0] * inv, acc[i][1] * inv,
                                acc[i][2] * inv, acc[i][3] * inv);
        *(float4*)(o + ((size_t)(b * S + qrow_g[i])) * H + hoff + tx * 4) = ov;
    }
}

// ---------------- Discretize: fp16 swizzled z + fp32 fallback ----------------
__global__ __launch_bounds__(256) void discretize_h_k(const float* __restrict__ logits,
    const float* __restrict__ gumbel, _Float16* __restrict__ z, int* __restrict__ chosen)
{
    int bs = blockIdx.x;
    const float* lg = logits + (size_t)bs * CV1;
    const float* gm = gumbel + (size_t)bs * CV1;
    __shared__ float redv[256]; __shared__ int redi[256];
    int tid = threadIdx.x;
    float m = -3.4e38f; int mi = CV1;
    for (int j = tid; j < CV1; j += 256) {
        float a = lg[j] + gm[j];
        if (a > m) { m = a; mi = j; }
    }
    redv[tid] = m; redi[tid] = mi; __syncthreads();
    for (int off = 128; off > 0; off >>= 1) {
        if (tid < off) {
            float vo = redv[tid + off]; int io = redi[tid + off];
            if (vo > redv[tid] || (vo == redv[tid] && io < redi[tid])) { redv[tid] = vo; redi[tid] = io; }
        }
        __syncthreads();
    }
    m = redv[0]; int amax = redi[0];
    __syncthreads();
    float ssum = 0.f;
    for (int j = tid; j < CV1; j += 256) ssum += expf(lg[j] + gm[j] - m);
    redv[tid] = ssum; __syncthreads();
    for (int off = 128; off > 0; off >>= 1) {
        if (tid < off) redv[tid] += redv[tid + off];
        __syncthreads();
    }
    float inv = 1.0f / redv[0];
    size_t rowbase = (size_t)bs * CV;
    int phi = (bs >> 1) & 3;
    for (int j = tid; j < CV; j += 256) {
        float zv = expf(lg[j] + gm[j] - m) * inv;
        z[swz_idx(rowbase, j, phi)] = (_Float16)zv;
    }
    if (tid == 0) chosen[bs] = amax;
}

__global__ __launch_bounds__(256) void discretize_k(const float* __restrict__ logits,
    const float* __restrict__ gumbel, float* __restrict__ z, int* __restrict__ chosen)
{
    int bs = blockIdx.x;
    const float* lg = logits + (size_t)bs * CV1;
    const float* gm = gumbel + (size_t)bs * CV1;
    __shared__ float redv[256]; __shared__ int redi[256];
    int tid = threadIdx.x;
    float m = -3.4e38f; int mi = CV1;
    for (int j = tid; j < CV1; j += 256) {
        float a = lg[j] + gm[j];
        if (a > m) { m = a; mi = j; }
    }
    redv[tid] = m; redi[tid] = mi; __syncthreads();
    for (int off = 128; off > 0; off >>= 1) {
        if (tid < off) {
            float vo = redv[tid + off]; int io = redi[tid + off];
            if (vo > redv[tid] || (vo == redv[tid] && io < redi[tid])) { redv[tid] = vo; redi[tid] = io; }
        }
        __syncthreads();
    }
    m = redv[0]; int amax = redi[0];
    __syncthreads();
    float ssum = 0.f;
    for (int j = tid; j < CV1; j += 256) ssum += expf(lg[j] + gm[j] - m);
    redv[tid] = ssum; __syncthreads();
    for (int off = 128; off > 0; off >>= 1) {
        if (tid < off) redv[tid] += redv[tid + off];
        __syncthreads();
    }
    float inv = 1.0f / redv[0];
    for (int j = tid; j < CV; j += 256)
        z[(size_t)bs * CV + j] = expf(lg[j] + gm[j] - m) * inv;
    if (tid == 0) chosen[bs] = amax;
}

// ---------------- cea + loss ----------------
__global__ __launch_bounds__(256) void cea_k(const float* __restrict__ esoft,
    const float* __restrict__ cemb, const int* __restrict__ chosen,
    const int* __restrict__ amask, float* __restrict__ cea, float* __restrict__ partial)
{
    int bs = blockIdx.x;
    int ch = chosen[bs]; int vm = amask[bs];
    int comp = (ch != CV) && vm;
    const float* ehr = cemb + (size_t)(ch < CV - 1 ? ch : CV - 1) * H;
    __shared__ float red[256];
    float part = 0.f;
    float vmf = vm ? 1.f : 0.f;
    for (int i = threadIdx.x; i < H; i += 256) {
        float es = esoft[(size_t)bs * H + i];
        float eh = comp ? ehr[i] : 0.f;
        cea[(size_t)bs * H + i] = ((eh + es) - es) * vmf;
        float d = es - eh;
        part += d * d;
    }
    red[threadIdx.x] = part; __syncthreads();
    for (int off = 128; off > 0; off >>= 1) {
        if (threadIdx.x < off) red[threadIdx.x] += red[threadIdx.x + off];
        __syncthreads();
    }
    if (threadIdx.x == 0) partial[bs] = red[0];
}

__global__ __launch_bounds__(256) void loss_k(const float* __restrict__ partial, float* __restrict__ out)
{
    __shared__ float red[256];
    float s = 0.f;
    for (int i = threadIdx.x; i < BS; i += 256) s += partial[i];
    red[threadIdx.x] = s; __syncthreads();
    for (int off = 128; off > 0; off >>= 1) {
        if (threadIdx.x < off) red[threadIdx.x] += red[threadIdx.x + off];
        __syncthreads();
    }
    if (threadIdx.x == 0) out[0] = 1.25f * red[0] / (float)BSH;
}

// ---------------- Stable pack ----------------
__global__ void pack_k(const int* __restrict__ chosen, const int* __restrict__ amask,
    int* __restrict__ order, int* __restrict__ cpos, int* __restrict__ cvalid,
    int* __restrict__ counts)
{
    int b = blockIdx.x;
    if (threadIdx.x != 0) return;
    int cnt = 0;
    for (int s2 = 0; s2 < S; ++s2)
        if (chosen[b * S + s2] != CV && amask[b * S + s2]) order[b * S + cnt++] = s2;
    counts[b] = cnt;
    int j2 = cnt;
    for (int s2 = 0; s2 < S; ++s2)
        if (!(chosen[b * S + s2] != CV && amask[b * S + s2])) order[b * S + j2++] = s2;
    for (int j3 = 0; j3 < S; ++j3) {
        cvalid[b * S + j3] = (j3 < cnt) ? 1 : 0;
        cpos[b * S + j3]   = (j3 < cnt) ? order[b * S + j3] : 0;
    }
}

__global__ __launch_bounds__(256) void gather_k(const float* __restrict__ cea,
    const int* __restrict__ order, const int* __restrict__ cvalid, float* __restrict__ h)
{
    int bs = blockIdx.x;
    int b = bs >> 10;
    int src = order[bs];
    float f = cvalid[bs] ? 1.f : 0.f;
    const float* sp = cea + (size_t)(b * S + src) * H;
    float* dst = h + (size_t)bs * H;
    for (int i = threadIdx.x; i < H; i += 256) dst[i] = sp[i] * f;
}

__global__ __launch_bounds__(256) void outmask_k(const float* __restrict__ h,
    const int* __restrict__ cvalid, float* __restrict__ out)
{
    int bs = blockIdx.x;
    float f = cvalid[bs] ? 1.f : 0.f;
    for (int i = threadIdx.x; i < H; i += 256)
        out[(size_t)bs * H + i] = h[(size_t)bs * H + i] * f;
}

__global__ __launch_bounds__(256) void iota_k(int* __restrict__ pos)
{
    int idx = blockIdx.x * 256 + threadIdx.x;
    if (idx < BS) pos[idx] = idx & (S - 1);
}

// ================= Host-side drivers =================
static void run_block_f32(int layer,
    const float* ln1, const float* wq, const float* wk, const float* wv,
    const float* wo, const float* ln2, const float* wg, const float* wu, const float* wd,
    float* h, float* hn, float* q, float* k, float* v, float* o, float* f1,
    const int* valid, const int* pos, hipStream_t stream)
{
    size_t LHH = (size_t)layer * H * H;
    size_t LHF = (size_t)layer * H * FF;
    rmsnorm_k<<<BS, 256, 0, stream>>>(h, ln1 + (size_t)layer * H, hn);
    gemm_k<<<dim3(16, 64), 256, 0, stream>>>(hn, wq + LHH, nullptr, q, BS, H, H, H, H, H, 0);
    gemm_k<<<dim3(16, 64), 256, 0, stream>>>(hn, wk + LHH, nullptr, k, BS, H, H, H, H, H, 0);
    gemm_k<<<dim3(16, 64), 256, 0, stream>>>(hn, wv + LHH, nullptr, v, BS, H, H, H, H, H, 0);
    rope_k<<<8192, 256, 0, stream>>>(q, pos);
    rope_k<<<8192, 256, 0, stream>>>(k, pos);
    fattn_k<<<dim3(S / 64, NH, B), 256, 0, stream>>>(q, k, v, o, valid);
    gemm_k<<<dim3(16, 64), 256, 0, stream>>>(o, wo + LHH, nullptr, h, BS, H, H, H, H, H, F_RESID);
    rmsnorm_k<<<BS, 256, 0, stream>>>(h, ln2 + (size_t)layer * H, hn);
    gemm_k<<<dim3(64, 64), 256, 0, stream>>>(hn, wg + LHF, nullptr, f1, BS, FF, H, H, FF, FF, F_SILU);
    gemm_k<<<dim3(64, 64), 256, 0, stream>>>(hn, wu + LHF, nullptr, f1, BS, FF, H, H, FF, FF, F_MULIN);
    gemm_k<<<dim3(16, 64), 256, 0, stream>>>(f1, wd + (size_t)layer * FF * H, nullptr, h, BS, H, FF, FF, H, H, F_RESID);
}

// MFMA block, templated on split planes / products (shallow <2,3>, mid <1,1>)
template<int NP, int NPROD>
static void run_block_mf(int layer,
    const float* ln1, const float* wq, const float* wk, const float* wv,
    const float* wo, const float* ln2, const float* wg, const float* wu, const float* wd,
    float* h, float* qkv,
    _Float16* hnsp, _Float16* osp, _Float16* wsp, _Float16* wsp2, _Float16* f1sp,
    _Float16* qsp, _Float16* ksp, _Float16* vtp,
    const int* valid, const int* pos, hipStream_t stream)
{
    const size_t PH = (size_t)H * H;        // wo plane
    const size_t P3H = 3 * PH;              // fused qkv plane
    const size_t PGU = (size_t)H * FF;      // wg/wu/wd plane
    const size_t PA = BSH;                  // activation plane
    const size_t PF = BSF;                  // f1 plane
    size_t LHH = (size_t)layer * H * H;
    size_t LHF = (size_t)layer * H * FF;
    dim3 gw32(H / 32, H / 32);

    rmsnorm_split_k<<<BS, 256, 0, stream>>>(h, ln1 + (size_t)layer * H, hnsp, PA, NP);
    splitwt_k<<<gw32, 256, 0, stream>>>(wq + LHH, wsp,                    H, H, H, P3H, NP);
    splitwt_k<<<gw32, 256, 0, stream>>>(wk + LHH, wsp + (size_t)H * H,    H, H, H, P3H, NP);
    splitwt_k<<<gw32, 256, 0, stream>>>(wv + LHH, wsp + (size_t)2 * H * H, H, H, H, P3H, NP);
    gemm_mf_k<NP, NPROD><<<dim3(3 * H / 128, BS / 128), 256, 0, stream>>>(
        hnsp, wsp, nullptr, qkv, nullptr, BS, 3 * H, H, 3 * H, PA, P3H, 0);
    rope_split_k<<<8192, 256, 0, stream>>>(qkv, 3 * H, 0, pos, qsp, PA, NP);
    rope_split_k<<<8192, 256, 0, stream>>>(qkv, 3 * H, H, pos, ksp, PA, NP);
    splitvt_k<<<dim3(S / 32, H / 32, B), 256, 0, stream>>>(qkv, 3 * H, 2 * H, vtp, PA, NP);
    mfattn_k<NP, NPROD><<<dim3(S / 64, NH, B), 256, 0, stream>>>(qsp, ksp, vtp, osp, valid);
    splitwt_k<<<gw32, 256, 0, stream>>>(wo + LHH, wsp, H, H, H, PH, NP);
    gemm_mf_k<NP, NPROD><<<dim3(H / 128, BS / 128), 256, 0, stream>>>(
        osp, wsp, nullptr, h, h, BS, H, H, H, PA, PH, 1);
    rmsnorm_split_k<<<BS, 256, 0, stream>>>(h, ln2 + (size_t)layer * H, hnsp, PA, NP);
    splitwt_k<<<dim3(FF / 32, H / 32), 256, 0, stream>>>(wg + LHF, wsp,  H, FF, FF, PGU, NP);
    splitwt_k<<<dim3(FF / 32, H / 32), 256, 0, stream>>>(wu + LHF, wsp2, H, FF, FF, PGU, NP);
    gateup_k<NP, NPROD><<<dim3(FF / 128, BS / 128), 256, 0, stream>>>(
        hnsp, wsp, wsp2, f1sp, BS, FF, H, PA, PGU, PF, NP, 2);
    splitwt_k<<<dim3(H / 32, FF / 32), 256, 0, stream>>>(wd + (size_t)layer * FF * H, wsp, FF, H, H, PGU, NP);
    gemm_mf_k<NP, NPROD><<<dim3(H / 128, BS / 128), 256, 0, stream>>>(
        f1sp, wsp, nullptr, h, h, BS, H, FF, H, PF, PGU, 1);
}

extern "C" void kernel_launch(void* const* d_in, const int* in_sizes, int n_in,
                              void* d_out, int out_size, void* d_ws, size_t ws_size,
                              hipStream_t stream)
{
    const int*   ids    = (const int*)d_in[0];
    const int*   amask  = (const int*)d_in[1];
    const float* embed  = (const float*)d_in[2];
    const float* ln1    = (const float*)d_in[3];
    const float* wq     = (const float*)d_in[4];
    const float* wk     = (const float*)d_in[5];
    const float* wv     = (const float*)d_in[6];
    const float* wo     = (const float*)d_in[7];
    const float* ln2    = (const float*)d_in[8];
    const float* wg     = (const float*)d_in[9];
    const float* wu     = (const float*)d_in[10];
    const float* wd     = (const float*)d_in[11];
    const float* head_w = (const float*)d_in[12];
    const float* head_b = (const float*)d_in[13];
    const float* cemb   = (const float*)d_in[14];
    const float* gumbel = (const float*)d_in[15];
    float* out = (float*)d_out;

    const size_t MB = 1ull << 20;
    const size_t NEED = 274 * MB;

    if (ws_size >= NEED) {
        // ===== MFMA path =====
        char* base = (char*)d_ws;
        float* h   = (float*)base;                  // 16MB
        float* qkv = (float*)(base + 16 * MB);      // 48MB [BS][3072]
        _Float16* zb   = (_Float16*)(base + 64 * MB);   // 16MB [BS][CV]
        _Float16* hnsp = (_Float16*)(base + 80 * MB);   // 2 planes x 8MB
        _Float16* osp  = (_Float16*)(base + 104 * MB);
        _Float16* wsp  = (_Float16*)(base + 128 * MB);  // <=24MB weight planes
        _Float16* wsp2 = (_Float16*)(base + 152 * MB);
        _Float16* f1sp = (_Float16*)(base + 176 * MB);  // 2 planes x 32MB
        _Float16* qsp  = (_Float16*)(base + 176 * MB);  // alias f1sp (disjoint lifetime)
        _Float16* ksp  = (_Float16*)(base + 200 * MB);
        _Float16* vtp  = (_Float16*)(base + 224 * MB);
        int* meta   = (int*)(base + 272 * MB);
        int* chosen = meta;
        int* order  = meta + BS;
        int* cpos   = meta + 2 * BS;
        int* cvalid = meta + 3 * BS;
        int* counts = meta + 4 * BS;
        int* pos_sh = meta + 5 * BS;
        float* partial = (float*)(meta + 6 * BS);
        float* logits = qkv;          // qkv dead after shallow blocks
        float* esoft  = qkv;
        float* ceab   = qkv + BSH;

        embed_k<<<BS, 256, 0, stream>>>(ids, embed, h);
        iota_k<<<16, 256, 0, stream>>>(pos_sh);

        for (int L = 0; L < 2; ++L)
            run_block_mf<2, 3>(L, ln1, wq, wk, wv, wo, ln2, wg, wu, wd,
                               h, qkv, hnsp, osp, wsp, wsp2, f1sp,
                               qsp, ksp, vtp, amask, pos_sh, stream);

        // ---- head logits: fp16 2-plane, ALL 4 products (argmax-critical) ----
        splita_swz_k<<<BS, 256, 0, stream>>>(h, hnsp, BSH, 2);
        splitwt_k<<<dim3(CV / 32, H / 32), 256, 0, stream>>>(head_w, wsp, H, CV, CV1, (size_t)CV * H, 2);
        gemm_mf_k<2, 4><<<dim3(CV / 128, BS / 128), 256, 0, stream>>>(
            hnsp, wsp, head_b, logits, nullptr, BS, CV, H, CV1, BSH, (size_t)CV * H, 1);
        headcol_k<<<BS, 64, 0, stream>>>(h, head_w, head_b, logits);
        discretize_h_k<<<BS, 256, 0, stream>>>(logits, gumbel, zb, chosen);

        // ---- e_soft = z @ cemb (fp16 1-plane) ----
        splitwt_k<<<dim3(H / 32, CV / 32), 256, 0, stream>>>(cemb, wsp, CV, H, H, (size_t)H * CV, 1);
        gemm_mf_k<1, 1><<<dim3(H / 128, BS / 128), 256, 0, stream>>>(
            zb, wsp, nullptr, esoft, nullptr, BS, H, CV, H, (size_t)BS * CV, (size_t)H * CV, 0);

        cea_k<<<BS, 256, 0, stream>>>(esoft, cemb, chosen, amask, ceab, partial);
        loss_k<<<1, 256, 0, stream>>>(partial, out + BSH);
        pack_k<<<B, 64, 0, stream>>>(chosen, amask, order, cpos, cvalid, counts);
        gather_k<<<BS, 256, 0, stream>>>(ceab, order, cvalid, h);

        for (int L = 2; L < 4; ++L)
            run_block_mf<1, 1>(L, ln1, wq, wk, wv, wo, ln2, wg, wu, wd,
                               h, qkv, hnsp, osp, wsp, wsp2, f1sp,
                               qsp, ksp, vtp, cvalid, cpos, stream);

        outmask_k<<<BS, 256, 0, stream>>>(h, cvalid, out);
    } else {
        // ===== fallback: fp32 path =====
        float* wsf = (float*)d_ws;
        float* h   = wsf;
        float* hn  = wsf + BSH;
        float* q   = wsf + 2 * BSH;
        float* k   = wsf + 3 * BSH;
        float* v   = wsf + 4 * BSH;
        float* o   = wsf + 5 * BSH;
        float* f1  = wsf + 6 * BSH;
        float* zbuf  = q;
        float* esoft = v;
        float* ceab  = o;
        int* meta   = (int*)(wsf + 6 * BSH + BSF);
        int* chosen = meta;
        int* order  = meta + BS;
        int* cpos   = meta + 2 * BS;
        int* cvalid = meta + 3 * BS;
        int* counts = meta + 4 * BS;
        int* pos_sh = meta + 5 * BS;
        float* partial = (float*)(meta + 6 * BS);

        embed_k<<<BS, 256, 0, stream>>>(ids, embed, h);
        iota_k<<<16, 256, 0, stream>>>(pos_sh);
        for (int L = 0; L < 2; ++L)
            run_block_f32(L, ln1, wq, wk, wv, wo, ln2, wg, wu, wd,
                          h, hn, q, k, v, o, f1, amask, pos_sh, stream);
        gemm_k<<<dim3(33, 64), 256, 0, stream>>>(h, head_w, head_b, f1, BS, CV1, H, H, CV1, CV1, F_BIAS);
        discretize_k<<<BS, 256, 0, stream>>>(f1, gumbel, zbuf, chosen);
        gemm_k<<<dim3(16, 64), 256, 0, stream>>>(zbuf, cemb, nullptr, esoft, BS, H, CV, CV, H, H, 0);
        cea_k<<<BS, 256, 0, stream>>>(esoft, cemb, chosen, amask, ceab, partial);
        loss_k<<<1, 256, 0, stream>>>(partial, out + BSH);
        pack_k<<<B, 64, 0, stream>>>(chosen, amask, order, cpos, cvalid, counts);
        gather_k<<<BS, 256, 0, stream>>>(ceab, order, cvalid, h);
        for (int L = 2; L < 4; ++L)
            run_block_f32(L, ln1, wq, wk, wv, wo, ln2, wg, wu, wd,
                          h, hn, q, k, v, o, f1, cvalid, cpos, stream);
        outmask_k<<<BS, 256, 0, stream>>>(h, cvalid, out);
    }
}

// Round 8
// 2731.495 us; speedup vs baseline: 13.0872x; 1.1221x over previous
//
#include <hip/hip_runtime.h>
#include <hip/hip_bf16.h>
#include <cmath>

#define B 4
#define S 1024
#define H 1024
#define NH 16
#define HD 64
#define FF 4096
#define CV 2048
#define CV1 2049
#define BS (B*S)            // 4096
#define BSH ((size_t)BS*H)  // 4194304
#define BSF ((size_t)BS*FF) // 16777216

#define F_BIAS  1
#define F_RESID 2
#define F_SILU  4
#define F_MULIN 8

typedef __attribute__((ext_vector_type(8))) _Float16 f16x8;
typedef __attribute__((ext_vector_type(4))) float f32x4;

// Pre-swizzled plane write: element (row,col) stored at
// rowbase + (col&~31) + ((((col>>3)&3)^phi)<<3) + (col&7), phi=(row>>1)&3.
// Linear global_load_lds DMA then reproduces the LDS image the MFMA ds_reads expect.
static __device__ inline size_t swz_idx(size_t rowbase, int col, int phi) {
    return rowbase + (size_t)(col & ~31) + ((size_t)(((col >> 3) & 3) ^ phi) << 3) + (col & 7);
}
// fp16 2-plane split store (np=1: single plane)
static __device__ inline void split_store_swz(float v, _Float16* p, size_t plane,
                                              size_t rowbase, int col, int phi, int np) {
    size_t idx = swz_idx(rowbase, col, phi);
    _Float16 h0 = (_Float16)v; p[idx] = h0;
    if (np == 2) p[plane + idx] = (_Float16)(v - (float)h0);
}

// global->LDS async DMA, 16B per lane, LDS dest = base + lane*16
static __device__ inline void gload16(const void* g, void* l) {
    __builtin_amdgcn_global_load_lds(
        (const __attribute__((address_space(1))) void*)g,
        (__attribute__((address_space(3))) void*)l, 16, 0, 0);
}

// XCD-chunk block swizzle. swz=0 none; 1=M-contig chunks; 2=N-contig chunks.
// Requires gridDim.x*gridDim.y % 8 == 0.
static __device__ inline void tile_coords(int swz, int& bx, int& by) {
    if (swz == 0) { bx = blockIdx.x; by = blockIdx.y; return; }
    int nbx = gridDim.x, nby = gridDim.y;
    int L = blockIdx.y * nbx + blockIdx.x;
    int cpx = (nbx * nby) >> 3;
    int cid = (L & 7) * cpx + (L >> 3);
    if (swz == 1) { by = cid / nbx; bx = cid % nbx; }
    else          { bx = cid / nby; by = cid % nby; }
}

// ============ MFMA GEMM (pass-fused): C = resid? + bias? + sum_{pr<NPROD} A_pa @ Wt_pw^T ============
template<int NP, int NPROD>
__global__ __launch_bounds__(256) void gemm_mf_k(
    const _Float16* __restrict__ A, const _Float16* __restrict__ Wt,
    const float* __restrict__ bias, float* __restrict__ C, const float* __restrict__ resid,
    int M, int N, int K, int ldc, size_t planeA, size_t planeW, int swz)
{
    __shared__ _Float16 As[NP][128 * 32];
    __shared__ _Float16 Bs[NP][128 * 32];
    const int tid = threadIdx.x;
    const int w = tid >> 6, l = tid & 63;
    const int wm = w >> 1, wn = w & 1;
    int bx, by; tile_coords(swz, bx, by);
    const int row0 = by * 128, col0 = bx * 128;
    const int rA = l >> 2;
    const int cq8 = (l & 3) * 8;
    const int PA[4] = {0, 0, 1, 1};
    const int PW[4] = {0, 1, 0, 1};

    f32x4 acc[4][4];
    #pragma unroll
    for (int i = 0; i < 4; ++i)
        #pragma unroll
        for (int j = 0; j < 4; ++j)
            #pragma unroll
            for (int r = 0; r < 4; ++r) acc[i][j][r] = 0.f;

    const int lr = l & 15, q = l >> 4;
    for (int k0 = 0; k0 < K; k0 += 32) {
        __syncthreads();
        #pragma unroll
        for (int p = 0; p < NP; ++p)
            #pragma unroll
            for (int s = 0; s < 2; ++s) {
                int rr = (w * 2 + s) * 16 + rA;
                gload16(A + (size_t)p * planeA + (size_t)(row0 + rr) * K + k0 + cq8,
                        &As[p][(w * 2 + s) * 512]);
                gload16(Wt + (size_t)p * planeW + (size_t)(col0 + rr) * K + k0 + cq8,
                        &Bs[p][(w * 2 + s) * 512]);
            }
        __syncthreads();
        f16x8 af[NP][4], bfv[NP][4];
        #pragma unroll
        for (int p = 0; p < NP; ++p)
            #pragma unroll
            for (int i = 0; i < 4; ++i) {
                int ra = wm * 64 + i * 16 + lr;
                af[p][i] = *(const f16x8*)&As[p][ra * 32 + (q ^ ((ra >> 1) & 3)) * 8];
                int rb = wn * 64 + i * 16 + lr;
                bfv[p][i] = *(const f16x8*)&Bs[p][rb * 32 + (q ^ ((rb >> 1) & 3)) * 8];
            }
        #pragma unroll
        for (int pr = 0; pr < NPROD; ++pr) {
            const int pa = PA[pr], pw = PW[pr];
            #pragma unroll
            for (int mi = 0; mi < 4; ++mi)
                #pragma unroll
                for (int ni = 0; ni < 4; ++ni)
                    acc[mi][ni] = __builtin_amdgcn_mfma_f32_16x16x32_f16(
                        af[pa][mi], bfv[pw][ni], acc[mi][ni], 0, 0, 0);
        }
    }
    const int cw = l & 15, rw = (l >> 4) * 4;
    #pragma unroll
    for (int mi = 0; mi < 4; ++mi)
        #pragma unroll
        for (int ni = 0; ni < 4; ++ni)
            #pragma unroll
            for (int r = 0; r < 4; ++r) {
                int gr = row0 + wm * 64 + mi * 16 + rw + r;
                int gc = col0 + wn * 64 + ni * 16 + cw;
                size_t ci = (size_t)gr * ldc + gc;
                float val = acc[mi][ni][r];
                if (bias)  val += bias[gc];
                if (resid) val += resid[ci];
                C[ci] = val;
            }
}

// ============ Fused gate-up (pass-fused): F = silu(A@Wg)*(A@Wu) -> pre-swz split planes ============
template<int NP, int NPROD>
__global__ __launch_bounds__(256) void gateup_k(
    const _Float16* __restrict__ A, const _Float16* __restrict__ Wg, const _Float16* __restrict__ Wu,
    _Float16* __restrict__ F, int M, int N, int K,
    size_t planeA, size_t planeW, size_t planeF, int npOut, int swz)
{
    __shared__ _Float16 As[NP][128 * 32];
    __shared__ _Float16 Bg[NP][128 * 32];
    __shared__ _Float16 Bu[NP][128 * 32];
    const int tid = threadIdx.x;
    const int w = tid >> 6, l = tid & 63;
    const int wm = w >> 1, wn = w & 1;
    int bx, by; tile_coords(swz, bx, by);
    const int row0 = by * 128, col0 = bx * 128;
    const int rA = l >> 2;
    const int cq8 = (l & 3) * 8;
    const int PA[4] = {0, 0, 1, 1};
    const int PW[4] = {0, 1, 0, 1};

    f32x4 accg[4][4], accu[4][4];
    #pragma unroll
    for (int i = 0; i < 4; ++i)
        #pragma unroll
        for (int j = 0; j < 4; ++j)
            #pragma unroll
            for (int r = 0; r < 4; ++r) { accg[i][j][r] = 0.f; accu[i][j][r] = 0.f; }

    const int lr = l & 15, q = l >> 4;
    for (int k0 = 0; k0 < K; k0 += 32) {
        __syncthreads();
        #pragma unroll
        for (int p = 0; p < NP; ++p)
            #pragma unroll
            for (int s = 0; s < 2; ++s) {
                int rr = (w * 2 + s) * 16 + rA;
                gload16(A  + (size_t)p * planeA + (size_t)(row0 + rr) * K + k0 + cq8,
                        &As[p][(w * 2 + s) * 512]);
                gload16(Wg + (size_t)p * planeW + (size_t)(col0 + rr) * K + k0 + cq8,
                        &Bg[p][(w * 2 + s) * 512]);
                gload16(Wu + (size_t)p * planeW + (size_t)(col0 + rr) * K + k0 + cq8,
                        &Bu[p][(w * 2 + s) * 512]);
            }
        __syncthreads();
        f16x8 af[NP][4];
        #pragma unroll
        for (int p = 0; p < NP; ++p)
            #pragma unroll
            for (int i = 0; i < 4; ++i) {
                int ra = wm * 64 + i * 16 + lr;
                af[p][i] = *(const f16x8*)&As[p][ra * 32 + (q ^ ((ra >> 1) & 3)) * 8];
            }
        #pragma unroll
        for (int pr = 0; pr < NPROD; ++pr) {
            const int pa = PA[pr], pw = PW[pr];
            f16x8 bg[4], bu[4];
            #pragma unroll
            for (int i = 0; i < 4; ++i) {
                int rb = wn * 64 + i * 16 + lr;
                int sb = (q ^ ((rb >> 1) & 3)) * 8;
                bg[i] = *(const f16x8*)&Bg[pw][rb * 32 + sb];
                bu[i] = *(const f16x8*)&Bu[pw][rb * 32 + sb];
            }
            #pragma unroll
            for (int mi = 0; mi < 4; ++mi)
                #pragma unroll
                for (int ni = 0; ni < 4; ++ni) {
                    accg[mi][ni] = __builtin_amdgcn_mfma_f32_16x16x32_f16(
                        af[pa][mi], bg[ni], accg[mi][ni], 0, 0, 0);
                    accu[mi][ni] = __builtin_amdgcn_mfma_f32_16x16x32_f16(
                        af[pa][mi], bu[ni], accu[mi][ni], 0, 0, 0);
                }
        }
    }
    const int cw = l & 15, rw = (l >> 4) * 4;
    #pragma unroll
    for (int mi = 0; mi < 4; ++mi)
        #pragma unroll
        for (int ni = 0; ni < 4; ++ni)
            #pragma unroll
            for (int r = 0; r < 4; ++r) {
                int gr = row0 + wm * 64 + mi * 16 + rw + r;
                int gc = col0 + wn * 64 + ni * 16 + cw;
                float g = accg[mi][ni][r], u = accu[mi][ni][r];
                float val = g / (1.f + expf(-g)) * u;
                split_store_swz(val, F, planeF, (size_t)gr * N, gc, (gr >> 1) & 3, npOut);
            }
}

// ============ MFMA flash attention (fp16, pre-swizzled planes, gload staging) ============
template<int NP, int NPROD>
__global__ __launch_bounds__(256) void mfattn_k(
    const _Float16* __restrict__ qsp, const _Float16* __restrict__ ksp,
    const _Float16* __restrict__ vtp, _Float16* __restrict__ osp,
    const int* __restrict__ valid)
{
    __shared__ _Float16 KP[NP][2][64 * 32];   // K tile; reused as P planes
    __shared__ _Float16 Vt[NP][2][64 * 32];   // V^T tile
    __shared__ int kvs[64];
    const int tid = threadIdx.x;
    const int w = tid >> 6, l = tid & 63;
    const int lr = l & 15, lq = l >> 4;
    const int qt = blockIdx.x, hh = blockIdx.y, b = blockIdx.z;
    const int rT = l >> 2;
    const int cq8 = (l & 3) * 8;
    const int PA[4] = {0, 0, 1, 1};
    const int PW[4] = {0, 1, 0, 1};

    f16x8 aq[NP][2];
    {
        const int qrowa = qt * 64 + w * 16 + lr;
        const int phiq = (qrowa >> 1) & 3;
        #pragma unroll
        for (int p = 0; p < NP; ++p)
            #pragma unroll
            for (int ks = 0; ks < 2; ++ks)
                aq[p][ks] = *(const f16x8*)(qsp + (size_t)p * BSH
                    + (size_t)(b * S + qrowa) * H + hh * 64 + ks * 32 + ((lq ^ phiq) << 3));
    }
    int qvr[4];
    #pragma unroll
    for (int r = 0; r < 4; ++r)
        qvr[r] = valid[b * S + qt * 64 + w * 16 + lq * 4 + r];

    float m[4], lsum[4];
    f32x4 acco[4];
    #pragma unroll
    for (int r = 0; r < 4; ++r) { m[r] = -3.4e38f; lsum[r] = 0.f; }
    #pragma unroll
    for (int n = 0; n < 4; ++n)
        #pragma unroll
        for (int r = 0; r < 4; ++r) acco[n][r] = 0.f;

    for (int kt = 0; kt < S / 64; ++kt) {
        __syncthreads();
        {
            const int r = w * 16 + rT;
            #pragma unroll
            for (int p = 0; p < NP; ++p)
                #pragma unroll
                for (int hf = 0; hf < 2; ++hf) {
                    gload16(ksp + (size_t)p * BSH
                            + (size_t)(b * S + kt * 64 + r) * H + hh * 64 + hf * 32 + cq8,
                            &KP[p][hf][w * 512]);
                    gload16(vtp + (size_t)p * BSH
                            + ((size_t)(hh * 64 + r) * B + b) * S + kt * 64 + hf * 32 + cq8,
                            &Vt[p][hf][w * 512]);
                }
        }
        if (tid < 64) kvs[tid] = valid[b * S + kt * 64 + tid];
        __syncthreads();

        // ---- S = Q @ K^T ----
        f32x4 accs[4];
        #pragma unroll
        for (int n = 0; n < 4; ++n)
            #pragma unroll
            for (int r = 0; r < 4; ++r) accs[n][r] = 0.f;
        #pragma unroll
        for (int pr = 0; pr < NPROD; ++pr) {
            const int pa = PA[pr], pw = PW[pr];
            #pragma unroll
            for (int ks = 0; ks < 2; ++ks)
                #pragma unroll
                for (int n = 0; n < 4; ++n) {
                    int rb = n * 16 + lr;
                    f16x8 bk = *(const f16x8*)&KP[pw][ks][rb * 32 + ((lq ^ ((rb >> 1) & 3))) * 8];
                    accs[n] = __builtin_amdgcn_mfma_f32_16x16x32_f16(
                        aq[pa][ks], bk, accs[n], 0, 0, 0);
                }
        }
        // ---- mask + online softmax ----
        float pf[4][4];
        int kva[4];
        #pragma unroll
        for (int n = 0; n < 4; ++n) kva[n] = kvs[n * 16 + lr];
        #pragma unroll
        for (int r = 0; r < 4; ++r) {
            int qr = qt * 64 + w * 16 + lq * 4 + r;
            float rowm = -3.4e38f;
            #pragma unroll
            for (int n = 0; n < 4; ++n) {
                int kc = kt * 64 + n * 16 + lr;
                float sv = accs[n][r] * 0.125f;
                int allowed = (kc <= qr) && qvr[r] && kva[n];
                if (!allowed) sv = sv + -1e9f;
                pf[n][r] = sv;
                rowm = fmaxf(rowm, sv);
            }
            rowm = fmaxf(rowm, __shfl_xor(rowm, 1));
            rowm = fmaxf(rowm, __shfl_xor(rowm, 2));
            rowm = fmaxf(rowm, __shfl_xor(rowm, 4));
            rowm = fmaxf(rowm, __shfl_xor(rowm, 8));
            float mn = fmaxf(m[r], rowm);
            float co = __expf(m[r] - mn);
            float rs = 0.f;
            #pragma unroll
            for (int n = 0; n < 4; ++n) { pf[n][r] = __expf(pf[n][r] - mn); rs += pf[n][r]; }
            rs += __shfl_xor(rs, 1);
            rs += __shfl_xor(rs, 2);
            rs += __shfl_xor(rs, 4);
            rs += __shfl_xor(rs, 8);
            lsum[r] = lsum[r] * co + rs;
            m[r] = mn;
            #pragma unroll
            for (int n = 0; n < 4; ++n) acco[n][r] *= co;
        }
        __syncthreads();
        // ---- write P (fp16 split) into KP, swizzled for a-frag reads ----
        #pragma unroll
        for (int n = 0; n < 4; ++n) {
            int col = n * 16 + lr;
            int hf = col >> 5, colh = col & 31, cq2 = colh >> 3, pos = colh & 7;
            #pragma unroll
            for (int r = 0; r < 4; ++r) {
                int rowg = w * 16 + lq * 4 + r;
                int off = rowg * 32 + (cq2 ^ ((rowg >> 1) & 3)) * 8 + pos;
                float pv = pf[n][r];
                _Float16 h0 = (_Float16)pv;
                KP[0][hf][off] = h0;
                if (NP == 2) KP[1][hf][off] = (_Float16)(pv - (float)h0);
            }
        }
        __syncthreads();
        // ---- O += P @ V ----
        #pragma unroll
        for (int pr = 0; pr < NPROD; ++pr) {
            const int pa = PA[pr], pw = PW[pr];
            #pragma unroll
            for (int ks = 0; ks < 2; ++ks) {
                int ra = w * 16 + lr;
                f16x8 ap = *(const f16x8*)&KP[pa][ks][ra * 32 + ((lq ^ ((ra >> 1) & 3))) * 8];
                #pragma unroll
                for (int n = 0; n < 4; ++n) {
                    int rb = n * 16 + lr;
                    f16x8 bv = *(const f16x8*)&Vt[pw][ks][rb * 32 + ((lq ^ ((rb >> 1) & 3))) * 8];
                    acco[n] = __builtin_amdgcn_mfma_f32_16x16x32_f16(
                        ap, bv, acco[n], 0, 0, 0);
                }
            }
        }
    }
    // ---- write O as pre-swizzled split planes ----
    #pragma unroll
    for (int r = 0; r < 4; ++r) {
        float inv = 1.0f / lsum[r];
        int qr = qt * 64 + w * 16 + lq * 4 + r;
        size_t rowbase = (size_t)(b * S + qr) * H;
        int phi = ((b * S + qr) >> 1) & 3;
        #pragma unroll
        for (int n = 0; n < 4; ++n)
            split_store_swz(acco[n][r] * inv, osp, BSH, rowbase, hh * 64 + n * 16 + lr, phi, NP);
    }
}

// ============ Trig table: ct/st[p][i] = cos/sin(p * 10000^(-2i/64)), fp64-accurate ============
__global__ __launch_bounds__(256) void trigtab_k(float* __restrict__ ct, float* __restrict__ st)
{
    int idx = blockIdx.x * 256 + threadIdx.x;   // S*32 total
    int i = idx & 31, p = idx >> 5;
    double inv = exp(-((double)(2 * i) / 64.0) * log(10000.0));
    double ang = (double)p * inv;
    ct[idx] = (float)cos(ang);
    st[idx] = (float)sin(ang);
}

// ============ RoPE + fp16 split -> pre-swizzled planes (table-driven trig) ============
__global__ __launch_bounds__(256) void rope_split_k(const float* __restrict__ x,
    int xld, int xoff, const int* __restrict__ pos,
    const float* __restrict__ ct, const float* __restrict__ st,
    _Float16* __restrict__ y, size_t plane, int np)
{
    int idx = blockIdx.x * 256 + threadIdx.x;
    int i = idx & 31;
    int head = (idx >> 5) & 15;
    int bs = idx >> 9;
    int p = pos[bs];
    float c = ct[p * 32 + i], sn = st[p * 32 + i];
    const float* base = x + (size_t)bs * xld + xoff + head * 64;
    float x1 = base[i], x2 = base[i + 32];
    size_t rowbase = (size_t)bs * H;
    int phi = (bs >> 1) & 3;
    split_store_swz(x1 * c - x2 * sn, y, plane, rowbase, head * 64 + i, phi, np);
    split_store_swz(x2 * c + x1 * sn, y, plane, rowbase, head * 64 + i + 32, phi, np);
}

// ============ V transpose + split (reads strided qkv) -> planes [(h*64+d)*B+b][S] ============
__global__ __launch_bounds__(256) void splitvt_k(const float* __restrict__ V,
    int vld, int voff, _Float16* __restrict__ Vt, size_t plane, int np)
{
    __shared__ float t[32][33];
    const int tid = threadIdx.x;
    const int s0 = blockIdx.x * 32;
    const int hd0 = blockIdx.y * 32;
    const int b = blockIdx.z;
    #pragma unroll
    for (int i = 0; i < 4; ++i) {
        int e = tid + i * 256;
        int rr = e >> 5, cc = e & 31;
        t[rr][cc] = V[(size_t)(b * S + s0 + rr) * vld + voff + hd0 + cc];
    }
    __syncthreads();
    #pragma unroll
    for (int i = 0; i < 4; ++i) {
        int e = tid + i * 256;
        int rn = e >> 5, ck = e & 31;
        int hd = hd0 + rn;
        size_t rowbase = ((size_t)hd * B + b) * S;
        split_store_swz(t[ck][rn], Vt, plane, rowbase, s0 + ck, ((hd & 63) >> 1) & 3, np);
    }
}

// ============ Weight transpose + fp16 split: W[K,N](srcld) -> Wt planes [N][K] ============
__global__ __launch_bounds__(256) void splitwt_k(const float* __restrict__ W,
    _Float16* __restrict__ Wt, int K, int N, int srcld, size_t plane, int np)
{
    __shared__ float t[32][33];
    const int tid = threadIdx.x;
    const int n0 = blockIdx.x * 32, k0 = blockIdx.y * 32;
    #pragma unroll
    for (int i = 0; i < 4; ++i) {
        int e = tid + i * 256;
        int rk = e >> 5, cn = e & 31;
        t[rk][cn] = W[(size_t)(k0 + rk) * srcld + n0 + cn];
    }
    __syncthreads();
    #pragma unroll
    for (int i = 0; i < 4; ++i) {
        int e = tid + i * 256;
        int rn = e >> 5, ck = e & 31;
        int nn = n0 + rn;
        split_store_swz(t[ck][rn], Wt, plane, (size_t)nn * K, k0 + ck, (nn >> 1) & 3, np);
    }
}

// ============ Plain fp32 -> fp16 split planes (rows of length H) ============
__global__ __launch_bounds__(256) void splita_swz_k(const float* __restrict__ x,
    _Float16* __restrict__ y, size_t plane, int np)
{
    int row = blockIdx.x;
    size_t rowbase = (size_t)row * H;
    int phi = (row >> 1) & 3;
    for (int i = threadIdx.x; i < H; i += 256)
        split_store_swz(x[rowbase + i], y, plane, rowbase, i, phi, np);
}

// ============ RMSNorm -> pre-swz fp16 split ============
__global__ __launch_bounds__(256) void rmsnorm_split_k(const float* __restrict__ x,
    const float* __restrict__ w, _Float16* __restrict__ y, size_t plane, int np)
{
    int row = blockIdx.x;
    const float* xr = x + (size_t)row * H;
    __shared__ float red[256];
    float s = 0.f;
    for (int i = threadIdx.x; i < H; i += 256) { float v = xr[i]; s += v * v; }
    red[threadIdx.x] = s; __syncthreads();
    for (int off = 128; off > 0; off >>= 1) {
        if (threadIdx.x < off) red[threadIdx.x] += red[threadIdx.x + off];
        __syncthreads();
    }
    float r = 1.0f / sqrtf(red[0] / (float)H + 1e-6f);
    size_t rowbase = (size_t)row * H;
    int phi = (row >> 1) & 3;
    for (int i = threadIdx.x; i < H; i += 256)
        split_store_swz(xr[i] * r * w[i], y, plane, rowbase, i, phi, np);
}

// ============ Head column 2048 (null logit), exact fp32 ============
__global__ __launch_bounds__(64) void headcol_k(const float* __restrict__ h,
    const float* __restrict__ head_w, const float* __restrict__ head_b,
    float* __restrict__ logits)
{
    int row = blockIdx.x;
    int l = threadIdx.x;
    float s = 0.f;
    for (int j = l; j < H; j += 64) s += h[(size_t)row * H + j] * head_w[(size_t)j * CV1 + CV];
    s += __shfl_xor(s, 1);
    s += __shfl_xor(s, 2);
    s += __shfl_xor(s, 4);
    s += __shfl_xor(s, 8);
    s += __shfl_xor(s, 16);
    s += __shfl_xor(s, 32);
    if (l == 0) logits[(size_t)row * CV1 + CV] = s + head_b[CV];
}

// ---------------- fp32 GEMM (fallback path) ----------------
__global__ __launch_bounds__(256) void gemm_k(
    const float* __restrict__ A, const float* __restrict__ Wm,
    const float* __restrict__ bias, float* __restrict__ C,
    int M, int N, int K, int lda, int ldb, int ldc, int flags)
{
    __shared__ float As[16][65];
    __shared__ float Bs[16][65];
    const int tid = threadIdx.x;
    const int tx = tid & 15, ty = tid >> 4;
    const int row0 = blockIdx.y * 64, col0 = blockIdx.x * 64;
    float acc[4][4] = {};
    for (int k0 = 0; k0 < K; k0 += 16) {
        #pragma unroll
        for (int l = 0; l < 4; ++l) {
            int e = tid + l * 256;
            int r = e >> 4, c = e & 15;
            int gr = row0 + r;
            float vv = 0.f;
            if (gr < M) vv = A[(size_t)gr * lda + (k0 + c)];
            As[c][r] = vv;
        }
        #pragma unroll
        for (int l = 0; l < 4; ++l) {
            int e = tid + l * 256;
            int r = e >> 6, c = e & 63;
            int gc = col0 + c;
            float vv = 0.f;
            if (gc < N) vv = Wm[(size_t)(k0 + r) * ldb + gc];
            Bs[r][c] = vv;
        }
        __syncthreads();
        #pragma unroll
        for (int kk = 0; kk < 16; ++kk) {
            float a[4], bb[4];
            #pragma unroll
            for (int i = 0; i < 4; ++i) a[i] = As[kk][ty * 4 + i];
            #pragma unroll
            for (int j = 0; j < 4; ++j) bb[j] = Bs[kk][tx * 4 + j];
            #pragma unroll
            for (int i = 0; i < 4; ++i)
                #pragma unroll
                for (int j = 0; j < 4; ++j)
                    acc[i][j] += a[i] * bb[j];
        }
        __syncthreads();
    }
    #pragma unroll
    for (int i = 0; i < 4; ++i) {
        int gr = row0 + ty * 4 + i;
        if (gr >= M) continue;
        #pragma unroll
        for (int j = 0; j < 4; ++j) {
            int gc = col0 + tx * 4 + j;
            if (gc >= N) continue;
            float vv = acc[i][j];
            if (flags & F_BIAS)  vv += bias[gc];
            if (flags & F_SILU)  vv = vv / (1.f + expf(-vv));
            size_t cidx = (size_t)gr * ldc + gc;
            if (flags & F_MULIN) vv *= C[cidx];
            if (flags & F_RESID) vv += C[cidx];
            C[cidx] = vv;
        }
    }
}

// ---------------- RMSNorm fp32 (fallback) ----------------
__global__ __launch_bounds__(256) void rmsnorm_k(const float* __restrict__ x,
    const float* __restrict__ w, float* __restrict__ y)
{
    int row = blockIdx.x;
    const float* xr = x + (size_t)row * H;
    float* yr = y + (size_t)row * H;
    __shared__ float red[256];
    float s = 0.f;
    for (int i = threadIdx.x; i < H; i += 256) { float v = xr[i]; s += v * v; }
    red[threadIdx.x] = s; __syncthreads();
    for (int off = 128; off > 0; off >>= 1) {
        if (threadIdx.x < off) red[threadIdx.x] += red[threadIdx.x + off];
        __syncthreads();
    }
    float r = 1.0f / sqrtf(red[0] / (float)H + 1e-6f);
    for (int i = threadIdx.x; i < H; i += 256) yr[i] = xr[i] * r * w[i];
}

// ---------------- Embed gather ----------------
__global__ __launch_bounds__(256) void embed_k(const int* __restrict__ ids,
    const float* __restrict__ emb, float* __restrict__ h)
{
    int bs = blockIdx.x;
    const float* e = emb + (size_t)ids[bs] * H;
    float* hr = h + (size_t)bs * H;
    for (int i = threadIdx.x; i < H; i += 256) hr[i] = e[i];
}

// ---------------- RoPE fp32 in-place (fallback) ----------------
__global__ __launch_bounds__(256) void rope_k(float* __restrict__ x, const int* __restrict__ pos)
{
    int idx = blockIdx.x * 256 + threadIdx.x;
    int i = idx & 31;
    int head = (idx >> 5) & 15;
    int bs = idx >> 9;
    int p = pos[bs];
    double inv = exp(-((double)(2 * i) / 64.0) * log(10000.0));
    double ang = (double)p * inv;
    float c = (float)cos(ang), sn = (float)sin(ang);
    float* base = x + (size_t)bs * H + head * 64;
    float x1 = base[i], x2 = base[i + 32];
    base[i]      = x1 * c - x2 * sn;
    base[i + 32] = x2 * c + x1 * sn;
}

// ---------------- Flash attention fp32 (fallback) ----------------
__global__ __launch_bounds__(256) void fattn_k(const float* __restrict__ q,
    const float* __restrict__ k, const float* __restrict__ v,
    float* __restrict__ o, const int* __restrict__ valid)
{
    const int qt = blockIdx.x, hh = blockIdx.y, b = blockIdx.z;
    const int tid = threadIdx.x;
    const int tx = tid & 15, ty = tid >> 4;
    __shared__ float Qs[64][68];
    __shared__ float Ks[64][68];
    __shared__ float Vs[64][68];
    __shared__ int   kvs[64];
    const size_t hoff = (size_t)hh * HD;

    {
        int row = tid >> 2, d0 = (tid & 3) * 16;
        const float* qp = q + ((size_t)(b * S + qt * 64 + row)) * H + hoff + d0;
        float4* dst = (float4*)&Qs[row][d0];
        const float4* src = (const float4*)qp;
        #pragma unroll
        for (int e = 0; e < 4; ++e) dst[e] = src[e];
    }
    int qv[4]; int qrow_g[4];
    #pragma unroll
    for (int i = 0; i < 4; ++i) {
        qrow_g[i] = qt * 64 + ty * 4 + i;
        qv[i] = valid[b * S + qrow_g[i]];
    }
    float m[4], l[4], acc[4][4];
    #pragma unroll
    for (int i = 0; i < 4; ++i) {
        m[i] = -3.4e38f; l[i] = 0.f;
        #pragma unroll
        for (int j = 0; j < 4; ++j) acc[i][j] = 0.f;
    }

    for (int kt = 0; kt < S / 64; ++kt) {
        __syncthreads();
        {
            int row = tid >> 2, d0 = (tid & 3) * 16;
            const float* kp = k + ((size_t)(b * S + kt * 64 + row)) * H + hoff + d0;
            float4* dst = (float4*)&Ks[row][d0];
            const float4* src = (const float4*)kp;
            #pragma unroll
            for (int e = 0; e < 4; ++e) dst[e] = src[e];
        }
        {
            int kk = tid >> 2, d0 = (tid & 3) * 16;
            const float* vp = v + ((size_t)(b * S + kt * 64 + kk)) * H + hoff + d0;
            #pragma unroll
            for (int e = 0; e < 16; e += 4) {
                float4 vv = *(const float4*)(vp + e);
                Vs[d0 + e + 0][kk] = vv.x;
                Vs[d0 + e + 1][kk] = vv.y;
                Vs[d0 + e + 2][kk] = vv.z;
                Vs[d0 + e + 3][kk] = vv.w;
            }
        }
        if (tid < 64) kvs[tid] = valid[b * S + kt * 64 + tid];
        __syncthreads();

        float s4[4][4];
        #pragma unroll
        for (int i = 0; i < 4; ++i)
            #pragma unroll
            for (int j = 0; j < 4; ++j) s4[i][j] = 0.f;
        #pragma unroll
        for (int c = 0; c < 16; ++c) {
            float4 a[4], bb[4];
            #pragma unroll
            for (int i = 0; i < 4; ++i) a[i]  = ((const float4*)&Qs[ty * 4 + i][0])[c];
            #pragma unroll
            for (int j = 0; j < 4; ++j) bb[j] = ((const float4*)&Ks[tx * 4 + j][0])[c];
            #pragma unroll
            for (int i = 0; i < 4; ++i)
                #pragma unroll
                for (int j = 0; j < 4; ++j) {
                    s4[i][j] += a[i].x * bb[j].x + a[i].y * bb[j].y
                              + a[i].z * bb[j].z + a[i].w * bb[j].w;
                }
        }
        float p[4][4];
        float corr[4];
        #pragma unroll
        for (int i = 0; i < 4; ++i) {
            float rm = -3.4e38f;
            #pragma unroll
            for (int j = 0; j < 4; ++j) {
                int kc = kt * 64 + tx * 4 + j;
                float sv = s4[i][j] * 0.125f;
                int allowed = (kc <= qrow_g[i]) && qv[i] && kvs[tx * 4 + j];
                if (!allowed) sv = sv + -1e9f;
                s4[i][j] = sv;
                rm = fmaxf(rm, sv);
            }
            rm = fmaxf(rm, __shfl_xor(rm, 1));
            rm = fmaxf(rm, __shfl_xor(rm, 2));
            rm = fmaxf(rm, __shfl_xor(rm, 4));
            rm = fmaxf(rm, __shfl_xor(rm, 8));
            float mn = fmaxf(m[i], rm);
            corr[i] = expf(m[i] - mn);
            float rs = 0.f;
            #pragma unroll
            for (int j = 0; j < 4; ++j) { p[i][j] = expf(s4[i][j] - mn); rs += p[i][j]; }
            rs += __shfl_xor(rs, 1);
            rs += __shfl_xor(rs, 2);
            rs += __shfl_xor(rs, 4);
            rs += __shfl_xor(rs, 8);
            l[i] = l[i] * corr[i] + rs;
            m[i] = mn;
            #pragma unroll
            for (int j = 0; j < 4; ++j) acc[i][j] *= corr[i];
        }
        __syncthreads();
        #pragma unroll
        for (int i = 0; i < 4; ++i) {
            float4 pv4 = make_float4(p[i][0], p[i][1], p[i][2], p[i][3]);
            *(float4*)&Ks[ty * 4 + i][tx * 4] = pv4;
        }
        __syncthreads();
        #pragma unroll
        for (int c = 0; c < 16; ++c) {
            float4 a[4], bb[4];
            #pragma unroll
            for (int i = 0; i < 4; ++i) a[i]  = ((const float4*)&Ks[ty * 4 + i][0])[c];
            #pragma unroll
            for (int j = 0; j < 4; ++j) bb[j] = ((const float4*)&Vs[tx * 4 + j][0])[c];
            #pragma unroll
            for (int i = 0; i < 4; ++i)
                #pragma unroll
                for (int j = 0; j < 4; ++j) {
                    acc[i][j] += a[i].x * bb[j].x + a[i].y * bb[j].y
                               + a[i].z * bb[j].z + a[i].w * bb[j].w;
                }
        }
    }
    #pragma unroll
    for (int i = 0; i < 4; ++i) {
        float inv = 1.0f / l[i];
        float4 ov = make_float4(acc[i][0] * inv, acc[i][1] * inv,
                                acc[i][2] * inv, acc[i][3] * inv);
        *(float4*)(o + ((size_t)(b * S + qrow_g[i])) * H + hoff + tx * 4) = ov;
    }
}

// ---------------- Discretize: fp16 swizzled z + fp32 fallback ----------------
__global__ __launch_bounds__(256) void discretize_h_k(const float* __restrict__ logits,
    const float* __restrict__ gumbel, _Float16* __restrict__ z, int* __restrict__ chosen)
{
    int bs = blockIdx.x;
    const float* lg = logits + (size_t)bs * CV1;
    const float* gm = gumbel + (size_t)bs * CV1;
    __shared__ float redv[256]; __shared__ int redi[256];
    int tid = threadIdx.x;
    float m = -3.4e38f; int mi = CV1;
    for (int j = tid; j < CV1; j += 256) {
        float a = lg[j] + gm[j];
        if (a > m) { m = a; mi = j; }
    }
    redv[tid] = m; redi[tid] = mi; __syncthreads();
    for (int off = 128; off > 0; off >>= 1) {
        if (tid < off) {
            float vo = redv[tid + off]; int io = redi[tid + off];
            if (vo > redv[tid] || (vo == redv[tid] && io < redi[tid])) { redv[tid] = vo; redi[tid] = io; }
        }
        __syncthreads();
    }
    m = redv[0]; int amax = redi[0];
    __syncthreads();
    float ssum = 0.f;
    for (int j = tid; j < CV1; j += 256) ssum += expf(lg[j] + gm[j] - m);
    redv[tid] = ssum; __syncthreads();
    for (int off = 128; off > 0; off >>= 1) {
        if (tid < off) redv[tid] += redv[tid + off];
        __syncthreads();
    }
    float inv = 1.0f / redv[0];
    size_t rowbase = (size_t)bs * CV;
    int phi = (bs >> 1) & 3;
    for (int j = tid; j < CV; j += 256) {
        float zv = expf(lg[j] + gm[j] - m) * inv;
        z[swz_idx(rowbase, j, phi)] = (_Float16)zv;
    }
    if (tid == 0) chosen[bs] = amax;
}

__global__ __launch_bounds__(256) void discretize_k(const float* __restrict__ logits,
    const float* __restrict__ gumbel, float* __restrict__ z, int* __restrict__ chosen)
{
    int bs = blockIdx.x;
    const float* lg = logits + (size_t)bs * CV1;
    const float* gm = gumbel + (size_t)bs * CV1;
    __shared__ float redv[256]; __shared__ int redi[256];
    int tid = threadIdx.x;
    float m = -3.4e38f; int mi = CV1;
    for (int j = tid; j < CV1; j += 256) {
        float a = lg[j] + gm[j];
        if (a > m) { m = a; mi = j; }
    }
    redv[tid] = m; redi[tid] = mi; __syncthreads();
    for (int off = 128; off > 0; off >>= 1) {
        if (tid < off) {
            float vo = redv[tid + off]; int io = redi[tid + off];
            if (vo > redv[tid] || (vo == redv[tid] && io < redi[tid])) { redv[tid] = vo; redi[tid] = io; }
        }
        __syncthreads();
    }
    m = redv[0]; int amax = redi[0];
    __syncthreads();
    float ssum = 0.f;
    for (int j = tid; j < CV1; j += 256) ssum += expf(lg[j] + gm[j] - m);
    redv[tid] = ssum; __syncthreads();
    for (int off = 128; off > 0; off >>= 1) {
        if (tid < off) redv[tid] += redv[tid + off];
        __syncthreads();
    }
    float inv = 1.0f / redv[0];
    for (int j = tid; j < CV; j += 256)
        z[(size_t)bs * CV + j] = expf(lg[j] + gm[j] - m) * inv;
    if (tid == 0) chosen[bs] = amax;
}

// ---------------- cea + loss ----------------
__global__ __launch_bounds__(256) void cea_k(const float* __restrict__ esoft,
    const float* __restrict__ cemb, const int* __restrict__ chosen,
    const int* __restrict__ amask, float* __restrict__ cea, float* __restrict__ partial)
{
    int bs = blockIdx.x;
    int ch = chosen[bs]; int vm = amask[bs];
    int comp = (ch != CV) && vm;
    const float* ehr = cemb + (size_t)(ch < CV - 1 ? ch : CV - 1) * H;
    __shared__ float red[256];
    float part = 0.f;
    float vmf = vm ? 1.f : 0.f;
    for (int i = threadIdx.x; i < H; i += 256) {
        float es = esoft[(size_t)bs * H + i];
        float eh = comp ? ehr[i] : 0.f;
        cea[(size_t)bs * H + i] = ((eh + es) - es) * vmf;
        float d = es - eh;
        part += d * d;
    }
    red[threadIdx.x] = part; __syncthreads();
    for (int off = 128; off > 0; off >>= 1) {
        if (threadIdx.x < off) red[threadIdx.x] += red[threadIdx.x + off];
        __syncthreads();
    }
    if (threadIdx.x == 0) partial[bs] = red[0];
}

__global__ __launch_bounds__(256) void loss_k(const float* __restrict__ partial, float* __restrict__ out)
{
    __shared__ float red[256];
    float s = 0.f;
    for (int i = threadIdx.x; i < BS; i += 256) s += partial[i];
    red[threadIdx.x] = s; __syncthreads();
    for (int off = 128; off > 0; off >>= 1) {
        if (threadIdx.x < off) red[threadIdx.x] += red[threadIdx.x + off];
        __syncthreads();
    }
    if (threadIdx.x == 0) out[0] = 1.25f * red[0] / (float)BSH;
}

// ---------------- Parallel stable pack: scan over is_comp flags ----------------
// Stable partition identical to serial reference: comp positions in order, then non-comp.
__global__ __launch_bounds__(1024) void pack_k(const int* __restrict__ chosen,
    const int* __restrict__ amask, int* __restrict__ order, int* __restrict__ cpos,
    int* __restrict__ cvalid, int* __restrict__ counts)
{
    int b = blockIdx.x, t = threadIdx.x;
    __shared__ int sc[1024];
    __shared__ int ord[1024];
    int f = (chosen[b * S + t] != CV && amask[b * S + t]) ? 1 : 0;
    sc[t] = f;
    __syncthreads();
    // Hillis-Steele inclusive scan
    #pragma unroll
    for (int off = 1; off < 1024; off <<= 1) {
        int add = (t >= off) ? sc[t - off] : 0;
        __syncthreads();
        sc[t] += add;
        __syncthreads();
    }
    int cnt = sc[1023];
    int pos = f ? (sc[t] - 1) : (cnt + t - sc[t]);
    ord[pos] = t;
    __syncthreads();
    int o = ord[t];
    order[b * S + t] = o;
    cvalid[b * S + t] = (t < cnt) ? 1 : 0;
    cpos[b * S + t] = (t < cnt) ? o : 0;
    if (t == 0) counts[b] = cnt;
}

__global__ __launch_bounds__(256) void gather_k(const float* __restrict__ cea,
    const int* __restrict__ order, const int* __restrict__ cvalid, float* __restrict__ h)
{
    int bs = blockIdx.x;
    int b = bs >> 10;
    int src = order[bs];
    float f = cvalid[bs] ? 1.f : 0.f;
    const float* sp = cea + (size_t)(b * S + src) * H;
    float* dst = h + (size_t)bs * H;
    for (int i = threadIdx.x; i < H; i += 256) dst[i] = sp[i] * f;
}

__global__ __launch_bounds__(256) void outmask_k(const float* __restrict__ h,
    const int* __restrict__ cvalid, float* __restrict__ out)
{
    int bs = blockIdx.x;
    float f = cvalid[bs] ? 1.f : 0.f;
    for (int i = threadIdx.x; i < H; i += 256)
        out[(size_t)bs * H + i] = h[(size_t)bs * H + i] * f;
}

__global__ __launch_bounds__(256) void iota_k(int* __restrict__ pos)
{
    int idx = blockIdx.x * 256 + threadIdx.x;
    if (idx < BS) pos[idx] = idx & (S - 1);
}

// ================= Host-side drivers =================
static void run_block_f32(int layer,
    const float* ln1, const float* wq, const float* wk, const float* wv,
    const float* wo, const float* ln2, const float* wg, const float* wu, const float* wd,
    float* h, float* hn, float* q, float* k, float* v, float* o, float* f1,
    const int* valid, const int* pos, hipStream_t stream)
{
    size_t LHH = (size_t)layer * H * H;
    size_t LHF = (size_t)layer * H * FF;
    rmsnorm_k<<<BS, 256, 0, stream>>>(h, ln1 + (size_t)layer * H, hn);
    gemm_k<<<dim3(16, 64), 256, 0, stream>>>(hn, wq + LHH, nullptr, q, BS, H, H, H, H, H, 0);
    gemm_k<<<dim3(16, 64), 256, 0, stream>>>(hn, wk + LHH, nullptr, k, BS, H, H, H, H, H, 0);
    gemm_k<<<dim3(16, 64), 256, 0, stream>>>(hn, wv + LHH, nullptr, v, BS, H, H, H, H, H, 0);
    rope_k<<<8192, 256, 0, stream>>>(q, pos);
    rope_k<<<8192, 256, 0, stream>>>(k, pos);
    fattn_k<<<dim3(S / 64, NH, B), 256, 0, stream>>>(q, k, v, o, valid);
    gemm_k<<<dim3(16, 64), 256, 0, stream>>>(o, wo + LHH, nullptr, h, BS, H, H, H, H, H, F_RESID);
    rmsnorm_k<<<BS, 256, 0, stream>>>(h, ln2 + (size_t)layer * H, hn);
    gemm_k<<<dim3(64, 64), 256, 0, stream>>>(hn, wg + LHF, nullptr, f1, BS, FF, H, H, FF, FF, F_SILU);
    gemm_k<<<dim3(64, 64), 256, 0, stream>>>(hn, wu + LHF, nullptr, f1, BS, FF, H, H, FF, FF, F_MULIN);
    gemm_k<<<dim3(16, 64), 256, 0, stream>>>(f1, wd + (size_t)layer * FF * H, nullptr, h, BS, H, FF, FF, H, H, F_RESID);
}

// MFMA block, templated on split planes / products (shallow <2,3>, mid <1,1>)
template<int NP, int NPROD>
static void run_block_mf(int layer,
    const float* ln1, const float* wq, const float* wk, const float* wv,
    const float* wo, const float* ln2, const float* wg, const float* wu, const float* wd,
    float* h, float* qkv,
    _Float16* hnsp, _Float16* osp, _Float16* wsp, _Float16* wsp2, _Float16* f1sp,
    _Float16* qsp, _Float16* ksp, _Float16* vtp,
    const float* ct, const float* st,
    const int* valid, const int* pos, hipStream_t stream)
{
    const size_t PH = (size_t)H * H;        // wo plane
    const size_t P3H = 3 * PH;              // fused qkv plane
    const size_t PGU = (size_t)H * FF;      // wg/wu/wd plane
    const size_t PA = BSH;                  // activation plane
    const size_t PF = BSF;                  // f1 plane
    size_t LHH = (size_t)layer * H * H;
    size_t LHF = (size_t)layer * H * FF;
    dim3 gw32(H / 32, H / 32);

    rmsnorm_split_k<<<BS, 256, 0, stream>>>(h, ln1 + (size_t)layer * H, hnsp, PA, NP);
    splitwt_k<<<gw32, 256, 0, stream>>>(wq + LHH, wsp,                    H, H, H, P3H, NP);
    splitwt_k<<<gw32, 256, 0, stream>>>(wk + LHH, wsp + (size_t)H * H,    H, H, H, P3H, NP);
    splitwt_k<<<gw32, 256, 0, stream>>>(wv + LHH, wsp + (size_t)2 * H * H, H, H, H, P3H, NP);
    gemm_mf_k<NP, NPROD><<<dim3(3 * H / 128, BS / 128), 256, 0, stream>>>(
        hnsp, wsp, nullptr, qkv, nullptr, BS, 3 * H, H, 3 * H, PA, P3H, 0);
    rope_split_k<<<8192, 256, 0, stream>>>(qkv, 3 * H, 0, pos, ct, st, qsp, PA, NP);
    rope_split_k<<<8192, 256, 0, stream>>>(qkv, 3 * H, H, pos, ct, st, ksp, PA, NP);
    splitvt_k<<<dim3(S / 32, H / 32, B), 256, 0, stream>>>(qkv, 3 * H, 2 * H, vtp, PA, NP);
    mfattn_k<NP, NPROD><<<dim3(S / 64, NH, B), 256, 0, stream>>>(qsp, ksp, vtp, osp, valid);
    splitwt_k<<<gw32, 256, 0, stream>>>(wo + LHH, wsp, H, H, H, PH, NP);
    gemm_mf_k<NP, NPROD><<<dim3(H / 128, BS / 128), 256, 0, stream>>>(
        osp, wsp, nullptr, h, h, BS, H, H, H, PA, PH, 1);
    rmsnorm_split_k<<<BS, 256, 0, stream>>>(h, ln2 + (size_t)layer * H, hnsp, PA, NP);
    splitwt_k<<<dim3(FF / 32, H / 32), 256, 0, stream>>>(wg + LHF, wsp,  H, FF, FF, PGU, NP);
    splitwt_k<<<dim3(FF / 32, H / 32), 256, 0, stream>>>(wu + LHF, wsp2, H, FF, FF, PGU, NP);
    gateup_k<NP, NPROD><<<dim3(FF / 128, BS / 128), 256, 0, stream>>>(
        hnsp, wsp, wsp2, f1sp, BS, FF, H, PA, PGU, PF, NP, 2);
    splitwt_k<<<dim3(H / 32, FF / 32), 256, 0, stream>>>(wd + (size_t)layer * FF * H, wsp, FF, H, H, PGU, NP);
    gemm_mf_k<NP, NPROD><<<dim3(H / 128, BS / 128), 256, 0, stream>>>(
        f1sp, wsp, nullptr, h, h, BS, H, FF, H, PF, PGU, 1);
}

extern "C" void kernel_launch(void* const* d_in, const int* in_sizes, int n_in,
                              void* d_out, int out_size, void* d_ws, size_t ws_size,
                              hipStream_t stream)
{
    const int*   ids    = (const int*)d_in[0];
    const int*   amask  = (const int*)d_in[1];
    const float* embed  = (const float*)d_in[2];
    const float* ln1    = (const float*)d_in[3];
    const float* wq     = (const float*)d_in[4];
    const float* wk     = (const float*)d_in[5];
    const float* wv     = (const float*)d_in[6];
    const float* wo     = (const float*)d_in[7];
    const float* ln2    = (const float*)d_in[8];
    const float* wg     = (const float*)d_in[9];
    const float* wu     = (const float*)d_in[10];
    const float* wd     = (const float*)d_in[11];
    const float* head_w = (const float*)d_in[12];
    const float* head_b = (const float*)d_in[13];
    const float* cemb   = (const float*)d_in[14];
    const float* gumbel = (const float*)d_in[15];
    float* out = (float*)d_out;

    const size_t MB = 1ull << 20;
    const size_t NEED = 274 * MB;

    if (ws_size >= NEED) {
        // ===== MFMA path =====
        char* base = (char*)d_ws;
        float* h   = (float*)base;                  // 16MB
        float* qkv = (float*)(base + 16 * MB);      // 48MB [BS][3072]
        _Float16* zb   = (_Float16*)(base + 64 * MB);   // 16MB [BS][CV]
        _Float16* hnsp = (_Float16*)(base + 80 * MB);   // 2 planes x 8MB
        _Float16* osp  = (_Float16*)(base + 104 * MB);
        _Float16* wsp  = (_Float16*)(base + 128 * MB);  // <=24MB weight planes
        _Float16* wsp2 = (_Float16*)(base + 152 * MB);
        _Float16* f1sp = (_Float16*)(base + 176 * MB);  // 2 planes x 32MB
        _Float16* qsp  = (_Float16*)(base + 176 * MB);  // alias f1sp (disjoint lifetime)
        _Float16* ksp  = (_Float16*)(base + 200 * MB);
        _Float16* vtp  = (_Float16*)(base + 224 * MB);
        int* meta   = (int*)(base + 272 * MB);
        int* chosen = meta;
        int* order  = meta + BS;
        int* cpos   = meta + 2 * BS;
        int* cvalid = meta + 3 * BS;
        int* counts = meta + 4 * BS;
        int* pos_sh = meta + 5 * BS;
        float* partial = (float*)(meta + 6 * BS);
        float* ct = (float*)(base + 273 * MB);          // S*32 floats (128KB)
        float* st = ct + S * 32;                        // S*32 floats
        float* logits = qkv;          // qkv dead after shallow blocks
        float* esoft  = qkv;
        float* ceab   = qkv + BSH;

        embed_k<<<BS, 256, 0, stream>>>(ids, embed, h);
        iota_k<<<16, 256, 0, stream>>>(pos_sh);
        trigtab_k<<<S * 32 / 256, 256, 0, stream>>>(ct, st);

        for (int L = 0; L < 2; ++L)
            run_block_mf<2, 3>(L, ln1, wq, wk, wv, wo, ln2, wg, wu, wd,
                               h, qkv, hnsp, osp, wsp, wsp2, f1sp,
                               qsp, ksp, vtp, ct, st, amask, pos_sh, stream);

        // ---- head logits: fp16 2-plane, ALL 4 products (argmax-critical) ----
        splita_swz_k<<<BS, 256, 0, stream>>>(h, hnsp, BSH, 2);
        splitwt_k<<<dim3(CV / 32, H / 32), 256, 0, stream>>>(head_w, wsp, H, CV, CV1, (size_t)CV * H, 2);
        gemm_mf_k<2, 4><<<dim3(CV / 128, BS / 128), 256, 0, stream>>>(
            hnsp, wsp, head_b, logits, nullptr, BS, CV, H, CV1, BSH, (size_t)CV * H, 1);
        headcol_k<<<BS, 64, 0, stream>>>(h, head_w, head_b, logits);
        discretize_h_k<<<BS, 256, 0, stream>>>(logits, gumbel, zb, chosen);

        // ---- e_soft = z @ cemb (fp16 1-plane) ----
        splitwt_k<<<dim3(H / 32, CV / 32), 256, 0, stream>>>(cemb, wsp, CV, H, H, (size_t)H * CV, 1);
        gemm_mf_k<1, 1><<<dim3(H / 128, BS / 128), 256, 0, stream>>>(
            zb, wsp, nullptr, esoft, nullptr, BS, H, CV, H, (size_t)BS * CV, (size_t)H * CV, 0);

        cea_k<<<BS, 256, 0, stream>>>(esoft, cemb, chosen, amask, ceab, partial);
        loss_k<<<1, 256, 0, stream>>>(partial, out + BSH);
        pack_k<<<B, 1024, 0, stream>>>(chosen, amask, order, cpos, cvalid, counts);
        gather_k<<<BS, 256, 0, stream>>>(ceab, order, cvalid, h);

        for (int L = 2; L < 4; ++L)
            run_block_mf<1, 1>(L, ln1, wq, wk, wv, wo, ln2, wg, wu, wd,
                               h, qkv, hnsp, osp, wsp, wsp2, f1sp,
                               qsp, ksp, vtp, ct, st, cvalid, cpos, stream);

        outmask_k<<<BS, 256, 0, stream>>>(h, cvalid, out);
    } else {
        // ===== fallback: fp32 path =====
        float* wsf = (float*)d_ws;
        float* h   = wsf;
        float* hn  = wsf + BSH;
        float* q   = wsf + 2 * BSH;
        float* k   = wsf + 3 * BSH;
        float* v   = wsf + 4 * BSH;
        float* o   = wsf + 5 * BSH;
        float* f1  = wsf + 6 * BSH;
        float* zbuf  = q;
        float* esoft = v;
        float* ceab  = o;
        int* meta   = (int*)(wsf + 6 * BSH + BSF);
        int* chosen = meta;
        int* order  = meta + BS;
        int* cpos   = meta + 2 * BS;
        int* cvalid = meta + 3 * BS;
        int* counts = meta + 4 * BS;
        int* pos_sh = meta + 5 * BS;
        float* partial = (float*)(meta + 6 * BS);

        embed_k<<<BS, 256, 0, stream>>>(ids, embed, h);
        iota_k<<<16, 256, 0, stream>>>(pos_sh);
        for (int L = 0; L < 2; ++L)
            run_block_f32(L, ln1, wq, wk, wv, wo, ln2, wg, wu, wd,
                          h, hn, q, k, v, o, f1, amask, pos_sh, stream);
        gemm_k<<<dim3(33, 64), 256, 0, stream>>>(h, head_w, head_b, f1, BS, CV1, H, H, CV1, CV1, F_BIAS);
        discretize_k<<<BS, 256, 0, stream>>>(f1, gumbel, zbuf, chosen);
        gemm_k<<<dim3(16, 64), 256, 0, stream>>>(zbuf, cemb, nullptr, esoft, BS, H, CV, CV, H, H, 0);
        cea_k<<<BS, 256, 0, stream>>>(esoft, cemb, chosen, amask, ceab, partial);
        loss_k<<<1, 256, 0, stream>>>(partial, out + BSH);
        pack_k<<<B, 1024, 0, stream>>>(chosen, amask, order, cpos, cvalid, counts);
        gather_k<<<BS, 256, 0, stream>>>(ceab, order, cvalid, h);
        for (int L = 2; L < 4; ++L)
            run_block_f32(L, ln1, wq, wk, wv, wo, ln2, wg, wu, wd,
                          h, hn, q, k, v, o, f1, cvalid, cpos, stream);
        outmask_k<<<BS, 256, 0, stream>>>(h, cvalid, out);
    }
}

// Round 9
// 2640.714 us; speedup vs baseline: 13.5371x; 1.0344x over previous
//
#include <hip/hip_runtime.h>
#include <hip/hip_bf16.h>
#include <cmath>

#define B 4
#define S 1024
#define H 1024
#define NH 16
#define HD 64
#define FF 4096
#define CV 2048
#define CV1 2049
#define BS (B*S)            // 4096
#define BSH ((size_t)BS*H)  // 4194304
#define BSF ((size_t)BS*FF) // 16777216

#define F_BIAS  1
#define F_RESID 2
#define F_SILU  4
#define F_MULIN 8

typedef __attribute__((ext_vector_type(8))) _Float16 f16x8;
typedef __attribute__((ext_vector_type(4))) float f32x4;

// Pre-swizzled plane write: element (row,col) stored at
// rowbase + (col&~31) + ((((col>>3)&3)^phi)<<3) + (col&7), phi=(row>>1)&3.
// Linear global_load_lds DMA then reproduces the LDS image the MFMA ds_reads expect.
static __device__ inline size_t swz_idx(size_t rowbase, int col, int phi) {
    return rowbase + (size_t)(col & ~31) + ((size_t)(((col >> 3) & 3) ^ phi) << 3) + (col & 7);
}
// fp16 2-plane split store (np=1: single plane)
static __device__ inline void split_store_swz(float v, _Float16* p, size_t plane,
                                              size_t rowbase, int col, int phi, int np) {
    size_t idx = swz_idx(rowbase, col, phi);
    _Float16 h0 = (_Float16)v; p[idx] = h0;
    if (np == 2) p[plane + idx] = (_Float16)(v - (float)h0);
}

// global->LDS async DMA, 16B per lane, LDS dest = base + lane*16
static __device__ inline void gload16(const void* g, void* l) {
    __builtin_amdgcn_global_load_lds(
        (const __attribute__((address_space(1))) void*)g,
        (__attribute__((address_space(3))) void*)l, 16, 0, 0);
}

// XCD-chunk block swizzle. swz=0 none; 1=M-contig chunks; 2=N-contig chunks.
// Requires gridDim.x*gridDim.y % 8 == 0.
static __device__ inline void tile_coords(int swz, int& bx, int& by) {
    if (swz == 0) { bx = blockIdx.x; by = blockIdx.y; return; }
    int nbx = gridDim.x, nby = gridDim.y;
    int L = blockIdx.y * nbx + blockIdx.x;
    int cpx = (nbx * nby) >> 3;
    int cid = (L & 7) * cpx + (L >> 3);
    if (swz == 1) { by = cid / nbx; bx = cid % nbx; }
    else          { bx = cid / nby; by = cid % nby; }
}

// ============ MFMA GEMM (pass-fused, 2-phase dbuf): one barrier per K-step ============
// Prefetch K-step t+1 into buf^1 while computing buf; the compiler's vmcnt(0)
// before s_barrier now waits AFTER the MFMAs, hiding load latency (T3 recipe).
template<int NP, int NPROD>
__global__ __launch_bounds__(256) void gemm_mf_k(
    const _Float16* __restrict__ A, const _Float16* __restrict__ Wt,
    const float* __restrict__ bias, float* __restrict__ C, const float* __restrict__ resid,
    int M, int N, int K, int ldc, size_t planeA, size_t planeW, int swz)
{
    __shared__ _Float16 As[2][NP][128 * 32];
    __shared__ _Float16 Bs[2][NP][128 * 32];
    const int tid = threadIdx.x;
    const int w = tid >> 6, l = tid & 63;
    const int wm = w >> 1, wn = w & 1;
    int bx, by; tile_coords(swz, bx, by);
    const int row0 = by * 128, col0 = bx * 128;
    const int rA = l >> 2;
    const int cq8 = (l & 3) * 8;
    const int PA[4] = {0, 0, 1, 1};
    const int PW[4] = {0, 1, 0, 1};

    f32x4 acc[4][4];
    #pragma unroll
    for (int i = 0; i < 4; ++i)
        #pragma unroll
        for (int j = 0; j < 4; ++j)
            #pragma unroll
            for (int r = 0; r < 4; ++r) acc[i][j][r] = 0.f;

    const int lr = l & 15, q = l >> 4;

    auto stage = [&](int bf, int k0) {
        #pragma unroll
        for (int p = 0; p < NP; ++p)
            #pragma unroll
            for (int s = 0; s < 2; ++s) {
                int rr = (w * 2 + s) * 16 + rA;
                gload16(A + (size_t)p * planeA + (size_t)(row0 + rr) * K + k0 + cq8,
                        &As[bf][p][(w * 2 + s) * 512]);
                gload16(Wt + (size_t)p * planeW + (size_t)(col0 + rr) * K + k0 + cq8,
                        &Bs[bf][p][(w * 2 + s) * 512]);
            }
    };

    stage(0, 0);
    __syncthreads();
    int cur = 0;
    for (int k0 = 0; k0 < K; k0 += 32) {
        if (k0 + 32 < K) stage(cur ^ 1, k0 + 32);
        f16x8 af[NP][4], bfv[NP][4];
        #pragma unroll
        for (int p = 0; p < NP; ++p)
            #pragma unroll
            for (int i = 0; i < 4; ++i) {
                int ra = wm * 64 + i * 16 + lr;
                af[p][i] = *(const f16x8*)&As[cur][p][ra * 32 + (q ^ ((ra >> 1) & 3)) * 8];
                int rb = wn * 64 + i * 16 + lr;
                bfv[p][i] = *(const f16x8*)&Bs[cur][p][rb * 32 + (q ^ ((rb >> 1) & 3)) * 8];
            }
        #pragma unroll
        for (int pr = 0; pr < NPROD; ++pr) {
            const int pa = PA[pr], pw = PW[pr];
            #pragma unroll
            for (int mi = 0; mi < 4; ++mi)
                #pragma unroll
                for (int ni = 0; ni < 4; ++ni)
                    acc[mi][ni] = __builtin_amdgcn_mfma_f32_16x16x32_f16(
                        af[pa][mi], bfv[pw][ni], acc[mi][ni], 0, 0, 0);
        }
        __syncthreads();
        cur ^= 1;
    }
    const int cw = l & 15, rw = (l >> 4) * 4;
    #pragma unroll
    for (int mi = 0; mi < 4; ++mi)
        #pragma unroll
        for (int ni = 0; ni < 4; ++ni)
            #pragma unroll
            for (int r = 0; r < 4; ++r) {
                int gr = row0 + wm * 64 + mi * 16 + rw + r;
                int gc = col0 + wn * 64 + ni * 16 + cw;
                size_t ci = (size_t)gr * ldc + gc;
                float val = acc[mi][ni][r];
                if (bias)  val += bias[gc];
                if (resid) val += resid[ci];
                C[ci] = val;
            }
}

// ============ Fused gate-up: F = silu(A@Wg)*(A@Wu) -> pre-swz split planes ============
// NP=1 (mid): 2-phase dbuf (48KB, 3 blocks/CU). NP=2 (shallow): single-buffer
// (dbuf would need 96KB -> 1 block/CU, the m132 occupancy cliff).
template<int NP, int NPROD>
__global__ __launch_bounds__(256) void gateup_k(
    const _Float16* __restrict__ A, const _Float16* __restrict__ Wg, const _Float16* __restrict__ Wu,
    _Float16* __restrict__ F, int M, int N, int K,
    size_t planeA, size_t planeW, size_t planeF, int npOut, int swz)
{
    constexpr int NB = (NP == 1) ? 2 : 1;
    __shared__ _Float16 As[NB][NP][128 * 32];
    __shared__ _Float16 Bg[NB][NP][128 * 32];
    __shared__ _Float16 Bu[NB][NP][128 * 32];
    const int tid = threadIdx.x;
    const int w = tid >> 6, l = tid & 63;
    const int wm = w >> 1, wn = w & 1;
    int bx, by; tile_coords(swz, bx, by);
    const int row0 = by * 128, col0 = bx * 128;
    const int rA = l >> 2;
    const int cq8 = (l & 3) * 8;
    const int PA[4] = {0, 0, 1, 1};
    const int PW[4] = {0, 1, 0, 1};

    f32x4 accg[4][4], accu[4][4];
    #pragma unroll
    for (int i = 0; i < 4; ++i)
        #pragma unroll
        for (int j = 0; j < 4; ++j)
            #pragma unroll
            for (int r = 0; r < 4; ++r) { accg[i][j][r] = 0.f; accu[i][j][r] = 0.f; }

    const int lr = l & 15, q = l >> 4;

    auto stage = [&](int bf, int k0) {
        #pragma unroll
        for (int p = 0; p < NP; ++p)
            #pragma unroll
            for (int s = 0; s < 2; ++s) {
                int rr = (w * 2 + s) * 16 + rA;
                gload16(A  + (size_t)p * planeA + (size_t)(row0 + rr) * K + k0 + cq8,
                        &As[bf][p][(w * 2 + s) * 512]);
                gload16(Wg + (size_t)p * planeW + (size_t)(col0 + rr) * K + k0 + cq8,
                        &Bg[bf][p][(w * 2 + s) * 512]);
                gload16(Wu + (size_t)p * planeW + (size_t)(col0 + rr) * K + k0 + cq8,
                        &Bu[bf][p][(w * 2 + s) * 512]);
            }
    };
    auto compute = [&](int bf) {
        f16x8 af[NP][4];
        #pragma unroll
        for (int p = 0; p < NP; ++p)
            #pragma unroll
            for (int i = 0; i < 4; ++i) {
                int ra = wm * 64 + i * 16 + lr;
                af[p][i] = *(const f16x8*)&As[bf][p][ra * 32 + (q ^ ((ra >> 1) & 3)) * 8];
            }
        #pragma unroll
        for (int pr = 0; pr < NPROD; ++pr) {
            const int pa = PA[pr], pw = PW[pr];
            f16x8 bg[4], bu[4];
            #pragma unroll
            for (int i = 0; i < 4; ++i) {
                int rb = wn * 64 + i * 16 + lr;
                int sb = (q ^ ((rb >> 1) & 3)) * 8;
                bg[i] = *(const f16x8*)&Bg[bf][pw][rb * 32 + sb];
                bu[i] = *(const f16x8*)&Bu[bf][pw][rb * 32 + sb];
            }
            #pragma unroll
            for (int mi = 0; mi < 4; ++mi)
                #pragma unroll
                for (int ni = 0; ni < 4; ++ni) {
                    accg[mi][ni] = __builtin_amdgcn_mfma_f32_16x16x32_f16(
                        af[pa][mi], bg[ni], accg[mi][ni], 0, 0, 0);
                    accu[mi][ni] = __builtin_amdgcn_mfma_f32_16x16x32_f16(
                        af[pa][mi], bu[ni], accu[mi][ni], 0, 0, 0);
                }
        }
    };

    if constexpr (NB == 2) {
        stage(0, 0);
        __syncthreads();
        int cur = 0;
        for (int k0 = 0; k0 < K; k0 += 32) {
            if (k0 + 32 < K) stage(cur ^ 1, k0 + 32);
            compute(cur);
            __syncthreads();
            cur ^= 1;
        }
    } else {
        for (int k0 = 0; k0 < K; k0 += 32) {
            __syncthreads();
            stage(0, k0);
            __syncthreads();
            compute(0);
        }
    }

    const int cw = l & 15, rw = (l >> 4) * 4;
    #pragma unroll
    for (int mi = 0; mi < 4; ++mi)
        #pragma unroll
        for (int ni = 0; ni < 4; ++ni)
            #pragma unroll
            for (int r = 0; r < 4; ++r) {
                int gr = row0 + wm * 64 + mi * 16 + rw + r;
                int gc = col0 + wn * 64 + ni * 16 + cw;
                float g = accg[mi][ni][r], u = accu[mi][ni][r];
                float val = g / (1.f + expf(-g)) * u;
                split_store_swz(val, F, planeF, (size_t)gr * N, gc, (gr >> 1) & 3, npOut);
            }
}

// ============ MFMA flash attention (fp16, pre-swizzled planes, gload staging) ============
template<int NP, int NPROD>
__global__ __launch_bounds__(256) void mfattn_k(
    const _Float16* __restrict__ qsp, const _Float16* __restrict__ ksp,
    const _Float16* __restrict__ vtp, _Float16* __restrict__ osp,
    const int* __restrict__ valid)
{
    __shared__ _Float16 KP[NP][2][64 * 32];   // K tile; reused as P planes
    __shared__ _Float16 Vt[NP][2][64 * 32];   // V^T tile
    __shared__ int kvs[64];
    const int tid = threadIdx.x;
    const int w = tid >> 6, l = tid & 63;
    const int lr = l & 15, lq = l >> 4;
    const int qt = blockIdx.x, hh = blockIdx.y, b = blockIdx.z;
    const int rT = l >> 2;
    const int cq8 = (l & 3) * 8;
    const int PA[4] = {0, 0, 1, 1};
    const int PW[4] = {0, 1, 0, 1};

    f16x8 aq[NP][2];
    {
        const int qrowa = qt * 64 + w * 16 + lr;
        const int phiq = (qrowa >> 1) & 3;
        #pragma unroll
        for (int p = 0; p < NP; ++p)
            #pragma unroll
            for (int ks = 0; ks < 2; ++ks)
                aq[p][ks] = *(const f16x8*)(qsp + (size_t)p * BSH
                    + (size_t)(b * S + qrowa) * H + hh * 64 + ks * 32 + ((lq ^ phiq) << 3));
    }
    int qvr[4];
    #pragma unroll
    for (int r = 0; r < 4; ++r)
        qvr[r] = valid[b * S + qt * 64 + w * 16 + lq * 4 + r];

    float m[4], lsum[4];
    f32x4 acco[4];
    #pragma unroll
    for (int r = 0; r < 4; ++r) { m[r] = -3.4e38f; lsum[r] = 0.f; }
    #pragma unroll
    for (int n = 0; n < 4; ++n)
        #pragma unroll
        for (int r = 0; r < 4; ++r) acco[n][r] = 0.f;

    for (int kt = 0; kt < S / 64; ++kt) {
        __syncthreads();
        {
            const int r = w * 16 + rT;
            #pragma unroll
            for (int p = 0; p < NP; ++p)
                #pragma unroll
                for (int hf = 0; hf < 2; ++hf) {
                    gload16(ksp + (size_t)p * BSH
                            + (size_t)(b * S + kt * 64 + r) * H + hh * 64 + hf * 32 + cq8,
                            &KP[p][hf][w * 512]);
                    gload16(vtp + (size_t)p * BSH
                            + ((size_t)(hh * 64 + r) * B + b) * S + kt * 64 + hf * 32 + cq8,
                            &Vt[p][hf][w * 512]);
                }
        }
        if (tid < 64) kvs[tid] = valid[b * S + kt * 64 + tid];
        __syncthreads();

        // ---- S = Q @ K^T ----
        f32x4 accs[4];
        #pragma unroll
        for (int n = 0; n < 4; ++n)
            #pragma unroll
            for (int r = 0; r < 4; ++r) accs[n][r] = 0.f;
        #pragma unroll
        for (int pr = 0; pr < NPROD; ++pr) {
            const int pa = PA[pr], pw = PW[pr];
            #pragma unroll
            for (int ks = 0; ks < 2; ++ks)
                #pragma unroll
                for (int n = 0; n < 4; ++n) {
                    int rb = n * 16 + lr;
                    f16x8 bk = *(const f16x8*)&KP[pw][ks][rb * 32 + ((lq ^ ((rb >> 1) & 3))) * 8];
                    accs[n] = __builtin_amdgcn_mfma_f32_16x16x32_f16(
                        aq[pa][ks], bk, accs[n], 0, 0, 0);
                }
        }
        // ---- mask + online softmax ----
        float pf[4][4];
        int kva[4];
        #pragma unroll
        for (int n = 0; n < 4; ++n) kva[n] = kvs[n * 16 + lr];
        #pragma unroll
        for (int r = 0; r < 4; ++r) {
            int qr = qt * 64 + w * 16 + lq * 4 + r;
            float rowm = -3.4e38f;
            #pragma unroll
            for (int n = 0; n < 4; ++n) {
                int kc = kt * 64 + n * 16 + lr;
                float sv = accs[n][r] * 0.125f;
                int allowed = (kc <= qr) && qvr[r] && kva[n];
                if (!allowed) sv = sv + -1e9f;
                pf[n][r] = sv;
                rowm = fmaxf(rowm, sv);
            }
            rowm = fmaxf(rowm, __shfl_xor(rowm, 1));
            rowm = fmaxf(rowm, __shfl_xor(rowm, 2));
            rowm = fmaxf(rowm, __shfl_xor(rowm, 4));
            rowm = fmaxf(rowm, __shfl_xor(rowm, 8));
            float mn = fmaxf(m[r], rowm);
            float co = __expf(m[r] - mn);
            float rs = 0.f;
            #pragma unroll
            for (int n = 0; n < 4; ++n) { pf[n][r] = __expf(pf[n][r] - mn); rs += pf[n][r]; }
            rs += __shfl_xor(rs, 1);
            rs += __shfl_xor(rs, 2);
            rs += __shfl_xor(rs, 4);
            rs += __shfl_xor(rs, 8);
            lsum[r] = lsum[r] * co + rs;
            m[r] = mn;
            #pragma unroll
            for (int n = 0; n < 4; ++n) acco[n][r] *= co;
        }
        __syncthreads();
        // ---- write P (fp16 split) into KP, swizzled for a-frag reads ----
        #pragma unroll
        for (int n = 0; n < 4; ++n) {
            int col = n * 16 + lr;
            int hf = col >> 5, colh = col & 31, cq2 = colh >> 3, pos = colh & 7;
            #pragma unroll
            for (int r = 0; r < 4; ++r) {
                int rowg = w * 16 + lq * 4 + r;
                int off = rowg * 32 + (cq2 ^ ((rowg >> 1) & 3)) * 8 + pos;
                float pv = pf[n][r];
                _Float16 h0 = (_Float16)pv;
                KP[0][hf][off] = h0;
                if (NP == 2) KP[1][hf][off] = (_Float16)(pv - (float)h0);
            }
        }
        __syncthreads();
        // ---- O += P @ V ----
        #pragma unroll
        for (int pr = 0; pr < NPROD; ++pr) {
            const int pa = PA[pr], pw = PW[pr];
            #pragma unroll
            for (int ks = 0; ks < 2; ++ks) {
                int ra = w * 16 + lr;
                f16x8 ap = *(const f16x8*)&KP[pa][ks][ra * 32 + ((lq ^ ((ra >> 1) & 3))) * 8];
                #pragma unroll
                for (int n = 0; n < 4; ++n) {
                    int rb = n * 16 + lr;
                    f16x8 bv = *(const f16x8*)&Vt[pw][ks][rb * 32 + ((lq ^ ((rb >> 1) & 3))) * 8];
                    acco[n] = __builtin_amdgcn_mfma_f32_16x16x32_f16(
                        ap, bv, acco[n], 0, 0, 0);
                }
            }
        }
    }
    // ---- write O as pre-swizzled split planes ----
    #pragma unroll
    for (int r = 0; r < 4; ++r) {
        float inv = 1.0f / lsum[r];
        int qr = qt * 64 + w * 16 + lq * 4 + r;
        size_t rowbase = (size_t)(b * S + qr) * H;
        int phi = ((b * S + qr) >> 1) & 3;
        #pragma unroll
        for (int n = 0; n < 4; ++n)
            split_store_swz(acco[n][r] * inv, osp, BSH, rowbase, hh * 64 + n * 16 + lr, phi, NP);
    }
}

// ============ Trig table: ct/st[p][i] = cos/sin(p * 10000^(-2i/64)), fp64-accurate ============
__global__ __launch_bounds__(256) void trigtab_k(float* __restrict__ ct, float* __restrict__ st)
{
    int idx = blockIdx.x * 256 + threadIdx.x;   // S*32 total
    int i = idx & 31, p = idx >> 5;
    double inv = exp(-((double)(2 * i) / 64.0) * log(10000.0));
    double ang = (double)p * inv;
    ct[idx] = (float)cos(ang);
    st[idx] = (float)sin(ang);
}

// ============ RoPE + fp16 split -> pre-swizzled planes (table-driven trig) ============
__global__ __launch_bounds__(256) void rope_split_k(const float* __restrict__ x,
    int xld, int xoff, const int* __restrict__ pos,
    const float* __restrict__ ct, const float* __restrict__ st,
    _Float16* __restrict__ y, size_t plane, int np)
{
    int idx = blockIdx.x * 256 + threadIdx.x;
    int i = idx & 31;
    int head = (idx >> 5) & 15;
    int bs = idx >> 9;
    int p = pos[bs];
    float c = ct[p * 32 + i], sn = st[p * 32 + i];
    const float* base = x + (size_t)bs * xld + xoff + head * 64;
    float x1 = base[i], x2 = base[i + 32];
    size_t rowbase = (size_t)bs * H;
    int phi = (bs >> 1) & 3;
    split_store_swz(x1 * c - x2 * sn, y, plane, rowbase, head * 64 + i, phi, np);
    split_store_swz(x2 * c + x1 * sn, y, plane, rowbase, head * 64 + i + 32, phi, np);
}

// ============ V transpose + split (reads strided qkv) -> planes [(h*64+d)*B+b][S] ============
__global__ __launch_bounds__(256) void splitvt_k(const float* __restrict__ V,
    int vld, int voff, _Float16* __restrict__ Vt, size_t plane, int np)
{
    __shared__ float t[32][33];
    const int tid = threadIdx.x;
    const int s0 = blockIdx.x * 32;
    const int hd0 = blockIdx.y * 32;
    const int b = blockIdx.z;
    #pragma unroll
    for (int i = 0; i < 4; ++i) {
        int e = tid + i * 256;
        int rr = e >> 5, cc = e & 31;
        t[rr][cc] = V[(size_t)(b * S + s0 + rr) * vld + voff + hd0 + cc];
    }
    __syncthreads();
    #pragma unroll
    for (int i = 0; i < 4; ++i) {
        int e = tid + i * 256;
        int rn = e >> 5, ck = e & 31;
        int hd = hd0 + rn;
        size_t rowbase = ((size_t)hd * B + b) * S;
        split_store_swz(t[ck][rn], Vt, plane, rowbase, s0 + ck, ((hd & 63) >> 1) & 3, np);
    }
}

// ============ Weight transpose + fp16 split: W[K,N](srcld) -> Wt planes [N][K] ============
__global__ __launch_bounds__(256) void splitwt_k(const float* __restrict__ W,
    _Float16* __restrict__ Wt, int K, int N, int srcld, size_t plane, int np)
{
    __shared__ float t[32][33];
    const int tid = threadIdx.x;
    const int n0 = blockIdx.x * 32, k0 = blockIdx.y * 32;
    #pragma unroll
    for (int i = 0; i < 4; ++i) {
        int e = tid + i * 256;
        int rk = e >> 5, cn = e & 31;
        t[rk][cn] = W[(size_t)(k0 + rk) * srcld + n0 + cn];
    }
    __syncthreads();
    #pragma unroll
    for (int i = 0; i < 4; ++i) {
        int e = tid + i * 256;
        int rn = e >> 5, ck = e & 31;
        int nn = n0 + rn;
        split_store_swz(t[ck][rn], Wt, plane, (size_t)nn * K, k0 + ck, (nn >> 1) & 3, np);
    }
}

// ============ Plain fp32 -> fp16 split planes (rows of length H) ============
__global__ __launch_bounds__(256) void splita_swz_k(const float* __restrict__ x,
    _Float16* __restrict__ y, size_t plane, int np)
{
    int row = blockIdx.x;
    size_t rowbase = (size_t)row * H;
    int phi = (row >> 1) & 3;
    for (int i = threadIdx.x; i < H; i += 256)
        split_store_swz(x[rowbase + i], y, plane, rowbase, i, phi, np);
}

// ============ RMSNorm -> pre-swz fp16 split ============
__global__ __launch_bounds__(256) void rmsnorm_split_k(const float* __restrict__ x,
    const float* __restrict__ w, _Float16* __restrict__ y, size_t plane, int np)
{
    int row = blockIdx.x;
    const float* xr = x + (size_t)row * H;
    __shared__ float red[256];
    float s = 0.f;
    for (int i = threadIdx.x; i < H; i += 256) { float v = xr[i]; s += v * v; }
    red[threadIdx.x] = s; __syncthreads();
    for (int off = 128; off > 0; off >>= 1) {
        if (threadIdx.x < off) red[threadIdx.x] += red[threadIdx.x + off];
        __syncthreads();
    }
    float r = 1.0f / sqrtf(red[0] / (float)H + 1e-6f);
    size_t rowbase = (size_t)row * H;
    int phi = (row >> 1) & 3;
    for (int i = threadIdx.x; i < H; i += 256)
        split_store_swz(xr[i] * r * w[i], y, plane, rowbase, i, phi, np);
}

// ============ Head column 2048 (null logit), exact fp32 ============
__global__ __launch_bounds__(64) void headcol_k(const float* __restrict__ h,
    const float* __restrict__ head_w, const float* __restrict__ head_b,
    float* __restrict__ logits)
{
    int row = blockIdx.x;
    int l = threadIdx.x;
    float s = 0.f;
    for (int j = l; j < H; j += 64) s += h[(size_t)row * H + j] * head_w[(size_t)j * CV1 + CV];
    s += __shfl_xor(s, 1);
    s += __shfl_xor(s, 2);
    s += __shfl_xor(s, 4);
    s += __shfl_xor(s, 8);
    s += __shfl_xor(s, 16);
    s += __shfl_xor(s, 32);
    if (l == 0) logits[(size_t)row * CV1 + CV] = s + head_b[CV];
}

// ---------------- fp32 GEMM (fallback path) ----------------
__global__ __launch_bounds__(256) void gemm_k(
    const float* __restrict__ A, const float* __restrict__ Wm,
    const float* __restrict__ bias, float* __restrict__ C,
    int M, int N, int K, int lda, int ldb, int ldc, int flags)
{
    __shared__ float As[16][65];
    __shared__ float Bs[16][65];
    const int tid = threadIdx.x;
    const int tx = tid & 15, ty = tid >> 4;
    const int row0 = blockIdx.y * 64, col0 = blockIdx.x * 64;
    float acc[4][4] = {};
    for (int k0 = 0; k0 < K; k0 += 16) {
        #pragma unroll
        for (int l = 0; l < 4; ++l) {
            int e = tid + l * 256;
            int r = e >> 4, c = e & 15;
            int gr = row0 + r;
            float vv = 0.f;
            if (gr < M) vv = A[(size_t)gr * lda + (k0 + c)];
            As[c][r] = vv;
        }
        #pragma unroll
        for (int l = 0; l < 4; ++l) {
            int e = tid + l * 256;
            int r = e >> 6, c = e & 63;
            int gc = col0 + c;
            float vv = 0.f;
            if (gc < N) vv = Wm[(size_t)(k0 + r) * ldb + gc];
            Bs[r][c] = vv;
        }
        __syncthreads();
        #pragma unroll
        for (int kk = 0; kk < 16; ++kk) {
            float a[4], bb[4];
            #pragma unroll
            for (int i = 0; i < 4; ++i) a[i] = As[kk][ty * 4 + i];
            #pragma unroll
            for (int j = 0; j < 4; ++j) bb[j] = Bs[kk][tx * 4 + j];
            #pragma unroll
            for (int i = 0; i < 4; ++i)
                #pragma unroll
                for (int j = 0; j < 4; ++j)
                    acc[i][j] += a[i] * bb[j];
        }
        __syncthreads();
    }
    #pragma unroll
    for (int i = 0; i < 4; ++i) {
        int gr = row0 + ty * 4 + i;
        if (gr >= M) continue;
        #pragma unroll
        for (int j = 0; j < 4; ++j) {
            int gc = col0 + tx * 4 + j;
            if (gc >= N) continue;
            float vv = acc[i][j];
            if (flags & F_BIAS)  vv += bias[gc];
            if (flags & F_SILU)  vv = vv / (1.f + expf(-vv));
            size_t cidx = (size_t)gr * ldc + gc;
            if (flags & F_MULIN) vv *= C[cidx];
            if (flags & F_RESID) vv += C[cidx];
            C[cidx] = vv;
        }
    }
}

// ---------------- RMSNorm fp32 (fallback) ----------------
__global__ __launch_bounds__(256) void rmsnorm_k(const float* __restrict__ x,
    const float* __restrict__ w, float* __restrict__ y)
{
    int row = blockIdx.x;
    const float* xr = x + (size_t)row * H;
    float* yr = y + (size_t)row * H;
    __shared__ float red[256];
    float s = 0.f;
    for (int i = threadIdx.x; i < H; i += 256) { float v = xr[i]; s += v * v; }
    red[threadIdx.x] = s; __syncthreads();
    for (int off = 128; off > 0; off >>= 1) {
        if (threadIdx.x < off) red[threadIdx.x] += red[threadIdx.x + off];
        __syncthreads();
    }
    float r = 1.0f / sqrtf(red[0] / (float)H + 1e-6f);
    for (int i = threadIdx.x; i < H; i += 256) yr[i] = xr[i] * r * w[i];
}

// ---------------- Embed gather ----------------
__global__ __launch_bounds__(256) void embed_k(const int* __restrict__ ids,
    const float* __restrict__ emb, float* __restrict__ h)
{
    int bs = blockIdx.x;
    const float* e = emb + (size_t)ids[bs] * H;
    float* hr = h + (size_t)bs * H;
    for (int i = threadIdx.x; i < H; i += 256) hr[i] = e[i];
}

// ---------------- RoPE fp32 in-place (fallback) ----------------
__global__ __launch_bounds__(256) void rope_k(float* __restrict__ x, const int* __restrict__ pos)
{
    int idx = blockIdx.x * 256 + threadIdx.x;
    int i = idx & 31;
    int head = (idx >> 5) & 15;
    int bs = idx >> 9;
    int p = pos[bs];
    double inv = exp(-((double)(2 * i) / 64.0) * log(10000.0));
    double ang = (double)p * inv;
    float c = (float)cos(ang), sn = (float)sin(ang);
    float* base = x + (size_t)bs * H + head * 64;
    float x1 = base[i], x2 = base[i + 32];
    base[i]      = x1 * c - x2 * sn;
    base[i + 32] = x2 * c + x1 * sn;
}

// ---------------- Flash attention fp32 (fallback) ----------------
__global__ __launch_bounds__(256) void fattn_k(const float* __restrict__ q,
    const float* __restrict__ k, const float* __restrict__ v,
    float* __restrict__ o, const int* __restrict__ valid)
{
    const int qt = blockIdx.x, hh = blockIdx.y, b = blockIdx.z;
    const int tid = threadIdx.x;
    const int tx = tid & 15, ty = tid >> 4;
    __shared__ float Qs[64][68];
    __shared__ float Ks[64][68];
    __shared__ float Vs[64][68];
    __shared__ int   kvs[64];
    const size_t hoff = (size_t)hh * HD;

    {
        int row = tid >> 2, d0 = (tid & 3) * 16;
        const float* qp = q + ((size_t)(b * S + qt * 64 + row)) * H + hoff + d0;
        float4* dst = (float4*)&Qs[row][d0];
        const float4* src = (const float4*)qp;
        #pragma unroll
        for (int e = 0; e < 4; ++e) dst[e] = src[e];
    }
    int qv[4]; int qrow_g[4];
    #pragma unroll
    for (int i = 0; i < 4; ++i) {
        qrow_g[i] = qt * 64 + ty * 4 + i;
        qv[i] = valid[b * S + qrow_g[i]];
    }
    float m[4], l[4], acc[4][4];
    #pragma unroll
    for (int i = 0; i < 4; ++i) {
        m[i] = -3.4e38f; l[i] = 0.f;
        #pragma unroll
        for (int j = 0; j < 4; ++j) acc[i][j] = 0.f;
    }

    for (int kt = 0; kt < S / 64; ++kt) {
        __syncthreads();
        {
            int row = tid >> 2, d0 = (tid & 3) * 16;
            const float* kp = k + ((size_t)(b * S + kt * 64 + row)) * H + hoff + d0;
            float4* dst = (float4*)&Ks[row][d0];
            const float4* src = (const float4*)kp;
            #pragma unroll
            for (int e = 0; e < 4; ++e) dst[e] = src[e];
        }
        {
            int kk = tid >> 2, d0 = (tid & 3) * 16;
            const float* vp = v + ((size_t)(b * S + kt * 64 + kk)) * H + hoff + d0;
            #pragma unroll
            for (int e = 0; e < 16; e += 4) {
                float4 vv = *(const float4*)(vp + e);
                Vs[d0 + e + 0][kk] = vv.x;
                Vs[d0 + e + 1][kk] = vv.y;
                Vs[d0 + e + 2][kk] = vv.z;
                Vs[d0 + e + 3][kk] = vv.w;
            }
        }
        if (tid < 64) kvs[tid] = valid[b * S + kt * 64 + tid];
        __syncthreads();

        float s4[4][4];
        #pragma unroll
        for (int i = 0; i < 4; ++i)
            #pragma unroll
            for (int j = 0; j < 4; ++j) s4[i][j] = 0.f;
        #pragma unroll
        for (int c = 0; c < 16; ++c) {
            float4 a[4], bb[4];
            #pragma unroll
            for (int i = 0; i < 4; ++i) a[i]  = ((const float4*)&Qs[ty * 4 + i][0])[c];
            #pragma unroll
            for (int j = 0; j < 4; ++j) bb[j] = ((const float4*)&Ks[tx * 4 + j][0])[c];
            #pragma unroll
            for (int i = 0; i < 4; ++i)
                #pragma unroll
                for (int j = 0; j < 4; ++j) {
                    s4[i][j] += a[i].x * bb[j].x + a[i].y * bb[j].y
                              + a[i].z * bb[j].z + a[i].w * bb[j].w;
                }
        }
        float p[4][4];
        float corr[4];
        #pragma unroll
        for (int i = 0; i < 4; ++i) {
            float rm = -3.4e38f;
            #pragma unroll
            for (int j = 0; j < 4; ++j) {
                int kc = kt * 64 + tx * 4 + j;
                float sv = s4[i][j] * 0.125f;
                int allowed = (kc <= qrow_g[i]) && qv[i] && kvs[tx * 4 + j];
                if (!allowed) sv = sv + -1e9f;
                s4[i][j] = sv;
                rm = fmaxf(rm, sv);
            }
            rm = fmaxf(rm, __shfl_xor(rm, 1));
            rm = fmaxf(rm, __shfl_xor(rm, 2));
            rm = fmaxf(rm, __shfl_xor(rm, 4));
            rm = fmaxf(rm, __shfl_xor(rm, 8));
            float mn = fmaxf(m[i], rm);
            corr[i] = expf(m[i] - mn);
            float rs = 0.f;
            #pragma unroll
            for (int j = 0; j < 4; ++j) { p[i][j] = expf(s4[i][j] - mn); rs += p[i][j]; }
            rs += __shfl_xor(rs, 1);
            rs += __shfl_xor(rs, 2);
            rs += __shfl_xor(rs, 4);
            rs += __shfl_xor(rs, 8);
            l[i] = l[i] * corr[i] + rs;
            m[i] = mn;
            #pragma unroll
            for (int j = 0; j < 4; ++j) acc[i][j] *= corr[i];
        }
        __syncthreads();
        #pragma unroll
        for (int i = 0; i < 4; ++i) {
            float4 pv4 = make_float4(p[i][0], p[i][1], p[i][2], p[i][3]);
            *(float4*)&Ks[ty * 4 + i][tx * 4] = pv4;
        }
        __syncthreads();
        #pragma unroll
        for (int c = 0; c < 16; ++c) {
            float4 a[4], bb[4];
            #pragma unroll
            for (int i = 0; i < 4; ++i) a[i]  = ((const float4*)&Ks[ty * 4 + i][0])[c];
            #pragma unroll
            for (int j = 0; j < 4; ++j) bb[j] = ((const float4*)&Vs[tx * 4 + j][0])[c];
            #pragma unroll
            for (int i = 0; i < 4; ++i)
                #pragma unroll
                for (int j = 0; j < 4; ++j) {
                    acc[i][j] += a[i].x * bb[j].x + a[i].y * bb[j].y
                               + a[i].z * bb[j].z + a[i].w * bb[j].w;
                }
        }
    }
    #pragma unroll
    for (int i = 0; i < 4; ++i) {
        float inv = 1.0f / l[i];
        float4 ov = make_float4(acc[i][0] * inv, acc[i][1] * inv,
                                acc[i][2] * inv, acc[i][3] * inv);
        *(float4*)(o + ((size_t)(b * S + qrow_g[i])) * H + hoff + tx * 4) = ov;
    }
}

// ---------------- Discretize: fp16 swizzled z + fp32 fallback ----------------
__global__ __launch_bounds__(256) void discretize_h_k(const float* __restrict__ logits,
    const float* __restrict__ gumbel, _Float16* __restrict__ z, int* __restrict__ chosen)
{
    int bs = blockIdx.x;
    const float* lg = logits + (size_t)bs * CV1;
    const float* gm = gumbel + (size_t)bs * CV1;
    __shared__ float redv[256]; __shared__ int redi[256];
    int tid = threadIdx.x;
    float m = -3.4e38f; int mi = CV1;
    for (int j = tid; j < CV1; j += 256) {
        float a = lg[j] + gm[j];
        if (a > m) { m = a; mi = j; }
    }
    redv[tid] = m; redi[tid] = mi; __syncthreads();
    for (int off = 128; off > 0; off >>= 1) {
        if (tid < off) {
            float vo = redv[tid + off]; int io = redi[tid + off];
            if (vo > redv[tid] || (vo == redv[tid] && io < redi[tid])) { redv[tid] = vo; redi[tid] = io; }
        }
        __syncthreads();
    }
    m = redv[0]; int amax = redi[0];
    __syncthreads();
    float ssum = 0.f;
    for (int j = tid; j < CV1; j += 256) ssum += expf(lg[j] + gm[j] - m);
    redv[tid] = ssum; __syncthreads();
    for (int off = 128; off > 0; off >>= 1) {
        if (tid < off) redv[tid] += redv[tid + off];
        __syncthreads();
    }
    float inv = 1.0f / redv[0];
    size_t rowbase = (size_t)bs * CV;
    int phi = (bs >> 1) & 3;
    for (int j = tid; j < CV; j += 256) {
        float zv = expf(lg[j] + gm[j] - m) * inv;
        z[swz_idx(rowbase, j, phi)] = (_Float16)zv;
    }
    if (tid == 0) chosen[bs] = amax;
}

__global__ __launch_bounds__(256) void discretize_k(const float* __restrict__ logits,
    const float* __restrict__ gumbel, float* __restrict__ z, int* __restrict__ chosen)
{
    int bs = blockIdx.x;
    const float* lg = logits + (size_t)bs * CV1;
    const float* gm = gumbel + (size_t)bs * CV1;
    __shared__ float redv[256]; __shared__ int redi[256];
    int tid = threadIdx.x;
    float m = -3.4e38f; int mi = CV1;
    for (int j = tid; j < CV1; j += 256) {
        float a = lg[j] + gm[j];
        if (a > m) { m = a; mi = j; }
    }
    redv[tid] = m; redi[tid] = mi; __syncthreads();
    for (int off = 128; off > 0; off >>= 1) {
        if (tid < off) {
            float vo = redv[tid + off]; int io = redi[tid + off];
            if (vo > redv[tid] || (vo == redv[tid] && io < redi[tid])) { redv[tid] = vo; redi[tid] = io; }
        }
        __syncthreads();
    }
    m = redv[0]; int amax = redi[0];
    __syncthreads();
    float ssum = 0.f;
    for (int j = tid; j < CV1; j += 256) ssum += expf(lg[j] + gm[j] - m);
    redv[tid] = ssum; __syncthreads();
    for (int off = 128; off > 0; off >>= 1) {
        if (tid < off) redv[tid] += redv[tid + off];
        __syncthreads();
    }
    float inv = 1.0f / redv[0];
    for (int j = tid; j < CV; j += 256)
        z[(size_t)bs * CV + j] = expf(lg[j] + gm[j] - m) * inv;
    if (tid == 0) chosen[bs] = amax;
}

// ---------------- cea + loss ----------------
__global__ __launch_bounds__(256) void cea_k(const float* __restrict__ esoft,
    const float* __restrict__ cemb, const int* __restrict__ chosen,
    const int* __restrict__ amask, float* __restrict__ cea, float* __restrict__ partial)
{
    int bs = blockIdx.x;
    int ch = chosen[bs]; int vm = amask[bs];
    int comp = (ch != CV) && vm;
    const float* ehr = cemb + (size_t)(ch < CV - 1 ? ch : CV - 1) * H;
    __shared__ float red[256];
    float part = 0.f;
    float vmf = vm ? 1.f : 0.f;
    for (int i = threadIdx.x; i < H; i += 256) {
        float es = esoft[(size_t)bs * H + i];
        float eh = comp ? ehr[i] : 0.f;
        cea[(size_t)bs * H + i] = ((eh + es) - es) * vmf;
        float d = es - eh;
        part += d * d;
    }
    red[threadIdx.x] = part; __syncthreads();
    for (int off = 128; off > 0; off >>= 1) {
        if (threadIdx.x < off) red[threadIdx.x] += red[threadIdx.x + off];
        __syncthreads();
    }
    if (threadIdx.x == 0) partial[bs] = red[0];
}

__global__ __launch_bounds__(256) void loss_k(const float* __restrict__ partial, float* __restrict__ out)
{
    __shared__ float red[256];
    float s = 0.f;
    for (int i = threadIdx.x; i < BS; i += 256) s += partial[i];
    red[threadIdx.x] = s; __syncthreads();
    for (int off = 128; off > 0; off >>= 1) {
        if (threadIdx.x < off) red[threadIdx.x] += red[threadIdx.x + off];
        __syncthreads();
    }
    if (threadIdx.x == 0) out[0] = 1.25f * red[0] / (float)BSH;
}

// ---------------- Parallel stable pack: scan over is_comp flags ----------------
__global__ __launch_bounds__(1024) void pack_k(const int* __restrict__ chosen,
    const int* __restrict__ amask, int* __restrict__ order, int* __restrict__ cpos,
    int* __restrict__ cvalid, int* __restrict__ counts)
{
    int b = blockIdx.x, t = threadIdx.x;
    __shared__ int sc[1024];
    __shared__ int ord[1024];
    int f = (chosen[b * S + t] != CV && amask[b * S + t]) ? 1 : 0;
    sc[t] = f;
    __syncthreads();
    #pragma unroll
    for (int off = 1; off < 1024; off <<= 1) {
        int add = (t >= off) ? sc[t - off] : 0;
        __syncthreads();
        sc[t] += add;
        __syncthreads();
    }
    int cnt = sc[1023];
    int pos = f ? (sc[t] - 1) : (cnt + t - sc[t]);
    ord[pos] = t;
    __syncthreads();
    int o = ord[t];
    order[b * S + t] = o;
    cvalid[b * S + t] = (t < cnt) ? 1 : 0;
    cpos[b * S + t] = (t < cnt) ? o : 0;
    if (t == 0) counts[b] = cnt;
}

__global__ __launch_bounds__(256) void gather_k(const float* __restrict__ cea,
    const int* __restrict__ order, const int* __restrict__ cvalid, float* __restrict__ h)
{
    int bs = blockIdx.x;
    int b = bs >> 10;
    int src = order[bs];
    float f = cvalid[bs] ? 1.f : 0.f;
    const float* sp = cea + (size_t)(b * S + src) * H;
    float* dst = h + (size_t)bs * H;
    for (int i = threadIdx.x; i < H; i += 256) dst[i] = sp[i] * f;
}

__global__ __launch_bounds__(256) void outmask_k(const float* __restrict__ h,
    const int* __restrict__ cvalid, float* __restrict__ out)
{
    int bs = blockIdx.x;
    float f = cvalid[bs] ? 1.f : 0.f;
    for (int i = threadIdx.x; i < H; i += 256)
        out[(size_t)bs * H + i] = h[(size_t)bs * H + i] * f;
}

__global__ __launch_bounds__(256) void iota_k(int* __restrict__ pos)
{
    int idx = blockIdx.x * 256 + threadIdx.x;
    if (idx < BS) pos[idx] = idx & (S - 1);
}

// ================= Host-side drivers =================
static void run_block_f32(int layer,
    const float* ln1, const float* wq, const float* wk, const float* wv,
    const float* wo, const float* ln2, const float* wg, const float* wu, const float* wd,
    float* h, float* hn, float* q, float* k, float* v, float* o, float* f1,
    const int* valid, const int* pos, hipStream_t stream)
{
    size_t LHH = (size_t)layer * H * H;
    size_t LHF = (size_t)layer * H * FF;
    rmsnorm_k<<<BS, 256, 0, stream>>>(h, ln1 + (size_t)layer * H, hn);
    gemm_k<<<dim3(16, 64), 256, 0, stream>>>(hn, wq + LHH, nullptr, q, BS, H, H, H, H, H, 0);
    gemm_k<<<dim3(16, 64), 256, 0, stream>>>(hn, wk + LHH, nullptr, k, BS, H, H, H, H, H, 0);
    gemm_k<<<dim3(16, 64), 256, 0, stream>>>(hn, wv + LHH, nullptr, v, BS, H, H, H, H, H, 0);
    rope_k<<<8192, 256, 0, stream>>>(q, pos);
    rope_k<<<8192, 256, 0, stream>>>(k, pos);
    fattn_k<<<dim3(S / 64, NH, B), 256, 0, stream>>>(q, k, v, o, valid);
    gemm_k<<<dim3(16, 64), 256, 0, stream>>>(o, wo + LHH, nullptr, h, BS, H, H, H, H, H, F_RESID);
    rmsnorm_k<<<BS, 256, 0, stream>>>(h, ln2 + (size_t)layer * H, hn);
    gemm_k<<<dim3(64, 64), 256, 0, stream>>>(hn, wg + LHF, nullptr, f1, BS, FF, H, H, FF, FF, F_SILU);
    gemm_k<<<dim3(64, 64), 256, 0, stream>>>(hn, wu + LHF, nullptr, f1, BS, FF, H, H, FF, FF, F_MULIN);
    gemm_k<<<dim3(16, 64), 256, 0, stream>>>(f1, wd + (size_t)layer * FF * H, nullptr, h, BS, H, FF, FF, H, H, F_RESID);
}

// MFMA block, templated on split planes / products (shallow <2,3>, mid <1,1>)
template<int NP, int NPROD>
static void run_block_mf(int layer,
    const float* ln1, const float* wq, const float* wk, const float* wv,
    const float* wo, const float* ln2, const float* wg, const float* wu, const float* wd,
    float* h, float* qkv,
    _Float16* hnsp, _Float16* osp, _Float16* wsp, _Float16* wsp2, _Float16* f1sp,
    _Float16* qsp, _Float16* ksp, _Float16* vtp,
    const float* ct, const float* st,
    const int* valid, const int* pos, hipStream_t stream)
{
    const size_t PH = (size_t)H * H;        // wo plane
    const size_t P3H = 3 * PH;              // fused qkv plane
    const size_t PGU = (size_t)H * FF;      // wg/wu/wd plane
    const size_t PA = BSH;                  // activation plane
    const size_t PF = BSF;                  // f1 plane
    size_t LHH = (size_t)layer * H * H;
    size_t LHF = (size_t)layer * H * FF;
    dim3 gw32(H / 32, H / 32);

    rmsnorm_split_k<<<BS, 256, 0, stream>>>(h, ln1 + (size_t)layer * H, hnsp, PA, NP);
    splitwt_k<<<gw32, 256, 0, stream>>>(wq + LHH, wsp,                    H, H, H, P3H, NP);
    splitwt_k<<<gw32, 256, 0, stream>>>(wk + LHH, wsp + (size_t)H * H,    H, H, H, P3H, NP);
    splitwt_k<<<gw32, 256, 0, stream>>>(wv + LHH, wsp + (size_t)2 * H * H, H, H, H, P3H, NP);
    gemm_mf_k<NP, NPROD><<<dim3(3 * H / 128, BS / 128), 256, 0, stream>>>(
        hnsp, wsp, nullptr, qkv, nullptr, BS, 3 * H, H, 3 * H, PA, P3H, 1);
    rope_split_k<<<8192, 256, 0, stream>>>(qkv, 3 * H, 0, pos, ct, st, qsp, PA, NP);
    rope_split_k<<<8192, 256, 0, stream>>>(qkv, 3 * H, H, pos, ct, st, ksp, PA, NP);
    splitvt_k<<<dim3(S / 32, H / 32, B), 256, 0, stream>>>(qkv, 3 * H, 2 * H, vtp, PA, NP);
    mfattn_k<NP, NPROD><<<dim3(S / 64, NH, B), 256, 0, stream>>>(qsp, ksp, vtp, osp, valid);
    splitwt_k<<<gw32, 256, 0, stream>>>(wo + LHH, wsp, H, H, H, PH, NP);
    gemm_mf_k<NP, NPROD><<<dim3(H / 128, BS / 128), 256, 0, stream>>>(
        osp, wsp, nullptr, h, h, BS, H, H, H, PA, PH, 1);
    rmsnorm_split_k<<<BS, 256, 0, stream>>>(h, ln2 + (size_t)layer * H, hnsp, PA, NP);
    splitwt_k<<<dim3(FF / 32, H / 32), 256, 0, stream>>>(wg + LHF, wsp,  H, FF, FF, PGU, NP);
    splitwt_k<<<dim3(FF / 32, H / 32), 256, 0, stream>>>(wu + LHF, wsp2, H, FF, FF, PGU, NP);
    gateup_k<NP, NPROD><<<dim3(FF / 128, BS / 128), 256, 0, stream>>>(
        hnsp, wsp, wsp2, f1sp, BS, FF, H, PA, PGU, PF, NP, 2);
    splitwt_k<<<dim3(H / 32, FF / 32), 256, 0, stream>>>(wd + (size_t)layer * FF * H, wsp, FF, H, H, PGU, NP);
    gemm_mf_k<NP, NPROD><<<dim3(H / 128, BS / 128), 256, 0, stream>>>(
        f1sp, wsp, nullptr, h, h, BS, H, FF, H, PF, PGU, 1);
}

extern "C" void kernel_launch(void* const* d_in, const int* in_sizes, int n_in,
                              void* d_out, int out_size, void* d_ws, size_t ws_size,
                              hipStream_t stream)
{
    const int*   ids    = (const int*)d_in[0];
    const int*   amask  = (const int*)d_in[1];
    const float* embed  = (const float*)d_in[2];
    const float* ln1    = (const float*)d_in[3];
    const float* wq     = (const float*)d_in[4];
    const float* wk     = (const float*)d_in[5];
    const float* wv     = (const float*)d_in[6];
    const float* wo     = (const float*)d_in[7];
    const float* ln2    = (const float*)d_in[8];
    const float* wg     = (const float*)d_in[9];
    const float* wu     = (const float*)d_in[10];
    const float* wd     = (const float*)d_in[11];
    const float* head_w = (const float*)d_in[12];
    const float* head_b = (const float*)d_in[13];
    const float* cemb   = (const float*)d_in[14];
    const float* gumbel = (const float*)d_in[15];
    float* out = (float*)d_out;

    const size_t MB = 1ull << 20;
    const size_t NEED = 274 * MB;

    if (ws_size >= NEED) {
        // ===== MFMA path =====
        char* base = (char*)d_ws;
        float* h   = (float*)base;                  // 16MB
        float* qkv = (float*)(base + 16 * MB);      // 48MB [BS][3072]
        _Float16* zb   = (_Float16*)(base + 64 * MB);   // 16MB [BS][CV]
        _Float16* hnsp = (_Float16*)(base + 80 * MB);   // 2 planes x 8MB
        _Float16* osp  = (_Float16*)(base + 104 * MB);
        _Float16* wsp  = (_Float16*)(base + 128 * MB);  // <=24MB weight planes
        _Float16* wsp2 = (_Float16*)(base + 152 * MB);
        _Float16* f1sp = (_Float16*)(base + 176 * MB);  // 2 planes x 32MB
        _Float16* qsp  = (_Float16*)(base + 176 * MB);  // alias f1sp (disjoint lifetime)
        _Float16* ksp  = (_Float16*)(base + 200 * MB);
        _Float16* vtp  = (_Float16*)(base + 224 * MB);
        int* meta   = (int*)(base + 272 * MB);
        int* chosen = meta;
        int* order  = meta + BS;
        int* cpos   = meta + 2 * BS;
        int* cvalid = meta + 3 * BS;
        int* counts = meta + 4 * BS;
        int* pos_sh = meta + 5 * BS;
        float* partial = (float*)(meta + 6 * BS);
        float* ct = (float*)(base + 273 * MB);          // S*32 floats (128KB)
        float* st = ct + S * 32;                        // S*32 floats
        float* logits = qkv;          // qkv dead after shallow blocks
        float* esoft  = qkv;
        float* ceab   = qkv + BSH;

        embed_k<<<BS, 256, 0, stream>>>(ids, embed, h);
        iota_k<<<16, 256, 0, stream>>>(pos_sh);
        trigtab_k<<<S * 32 / 256, 256, 0, stream>>>(ct, st);

        for (int L = 0; L < 2; ++L)
            run_block_mf<2, 3>(L, ln1, wq, wk, wv, wo, ln2, wg, wu, wd,
                               h, qkv, hnsp, osp, wsp, wsp2, f1sp,
                               qsp, ksp, vtp, ct, st, amask, pos_sh, stream);

        // ---- head logits: fp16 2-plane, ALL 4 products (argmax-critical) ----
        splita_swz_k<<<BS, 256, 0, stream>>>(h, hnsp, BSH, 2);
        splitwt_k<<<dim3(CV / 32, H / 32), 256, 0, stream>>>(head_w, wsp, H, CV, CV1, (size_t)CV * H, 2);
        gemm_mf_k<2, 4><<<dim3(CV / 128, BS / 128), 256, 0, stream>>>(
            hnsp, wsp, head_b, logits, nullptr, BS, CV, H, CV1, BSH, (size_t)CV * H, 1);
        headcol_k<<<BS, 64, 0, stream>>>(h, head_w, head_b, logits);
        discretize_h_k<<<BS, 256, 0, stream>>>(logits, gumbel, zb, chosen);

        // ---- e_soft = z @ cemb (fp16 1-plane) ----
        splitwt_k<<<dim3(H / 32, CV / 32), 256, 0, stream>>>(cemb, wsp, CV, H, H, (size_t)H * CV, 1);
        gemm_mf_k<1, 1><<<dim3(H / 128, BS / 128), 256, 0, stream>>>(
            zb, wsp, nullptr, esoft, nullptr, BS, H, CV, H, (size_t)BS * CV, (size_t)H * CV, 0);

        cea_k<<<BS, 256, 0, stream>>>(esoft, cemb, chosen, amask, ceab, partial);
        loss_k<<<1, 256, 0, stream>>>(partial, out + BSH);
        pack_k<<<B, 1024, 0, stream>>>(chosen, amask, order, cpos, cvalid, counts);
        gather_k<<<BS, 256, 0, stream>>>(ceab, order, cvalid, h);

        for (int L = 2; L < 4; ++L)
            run_block_mf<1, 1>(L, ln1, wq, wk, wv, wo, ln2, wg, wu, wd,
                               h, qkv, hnsp, osp, wsp, wsp2, f1sp,
                               qsp, ksp, vtp, ct, st, cvalid, cpos, stream);

        outmask_k<<<BS, 256, 0, stream>>>(h, cvalid, out);
    } else {
        // ===== fallback: fp32 path =====
        float* wsf = (float*)d_ws;
        float* h   = wsf;
        float* hn  = wsf + BSH;
        float* q   = wsf + 2 * BSH;
        float* k   = wsf + 3 * BSH;
        float* v   = wsf + 4 * BSH;
        float* o   = wsf + 5 * BSH;
        float* f1  = wsf + 6 * BSH;
        float* zbuf  = q;
        float* esoft = v;
        float* ceab  = o;
        int* meta   = (int*)(wsf + 6 * BSH + BSF);
        int* chosen = meta;
        int* order  = meta + BS;
        int* cpos   = meta + 2 * BS;
        int* cvalid = meta + 3 * BS;
        int* counts = meta + 4 * BS;
        int* pos_sh = meta + 5 * BS;
        float* partial = (float*)(meta + 6 * BS);

        embed_k<<<BS, 256, 0, stream>>>(ids, embed, h);
        iota_k<<<16, 256, 0, stream>>>(pos_sh);
        for (int L = 0; L < 2; ++L)
            run_block_f32(L, ln1, wq, wk, wv, wo, ln2, wg, wu, wd,
                          h, hn, q, k, v, o, f1, amask, pos_sh, stream);
        gemm_k<<<dim3(33, 64), 256, 0, stream>>>(h, head_w, head_b, f1, BS, CV1, H, H, CV1, CV1, F_BIAS);
        discretize_k<<<BS, 256, 0, stream>>>(f1, gumbel, zbuf, chosen);
        gemm_k<<<dim3(16, 64), 256, 0, stream>>>(zbuf, cemb, nullptr, esoft, BS, H, CV, CV, H, H, 0);
        cea_k<<<BS, 256, 0, stream>>>(esoft, cemb, chosen, amask, ceab, partial);
        loss_k<<<1, 256, 0, stream>>>(partial, out + BSH);
        pack_k<<<B, 1024, 0, stream>>>(chosen, amask, order, cpos, cvalid, counts);
        gather_k<<<BS, 256, 0, stream>>>(ceab, order, cvalid, h);
        for (int L = 2; L < 4; ++L)
            run_block_f32(L, ln1, wq, wk, wv, wo, ln2, wg, wu, wd,
                          h, hn, q, k, v, o, f1, cvalid, cpos, stream);
        outmask_k<<<BS, 256, 0, stream>>>(h, cvalid, out);
    }
}

// Round 10
// 2559.246 us; speedup vs baseline: 13.9680x; 1.0318x over previous
//
#include <hip/hip_runtime.h>
#include <hip/hip_bf16.h>
#include <cmath>

#define B 4
#define S 1024
#define H 1024
#define NH 16
#define HD 64
#define FF 4096
#define CV 2048
#define CV1 2049
#define BS (B*S)            // 4096
#define BSH ((size_t)BS*H)  // 4194304
#define BSF ((size_t)BS*FF) // 16777216

#define F_BIAS  1
#define F_RESID 2
#define F_SILU  4
#define F_MULIN 8

typedef __attribute__((ext_vector_type(8))) _Float16 f16x8;
typedef __attribute__((ext_vector_type(4))) float f32x4;

// Pre-swizzled plane write: element (row,col) stored at
// rowbase + (col&~31) + ((((col>>3)&3)^phi)<<3) + (col&7), phi=(row>>1)&3.
static __device__ inline size_t swz_idx(size_t rowbase, int col, int phi) {
    return rowbase + (size_t)(col & ~31) + ((size_t)(((col >> 3) & 3) ^ phi) << 3) + (col & 7);
}
static __device__ inline void split_store_swz(float v, _Float16* p, size_t plane,
                                              size_t rowbase, int col, int phi, int np) {
    size_t idx = swz_idx(rowbase, col, phi);
    _Float16 h0 = (_Float16)v; p[idx] = h0;
    if (np == 2) p[plane + idx] = (_Float16)(v - (float)h0);
}

// global->LDS async DMA, 16B per lane, LDS dest = base + lane*16
static __device__ inline void gload16(const void* g, void* l) {
    __builtin_amdgcn_global_load_lds(
        (const __attribute__((address_space(1))) void*)g,
        (__attribute__((address_space(3))) void*)l, 16, 0, 0);
}

// XCD-chunk block swizzle. swz=0 none; 1=M-contig chunks; 2=N-contig chunks.
static __device__ inline void tile_coords(int swz, int& bx, int& by) {
    if (swz == 0) { bx = blockIdx.x; by = blockIdx.y; return; }
    int nbx = gridDim.x, nby = gridDim.y;
    int L = blockIdx.y * nbx + blockIdx.x;
    int cpx = (nbx * nby) >> 3;
    int cid = (L & 7) * cpx + (L >> 3);
    if (swz == 1) { by = cid / nbx; bx = cid % nbx; }
    else          { bx = cid / nby; by = cid % nby; }
}

// ============ MFMA GEMM (pass-fused, 2-phase dbuf): one barrier per K-step ============
template<int NP, int NPROD>
__global__ __launch_bounds__(256) void gemm_mf_k(
    const _Float16* __restrict__ A, const _Float16* __restrict__ Wt,
    const float* __restrict__ bias, float* __restrict__ C, const float* __restrict__ resid,
    int M, int N, int K, int ldc, size_t planeA, size_t planeW, int swz)
{
    __shared__ _Float16 As[2][NP][128 * 32];
    __shared__ _Float16 Bs[2][NP][128 * 32];
    const int tid = threadIdx.x;
    const int w = tid >> 6, l = tid & 63;
    const int wm = w >> 1, wn = w & 1;
    int bx, by; tile_coords(swz, bx, by);
    const int row0 = by * 128, col0 = bx * 128;
    const int rA = l >> 2;
    const int cq8 = (l & 3) * 8;
    const int PA[4] = {0, 0, 1, 1};
    const int PW[4] = {0, 1, 0, 1};

    f32x4 acc[4][4];
    #pragma unroll
    for (int i = 0; i < 4; ++i)
        #pragma unroll
        for (int j = 0; j < 4; ++j)
            #pragma unroll
            for (int r = 0; r < 4; ++r) acc[i][j][r] = 0.f;

    const int lr = l & 15, q = l >> 4;

    auto stage = [&](int bf, int k0) {
        #pragma unroll
        for (int p = 0; p < NP; ++p)
            #pragma unroll
            for (int s = 0; s < 2; ++s) {
                int rr = (w * 2 + s) * 16 + rA;
                gload16(A + (size_t)p * planeA + (size_t)(row0 + rr) * K + k0 + cq8,
                        &As[bf][p][(w * 2 + s) * 512]);
                gload16(Wt + (size_t)p * planeW + (size_t)(col0 + rr) * K + k0 + cq8,
                        &Bs[bf][p][(w * 2 + s) * 512]);
            }
    };

    stage(0, 0);
    __syncthreads();
    int cur = 0;
    for (int k0 = 0; k0 < K; k0 += 32) {
        if (k0 + 32 < K) stage(cur ^ 1, k0 + 32);
        f16x8 af[NP][4], bfv[NP][4];
        #pragma unroll
        for (int p = 0; p < NP; ++p)
            #pragma unroll
            for (int i = 0; i < 4; ++i) {
                int ra = wm * 64 + i * 16 + lr;
                af[p][i] = *(const f16x8*)&As[cur][p][ra * 32 + (q ^ ((ra >> 1) & 3)) * 8];
                int rb = wn * 64 + i * 16 + lr;
                bfv[p][i] = *(const f16x8*)&Bs[cur][p][rb * 32 + (q ^ ((rb >> 1) & 3)) * 8];
            }
        #pragma unroll
        for (int pr = 0; pr < NPROD; ++pr) {
            const int pa = PA[pr], pw = PW[pr];
            #pragma unroll
            for (int mi = 0; mi < 4; ++mi)
                #pragma unroll
                for (int ni = 0; ni < 4; ++ni)
                    acc[mi][ni] = __builtin_amdgcn_mfma_f32_16x16x32_f16(
                        af[pa][mi], bfv[pw][ni], acc[mi][ni], 0, 0, 0);
        }
        __syncthreads();
        cur ^= 1;
    }
    const int cw = l & 15, rw = (l >> 4) * 4;
    #pragma unroll
    for (int mi = 0; mi < 4; ++mi)
        #pragma unroll
        for (int ni = 0; ni < 4; ++ni)
            #pragma unroll
            for (int r = 0; r < 4; ++r) {
                int gr = row0 + wm * 64 + mi * 16 + rw + r;
                int gc = col0 + wn * 64 + ni * 16 + cw;
                size_t ci = (size_t)gr * ldc + gc;
                float val = acc[mi][ni][r];
                if (bias)  val += bias[gc];
                if (resid) val += resid[ci];
                C[ci] = val;
            }
}

// ============ Fused gate-up: F = silu(A@Wg)*(A@Wu) -> pre-swz split planes ============
// NP=2 (shallow): R8 single-buffer straight-line code (144 VGPR).
// NP=1 (mid): 2-phase dbuf (48KB LDS, 3 blocks/CU), inline.
template<int NP, int NPROD>
__global__ __launch_bounds__(256) void gateup_k(
    const _Float16* __restrict__ A, const _Float16* __restrict__ Wg, const _Float16* __restrict__ Wu,
    _Float16* __restrict__ F, int M, int N, int K,
    size_t planeA, size_t planeW, size_t planeF, int npOut, int swz)
{
    const int tid = threadIdx.x;
    const int w = tid >> 6, l = tid & 63;
    const int wm = w >> 1, wn = w & 1;
    int bx, by; tile_coords(swz, bx, by);
    const int row0 = by * 128, col0 = bx * 128;
    const int rA = l >> 2;
    const int cq8 = (l & 3) * 8;
    const int PA[4] = {0, 0, 1, 1};
    const int PW[4] = {0, 1, 0, 1};
    const int lr = l & 15, q = l >> 4;

    f32x4 accg[4][4], accu[4][4];
    #pragma unroll
    for (int i = 0; i < 4; ++i)
        #pragma unroll
        for (int j = 0; j < 4; ++j)
            #pragma unroll
            for (int r = 0; r < 4; ++r) { accg[i][j][r] = 0.f; accu[i][j][r] = 0.f; }

    if constexpr (NP == 2) {
        // ---- R8 verbatim: single-buffer, two barriers per K-step ----
        __shared__ _Float16 As[NP][128 * 32];
        __shared__ _Float16 Bg[NP][128 * 32];
        __shared__ _Float16 Bu[NP][128 * 32];
        for (int k0 = 0; k0 < K; k0 += 32) {
            __syncthreads();
            #pragma unroll
            for (int p = 0; p < NP; ++p)
                #pragma unroll
                for (int s = 0; s < 2; ++s) {
                    int rr = (w * 2 + s) * 16 + rA;
                    gload16(A  + (size_t)p * planeA + (size_t)(row0 + rr) * K + k0 + cq8,
                            &As[p][(w * 2 + s) * 512]);
                    gload16(Wg + (size_t)p * planeW + (size_t)(col0 + rr) * K + k0 + cq8,
                            &Bg[p][(w * 2 + s) * 512]);
                    gload16(Wu + (size_t)p * planeW + (size_t)(col0 + rr) * K + k0 + cq8,
                            &Bu[p][(w * 2 + s) * 512]);
                }
            __syncthreads();
            f16x8 af[NP][4];
            #pragma unroll
            for (int p = 0; p < NP; ++p)
                #pragma unroll
                for (int i = 0; i < 4; ++i) {
                    int ra = wm * 64 + i * 16 + lr;
                    af[p][i] = *(const f16x8*)&As[p][ra * 32 + (q ^ ((ra >> 1) & 3)) * 8];
                }
            #pragma unroll
            for (int pr = 0; pr < NPROD; ++pr) {
                const int pa = PA[pr], pw = PW[pr];
                f16x8 bg[4], bu[4];
                #pragma unroll
                for (int i = 0; i < 4; ++i) {
                    int rb = wn * 64 + i * 16 + lr;
                    int sb = (q ^ ((rb >> 1) & 3)) * 8;
                    bg[i] = *(const f16x8*)&Bg[pw][rb * 32 + sb];
                    bu[i] = *(const f16x8*)&Bu[pw][rb * 32 + sb];
                }
                #pragma unroll
                for (int mi = 0; mi < 4; ++mi)
                    #pragma unroll
                    for (int ni = 0; ni < 4; ++ni) {
                        accg[mi][ni] = __builtin_amdgcn_mfma_f32_16x16x32_f16(
                            af[pa][mi], bg[ni], accg[mi][ni], 0, 0, 0);
                        accu[mi][ni] = __builtin_amdgcn_mfma_f32_16x16x32_f16(
                            af[pa][mi], bu[ni], accu[mi][ni], 0, 0, 0);
                    }
            }
        }
    } else {
        // ---- NP=1: 2-phase dbuf, one barrier per K-step ----
        __shared__ _Float16 As[2][128 * 32];
        __shared__ _Float16 Bg[2][128 * 32];
        __shared__ _Float16 Bu[2][128 * 32];
        #pragma unroll
        for (int s = 0; s < 2; ++s) {
            int rr = (w * 2 + s) * 16 + rA;
            gload16(A  + (size_t)(row0 + rr) * K + cq8, &As[0][(w * 2 + s) * 512]);
            gload16(Wg + (size_t)(col0 + rr) * K + cq8, &Bg[0][(w * 2 + s) * 512]);
            gload16(Wu + (size_t)(col0 + rr) * K + cq8, &Bu[0][(w * 2 + s) * 512]);
        }
        __syncthreads();
        int cur = 0;
        for (int k0 = 0; k0 < K; k0 += 32) {
            if (k0 + 32 < K) {
                #pragma unroll
                for (int s = 0; s < 2; ++s) {
                    int rr = (w * 2 + s) * 16 + rA;
                    gload16(A  + (size_t)(row0 + rr) * K + k0 + 32 + cq8, &As[cur ^ 1][(w * 2 + s) * 512]);
                    gload16(Wg + (size_t)(col0 + rr) * K + k0 + 32 + cq8, &Bg[cur ^ 1][(w * 2 + s) * 512]);
                    gload16(Wu + (size_t)(col0 + rr) * K + k0 + 32 + cq8, &Bu[cur ^ 1][(w * 2 + s) * 512]);
                }
            }
            f16x8 af[4], bg[4], bu[4];
            #pragma unroll
            for (int i = 0; i < 4; ++i) {
                int ra = wm * 64 + i * 16 + lr;
                af[i] = *(const f16x8*)&As[cur][ra * 32 + (q ^ ((ra >> 1) & 3)) * 8];
                int rb = wn * 64 + i * 16 + lr;
                int sb = (q ^ ((rb >> 1) & 3)) * 8;
                bg[i] = *(const f16x8*)&Bg[cur][rb * 32 + sb];
                bu[i] = *(const f16x8*)&Bu[cur][rb * 32 + sb];
            }
            #pragma unroll
            for (int mi = 0; mi < 4; ++mi)
                #pragma unroll
                for (int ni = 0; ni < 4; ++ni) {
                    accg[mi][ni] = __builtin_amdgcn_mfma_f32_16x16x32_f16(
                        af[mi], bg[ni], accg[mi][ni], 0, 0, 0);
                    accu[mi][ni] = __builtin_amdgcn_mfma_f32_16x16x32_f16(
                        af[mi], bu[ni], accu[mi][ni], 0, 0, 0);
                }
            __syncthreads();
            cur ^= 1;
        }
    }

    const int cw = l & 15, rw = (l >> 4) * 4;
    #pragma unroll
    for (int mi = 0; mi < 4; ++mi)
        #pragma unroll
        for (int ni = 0; ni < 4; ++ni)
            #pragma unroll
            for (int r = 0; r < 4; ++r) {
                int gr = row0 + wm * 64 + mi * 16 + rw + r;
                int gc = col0 + wn * 64 + ni * 16 + cw;
                float g = accg[mi][ni][r], u = accu[mi][ni][r];
                float val = g / (1.f + expf(-g)) * u;
                split_store_swz(val, F, planeF, (size_t)gr * N, gc, (gr >> 1) & 3, npOut);
            }
}

// ============ MFMA flash attention (fp16, pre-swizzled planes, gload staging) ============
template<int NP, int NPROD>
__global__ __launch_bounds__(256) void mfattn_k(
    const _Float16* __restrict__ qsp, const _Float16* __restrict__ ksp,
    const _Float16* __restrict__ vtp, _Float16* __restrict__ osp,
    const int* __restrict__ valid)
{
    __shared__ _Float16 KP[NP][2][64 * 32];   // K tile; reused as P planes
    __shared__ _Float16 Vt[NP][2][64 * 32];   // V^T tile
    __shared__ int kvs[64];
    const int tid = threadIdx.x;
    const int w = tid >> 6, l = tid & 63;
    const int lr = l & 15, lq = l >> 4;
    const int qt = blockIdx.x, hh = blockIdx.y, b = blockIdx.z;
    const int rT = l >> 2;
    const int cq8 = (l & 3) * 8;
    const int PA[4] = {0, 0, 1, 1};
    const int PW[4] = {0, 1, 0, 1};

    f16x8 aq[NP][2];
    {
        const int qrowa = qt * 64 + w * 16 + lr;
        const int phiq = (qrowa >> 1) & 3;
        #pragma unroll
        for (int p = 0; p < NP; ++p)
            #pragma unroll
            for (int ks = 0; ks < 2; ++ks)
                aq[p][ks] = *(const f16x8*)(qsp + (size_t)p * BSH
                    + (size_t)(b * S + qrowa) * H + hh * 64 + ks * 32 + ((lq ^ phiq) << 3));
    }
    int qvr[4];
    #pragma unroll
    for (int r = 0; r < 4; ++r)
        qvr[r] = valid[b * S + qt * 64 + w * 16 + lq * 4 + r];

    float m[4], lsum[4];
    f32x4 acco[4];
    #pragma unroll
    for (int r = 0; r < 4; ++r) { m[r] = -3.4e38f; lsum[r] = 0.f; }
    #pragma unroll
    for (int n = 0; n < 4; ++n)
        #pragma unroll
        for (int r = 0; r < 4; ++r) acco[n][r] = 0.f;

    for (int kt = 0; kt < S / 64; ++kt) {
        __syncthreads();
        {
            const int r = w * 16 + rT;
            #pragma unroll
            for (int p = 0; p < NP; ++p)
                #pragma unroll
                for (int hf = 0; hf < 2; ++hf) {
                    gload16(ksp + (size_t)p * BSH
                            + (size_t)(b * S + kt * 64 + r) * H + hh * 64 + hf * 32 + cq8,
                            &KP[p][hf][w * 512]);
                    gload16(vtp + (size_t)p * BSH
                            + ((size_t)(hh * 64 + r) * B + b) * S + kt * 64 + hf * 32 + cq8,
                            &Vt[p][hf][w * 512]);
                }
        }
        if (tid < 64) kvs[tid] = valid[b * S + kt * 64 + tid];
        __syncthreads();

        // ---- S = Q @ K^T ----
        f32x4 accs[4];
        #pragma unroll
        for (int n = 0; n < 4; ++n)
            #pragma unroll
            for (int r = 0; r < 4; ++r) accs[n][r] = 0.f;
        #pragma unroll
        for (int pr = 0; pr < NPROD; ++pr) {
            const int pa = PA[pr], pw = PW[pr];
            #pragma unroll
            for (int ks = 0; ks < 2; ++ks)
                #pragma unroll
                for (int n = 0; n < 4; ++n) {
                    int rb = n * 16 + lr;
                    f16x8 bk = *(const f16x8*)&KP[pw][ks][rb * 32 + ((lq ^ ((rb >> 1) & 3))) * 8];
                    accs[n] = __builtin_amdgcn_mfma_f32_16x16x32_f16(
                        aq[pa][ks], bk, accs[n], 0, 0, 0);
                }
        }
        // ---- mask + online softmax ----
        float pf[4][4];
        int kva[4];
        #pragma unroll
        for (int n = 0; n < 4; ++n) kva[n] = kvs[n * 16 + lr];
        #pragma unroll
        for (int r = 0; r < 4; ++r) {
            int qr = qt * 64 + w * 16 + lq * 4 + r;
            float rowm = -3.4e38f;
            #pragma unroll
            for (int n = 0; n < 4; ++n) {
                int kc = kt * 64 + n * 16 + lr;
                float sv = accs[n][r] * 0.125f;
                int allowed = (kc <= qr) && qvr[r] && kva[n];
                if (!allowed) sv = sv + -1e9f;
                pf[n][r] = sv;
                rowm = fmaxf(rowm, sv);
            }
            rowm = fmaxf(rowm, __shfl_xor(rowm, 1));
            rowm = fmaxf(rowm, __shfl_xor(rowm, 2));
            rowm = fmaxf(rowm, __shfl_xor(rowm, 4));
            rowm = fmaxf(rowm, __shfl_xor(rowm, 8));
            float mn = fmaxf(m[r], rowm);
            float co = __expf(m[r] - mn);
            float rs = 0.f;
            #pragma unroll
            for (int n = 0; n < 4; ++n) { pf[n][r] = __expf(pf[n][r] - mn); rs += pf[n][r]; }
            rs += __shfl_xor(rs, 1);
            rs += __shfl_xor(rs, 2);
            rs += __shfl_xor(rs, 4);
            rs += __shfl_xor(rs, 8);
            lsum[r] = lsum[r] * co + rs;
            m[r] = mn;
            #pragma unroll
            for (int n = 0; n < 4; ++n) acco[n][r] *= co;
        }
        __syncthreads();
        // ---- write P (fp16 split) into KP, swizzled for a-frag reads ----
        #pragma unroll
        for (int n = 0; n < 4; ++n) {
            int col = n * 16 + lr;
            int hf = col >> 5, colh = col & 31, cq2 = colh >> 3, pos = colh & 7;
            #pragma unroll
            for (int r = 0; r < 4; ++r) {
                int rowg = w * 16 + lq * 4 + r;
                int off = rowg * 32 + (cq2 ^ ((rowg >> 1) & 3)) * 8 + pos;
                float pv = pf[n][r];
                _Float16 h0 = (_Float16)pv;
                KP[0][hf][off] = h0;
                if (NP == 2) KP[1][hf][off] = (_Float16)(pv - (float)h0);
            }
        }
        __syncthreads();
        // ---- O += P @ V ----
        #pragma unroll
        for (int pr = 0; pr < NPROD; ++pr) {
            const int pa = PA[pr], pw = PW[pr];
            #pragma unroll
            for (int ks = 0; ks < 2; ++ks) {
                int ra = w * 16 + lr;
                f16x8 ap = *(const f16x8*)&KP[pa][ks][ra * 32 + ((lq ^ ((ra >> 1) & 3))) * 8];
                #pragma unroll
                for (int n = 0; n < 4; ++n) {
                    int rb = n * 16 + lr;
                    f16x8 bv = *(const f16x8*)&Vt[pw][ks][rb * 32 + ((lq ^ ((rb >> 1) & 3))) * 8];
                    acco[n] = __builtin_amdgcn_mfma_f32_16x16x32_f16(
                        ap, bv, acco[n], 0, 0, 0);
                }
            }
        }
    }
    // ---- write O as pre-swizzled split planes ----
    #pragma unroll
    for (int r = 0; r < 4; ++r) {
        float inv = 1.0f / lsum[r];
        int qr = qt * 64 + w * 16 + lq * 4 + r;
        size_t rowbase = (size_t)(b * S + qr) * H;
        int phi = ((b * S + qr) >> 1) & 3;
        #pragma unroll
        for (int n = 0; n < 4; ++n)
            split_store_swz(acco[n][r] * inv, osp, BSH, rowbase, hh * 64 + n * 16 + lr, phi, NP);
    }
}

// ============ Trig table ============
__global__ __launch_bounds__(256) void trigtab_k(float* __restrict__ ct, float* __restrict__ st)
{
    int idx = blockIdx.x * 256 + threadIdx.x;   // S*32 total
    int i = idx & 31, p = idx >> 5;
    double inv = exp(-((double)(2 * i) / 64.0) * log(10000.0));
    double ang = (double)p * inv;
    ct[idx] = (float)cos(ang);
    st[idx] = (float)sin(ang);
}

// ============ RoPE (q AND k in one launch) + fp16 split -> pre-swizzled planes ============
__global__ __launch_bounds__(256) void rope2_split_k(const float* __restrict__ x,
    int xld, const int* __restrict__ pos,
    const float* __restrict__ ct, const float* __restrict__ st,
    _Float16* __restrict__ yq, _Float16* __restrict__ yk, size_t plane, int np)
{
    int gidx = blockIdx.x * 256 + threadIdx.x;  // 2 * B*S*NH*32
    int sel = gidx >= (BS * NH * 32);           // 0 = q, 1 = k
    int idx = gidx - sel * (BS * NH * 32);
    int i = idx & 31;
    int head = (idx >> 5) & 15;
    int bs = idx >> 9;
    int p = pos[bs];
    float c = ct[p * 32 + i], sn = st[p * 32 + i];
    const float* base = x + (size_t)bs * xld + sel * H + head * 64;
    float x1 = base[i], x2 = base[i + 32];
    _Float16* y = sel ? yk : yq;
    size_t rowbase = (size_t)bs * H;
    int phi = (bs >> 1) & 3;
    split_store_swz(x1 * c - x2 * sn, y, plane, rowbase, head * 64 + i, phi, np);
    split_store_swz(x2 * c + x1 * sn, y, plane, rowbase, head * 64 + i + 32, phi, np);
}

// ============ V transpose + split (reads strided qkv) -> planes [(h*64+d)*B+b][S] ============
__global__ __launch_bounds__(256) void splitvt_k(const float* __restrict__ V,
    int vld, int voff, _Float16* __restrict__ Vt, size_t plane, int np)
{
    __shared__ float t[32][33];
    const int tid = threadIdx.x;
    const int s0 = blockIdx.x * 32;
    const int hd0 = blockIdx.y * 32;
    const int b = blockIdx.z;
    #pragma unroll
    for (int i = 0; i < 4; ++i) {
        int e = tid + i * 256;
        int rr = e >> 5, cc = e & 31;
        t[rr][cc] = V[(size_t)(b * S + s0 + rr) * vld + voff + hd0 + cc];
    }
    __syncthreads();
    #pragma unroll
    for (int i = 0; i < 4; ++i) {
        int e = tid + i * 256;
        int rn = e >> 5, ck = e & 31;
        int hd = hd0 + rn;
        size_t rowbase = ((size_t)hd * B + b) * S;
        split_store_swz(t[ck][rn], Vt, plane, rowbase, s0 + ck, ((hd & 63) >> 1) & 3, np);
    }
}

// ============ Weight transpose + fp16 split: W[K,N](srcld) -> Wt planes [N][K] ============
__global__ __launch_bounds__(256) void splitwt_k(const float* __restrict__ W,
    _Float16* __restrict__ Wt, int K, int N, int srcld, size_t plane, int np)
{
    __shared__ float t[32][33];
    const int tid = threadIdx.x;
    const int n0 = blockIdx.x * 32, k0 = blockIdx.y * 32;
    #pragma unroll
    for (int i = 0; i < 4; ++i) {
        int e = tid + i * 256;
        int rk = e >> 5, cn = e & 31;
        t[rk][cn] = W[(size_t)(k0 + rk) * srcld + n0 + cn];
    }
    __syncthreads();
    #pragma unroll
    for (int i = 0; i < 4; ++i) {
        int e = tid + i * 256;
        int rn = e >> 5, ck = e & 31;
        int nn = n0 + rn;
        split_store_swz(t[ck][rn], Wt, plane, (size_t)nn * K, k0 + ck, (nn >> 1) & 3, np);
    }
}

// ============ 3-way merged weight split (QKV): z picks source; rows offset by z*H ============
__global__ __launch_bounds__(256) void splitwt3_k(const float* __restrict__ W0,
    const float* __restrict__ W1, const float* __restrict__ W2,
    _Float16* __restrict__ Wt, size_t plane, int np)
{
    __shared__ float t[32][33];
    const int tid = threadIdx.x;
    const int n0 = blockIdx.x * 32, k0 = blockIdx.y * 32;
    const int z = blockIdx.z;
    const float* W = (z == 0) ? W0 : (z == 1) ? W1 : W2;
    #pragma unroll
    for (int i = 0; i < 4; ++i) {
        int e = tid + i * 256;
        int rk = e >> 5, cn = e & 31;
        t[rk][cn] = W[(size_t)(k0 + rk) * H + n0 + cn];
    }
    __syncthreads();
    #pragma unroll
    for (int i = 0; i < 4; ++i) {
        int e = tid + i * 256;
        int rn = e >> 5, ck = e & 31;
        int nn = n0 + rn;               // 0..H-1 local
        int ng = z * H + nn;            // global row in [3H]
        split_store_swz(t[ck][rn], Wt, plane, (size_t)ng * H, k0 + ck, (nn >> 1) & 3, np);
    }
}

// ============ 2-way merged weight split (Wg/Wu) ============
__global__ __launch_bounds__(256) void splitwt2_k(const float* __restrict__ W0,
    const float* __restrict__ W1, _Float16* __restrict__ D0, _Float16* __restrict__ D1,
    size_t plane, int np)
{
    __shared__ float t[32][33];
    const int tid = threadIdx.x;
    const int n0 = blockIdx.x * 32, k0 = blockIdx.y * 32;
    const int z = blockIdx.z;
    const float* W = z ? W1 : W0;
    _Float16* Wt = z ? D1 : D0;
    #pragma unroll
    for (int i = 0; i < 4; ++i) {
        int e = tid + i * 256;
        int rk = e >> 5, cn = e & 31;
        t[rk][cn] = W[(size_t)(k0 + rk) * FF + n0 + cn];
    }
    __syncthreads();
    #pragma unroll
    for (int i = 0; i < 4; ++i) {
        int e = tid + i * 256;
        int rn = e >> 5, ck = e & 31;
        int nn = n0 + rn;
        split_store_swz(t[ck][rn], Wt, plane, (size_t)nn * H, k0 + ck, (nn >> 1) & 3, np);
    }
}

// ============ Plain fp32 -> fp16 split planes (rows of length H) ============
__global__ __launch_bounds__(256) void splita_swz_k(const float* __restrict__ x,
    _Float16* __restrict__ y, size_t plane, int np)
{
    int row = blockIdx.x;
    size_t rowbase = (size_t)row * H;
    int phi = (row >> 1) & 3;
    for (int i = threadIdx.x; i < H; i += 256)
        split_store_swz(x[rowbase + i], y, plane, rowbase, i, phi, np);
}

// ============ RMSNorm -> pre-swz fp16 split ============
__global__ __launch_bounds__(256) void rmsnorm_split_k(const float* __restrict__ x,
    const float* __restrict__ w, _Float16* __restrict__ y, size_t plane, int np)
{
    int row = blockIdx.x;
    const float* xr = x + (size_t)row * H;
    __shared__ float red[256];
    float s = 0.f;
    for (int i = threadIdx.x; i < H; i += 256) { float v = xr[i]; s += v * v; }
    red[threadIdx.x] = s; __syncthreads();
    for (int off = 128; off > 0; off >>= 1) {
        if (threadIdx.x < off) red[threadIdx.x] += red[threadIdx.x + off];
        __syncthreads();
    }
    float r = 1.0f / sqrtf(red[0] / (float)H + 1e-6f);
    size_t rowbase = (size_t)row * H;
    int phi = (row >> 1) & 3;
    for (int i = threadIdx.x; i < H; i += 256)
        split_store_swz(xr[i] * r * w[i], y, plane, rowbase, i, phi, np);
}

// ============ Head column 2048 (null logit), exact fp32 ============
__global__ __launch_bounds__(64) void headcol_k(const float* __restrict__ h,
    const float* __restrict__ head_w, const float* __restrict__ head_b,
    float* __restrict__ logits)
{
    int row = blockIdx.x;
    int l = threadIdx.x;
    float s = 0.f;
    for (int j = l; j < H; j += 64) s += h[(size_t)row * H + j] * head_w[(size_t)j * CV1 + CV];
    s += __shfl_xor(s, 1);
    s += __shfl_xor(s, 2);
    s += __shfl_xor(s, 4);
    s += __shfl_xor(s, 8);
    s += __shfl_xor(s, 16);
    s += __shfl_xor(s, 32);
    if (l == 0) logits[(size_t)row * CV1 + CV] = s + head_b[CV];
}

// ---------------- fp32 GEMM (fallback path) ----------------
__global__ __launch_bounds__(256) void gemm_k(
    const float* __restrict__ A, const float* __restrict__ Wm,
    const float* __restrict__ bias, float* __restrict__ C,
    int M, int N, int K, int lda, int ldb, int ldc, int flags)
{
    __shared__ float As[16][65];
    __shared__ float Bs[16][65];
    const int tid = threadIdx.x;
    const int tx = tid & 15, ty = tid >> 4;
    const int row0 = blockIdx.y * 64, col0 = blockIdx.x * 64;
    float acc[4][4] = {};
    for (int k0 = 0; k0 < K; k0 += 16) {
        #pragma unroll
        for (int l = 0; l < 4; ++l) {
            int e = tid + l * 256;
            int r = e >> 4, c = e & 15;
            int gr = row0 + r;
            float vv = 0.f;
            if (gr < M) vv = A[(size_t)gr * lda + (k0 + c)];
            As[c][r] = vv;
        }
        #pragma unroll
        for (int l = 0; l < 4; ++l) {
            int e = tid + l * 256;
            int r = e >> 6, c = e & 63;
            int gc = col0 + c;
            float vv = 0.f;
            if (gc < N) vv = Wm[(size_t)(k0 + r) * ldb + gc];
            Bs[r][c] = vv;
        }
        __syncthreads();
        #pragma unroll
        for (int kk = 0; kk < 16; ++kk) {
            float a[4], bb[4];
            #pragma unroll
            for (int i = 0; i < 4; ++i) a[i] = As[kk][ty * 4 + i];
            #pragma unroll
            for (int j = 0; j < 4; ++j) bb[j] = Bs[kk][tx * 4 + j];
            #pragma unroll
            for (int i = 0; i < 4; ++i)
                #pragma unroll
                for (int j = 0; j < 4; ++j)
                    acc[i][j] += a[i] * bb[j];
        }
        __syncthreads();
    }
    #pragma unroll
    for (int i = 0; i < 4; ++i) {
        int gr = row0 + ty * 4 + i;
        if (gr >= M) continue;
        #pragma unroll
        for (int j = 0; j < 4; ++j) {
            int gc = col0 + tx * 4 + j;
            if (gc >= N) continue;
            float vv = acc[i][j];
            if (flags & F_BIAS)  vv += bias[gc];
            if (flags & F_SILU)  vv = vv / (1.f + expf(-vv));
            size_t cidx = (size_t)gr * ldc + gc;
            if (flags & F_MULIN) vv *= C[cidx];
            if (flags & F_RESID) vv += C[cidx];
            C[cidx] = vv;
        }
    }
}

// ---------------- RMSNorm fp32 (fallback) ----------------
__global__ __launch_bounds__(256) void rmsnorm_k(const float* __restrict__ x,
    const float* __restrict__ w, float* __restrict__ y)
{
    int row = blockIdx.x;
    const float* xr = x + (size_t)row * H;
    float* yr = y + (size_t)row * H;
    __shared__ float red[256];
    float s = 0.f;
    for (int i = threadIdx.x; i < H; i += 256) { float v = xr[i]; s += v * v; }
    red[threadIdx.x] = s; __syncthreads();
    for (int off = 128; off > 0; off >>= 1) {
        if (threadIdx.x < off) red[threadIdx.x] += red[threadIdx.x + off];
        __syncthreads();
    }
    float r = 1.0f / sqrtf(red[0] / (float)H + 1e-6f);
    for (int i = threadIdx.x; i < H; i += 256) yr[i] = xr[i] * r * w[i];
}

// ---------------- Embed gather ----------------
__global__ __launch_bounds__(256) void embed_k(const int* __restrict__ ids,
    const float* __restrict__ emb, float* __restrict__ h)
{
    int bs = blockIdx.x;
    const float* e = emb + (size_t)ids[bs] * H;
    float* hr = h + (size_t)bs * H;
    for (int i = threadIdx.x; i < H; i += 256) hr[i] = e[i];
}

// ---------------- RoPE fp32 in-place (fallback) ----------------
__global__ __launch_bounds__(256) void rope_k(float* __restrict__ x, const int* __restrict__ pos)
{
    int idx = blockIdx.x * 256 + threadIdx.x;
    int i = idx & 31;
    int head = (idx >> 5) & 15;
    int bs = idx >> 9;
    int p = pos[bs];
    double inv = exp(-((double)(2 * i) / 64.0) * log(10000.0));
    double ang = (double)p * inv;
    float c = (float)cos(ang), sn = (float)sin(ang);
    float* base = x + (size_t)bs * H + head * 64;
    float x1 = base[i], x2 = base[i + 32];
    base[i]      = x1 * c - x2 * sn;
    base[i + 32] = x2 * c + x1 * sn;
}

// ---------------- Flash attention fp32 (fallback) ----------------
__global__ __launch_bounds__(256) void fattn_k(const float* __restrict__ q,
    const float* __restrict__ k, const float* __restrict__ v,
    float* __restrict__ o, const int* __restrict__ valid)
{
    const int qt = blockIdx.x, hh = blockIdx.y, b = blockIdx.z;
    const int tid = threadIdx.x;
    const int tx = tid & 15, ty = tid >> 4;
    __shared__ float Qs[64][68];
    __shared__ float Ks[64][68];
    __shared__ float Vs[64][68];
    __shared__ int   kvs[64];
    const size_t hoff = (size_t)hh * HD;

    {
        int row = tid >> 2, d0 = (tid & 3) * 16;
        const float* qp = q + ((size_t)(b * S + qt * 64 + row)) * H + hoff + d0;
        float4* dst = (float4*)&Qs[row][d0];
        const float4* src = (const float4*)qp;
        #pragma unroll
        for (int e = 0; e < 4; ++e) dst[e] = src[e];
    }
    int qv[4]; int qrow_g[4];
    #pragma unroll
    for (int i = 0; i < 4; ++i) {
        qrow_g[i] = qt * 64 + ty * 4 + i;
        qv[i] = valid[b * S + qrow_g[i]];
    }
    float m[4], l[4], acc[4][4];
    #pragma unroll
    for (int i = 0; i < 4; ++i) {
        m[i] = -3.4e38f; l[i] = 0.f;
        #pragma unroll
        for (int j = 0; j < 4; ++j) acc[i][j] = 0.f;
    }

    for (int kt = 0; kt < S / 64; ++kt) {
        __syncthreads();
        {
            int row = tid >> 2, d0 = (tid & 3) * 16;
            const float* kp = k + ((size_t)(b * S + kt * 64 + row)) * H + hoff + d0;
            float4* dst = (float4*)&Ks[row][d0];
            const float4* src = (const float4*)kp;
            #pragma unroll
            for (int e = 0; e < 4; ++e) dst[e] = src[e];
        }
        {
            int kk = tid >> 2, d0 = (tid & 3) * 16;
            const float* vp = v + ((size_t)(b * S + kt * 64 + kk)) * H + hoff + d0;
            #pragma unroll
            for (int e = 0; e < 16; e += 4) {
                float4 vv = *(const float4*)(vp + e);
                Vs[d0 + e + 0][kk] = vv.x;
                Vs[d0 + e + 1][kk] = vv.y;
                Vs[d0 + e + 2][kk] = vv.z;
                Vs[d0 + e + 3][kk] = vv.w;
            }
        }
        if (tid < 64) kvs[tid] = valid[b * S + kt * 64 + tid];
        __syncthreads();

        float s4[4][4];
        #pragma unroll
        for (int i = 0; i < 4; ++i)
            #pragma unroll
            for (int j = 0; j < 4; ++j) s4[i][j] = 0.f;
        #pragma unroll
        for (int c = 0; c < 16; ++c) {
            float4 a[4], bb[4];
            #pragma unroll
            for (int i = 0; i < 4; ++i) a[i]  = ((const float4*)&Qs[ty * 4 + i][0])[c];
            #pragma unroll
            for (int j = 0; j < 4; ++j) bb[j] = ((const float4*)&Ks[tx * 4 + j][0])[c];
            #pragma unroll
            for (int i = 0; i < 4; ++i)
                #pragma unroll
                for (int j = 0; j < 4; ++j) {
                    s4[i][j] += a[i].x * bb[j].x + a[i].y * bb[j].y
                              + a[i].z * bb[j].z + a[i].w * bb[j].w;
                }
        }
        float p[4][4];
        float corr[4];
        #pragma unroll
        for (int i = 0; i < 4; ++i) {
            float rm = -3.4e38f;
            #pragma unroll
            for (int j = 0; j < 4; ++j) {
                int kc = kt * 64 + tx * 4 + j;
                float sv = s4[i][j] * 0.125f;
                int allowed = (kc <= qrow_g[i]) && qv[i] && kvs[tx * 4 + j];
                if (!allowed) sv = sv + -1e9f;
                s4[i][j] = sv;
                rm = fmaxf(rm, sv);
            }
            rm = fmaxf(rm, __shfl_xor(rm, 1));
            rm = fmaxf(rm, __shfl_xor(rm, 2));
            rm = fmaxf(rm, __shfl_xor(rm, 4));
            rm = fmaxf(rm, __shfl_xor(rm, 8));
            float mn = fmaxf(m[i], rm);
            corr[i] = expf(m[i] - mn);
            float rs = 0.f;
            #pragma unroll
            for (int j = 0; j < 4; ++j) { p[i][j] = expf(s4[i][j] - mn); rs += p[i][j]; }
            rs += __shfl_xor(rs, 1);
            rs += __shfl_xor(rs, 2);
            rs += __shfl_xor(rs, 4);
            rs += __shfl_xor(rs, 8);
            l[i] = l[i] * corr[i] + rs;
            m[i] = mn;
            #pragma unroll
            for (int j = 0; j < 4; ++j) acc[i][j] *= corr[i];
        }
        __syncthreads();
        #pragma unroll
        for (int i = 0; i < 4; ++i) {
            float4 pv4 = make_float4(p[i][0], p[i][1], p[i][2], p[i][3]);
            *(float4*)&Ks[ty * 4 + i][tx * 4] = pv4;
        }
        __syncthreads();
        #pragma unroll
        for (int c = 0; c < 16; ++c) {
            float4 a[4], bb[4];
            #pragma unroll
            for (int i = 0; i < 4; ++i) a[i]  = ((const float4*)&Ks[ty * 4 + i][0])[c];
            #pragma unroll
            for (int j = 0; j < 4; ++j) bb[j] = ((const float4*)&Vs[tx * 4 + j][0])[c];
            #pragma unroll
            for (int i = 0; i < 4; ++i)
                #pragma unroll
                for (int j = 0; j < 4; ++j) {
                    acc[i][j] += a[i].x * bb[j].x + a[i].y * bb[j].y
                               + a[i].z * bb[j].z + a[i].w * bb[j].w;
                }
        }
    }
    #pragma unroll
    for (int i = 0; i < 4; ++i) {
        float inv = 1.0f / l[i];
        float4 ov = make_float4(acc[i][0] * inv, acc[i][1] * inv,
                                acc[i][2] * inv, acc[i][3] * inv);
        *(float4*)(o + ((size_t)(b * S + qrow_g[i])) * H + hoff + tx * 4) = ov;
    }
}

// ---------------- Discretize: fp16 swizzled z + fp32 fallback ----------------
__global__ __launch_bounds__(256) void discretize_h_k(const float* __restrict__ logits,
    const float* __restrict__ gumbel, _Float16* __restrict__ z, int* __restrict__ chosen)
{
    int bs = blockIdx.x;
    const float* lg = logits + (size_t)bs * CV1;
    const float* gm = gumbel + (size_t)bs * CV1;
    __shared__ float redv[256]; __shared__ int redi[256];
    int tid = threadIdx.x;
    float m = -3.4e38f; int mi = CV1;
    for (int j = tid; j < CV1; j += 256) {
        float a = lg[j] + gm[j];
        if (a > m) { m = a; mi = j; }
    }
    redv[tid] = m; redi[tid] = mi; __syncthreads();
    for (int off = 128; off > 0; off >>= 1) {
        if (tid < off) {
            float vo = redv[tid + off]; int io = redi[tid + off];
            if (vo > redv[tid] || (vo == redv[tid] && io < redi[tid])) { redv[tid] = vo; redi[tid] = io; }
        }
        __syncthreads();
    }
    m = redv[0]; int amax = redi[0];
    __syncthreads();
    float ssum = 0.f;
    for (int j = tid; j < CV1; j += 256) ssum += expf(lg[j] + gm[j] - m);
    redv[tid] = ssum; __syncthreads();
    for (int off = 128; off > 0; off >>= 1) {
        if (tid < off) redv[tid] += redv[tid + off];
        __syncthreads();
    }
    float inv = 1.0f / redv[0];
    size_t rowbase = (size_t)bs * CV;
    int phi = (bs >> 1) & 3;
    for (int j = tid; j < CV; j += 256) {
        float zv = expf(lg[j] + gm[j] - m) * inv;
        z[swz_idx(rowbase, j, phi)] = (_Float16)zv;
    }
    if (tid == 0) chosen[bs] = amax;
}

__global__ __launch_bounds__(256) void discretize_k(const float* __restrict__ logits,
    const float* __restrict__ gumbel, float* __restrict__ z, int* __restrict__ chosen)
{
    int bs = blockIdx.x;
    const float* lg = logits + (size_t)bs * CV1;
    const float* gm = gumbel + (size_t)bs * CV1;
    __shared__ float redv[256]; __shared__ int redi[256];
    int tid = threadIdx.x;
    float m = -3.4e38f; int mi = CV1;
    for (int j = tid; j < CV1; j += 256) {
        float a = lg[j] + gm[j];
        if (a > m) { m = a; mi = j; }
    }
    redv[tid] = m; redi[tid] = mi; __syncthreads();
    for (int off = 128; off > 0; off >>= 1) {
        if (tid < off) {
            float vo = redv[tid + off]; int io = redi[tid + off];
            if (vo > redv[tid] || (vo == redv[tid] && io < redi[tid])) { redv[tid] = vo; redi[tid] = io; }
        }
        __syncthreads();
    }
    m = redv[0]; int amax = redi[0];
    __syncthreads();
    float ssum = 0.f;
    for (int j = tid; j < CV1; j += 256) ssum += expf(lg[j] + gm[j] - m);
    redv[tid] = ssum; __syncthreads();
    for (int off = 128; off > 0; off >>= 1) {
        if (tid < off) redv[tid] += redv[tid + off];
        __syncthreads();
    }
    float inv = 1.0f / redv[0];
    for (int j = tid; j < CV; j += 256)
        z[(size_t)bs * CV + j] = expf(lg[j] + gm[j] - m) * inv;
    if (tid == 0) chosen[bs] = amax;
}

// ---------------- cea + loss ----------------
__global__ __launch_bounds__(256) void cea_k(const float* __restrict__ esoft,
    const float* __restrict__ cemb, const int* __restrict__ chosen,
    const int* __restrict__ amask, float* __restrict__ cea, float* __restrict__ partial)
{
    int bs = blockIdx.x;
    int ch = chosen[bs]; int vm = amask[bs];
    int comp = (ch != CV) && vm;
    const float* ehr = cemb + (size_t)(ch < CV - 1 ? ch : CV - 1) * H;
    __shared__ float red[256];
    float part = 0.f;
    float vmf = vm ? 1.f : 0.f;
    for (int i = threadIdx.x; i < H; i += 256) {
        float es = esoft[(size_t)bs * H + i];
        float eh = comp ? ehr[i] : 0.f;
        cea[(size_t)bs * H + i] = ((eh + es) - es) * vmf;
        float d = es - eh;
        part += d * d;
    }
    red[threadIdx.x] = part; __syncthreads();
    for (int off = 128; off > 0; off >>= 1) {
        if (threadIdx.x < off) red[threadIdx.x] += red[threadIdx.x + off];
        __syncthreads();
    }
    if (threadIdx.x == 0) partial[bs] = red[0];
}

__global__ __launch_bounds__(256) void loss_k(const float* __restrict__ partial, float* __restrict__ out)
{
    __shared__ float red[256];
    float s = 0.f;
    for (int i = threadIdx.x; i < BS; i += 256) s += partial[i];
    red[threadIdx.x] = s; __syncthreads();
    for (int off = 128; off > 0; off >>= 1) {
        if (threadIdx.x < off) red[threadIdx.x] += red[threadIdx.x + off];
        __syncthreads();
    }
    if (threadIdx.x == 0) out[0] = 1.25f * red[0] / (float)BSH;
}

// ---------------- Parallel stable pack: scan over is_comp flags ----------------
__global__ __launch_bounds__(1024) void pack_k(const int* __restrict__ chosen,
    const int* __restrict__ amask, int* __restrict__ order, int* __restrict__ cpos,
    int* __restrict__ cvalid, int* __restrict__ counts)
{
    int b = blockIdx.x, t = threadIdx.x;
    __shared__ int sc[1024];
    __shared__ int ord[1024];
    int f = (chosen[b * S + t] != CV && amask[b * S + t]) ? 1 : 0;
    sc[t] = f;
    __syncthreads();
    #pragma unroll
    for (int off = 1; off < 1024; off <<= 1) {
        int add = (t >= off) ? sc[t - off] : 0;
        __syncthreads();
        sc[t] += add;
        __syncthreads();
    }
    int cnt = sc[1023];
    int pos = f ? (sc[t] - 1) : (cnt + t - sc[t]);
    ord[pos] = t;
    __syncthreads();
    int o = ord[t];
    order[b * S + t] = o;
    cvalid[b * S + t] = (t < cnt) ? 1 : 0;
    cpos[b * S + t] = (t < cnt) ? o : 0;
    if (t == 0) counts[b] = cnt;
}

__global__ __launch_bounds__(256) void gather_k(const float* __restrict__ cea,
    const int* __restrict__ order, const int* __restrict__ cvalid, float* __restrict__ h)
{
    int bs = blockIdx.x;
    int b = bs >> 10;
    int src = order[bs];
    float f = cvalid[bs] ? 1.f : 0.f;
    const float* sp = cea + (size_t)(b * S + src) * H;
    float* dst = h + (size_t)bs * H;
    for (int i = threadIdx.x; i < H; i += 256) dst[i] = sp[i] * f;
}

__global__ __launch_bounds__(256) void outmask_k(const float* __restrict__ h,
    const int* __restrict__ cvalid, float* __restrict__ out)
{
    int bs = blockIdx.x;
    float f = cvalid[bs] ? 1.f : 0.f;
    for (int i = threadIdx.x; i < H; i += 256)
        out[(size_t)bs * H + i] = h[(size_t)bs * H + i] * f;
}

__global__ __launch_bounds__(256) void iota_k(int* __restrict__ pos)
{
    int idx = blockIdx.x * 256 + threadIdx.x;
    if (idx < BS) pos[idx] = idx & (S - 1);
}

// ================= Host-side drivers =================
static void run_block_f32(int layer,
    const float* ln1, const float* wq, const float* wk, const float* wv,
    const float* wo, const float* ln2, const float* wg, const float* wu, const float* wd,
    float* h, float* hn, float* q, float* k, float* v, float* o, float* f1,
    const int* valid, const int* pos, hipStream_t stream)
{
    size_t LHH = (size_t)layer * H * H;
    size_t LHF = (size_t)layer * H * FF;
    rmsnorm_k<<<BS, 256, 0, stream>>>(h, ln1 + (size_t)layer * H, hn);
    gemm_k<<<dim3(16, 64), 256, 0, stream>>>(hn, wq + LHH, nullptr, q, BS, H, H, H, H, H, 0);
    gemm_k<<<dim3(16, 64), 256, 0, stream>>>(hn, wk + LHH, nullptr, k, BS, H, H, H, H, H, 0);
    gemm_k<<<dim3(16, 64), 256, 0, stream>>>(hn, wv + LHH, nullptr, v, BS, H, H, H, H, H, 0);
    rope_k<<<8192, 256, 0, stream>>>(q, pos);
    rope_k<<<8192, 256, 0, stream>>>(k, pos);
    fattn_k<<<dim3(S / 64, NH, B), 256, 0, stream>>>(q, k, v, o, valid);
    gemm_k<<<dim3(16, 64), 256, 0, stream>>>(o, wo + LHH, nullptr, h, BS, H, H, H, H, H, F_RESID);
    rmsnorm_k<<<BS, 256, 0, stream>>>(h, ln2 + (size_t)layer * H, hn);
    gemm_k<<<dim3(64, 64), 256, 0, stream>>>(hn, wg + LHF, nullptr, f1, BS, FF, H, H, FF, FF, F_SILU);
    gemm_k<<<dim3(64, 64), 256, 0, stream>>>(hn, wu + LHF, nullptr, f1, BS, FF, H, H, FF, FF, F_MULIN);
    gemm_k<<<dim3(16, 64), 256, 0, stream>>>(f1, wd + (size_t)layer * FF * H, nullptr, h, BS, H, FF, FF, H, H, F_RESID);
}

// MFMA block, templated on split planes / products (shallow <2,3>, mid <1,1>)
template<int NP, int NPROD>
static void run_block_mf(int layer,
    const float* ln1, const float* wq, const float* wk, const float* wv,
    const float* wo, const float* ln2, const float* wg, const float* wu, const float* wd,
    float* h, float* qkv,
    _Float16* hnsp, _Float16* osp, _Float16* wsp, _Float16* wsp2, _Float16* f1sp,
    _Float16* qsp, _Float16* ksp, _Float16* vtp,
    const float* ct, const float* st,
    const int* valid, const int* pos, hipStream_t stream)
{
    const size_t PH = (size_t)H * H;        // wo plane
    const size_t P3H = 3 * PH;              // fused qkv plane
    const size_t PGU = (size_t)H * FF;      // wg/wu/wd plane
    const size_t PA = BSH;                  // activation plane
    const size_t PF = BSF;                  // f1 plane
    size_t LHH = (size_t)layer * H * H;
    size_t LHF = (size_t)layer * H * FF;

    rmsnorm_split_k<<<BS, 256, 0, stream>>>(h, ln1 + (size_t)layer * H, hnsp, PA, NP);
    splitwt3_k<<<dim3(H / 32, H / 32, 3), 256, 0, stream>>>(
        wq + LHH, wk + LHH, wv + LHH, wsp, P3H, NP);
    gemm_mf_k<NP, NPROD><<<dim3(3 * H / 128, BS / 128), 256, 0, stream>>>(
        hnsp, wsp, nullptr, qkv, nullptr, BS, 3 * H, H, 3 * H, PA, P3H, 1);
    rope2_split_k<<<16384, 256, 0, stream>>>(qkv, 3 * H, pos, ct, st, qsp, ksp, PA, NP);
    splitvt_k<<<dim3(S / 32, H / 32, B), 256, 0, stream>>>(qkv, 3 * H, 2 * H, vtp, PA, NP);
    mfattn_k<NP, NPROD><<<dim3(S / 64, NH, B), 256, 0, stream>>>(qsp, ksp, vtp, osp, valid);
    splitwt_k<<<dim3(H / 32, H / 32), 256, 0, stream>>>(wo + LHH, wsp, H, H, H, PH, NP);
    gemm_mf_k<NP, NPROD><<<dim3(H / 128, BS / 128), 256, 0, stream>>>(
        osp, wsp, nullptr, h, h, BS, H, H, H, PA, PH, 1);
    rmsnorm_split_k<<<BS, 256, 0, stream>>>(h, ln2 + (size_t)layer * H, hnsp, PA, NP);
    splitwt2_k<<<dim3(FF / 32, H / 32, 2), 256, 0, stream>>>(
        wg + LHF, wu + LHF, wsp, wsp2, PGU, NP);
    gateup_k<NP, NPROD><<<dim3(FF / 128, BS / 128), 256, 0, stream>>>(
        hnsp, wsp, wsp2, f1sp, BS, FF, H, PA, PGU, PF, NP, 2);
    splitwt_k<<<dim3(H / 32, FF / 32), 256, 0, stream>>>(wd + (size_t)layer * FF * H, wsp, FF, H, H, PGU, NP);
    gemm_mf_k<NP, NPROD><<<dim3(H / 128, BS / 128), 256, 0, stream>>>(
        f1sp, wsp, nullptr, h, h, BS, H, FF, H, PF, PGU, 1);
}

extern "C" void kernel_launch(void* const* d_in, const int* in_sizes, int n_in,
                              void* d_out, int out_size, void* d_ws, size_t ws_size,
                              hipStream_t stream)
{
    const int*   ids    = (const int*)d_in[0];
    const int*   amask  = (const int*)d_in[1];
    const float* embed  = (const float*)d_in[2];
    const float* ln1    = (const float*)d_in[3];
    const float* wq     = (const float*)d_in[4];
    const float* wk     = (const float*)d_in[5];
    const float* wv     = (const float*)d_in[6];
    const float* wo     = (const float*)d_in[7];
    const float* ln2    = (const float*)d_in[8];
    const float* wg     = (const float*)d_in[9];
    const float* wu     = (const float*)d_in[10];
    const float* wd     = (const float*)d_in[11];
    const float* head_w = (const float*)d_in[12];
    const float* head_b = (const float*)d_in[13];
    const float* cemb   = (const float*)d_in[14];
    const float* gumbel = (const float*)d_in[15];
    float* out = (float*)d_out;

    const size_t MB = 1ull << 20;
    const size_t NEED = 274 * MB;

    if (ws_size >= NEED) {
        // ===== MFMA path =====
        char* base = (char*)d_ws;
        float* h   = (float*)base;                  // 16MB
        float* qkv = (float*)(base + 16 * MB);      // 48MB [BS][3072]
        _Float16* zb   = (_Float16*)(base + 64 * MB);   // 16MB [BS][CV]
        _Float16* hnsp = (_Float16*)(base + 80 * MB);   // 2 planes x 8MB
        _Float16* osp  = (_Float16*)(base + 104 * MB);
        _Float16* wsp  = (_Float16*)(base + 128 * MB);  // <=24MB weight planes
        _Float16* wsp2 = (_Float16*)(base + 152 * MB);
        _Float16* f1sp = (_Float16*)(base + 176 * MB);  // 2 planes x 32MB
        _Float16* qsp  = (_Float16*)(base + 176 * MB);  // alias f1sp (disjoint lifetime)
        _Float16* ksp  = (_Float16*)(base + 200 * MB);
        _Float16* vtp  = (_Float16*)(base + 224 * MB);
        int* meta   = (int*)(base + 272 * MB);
        int* chosen = meta;
        int* order  = meta + BS;
        int* cpos   = meta + 2 * BS;
        int* cvalid = meta + 3 * BS;
        int* counts = meta + 4 * BS;
        int* pos_sh = meta + 5 * BS;
        float* partial = (float*)(meta + 6 * BS);
        float* ct = (float*)(base + 273 * MB);          // S*32 floats (128KB)
        float* st = ct + S * 32;                        // S*32 floats
        float* logits = qkv;          // qkv dead after shallow blocks
        float* esoft  = qkv;
        float* ceab   = qkv + BSH;

        embed_k<<<BS, 256, 0, stream>>>(ids, embed, h);
        iota_k<<<16, 256, 0, stream>>>(pos_sh);
        trigtab_k<<<S * 32 / 256, 256, 0, stream>>>(ct, st);

        for (int L = 0; L < 2; ++L)
            run_block_mf<2, 3>(L, ln1, wq, wk, wv, wo, ln2, wg, wu, wd,
                               h, qkv, hnsp, osp, wsp, wsp2, f1sp,
                               qsp, ksp, vtp, ct, st, amask, pos_sh, stream);

        // ---- head logits: fp16 2-plane, ALL 4 products (argmax-critical) ----
        splita_swz_k<<<BS, 256, 0, stream>>>(h, hnsp, BSH, 2);
        splitwt_k<<<dim3(CV / 32, H / 32), 256, 0, stream>>>(head_w, wsp, H, CV, CV1, (size_t)CV * H, 2);
        gemm_mf_k<2, 4><<<dim3(CV / 128, BS / 128), 256, 0, stream>>>(
            hnsp, wsp, head_b, logits, nullptr, BS, CV, H, CV1, BSH, (size_t)CV * H, 1);
        headcol_k<<<BS, 64, 0, stream>>>(h, head_w, head_b, logits);
        discretize_h_k<<<BS, 256, 0, stream>>>(logits, gumbel, zb, chosen);

        // ---- e_soft = z @ cemb (fp16 1-plane) ----
        splitwt_k<<<dim3(H / 32, CV / 32), 256, 0, stream>>>(cemb, wsp, CV, H, H, (size_t)H * CV, 1);
        gemm_mf_k<1, 1><<<dim3(H / 128, BS / 128), 256, 0, stream>>>(
            zb, wsp, nullptr, esoft, nullptr, BS, H, CV, H, (size_t)BS * CV, (size_t)H * CV, 0);

        cea_k<<<BS, 256, 0, stream>>>(esoft, cemb, chosen, amask, ceab, partial);
        loss_k<<<1, 256, 0, stream>>>(partial, out + BSH);
        pack_k<<<B, 1024, 0, stream>>>(chosen, amask, order, cpos, cvalid, counts);
        gather_k<<<BS, 256, 0, stream>>>(ceab, order, cvalid, h);

        for (int L = 2; L < 4; ++L)
            run_block_mf<1, 1>(L, ln1, wq, wk, wv, wo, ln2, wg, wu, wd,
                               h, qkv, hnsp, osp, wsp, wsp2, f1sp,
                               qsp, ksp, vtp, ct, st, cvalid, cpos, stream);

        outmask_k<<<BS, 256, 0, stream>>>(h, cvalid, out);
    } else {
        // ===== fallback: fp32 path =====
        float* wsf = (float*)d_ws;
        float* h   = wsf;
        float* hn  = wsf + BSH;
        float* q   = wsf + 2 * BSH;
        float* k   = wsf + 3 * BSH;
        float* v   = wsf + 4 * BSH;
        float* o   = wsf + 5 * BSH;
        float* f1  = wsf + 6 * BSH;
        float* zbuf  = q;
        float* esoft = v;
        float* ceab  = o;
        int* meta   = (int*)(wsf + 6 * BSH + BSF);
        int* chosen = meta;
        int* order  = meta + BS;
        int* cpos   = meta + 2 * BS;
        int* cvalid = meta + 3 * BS;
        int* counts = meta + 4 * BS;
        int* pos_sh = meta + 5 * BS;
        float* partial = (float*)(meta + 6 * BS);

        embed_k<<<BS, 256, 0, stream>>>(ids, embed, h);
        iota_k<<<16, 256, 0, stream>>>(pos_sh);
        for (int L = 0; L < 2; ++L)
            run_block_f32(L, ln1, wq, wk, wv, wo, ln2, wg, wu, wd,
                          h, hn, q, k, v, o, f1, amask, pos_sh, stream);
        gemm_k<<<dim3(33, 64), 256, 0, stream>>>(h, head_w, head_b, f1, BS, CV1, H, H, CV1, CV1, F_BIAS);
        discretize_k<<<BS, 256, 0, stream>>>(f1, gumbel, zbuf, chosen);
        gemm_k<<<dim3(16, 64), 256, 0, stream>>>(zbuf, cemb, nullptr, esoft, BS, H, CV, CV, H, H, 0);
        cea_k<<<BS, 256, 0, stream>>>(esoft, cemb, chosen, amask, ceab, partial);
        loss_k<<<1, 256, 0, stream>>>(partial, out + BSH);
        pack_k<<<B, 1024, 0, stream>>>(chosen, amask, order, cpos, cvalid, counts);
        gather_k<<<BS, 256, 0, stream>>>(ceab, order, cvalid, h);
        for (int L = 2; L < 4; ++L)
            run_block_f32(L, ln1, wq, wk, wv, wo, ln2, wg, wu, wd,
                          h, hn, q, k, v, o, f1, cvalid, cpos, stream);
        outmask_k<<<BS, 256, 0, stream>>>(h, cvalid, out);
    }
}